// Round 9
// baseline (483.263 us; speedup 1.0000x reference)
//
#include <hip/hip_runtime.h>
#include <math.h>

// NoiScaleModule: B=128, C=32(seq), S=512(d_model), EMB=256, NHEAD=8, DFF=2048
// All tensors FLOAT32. Outputs concat flat: res[2M], down_x[2M], fa[2M], up[2M]
//
// R11: XCD-chunked blockIdx swizzle (T1). 557->520.
// R15: schedule fusion (22->16 dispatches): wa+wm, uber-prep, qkv-dual,
//      relu_bln fused via LDS. 520->470.
// R16: BK=32 revert everywhere (R13 proved BK=64 neutral): halves GEMM LDS.
//      qkv_dual 48KB->24KB (3->6 blocks/CU, occupancy 17%->~33%) — LDS was
//      capping the one kernel that dominates (56us).

#define NROW 4096
#define NOUT 2097152

typedef __attribute__((ext_vector_type(8))) short short8;
typedef __attribute__((ext_vector_type(4))) float floatx4;

__device__ __forceinline__ unsigned short f2bf(float f) {
    union { float f; unsigned u; } v; v.f = f;
    return (unsigned short)((v.u + 0x7fffu + ((v.u >> 16) & 1u)) >> 16);
}
__device__ __forceinline__ float bf2f(unsigned short h) {
    union { unsigned u; float f; } v; v.u = ((unsigned)h) << 16;
    return v.f;
}

__device__ __forceinline__ void gload16(const unsigned short* g, unsigned short* l) {
    __builtin_amdgcn_global_load_lds((const __attribute__((address_space(1))) void*)g,
                                     (__attribute__((address_space(3))) void*)l, 16, 0, 0);
}

// XCD-chunked swizzle (T1): consecutive dispatch ids round-robin XCDs; remap so
// each XCD gets a contiguous chunk of logical tiles (requires nwg % 8 == 0).
__device__ __forceinline__ void xcd_swizzle(int& bx, int& by, int& bz) {
    const int gx = gridDim.x, gy = gridDim.y;
    const int nwg = gx * gy * gridDim.z;
    int b = (bz * gy + by) * gx + bx;
    const int chunk = nwg >> 3;
    const int lb = (b & 7) * chunk + (b >> 3);
    bx = lb % gx;
    const int rem = lb / gx;
    by = rem % gy;
    bz = rem / gy;
}

// ---------------- prep: cos/sin tables tab[n][k], n<512, k<256 ----------------
__global__ __launch_bounds__(256) void tab_kernel(float* __restrict__ tabC, float* __restrict__ tabS)
{
    int n = blockIdx.x, k = threadIdx.x;
    int m = (n * k) & 511;
    float th = (float)m * 0.01227184630308513f;  // 2*pi/512
    float s, c; sincosf(th, &s, &c);
    tabC[n * 256 + k] = c;
    tabS[n * 256 + k] = s;
}

// Wa (z=0) and Wm (z=1) in one dispatch; both emit bf16 hi/lo directly.
__global__ __launch_bounds__(256) void wawm_kernel(const float* __restrict__ l1_re, const float* __restrict__ l1_im,
                                                   const float* __restrict__ lc_w,
                                                   const float* __restrict__ tabC, const float* __restrict__ tabS,
                                                   unsigned short* __restrict__ WaH, unsigned short* __restrict__ WaL,
                                                   unsigned short* __restrict__ WmH, unsigned short* __restrict__ WmL)
{
    __shared__ float lw[512];
    const float inv = 0.04419417382415922f;  // 1/sqrt(512)
    if (blockIdx.z == 0) {
        int n  = blockIdx.x;
        int ep = blockIdx.y * 256 + threadIdx.x;
        float acc = 0.f;
        if (ep < 256) {
            for (int k = 0; k < 128; ++k) {
                float c = tabC[n * 256 + k], s = tabS[n * 256 + k];
                acc += c * l1_re[k * 256 + ep] + s * l1_im[k * 256 + ep];
            }
        } else {
            int e = ep - 256;
            for (int k = 0; k < 128; ++k) {
                float c = tabC[n * 256 + k], s = tabS[n * 256 + k];
                acc += c * l1_im[k * 256 + e] - s * l1_re[k * 256 + e];
            }
        }
        float v = acc * inv;
        size_t idx = (size_t)ep * 512 + n;
        unsigned short h = f2bf(v);
        WaH[idx] = h;
        WaL[idx] = f2bf(v - bf2f(h));
    } else {
        int s  = blockIdx.x;
        int kk = blockIdx.y * 256 + threadIdx.x;
        for (int i = threadIdx.x; i < 512; i += 256) lw[i] = lc_w[s * 512 + i];
        __syncthreads();
        float acc = 0.f;
        if (kk < 256) {
            int k = kk;
            for (int n = 0; n < 512; ++n) acc += tabC[n * 256 + k] * lw[n];
            acc *= (k == 0) ? inv : 2.f * inv;
        } else {
            int k = kk - 256;
            if (k == 0) acc = 0.f;
            else {
                for (int n = 0; n < 512; ++n) acc += tabS[n * 256 + k] * lw[n];
                acc *= -2.f * inv;
            }
        }
        size_t idx = (size_t)s * 512 + kk;
        unsigned short h = f2bf(acc);
        WmH[idx] = h;
        WmL[idx] = f2bf(acc - bf2f(h));
    }
}

// ---------------- uber elementwise prep: wcvt(+rinLo) | xsplit | lbpack ----------------
__global__ __launch_bounds__(256) void uber_prep_kernel(
    const float* s0, const float* s1, const float* s2, const float* s3, const float* s4,
    const float* s5, const float* s6, const float* s7, const float* s8, const float* s9,
    unsigned short* __restrict__ o, unsigned short* __restrict__ rinLo,
    const float* __restrict__ x, unsigned short* __restrict__ xhi,
    unsigned short* __restrict__ xlo, float* __restrict__ xcp,
    const float* __restrict__ lbre, const float* __restrict__ lbim, float* __restrict__ lbout)
{
    const int bid = blockIdx.x, tid = threadIdx.x;
    if (bid < 26624) {
        int i = bid * 256 + tid;  // exactly covers 6815744
        const float* s; int off;
        if (i < 3145728) {
            if (i < 1048576) { if (i < 786432) { s = s0; off = 0; } else { s = s1; off = 786432; } }
            else             { if (i < 2097152) { s = s2; off = 1048576; } else { s = s3; off = 2097152; } }
        } else {
            if (i < 5242880) {
                if (i < 3932160) { s = s4; off = 3145728; }
                else if (i < 4194304) { s = s5; off = 3932160; }
                else { s = s6; off = 4194304; }
            } else {
                if (i < 6291456) { s = s7; off = 5242880; }
                else if (i < 6553600) { s = s8; off = 6291456; }
                else { s = s9; off = 6553600; }
            }
        }
        float v = s[i - off];
        unsigned short h = f2bf(v);
        o[i] = h;
        if (i >= 3145728 && i < 3932160) rinLo[i - 3145728] = f2bf(v - bf2f(h));
    } else if (bid < 34816) {
        int i = (bid - 26624) * 256 + tid;  // exactly covers 2097152
        float v = x[i];
        unsigned short h = f2bf(v);
        xhi[i] = h;
        xlo[i] = f2bf(v - bf2f(h));
        xcp[i] = v;
    } else {
        int i = (bid - 34816) * 256 + tid;
        if (i < 512) lbout[i] = (i < 256) ? lbre[i] : lbim[i - 256];
    }
}

// ---------------- MFMA GEMM: C[M,N] = A[M,K](bf16) @ W[N,K](bf16)^T + bias ----------------
// TM x TN tile, BK=32, 4 waves (2x2), single LDS buffer, XCD-swizzled tiles.
template <int TM, int TN, int ACT, int WF, int WBF>
__global__ __launch_bounds__(256) void gemm_mfma(
    const unsigned short* __restrict__ A, const unsigned short* __restrict__ W,
    const float* __restrict__ bias, float* __restrict__ Cf,
    unsigned short* __restrict__ Cb, int N, int K)
{
    constexpr int MI = TM / 32, NJ = TN / 32;
    constexpr int ARW = TM / 4, BRW = TN / 4;
    __shared__ unsigned short As[TM * 32];
    __shared__ unsigned short Bs[TN * 32];
    const int tid = threadIdx.x;
    const int wave = tid >> 6, lane = tid & 63;
    int bx = blockIdx.x, by = blockIdx.y, bz = blockIdx.z;
    xcd_swizzle(bx, by, bz);
    const int m0 = by * TM, n0 = bx * TN;
    const int sr = lane >> 2, sc = (lane & 3) * 8;
    const unsigned short* aS = A + (size_t)(m0 + wave * ARW + sr) * K + sc;
    const unsigned short* wS = W + (size_t)(n0 + wave * BRW + sr) * K + sc;
    const int wm = (wave >> 1) * (TM / 2), wn = (wave & 1) * (TN / 2);
    const int fr = lane & 15, fko = (lane >> 4) * 8;

    floatx4 acc[MI][NJ];
#pragma unroll
    for (int i = 0; i < MI; ++i)
#pragma unroll
        for (int j = 0; j < NJ; ++j) acc[i][j] = (floatx4){0.f, 0.f, 0.f, 0.f};

    for (int k0 = 0; k0 < K; k0 += 32) {
#pragma unroll
        for (int c = 0; c < ARW / 16; ++c)
            gload16(aS + (size_t)(16 * c) * K + k0, &As[(wave * ARW + 16 * c) * 32]);
#pragma unroll
        for (int c = 0; c < BRW / 16; ++c)
            gload16(wS + (size_t)(16 * c) * K + k0, &Bs[(wave * BRW + 16 * c) * 32]);
        __syncthreads();
        short8 af[MI], bfr[NJ];
#pragma unroll
        for (int i = 0; i < MI; ++i) af[i] = *(const short8*)&As[(wm + i * 16 + fr) * 32 + fko];
#pragma unroll
        for (int j = 0; j < NJ; ++j) bfr[j] = *(const short8*)&Bs[(wn + j * 16 + fr) * 32 + fko];
#pragma unroll
        for (int i = 0; i < MI; ++i)
#pragma unroll
            for (int j = 0; j < NJ; ++j)
                acc[i][j] = __builtin_amdgcn_mfma_f32_16x16x32_bf16(af[i], bfr[j], acc[i][j], 0, 0, 0);
        __syncthreads();
    }
    const int r0 = m0 + wm + (lane >> 4) * 4;
#pragma unroll
    for (int i = 0; i < MI; ++i) {
#pragma unroll
        for (int j = 0; j < NJ; ++j) {
            int n = n0 + wn + j * 16 + fr;
            float bv = bias[n];
#pragma unroll
            for (int r = 0; r < 4; ++r) {
                int m = r0 + i * 16 + r;
                size_t idx = (size_t)m * N + n;
                float v = acc[i][j][r] + bv;
                if (ACT) v = fmaxf(v, 0.f);
                if (WF) Cf[idx] = v;
                if (WBF) Cb[idx] = f2bf(v);
            }
        }
    }
}

// ---------------- dual-branch GEMM: z=0 -> (A0,W0,b0)->out0, z=1 -> (A1,W1,b1)->out1 ------
template <int TM, int TN, int ACT, int WBF>
__global__ __launch_bounds__(256) void gemm_dual(
    const unsigned short* __restrict__ A0, const unsigned short* __restrict__ A1,
    const unsigned short* __restrict__ W0, const unsigned short* __restrict__ W1,
    const float* __restrict__ b0, const float* __restrict__ b1,
    float* __restrict__ C0, float* __restrict__ C1,
    unsigned short* __restrict__ D0, unsigned short* __restrict__ D1, int N, int K)
{
    constexpr int MI = TM / 32, NJ = TN / 32;
    constexpr int ARW = TM / 4, BRW = TN / 4;
    __shared__ unsigned short As[TM * 32];
    __shared__ unsigned short Bs[TN * 32];
    const int tid = threadIdx.x;
    const int wave = tid >> 6, lane = tid & 63;
    int bx = blockIdx.x, by = blockIdx.y, bz = blockIdx.z;
    xcd_swizzle(bx, by, bz);
    const int m0 = by * TM, n0 = bx * TN;
    const int z = bz;
    const unsigned short* A = z ? A1 : A0;
    const unsigned short* W = z ? W1 : W0;
    const float* bias = z ? b1 : b0;
    float* Cf = z ? C1 : C0;
    unsigned short* Cb = z ? D1 : D0;
    const int sr = lane >> 2, sc = (lane & 3) * 8;
    const unsigned short* aS = A + (size_t)(m0 + wave * ARW + sr) * K + sc;
    const unsigned short* wS = W + (size_t)(n0 + wave * BRW + sr) * K + sc;
    const int wm = (wave >> 1) * (TM / 2), wn = (wave & 1) * (TN / 2);
    const int fr = lane & 15, fko = (lane >> 4) * 8;

    floatx4 acc[MI][NJ];
#pragma unroll
    for (int i = 0; i < MI; ++i)
#pragma unroll
        for (int j = 0; j < NJ; ++j) acc[i][j] = (floatx4){0.f, 0.f, 0.f, 0.f};

    for (int k0 = 0; k0 < K; k0 += 32) {
#pragma unroll
        for (int c = 0; c < ARW / 16; ++c)
            gload16(aS + (size_t)(16 * c) * K + k0, &As[(wave * ARW + 16 * c) * 32]);
#pragma unroll
        for (int c = 0; c < BRW / 16; ++c)
            gload16(wS + (size_t)(16 * c) * K + k0, &Bs[(wave * BRW + 16 * c) * 32]);
        __syncthreads();
        short8 af[MI], bfr[NJ];
#pragma unroll
        for (int i = 0; i < MI; ++i) af[i] = *(const short8*)&As[(wm + i * 16 + fr) * 32 + fko];
#pragma unroll
        for (int j = 0; j < NJ; ++j) bfr[j] = *(const short8*)&Bs[(wn + j * 16 + fr) * 32 + fko];
#pragma unroll
        for (int i = 0; i < MI; ++i)
#pragma unroll
            for (int j = 0; j < NJ; ++j)
                acc[i][j] = __builtin_amdgcn_mfma_f32_16x16x32_bf16(af[i], bfr[j], acc[i][j], 0, 0, 0);
        __syncthreads();
    }
    const int r0 = m0 + wm + (lane >> 4) * 4;
#pragma unroll
    for (int i = 0; i < MI; ++i) {
#pragma unroll
        for (int j = 0; j < NJ; ++j) {
            int n = n0 + wn + j * 16 + fr;
            float bv = bias[n];
#pragma unroll
            for (int r = 0; r < 4; ++r) {
                int m = r0 + i * 16 + r;
                size_t idx = (size_t)m * N + n;
                float v = acc[i][j][r] + bv;
                if (ACT) v = fmaxf(v, 0.f);
                if (WBF) Cb[idx] = f2bf(v);
                else     Cf[idx] = v;
            }
        }
    }
}

// ---------------- fused hi/lo 3-product MFMA GEMM (BK=32, single-buffer) ----------------
template <int TM, int TN, int ACT, int WCOPY, int WHILO>
__global__ __launch_bounds__(256) void gemm_mfma3(
    const unsigned short* __restrict__ Ah, const unsigned short* __restrict__ Al,
    const unsigned short* __restrict__ Wh, const unsigned short* __restrict__ Wl,
    const float* __restrict__ bias, float* __restrict__ Cf, float* __restrict__ Ccopy,
    unsigned short* __restrict__ Hh, unsigned short* __restrict__ Hl, int N, int K)
{
    constexpr int MI = TM / 32, NJ = TN / 32;
    constexpr int ARW = TM / 4, BRW = TN / 4;
    __shared__ unsigned short Ash[TM * 32];
    __shared__ unsigned short Asl[TM * 32];
    __shared__ unsigned short Bsh[TN * 32];
    __shared__ unsigned short Bsl[TN * 32];
    const int tid = threadIdx.x;
    const int wave = tid >> 6, lane = tid & 63;
    int bx = blockIdx.x, by = blockIdx.y, bz = blockIdx.z;
    xcd_swizzle(bx, by, bz);
    const int m0 = by * TM, n0 = bx * TN;
    const int sr = lane >> 2, sc = (lane & 3) * 8;
    const size_t aoff = (size_t)(m0 + wave * ARW + sr) * K + sc;
    const size_t woff = (size_t)(n0 + wave * BRW + sr) * K + sc;
    const int wm = (wave >> 1) * (TM / 2), wn = (wave & 1) * (TN / 2);
    const int fr = lane & 15, fko = (lane >> 4) * 8;

    floatx4 acc[MI][NJ];
#pragma unroll
    for (int i = 0; i < MI; ++i)
#pragma unroll
        for (int j = 0; j < NJ; ++j) acc[i][j] = (floatx4){0.f, 0.f, 0.f, 0.f};

    for (int k0 = 0; k0 < K; k0 += 32) {
#pragma unroll
        for (int c = 0; c < ARW / 16; ++c) {
            gload16(Ah + aoff + (size_t)(16 * c) * K + k0, &Ash[(wave * ARW + 16 * c) * 32]);
            gload16(Al + aoff + (size_t)(16 * c) * K + k0, &Asl[(wave * ARW + 16 * c) * 32]);
        }
#pragma unroll
        for (int c = 0; c < BRW / 16; ++c) {
            gload16(Wh + woff + (size_t)(16 * c) * K + k0, &Bsh[(wave * BRW + 16 * c) * 32]);
            gload16(Wl + woff + (size_t)(16 * c) * K + k0, &Bsl[(wave * BRW + 16 * c) * 32]);
        }
        __syncthreads();
        short8 ah[MI], al[MI], bh[NJ], bl[NJ];
#pragma unroll
        for (int i = 0; i < MI; ++i) {
            ah[i] = *(const short8*)&Ash[(wm + i * 16 + fr) * 32 + fko];
            al[i] = *(const short8*)&Asl[(wm + i * 16 + fr) * 32 + fko];
        }
#pragma unroll
        for (int j = 0; j < NJ; ++j) {
            bh[j] = *(const short8*)&Bsh[(wn + j * 16 + fr) * 32 + fko];
            bl[j] = *(const short8*)&Bsl[(wn + j * 16 + fr) * 32 + fko];
        }
#pragma unroll
        for (int i = 0; i < MI; ++i)
#pragma unroll
            for (int j = 0; j < NJ; ++j) {
                acc[i][j] = __builtin_amdgcn_mfma_f32_16x16x32_bf16(al[i], bh[j], acc[i][j], 0, 0, 0);
                acc[i][j] = __builtin_amdgcn_mfma_f32_16x16x32_bf16(ah[i], bl[j], acc[i][j], 0, 0, 0);
                acc[i][j] = __builtin_amdgcn_mfma_f32_16x16x32_bf16(ah[i], bh[j], acc[i][j], 0, 0, 0);
            }
        __syncthreads();
    }
    const int r0 = m0 + wm + (lane >> 4) * 4;
#pragma unroll
    for (int i = 0; i < MI; ++i) {
#pragma unroll
        for (int j = 0; j < NJ; ++j) {
            int n = n0 + wn + j * 16 + fr;
            float bv = bias[n];
#pragma unroll
            for (int r = 0; r < 4; ++r) {
                int m = r0 + i * 16 + r;
                size_t idx = (size_t)m * N + n;
                float v = acc[i][j][r] + bv;
                if (ACT) v = fmaxf(v, 0.f);
                Cf[idx] = v;
                if (WCOPY) Ccopy[idx] = v;
                if (WHILO) {
                    unsigned short h = f2bf(v);
                    Hh[idx] = h;
                    Hl[idx] = f2bf(v - bf2f(h));
                }
            }
        }
    }
}

// ---------------- merged qkv GEMM: z=0 -> r-branch 3-product (f32 out),
//                  z=1 -> t-branch single-product (bf16 out). BK=32. --------------------
template <int TM, int TN>
__global__ __launch_bounds__(256) void gemm_qkv_dual(
    const unsigned short* __restrict__ Ah0, const unsigned short* __restrict__ Al0,
    const unsigned short* __restrict__ Wh0, const unsigned short* __restrict__ Wl0,
    const float* __restrict__ b0, float* __restrict__ C0,
    const unsigned short* __restrict__ A1, const unsigned short* __restrict__ W1,
    const float* __restrict__ b1, unsigned short* __restrict__ C1,
    int N, int K)
{
    constexpr int MI = TM / 32, NJ = TN / 32;
    constexpr int ARW = TM / 4, BRW = TN / 4;
    __shared__ unsigned short Ash[TM * 32];
    __shared__ unsigned short Asl[TM * 32];
    __shared__ unsigned short Bsh[TN * 32];
    __shared__ unsigned short Bsl[TN * 32];
    const int tid = threadIdx.x;
    const int wave = tid >> 6, lane = tid & 63;
    int bx = blockIdx.x, by = blockIdx.y, bz = blockIdx.z;
    xcd_swizzle(bx, by, bz);
    const int m0 = by * TM, n0 = bx * TN;
    const int sr = lane >> 2, sc = (lane & 3) * 8;
    const size_t aoff = (size_t)(m0 + wave * ARW + sr) * K + sc;
    const size_t woff = (size_t)(n0 + wave * BRW + sr) * K + sc;
    const int wm = (wave >> 1) * (TM / 2), wn = (wave & 1) * (TN / 2);
    const int fr = lane & 15, fko = (lane >> 4) * 8;

    floatx4 acc[MI][NJ];
#pragma unroll
    for (int i = 0; i < MI; ++i)
#pragma unroll
        for (int j = 0; j < NJ; ++j) acc[i][j] = (floatx4){0.f, 0.f, 0.f, 0.f};

    const int r0 = m0 + wm + (lane >> 4) * 4;

    if (bz == 0) {
        // ---- r-branch: 3-product hi/lo ----
        for (int k0 = 0; k0 < K; k0 += 32) {
#pragma unroll
            for (int c = 0; c < ARW / 16; ++c) {
                gload16(Ah0 + aoff + (size_t)(16 * c) * K + k0, &Ash[(wave * ARW + 16 * c) * 32]);
                gload16(Al0 + aoff + (size_t)(16 * c) * K + k0, &Asl[(wave * ARW + 16 * c) * 32]);
            }
#pragma unroll
            for (int c = 0; c < BRW / 16; ++c) {
                gload16(Wh0 + woff + (size_t)(16 * c) * K + k0, &Bsh[(wave * BRW + 16 * c) * 32]);
                gload16(Wl0 + woff + (size_t)(16 * c) * K + k0, &Bsl[(wave * BRW + 16 * c) * 32]);
            }
            __syncthreads();
            short8 ah[MI], al[MI], bh[NJ], bl[NJ];
#pragma unroll
            for (int i = 0; i < MI; ++i) {
                ah[i] = *(const short8*)&Ash[(wm + i * 16 + fr) * 32 + fko];
                al[i] = *(const short8*)&Asl[(wm + i * 16 + fr) * 32 + fko];
            }
#pragma unroll
            for (int j = 0; j < NJ; ++j) {
                bh[j] = *(const short8*)&Bsh[(wn + j * 16 + fr) * 32 + fko];
                bl[j] = *(const short8*)&Bsl[(wn + j * 16 + fr) * 32 + fko];
            }
#pragma unroll
            for (int i = 0; i < MI; ++i)
#pragma unroll
                for (int j = 0; j < NJ; ++j) {
                    acc[i][j] = __builtin_amdgcn_mfma_f32_16x16x32_bf16(al[i], bh[j], acc[i][j], 0, 0, 0);
                    acc[i][j] = __builtin_amdgcn_mfma_f32_16x16x32_bf16(ah[i], bl[j], acc[i][j], 0, 0, 0);
                    acc[i][j] = __builtin_amdgcn_mfma_f32_16x16x32_bf16(ah[i], bh[j], acc[i][j], 0, 0, 0);
                }
            __syncthreads();
        }
#pragma unroll
        for (int i = 0; i < MI; ++i)
#pragma unroll
            for (int j = 0; j < NJ; ++j) {
                int n = n0 + wn + j * 16 + fr;
                float bv = b0[n];
#pragma unroll
                for (int r = 0; r < 4; ++r) {
                    int m = r0 + i * 16 + r;
                    C0[(size_t)m * N + n] = acc[i][j][r] + bv;
                }
            }
    } else {
        // ---- t-branch: single product ----
        for (int k0 = 0; k0 < K; k0 += 32) {
#pragma unroll
            for (int c = 0; c < ARW / 16; ++c)
                gload16(A1 + aoff + (size_t)(16 * c) * K + k0, &Ash[(wave * ARW + 16 * c) * 32]);
#pragma unroll
            for (int c = 0; c < BRW / 16; ++c)
                gload16(W1 + woff + (size_t)(16 * c) * K + k0, &Bsh[(wave * BRW + 16 * c) * 32]);
            __syncthreads();
            short8 af[MI], bfr[NJ];
#pragma unroll
            for (int i = 0; i < MI; ++i) af[i] = *(const short8*)&Ash[(wm + i * 16 + fr) * 32 + fko];
#pragma unroll
            for (int j = 0; j < NJ; ++j) bfr[j] = *(const short8*)&Bsh[(wn + j * 16 + fr) * 32 + fko];
#pragma unroll
            for (int i = 0; i < MI; ++i)
#pragma unroll
                for (int j = 0; j < NJ; ++j)
                    acc[i][j] = __builtin_amdgcn_mfma_f32_16x16x32_bf16(af[i], bfr[j], acc[i][j], 0, 0, 0);
            __syncthreads();
        }
#pragma unroll
        for (int i = 0; i < MI; ++i)
#pragma unroll
            for (int j = 0; j < NJ; ++j) {
                int n = n0 + wn + j * 16 + fr;
                float bv = b1[n];
#pragma unroll
                for (int r = 0; r < 4; ++r) {
                    int m = r0 + i * 16 + r;
                    C1[(size_t)m * N + n] = f2bf(acc[i][j][r] + bv);
                }
            }
    }
}

// ---------------- TEL attention, DUAL: blocks [0,1024) = r (f32 qkv), [1024,2048) = t ----
__global__ __launch_bounds__(256) void attn_dual_kernel(const float* __restrict__ qkvF,
                                                        const unsigned short* __restrict__ qkvB,
                                                        unsigned short* __restrict__ outR,
                                                        unsigned short* __restrict__ outT)
{
    const int isT = blockIdx.x >> 10;
    const int bid = blockIdx.x & 1023;
    const int b = bid >> 3;
    const int h = bid & 7;
    __shared__ float qs[32][65], ks[32][65], vs[32][65];
    __shared__ float ps[32][33];
    const int tid = threadIdx.x;
    if (isT) {
        for (int i = tid; i < 2048; i += 256) {
            int s = i >> 6, d = i & 63;
            size_t base = ((size_t)(b * 32 + s)) * 1536 + h * 64 + d;
            qs[s][d] = bf2f(qkvB[base]);
            ks[s][d] = bf2f(qkvB[base + 512]);
            vs[s][d] = bf2f(qkvB[base + 1024]);
        }
    } else {
        for (int i = tid; i < 2048; i += 256) {
            int s = i >> 6, d = i & 63;
            size_t base = ((size_t)(b * 32 + s)) * 1536 + h * 64 + d;
            qs[s][d] = qkvF[base];
            ks[s][d] = qkvF[base + 512];
            vs[s][d] = qkvF[base + 1024];
        }
    }
    __syncthreads();
    for (int i = tid; i < 1024; i += 256) {
        int si = i >> 5, sj = i & 31;
        float acc = 0.f;
#pragma unroll 8
        for (int d = 0; d < 64; ++d) acc += qs[si][d] * ks[sj][d];
        ps[si][sj] = acc * 0.125f;
    }
    __syncthreads();
    if (tid < 32) {
        float mx = -1e30f;
        for (int j = 0; j < 32; ++j) mx = fmaxf(mx, ps[tid][j]);
        float sum = 0.f;
        for (int j = 0; j < 32; ++j) { float e = __expf(ps[tid][j] - mx); ps[tid][j] = e; sum += e; }
        float inv = 1.f / sum;
        for (int j = 0; j < 32; ++j) ps[tid][j] *= inv;
    }
    __syncthreads();
    unsigned short* ob = isT ? outT : outR;
    for (int i = tid; i < 2048; i += 256) {
        int s = i >> 6, d = i & 63;
        float acc = 0.f;
#pragma unroll 8
        for (int k = 0; k < 32; ++k) acc += ps[s][k] * vs[k][d];
        ob[((size_t)(b * 32 + s)) * 512 + h * 64 + d] = f2bf(acc);
    }
}

// ---------------- complex self-attention: LDS-resident, grid (128 batch, 2 half) ----------
__global__ __launch_bounds__(512) void cattn2_kernel(const float* __restrict__ LL,
                                                     unsigned short* __restrict__ outHi,
                                                     unsigned short* __restrict__ outLo)
{
    extern __shared__ float Xs[];
    __shared__ float Pr[16][33], Pi[16][33];
    const int b = blockIdx.x, half = blockIdx.y;
    const int tid = threadIdx.x;
    const float* base = LL + (size_t)b * 16384;
    for (int i = tid; i < 16384; i += 512) {
        int c = i >> 9, e = i & 511;
        Xs[e * 32 + ((c ^ e) & 31)] = base[i];
    }
    __syncthreads();
    {
        const int li = tid >> 5;                 // 0..15
        const int ci = half * 16 + li;
        const int ck = tid & 31;
        float ar = 0.f, ai = 0.f;
#pragma unroll 4
        for (int er = 0; er < 256; ++er) {
            const int sw = er & 31;
            float yr = Xs[er * 32 + ((ck ^ sw) & 31)];
            float yi = Xs[(er + 256) * 32 + ((ck ^ sw) & 31)];
            float xr = Xs[er * 32 + ((ci ^ sw) & 31)];
            float xi = Xs[(er + 256) * 32 + ((ci ^ sw) & 31)];
            ar += xr * yr - xi * yi;
            ai += xr * yi + xi * yr;
        }
        Pr[li][ck] = ar * 0.0625f;
        Pi[li][ck] = ai * 0.0625f;
    }
    __syncthreads();
    if (tid < 32) {
        int r = tid & 15;
        float (*P)[33] = (tid < 16) ? Pr : Pi;
        float mx = -1e30f;
        for (int j = 0; j < 32; ++j) mx = fmaxf(mx, P[r][j]);
        float s = 0.f;
        for (int j = 0; j < 32; ++j) { float e = __expf(P[r][j] - mx); P[r][j] = e; s += e; }
        float inv = 1.f / s;
        for (int j = 0; j < 32; ++j) P[r][j] *= inv;
    }
    __syncthreads();
    const int er = tid & 255;
    const int th = tid >> 8;                     // 0 or 1: t in [th*8, th*8+8)
    const int sw = er & 31;
    float accr[8], acci[8];
#pragma unroll
    for (int t = 0; t < 8; ++t) { accr[t] = 0.f; acci[t] = 0.f; }
    for (int k = 0; k < 32; ++k) {
        float yr = Xs[er * 32 + ((k ^ sw) & 31)];
        float yi = Xs[(er + 256) * 32 + ((k ^ sw) & 31)];
#pragma unroll
        for (int t = 0; t < 8; ++t) {
            float pr = Pr[th * 8 + t][k], pi = Pi[th * 8 + t][k];
            accr[t] += pr * yr - pi * yi;
            acci[t] += pr * yi + pi * yr;
        }
    }
#pragma unroll
    for (int t = 0; t < 8; ++t) {
        int c = half * 16 + th * 8 + t;
        float vr = Xs[er * 32 + ((c ^ sw) & 31)] + accr[t];
        float vi = Xs[(er + 256) * 32 + ((c ^ sw) & 31)] + acci[t];
        size_t ir = (size_t)b * 16384 + (size_t)c * 512 + er;
        unsigned short hr = f2bf(vr), hi2 = f2bf(vi);
        outHi[ir] = hr;        outLo[ir] = f2bf(vr - bf2f(hr));
        outHi[ir + 256] = hi2; outLo[ir + 256] = f2bf(vi - bf2f(hi2));
    }
}

// ---------------- DUAL add+LN (512), f32 resid, out bf16 hi/lo; rows>=4096 = branch 1 ----
__global__ __launch_bounds__(256) void add_ln_d1(
    const float* __restrict__ r0, const float* __restrict__ y0,
    const float* __restrict__ w0, const float* __restrict__ b0,
    unsigned short* __restrict__ h0, unsigned short* __restrict__ l0,
    const float* __restrict__ r1, const float* __restrict__ y1,
    const float* __restrict__ w1, const float* __restrict__ b1,
    unsigned short* __restrict__ h1, unsigned short* __restrict__ l1)
{
    const int row = blockIdx.x;
    const int br = row >> 12;
    const int rl = row & 4095;
    const float* resid = br ? r1 : r0;
    const float* y     = br ? y1 : y0;
    const float* w     = br ? w1 : w0;
    const float* bb    = br ? b1 : b0;
    unsigned short* oh = br ? h1 : h0;
    unsigned short* ol = br ? l1 : l0;
    const int tid = threadIdx.x;
    const size_t base = (size_t)rl * 512;
    float v0 = resid[base + tid] + y[base + tid];
    float v1 = resid[base + 256 + tid] + y[base + 256 + tid];
    float s = v0 + v1, q = v0 * v0 + v1 * v1;
    for (int off = 32; off; off >>= 1) { s += __shfl_down(s, off); q += __shfl_down(q, off); }
    __shared__ float sw[4], qw[4], ms, is;
    int wid = tid >> 6, lane = tid & 63;
    if (lane == 0) { sw[wid] = s; qw[wid] = q; }
    __syncthreads();
    if (tid == 0) {
        float S = sw[0] + sw[1] + sw[2] + sw[3];
        float Q = qw[0] + qw[1] + qw[2] + qw[3];
        float m = S * (1.f / 512.f);
        ms = m;
        is = rsqrtf(Q * (1.f / 512.f) - m * m + 1e-5f);
    }
    __syncthreads();
    float m = ms, inv = is;
    float o0 = (v0 - m) * inv * w[tid] + bb[tid];
    float o1 = (v1 - m) * inv * w[256 + tid] + bb[256 + tid];
    unsigned short e0 = f2bf(o0), e1 = f2bf(o1);
    oh[base + tid] = e0;       ol[base + tid] = f2bf(o0 - bf2f(e0));
    oh[base + 256 + tid] = e1; ol[base + 256 + tid] = f2bf(o1 - bf2f(e1));
}

// ---------------- DUAL add+LN (512), bf16 hi/lo resid, out f32 --------------------------
__global__ __launch_bounds__(256) void add_ln_d2(
    const unsigned short* __restrict__ rh0, const unsigned short* __restrict__ rl0,
    const float* __restrict__ y0, const float* __restrict__ w0, const float* __restrict__ b0,
    float* __restrict__ o0p,
    const unsigned short* __restrict__ rh1, const unsigned short* __restrict__ rl1,
    const float* __restrict__ y1, const float* __restrict__ w1, const float* __restrict__ b1,
    float* __restrict__ o1p)
{
    const int row = blockIdx.x;
    const int br = row >> 12;
    const int rl = row & 4095;
    const unsigned short* rh = br ? rh1 : rh0;
    const unsigned short* rlo = br ? rl1 : rl0;
    const float* y  = br ? y1 : y0;
    const float* w  = br ? w1 : w0;
    const float* bb = br ? b1 : b0;
    float* op = br ? o1p : o0p;
    const int tid = threadIdx.x;
    const size_t base = (size_t)rl * 512;
    float v0 = bf2f(rh[base + tid]) + bf2f(rlo[base + tid]) + y[base + tid];
    float v1 = bf2f(rh[base + 256 + tid]) + bf2f(rlo[base + 256 + tid]) + y[base + 256 + tid];
    float s = v0 + v1, q = v0 * v0 + v1 * v1;
    for (int off = 32; off; off >>= 1) { s += __shfl_down(s, off); q += __shfl_down(q, off); }
    __shared__ float sw[4], qw[4], ms, is;
    int wid = tid >> 6, lane = tid & 63;
    if (lane == 0) { sw[wid] = s; qw[wid] = q; }
    __syncthreads();
    if (tid == 0) {
        float S = sw[0] + sw[1] + sw[2] + sw[3];
        float Q = qw[0] + qw[1] + qw[2] + qw[3];
        float m = S * (1.f / 512.f);
        ms = m;
        is = rsqrtf(Q * (1.f / 512.f) - m * m + 1e-5f);
    }
    __syncthreads();
    float m = ms, inv = is;
    op[base + tid]       = (v0 - m) * inv * w[tid] + bb[tid];
    op[base + 256 + tid] = (v1 - m) * inv * w[256 + tid] + bb[256 + tid];
}

// ---------------- fused relu+batchLN x2: rf = LN(relu(x2R)) kept in LDS,
//                  res = LN(relu(x2T)) + rf. One block per batch, 1024 threads. ----------
__global__ __launch_bounds__(1024) void relu_bln_fused(
    const float* __restrict__ xR, const float* __restrict__ w2, const float* __restrict__ b2,
    const float* __restrict__ xT, const float* __restrict__ w1, const float* __restrict__ b1,
    float* __restrict__ out)
{
    __shared__ float rfs[16384];
    __shared__ float sw_[16], qw_[16], ms_, is_;
    const int bb = blockIdx.x, tid = threadIdx.x;
    const int wid = tid >> 6, lane = tid & 63;
    // pass 1: rf = LN(relu(xR[bb]))
    const float* xr = xR + (size_t)bb * 16384;
    float s = 0.f, q = 0.f;
    for (int i = tid; i < 16384; i += 1024) { float v = fmaxf(xr[i], 0.f); s += v; q += v * v; }
    for (int off = 32; off; off >>= 1) { s += __shfl_down(s, off); q += __shfl_down(q, off); }
    if (lane == 0) { sw_[wid] = s; qw_[wid] = q; }
    __syncthreads();
    if (tid == 0) {
        float S = 0.f, Q = 0.f;
        for (int i = 0; i < 16; ++i) { S += sw_[i]; Q += qw_[i]; }
        float m = S * (1.f / 16384.f);
        ms_ = m;
        is_ = rsqrtf(Q * (1.f / 16384.f) - m * m + 1e-5f);
    }
    __syncthreads();
    float m = ms_, inv = is_;
    for (int i = tid; i < 16384; i += 1024) {
        float v = fmaxf(xr[i], 0.f);
        rfs[i] = (v - m) * inv * w2[i] + b2[i];
    }
    // pass 2: res = LN(relu(xT[bb])) + rf
    const float* xt = xT + (size_t)bb * 16384;
    s = 0.f; q = 0.f;
    for (int i = tid; i < 16384; i += 1024) { float v = fmaxf(xt[i], 0.f); s += v; q += v * v; }
    for (int off = 32; off; off >>= 1) { s += __shfl_down(s, off); q += __shfl_down(q, off); }
    if (lane == 0) { sw_[wid] = s; qw_[wid] = q; }
    __syncthreads();
    if (tid == 0) {
        float S = 0.f, Q = 0.f;
        for (int i = 0; i < 16; ++i) { S += sw_[i]; Q += qw_[i]; }
        float m2 = S * (1.f / 16384.f);
        ms_ = m2;
        is_ = rsqrtf(Q * (1.f / 16384.f) - m2 * m2 + 1e-5f);
    }
    __syncthreads();
    m = ms_; inv = is_;
    float* op = out + (size_t)bb * 16384;
    for (int i = tid; i < 16384; i += 1024) {
        float v = fmaxf(xt[i], 0.f);
        op[i] = (v - m) * inv * w1[i] + b1[i] + rfs[i];
    }
}

extern "C" void kernel_launch(void* const* d_in, const int* in_sizes, int n_in,
                              void* d_out, int out_size, void* d_ws, size_t ws_size,
                              hipStream_t stream)
{
    (void)in_sizes; (void)n_in; (void)out_size; (void)ws_size;
    const float* x        = (const float*)d_in[0];
    const float* t_in_w   = (const float*)d_in[1];
    const float* t_in_b   = (const float*)d_in[2];
    const float* t_out_w  = (const float*)d_in[3];
    const float* t_out_b  = (const float*)d_in[4];
    const float* t_ln1_w  = (const float*)d_in[5];
    const float* t_ln1_b  = (const float*)d_in[6];
    const float* t_lin1_w = (const float*)d_in[7];
    const float* t_lin1_b = (const float*)d_in[8];
    const float* t_lin2_w = (const float*)d_in[9];
    const float* t_lin2_b = (const float*)d_in[10];
    const float* t_ln2_w  = (const float*)d_in[11];
    const float* t_ln2_b  = (const float*)d_in[12];
    const float* r_in_w   = (const float*)d_in[13];
    const float* r_in_b   = (const float*)d_in[14];
    const float* r_out_w  = (const float*)d_in[15];
    const float* r_out_b  = (const float*)d_in[16];
    const float* r_ln1_w  = (const float*)d_in[17];
    const float* r_ln1_b  = (const float*)d_in[18];
    const float* r_lin1_w = (const float*)d_in[19];
    const float* r_lin1_b = (const float*)d_in[20];
    const float* r_lin2_w = (const float*)d_in[21];
    const float* r_lin2_b = (const float*)d_in[22];
    const float* r_ln2_w  = (const float*)d_in[23];
    const float* r_ln2_b  = (const float*)d_in[24];
    const float* lc_w     = (const float*)d_in[25];
    const float* lc_b     = (const float*)d_in[26];
    const float* up1_w    = (const float*)d_in[27];
    const float* up1_b    = (const float*)d_in[28];
    const float* up2_w    = (const float*)d_in[29];
    const float* up2_b    = (const float*)d_in[30];
    const float* n1_w     = (const float*)d_in[31];
    const float* n1_b     = (const float*)d_in[32];
    const float* n2_w     = (const float*)d_in[33];
    const float* n2_b     = (const float*)d_in[34];
    const float* l1_re    = (const float*)d_in[35];
    const float* l1_im    = (const float*)d_in[36];
    const float* lb1_re   = (const float*)d_in[39];
    const float* lb1_im   = (const float*)d_in[40];

    float* outp = (float*)d_out;

    // ---- workspace map (float offsets; total 21,774,336 f = 87.1 MB) ----
    float* WS   = (float*)d_ws;
    float* LL   = WS;                                        // 2M f (also fa f32, later y_r)
    float* FA   = WS;
    float* yR   = WS;
    float* QR   = WS + 2097152;                              // 6.29M f
    float* tabC = QR;                                        // 131072
    float* tabS = QR + 131072;
    unsigned short* WaHu = (unsigned short*)(QR + 786432);
    unsigned short* WaLu = (unsigned short*)(QR + 917504);
    unsigned short* WmHu = (unsigned short*)(QR + 1048576);
    unsigned short* WmLu = (unsigned short*)(QR + 1179648);
    float* qkvR = QR;                                        // 6.29M f (r-qkv f32)
    unsigned short* x1rH = (unsigned short*)(WS + 2097152);
    unsigned short* x1rL = (unsigned short*)(WS + 3145728);
    unsigned short* x1tH = (unsigned short*)(WS + 4194304);
    unsigned short* x1tL = (unsigned short*)(WS + 5242880);
    float* yT   = WS + 6291456;                              // 2M f
    unsigned short* qkvT = (unsigned short*)(WS + 8388608);  // 6.29M ushort
    unsigned short* f1R  = (unsigned short*)(WS + 8388608);  // 8.39M ushort
    float* x2R  = WS + 8388608;                              // 2M f
    float* x2T  = WS + 10485760;                             // 2M f
    unsigned short* xHi = (unsigned short*)(WS + 11534336);
    unsigned short* xLo = (unsigned short*)(WS + 12582912);
    unsigned short* aoR = (unsigned short*)(WS + 11534336);
    unsigned short* aoT = (unsigned short*)(WS + 12582912);
    unsigned short* f1T = (unsigned short*)(WS + 12582912);  // 8.39M ushort
    unsigned short* LLH = (unsigned short*)(WS + 13631488);
    unsigned short* LLL = (unsigned short*)(WS + 14680064);
    unsigned short* u1b = (unsigned short*)(WS + 13631488);
    float* oR   = WS + 13631488;                             // 2M f
    float* oT   = WS + 15728640;                             // 2M f
    unsigned short* faHi = (unsigned short*)(WS + 15728640);
    unsigned short* faLo = (unsigned short*)(WS + 16777216);
    unsigned short* rinLoU = (unsigned short*)(WS + 17825792);  // 786432 ushort
    float* LB   = WS + 18219008;                             // 512 f
    unsigned short* WB = (unsigned short*)(WS + 18366464);

    unsigned short* w_tin  = WB + 0;        // 1536x512
    unsigned short* w_tout = WB + 786432;   // 512x512
    unsigned short* w_tl1  = WB + 1048576;  // 2048x512
    unsigned short* w_tl2  = WB + 2097152;  // 512x2048
    unsigned short* w_rin  = WB + 3145728;  // 1536x512
    unsigned short* w_rout = WB + 3932160;  // 512x512
    unsigned short* w_rl1  = WB + 4194304;  // 2048x512
    unsigned short* w_rl2  = WB + 5242880;  // 512x2048
    unsigned short* w_up1  = WB + 6291456;  // 512x512
    unsigned short* w_up2  = WB + 6553600;  // 512x512

    dim3 blk(256);

    // ---- prep (3 dispatches) ----
    tab_kernel<<<dim3(512), blk, 0, stream>>>(tabC, tabS);
    wawm_kernel<<<dim3(512, 2, 2), blk, 0, stream>>>(l1_re, l1_im, lc_w, tabC, tabS,
                                                     WaHu, WaLu, WmHu, WmLu);
    uber_prep_kernel<<<dim3(34818), blk, 0, stream>>>(t_in_w, t_out_w, t_lin1_w, t_lin2_w,
                                                      r_in_w, r_out_w, r_lin1_w, r_lin2_w,
                                                      up1_w, up2_w, WB, rinLoU,
                                                      x, xHi, xLo, outp + NOUT,
                                                      lb1_re, lb1_im, LB);

    // ---- freq branch ----
    gemm_mfma3<64,64,1,0,0><<<dim3(8, 64), blk, 0, stream>>>(xHi, xLo, WaHu, WaLu, LB,
                                                             LL, nullptr, nullptr, nullptr, 512, 512);
    cattn2_kernel<<<dim3(128, 2), dim3(512), 65536, stream>>>(LL, LLH, LLL);         // LL hi/lo
    gemm_mfma3<64,64,0,1,1><<<dim3(8, 64), blk, 0, stream>>>(LLH, LLL, WmHu, WmLu, lc_b,
                                                             FA, outp + 2 * NOUT, faHi, faLo, 512, 512);

    // ---- upsample (fa_hi) ----
    gemm_mfma<64,64,0,0,1><<<dim3(8, 64), blk, 0, stream>>>(faHi, w_up1, up1_b, nullptr, u1b, 512, 512);
    gemm_mfma<64,64,0,1,0><<<dim3(8, 64), blk, 0, stream>>>(u1b, w_up2, up2_b, outp + 3 * NOUT, nullptr, 512, 512);

    // ---- qkv for both TELs (merged) ----
    gemm_qkv_dual<64,128><<<dim3(12, 64, 2), blk, 0, stream>>>(faHi, faLo, w_rin, rinLoU, r_in_b, qkvR,
                                                               xHi, w_tin, t_in_b, qkvT, 1536, 512);

    // ---- dual TEL pipeline (z / row selects branch: 0=r, 1=t) ----
    attn_dual_kernel<<<dim3(2048), blk, 0, stream>>>(qkvR, qkvT, aoR, aoT);
    gemm_dual<64,64,0,0><<<dim3(8, 64, 2), blk, 0, stream>>>(aoR, aoT, w_rout, w_tout,
                                                             r_out_b, t_out_b, oR, oT,
                                                             nullptr, nullptr, 512, 512);
    add_ln_d1<<<dim3(8192), blk, 0, stream>>>(FA, oR, r_ln1_w, r_ln1_b, x1rH, x1rL,
                                              x,  oT, t_ln1_w, t_ln1_b, x1tH, x1tL);
    gemm_dual<64,128,1,1><<<dim3(16, 64, 2), blk, 0, stream>>>(x1rH, x1tH, w_rl1, w_tl1,
                                                               r_lin1_b, t_lin1_b, nullptr, nullptr,
                                                               f1R, f1T, 2048, 512);
    gemm_dual<64,64,0,0><<<dim3(8, 64, 2), blk, 0, stream>>>(f1R, f1T, w_rl2, w_tl2,
                                                             r_lin2_b, t_lin2_b, yR, yT,
                                                             nullptr, nullptr, 512, 2048);
    add_ln_d2<<<dim3(8192), blk, 0, stream>>>(x1rH, x1rL, yR, r_ln2_w, r_ln2_b, x2R,
                                              x1tH, x1tL, yT, t_ln2_w, t_ln2_b, x2T);
    relu_bln_fused<<<dim3(128), dim3(1024), 0, stream>>>(x2R, n2_w, n2_b, x2T, n1_w, n1_b, outp);
}

// Round 12
// 481.105 us; speedup vs baseline: 1.0045x; 1.0045x over previous
//
#include <hip/hip_runtime.h>
#include <math.h>

// NoiScaleModule: B=128, C=32(seq), S=512(d_model), EMB=256, NHEAD=8, DFF=2048
// All tensors FLOAT32. Outputs concat flat: res[2M], down_x[2M], fa[2M], up[2M]
//
// R15: schedule fusion (22->16 dispatches). 520->470.
// R17: up1->qkv(z=2), up2->out(z=2) — FAILED: u1b aliased oR (out_tri z=0 wrote
//      oR while z=2 read u1b).
// R18: u1b->WS+6291456 — FAILED: that lies INSIDE qkvR [2.1M,8.4M), written by
//      the SAME qkv_tri dispatch (z=0). Same-dispatch write collision.
// R19: u1b -> outp[0..1M floats) (res slot: dead until relu_bln_fused; harness
//      memsets output; nothing reads/writes res before the last kernel).
//      Full liveness of [qkv_tri,out_tri] window enumerated — no WS hole exists.

#define NROW 4096
#define NOUT 2097152

typedef __attribute__((ext_vector_type(8))) short short8;
typedef __attribute__((ext_vector_type(4))) float floatx4;

__device__ __forceinline__ unsigned short f2bf(float f) {
    union { float f; unsigned u; } v; v.f = f;
    return (unsigned short)((v.u + 0x7fffu + ((v.u >> 16) & 1u)) >> 16);
}
__device__ __forceinline__ float bf2f(unsigned short h) {
    union { unsigned u; float f; } v; v.u = ((unsigned)h) << 16;
    return v.f;
}

__device__ __forceinline__ void gload16(const unsigned short* g, unsigned short* l) {
    __builtin_amdgcn_global_load_lds((const __attribute__((address_space(1))) void*)g,
                                     (__attribute__((address_space(3))) void*)l, 16, 0, 0);
}

// XCD-chunked swizzle (T1): requires nwg % 8 == 0.
__device__ __forceinline__ void xcd_swizzle(int& bx, int& by, int& bz) {
    const int gx = gridDim.x, gy = gridDim.y;
    const int nwg = gx * gy * gridDim.z;
    int b = (bz * gy + by) * gx + bx;
    const int chunk = nwg >> 3;
    const int lb = (b & 7) * chunk + (b >> 3);
    bx = lb % gx;
    const int rem = lb / gx;
    by = rem % gy;
    bz = rem / gy;
}

// ---------------- prep: cos/sin tables tab[n][k], n<512, k<256 ----------------
__global__ __launch_bounds__(256) void tab_kernel(float* __restrict__ tabC, float* __restrict__ tabS)
{
    int n = blockIdx.x, k = threadIdx.x;
    int m = (n * k) & 511;
    float th = (float)m * 0.01227184630308513f;  // 2*pi/512
    float s, c; sincosf(th, &s, &c);
    tabC[n * 256 + k] = c;
    tabS[n * 256 + k] = s;
}

// Wa (z=0) and Wm (z=1) in one dispatch; both emit bf16 hi/lo directly.
__global__ __launch_bounds__(256) void wawm_kernel(const float* __restrict__ l1_re, const float* __restrict__ l1_im,
                                                   const float* __restrict__ lc_w,
                                                   const float* __restrict__ tabC, const float* __restrict__ tabS,
                                                   unsigned short* __restrict__ WaH, unsigned short* __restrict__ WaL,
                                                   unsigned short* __restrict__ WmH, unsigned short* __restrict__ WmL)
{
    __shared__ float lw[512];
    const float inv = 0.04419417382415922f;  // 1/sqrt(512)
    if (blockIdx.z == 0) {
        int n  = blockIdx.x;
        int ep = blockIdx.y * 256 + threadIdx.x;
        float acc = 0.f;
        if (ep < 256) {
            for (int k = 0; k < 128; ++k) {
                float c = tabC[n * 256 + k], s = tabS[n * 256 + k];
                acc += c * l1_re[k * 256 + ep] + s * l1_im[k * 256 + ep];
            }
        } else {
            int e = ep - 256;
            for (int k = 0; k < 128; ++k) {
                float c = tabC[n * 256 + k], s = tabS[n * 256 + k];
                acc += c * l1_im[k * 256 + e] - s * l1_re[k * 256 + e];
            }
        }
        float v = acc * inv;
        size_t idx = (size_t)ep * 512 + n;
        unsigned short h = f2bf(v);
        WaH[idx] = h;
        WaL[idx] = f2bf(v - bf2f(h));
    } else {
        int s  = blockIdx.x;
        int kk = blockIdx.y * 256 + threadIdx.x;
        for (int i = threadIdx.x; i < 512; i += 256) lw[i] = lc_w[s * 512 + i];
        __syncthreads();
        float acc = 0.f;
        if (kk < 256) {
            int k = kk;
            for (int n = 0; n < 512; ++n) acc += tabC[n * 256 + k] * lw[n];
            acc *= (k == 0) ? inv : 2.f * inv;
        } else {
            int k = kk - 256;
            if (k == 0) acc = 0.f;
            else {
                for (int n = 0; n < 512; ++n) acc += tabS[n * 256 + k] * lw[n];
                acc *= -2.f * inv;
            }
        }
        size_t idx = (size_t)s * 512 + kk;
        unsigned short h = f2bf(acc);
        WmH[idx] = h;
        WmL[idx] = f2bf(acc - bf2f(h));
    }
}

// ---------------- uber elementwise prep: wcvt(+rinLo) | xsplit | lbpack ----------------
__global__ __launch_bounds__(256) void uber_prep_kernel(
    const float* s0, const float* s1, const float* s2, const float* s3, const float* s4,
    const float* s5, const float* s6, const float* s7, const float* s8, const float* s9,
    unsigned short* __restrict__ o, unsigned short* __restrict__ rinLo,
    const float* __restrict__ x, unsigned short* __restrict__ xhi,
    unsigned short* __restrict__ xlo, float* __restrict__ xcp,
    const float* __restrict__ lbre, const float* __restrict__ lbim, float* __restrict__ lbout)
{
    const int bid = blockIdx.x, tid = threadIdx.x;
    if (bid < 26624) {
        int i = bid * 256 + tid;  // exactly covers 6815744
        const float* s; int off;
        if (i < 3145728) {
            if (i < 1048576) { if (i < 786432) { s = s0; off = 0; } else { s = s1; off = 786432; } }
            else             { if (i < 2097152) { s = s2; off = 1048576; } else { s = s3; off = 2097152; } }
        } else {
            if (i < 5242880) {
                if (i < 3932160) { s = s4; off = 3145728; }
                else if (i < 4194304) { s = s5; off = 3932160; }
                else { s = s6; off = 4194304; }
            } else {
                if (i < 6291456) { s = s7; off = 5242880; }
                else if (i < 6553600) { s = s8; off = 6291456; }
                else { s = s9; off = 6553600; }
            }
        }
        float v = s[i - off];
        unsigned short h = f2bf(v);
        o[i] = h;
        if (i >= 3145728 && i < 3932160) rinLo[i - 3145728] = f2bf(v - bf2f(h));
    } else if (bid < 34816) {
        int i = (bid - 26624) * 256 + tid;  // exactly covers 2097152
        float v = x[i];
        unsigned short h = f2bf(v);
        xhi[i] = h;
        xlo[i] = f2bf(v - bf2f(h));
        xcp[i] = v;
    } else {
        int i = (bid - 34816) * 256 + tid;
        if (i < 512) lbout[i] = (i < 256) ? lbre[i] : lbim[i - 256];
    }
}

// ---------------- dual-branch GEMM (BK=64): z=0/1 select. For lin1/lin2. ----------------
template <int TM, int TN, int ACT, int WBF>
__global__ __launch_bounds__(256) void gemm_dual(
    const unsigned short* __restrict__ A0, const unsigned short* __restrict__ A1,
    const unsigned short* __restrict__ W0, const unsigned short* __restrict__ W1,
    const float* __restrict__ b0, const float* __restrict__ b1,
    float* __restrict__ C0, float* __restrict__ C1,
    unsigned short* __restrict__ D0, unsigned short* __restrict__ D1, int N, int K)
{
    constexpr int MI = TM / 32, NJ = TN / 32;
    constexpr int ARW = TM / 4, BRW = TN / 4;
    __shared__ unsigned short As[2][TM * 32];
    __shared__ unsigned short Bs[2][TN * 32];
    const int tid = threadIdx.x;
    const int wave = tid >> 6, lane = tid & 63;
    int bx = blockIdx.x, by = blockIdx.y, bz = blockIdx.z;
    xcd_swizzle(bx, by, bz);
    const int m0 = by * TM, n0 = bx * TN;
    const int z = bz;
    const unsigned short* A = z ? A1 : A0;
    const unsigned short* W = z ? W1 : W0;
    const float* bias = z ? b1 : b0;
    float* Cf = z ? C1 : C0;
    unsigned short* Cb = z ? D1 : D0;
    const int sr = lane >> 2, sc = (lane & 3) * 8;
    const unsigned short* aS = A + (size_t)(m0 + wave * ARW + sr) * K + sc;
    const unsigned short* wS = W + (size_t)(n0 + wave * BRW + sr) * K + sc;
    const int wm = (wave >> 1) * (TM / 2), wn = (wave & 1) * (TN / 2);
    const int fr = lane & 15, fko = (lane >> 4) * 8;

    floatx4 acc[MI][NJ];
#pragma unroll
    for (int i = 0; i < MI; ++i)
#pragma unroll
        for (int j = 0; j < NJ; ++j) acc[i][j] = (floatx4){0.f, 0.f, 0.f, 0.f};

    for (int k0 = 0; k0 < K; k0 += 64) {
#pragma unroll
        for (int h = 0; h < 2; ++h) {
#pragma unroll
            for (int c = 0; c < ARW / 16; ++c)
                gload16(aS + (size_t)(16 * c) * K + k0 + 32 * h, &As[h][(wave * ARW + 16 * c) * 32]);
#pragma unroll
            for (int c = 0; c < BRW / 16; ++c)
                gload16(wS + (size_t)(16 * c) * K + k0 + 32 * h, &Bs[h][(wave * BRW + 16 * c) * 32]);
        }
        __syncthreads();
#pragma unroll
        for (int h = 0; h < 2; ++h) {
            short8 af[MI], bfr[NJ];
#pragma unroll
            for (int i = 0; i < MI; ++i) af[i] = *(const short8*)&As[h][(wm + i * 16 + fr) * 32 + fko];
#pragma unroll
            for (int j = 0; j < NJ; ++j) bfr[j] = *(const short8*)&Bs[h][(wn + j * 16 + fr) * 32 + fko];
#pragma unroll
            for (int i = 0; i < MI; ++i)
#pragma unroll
                for (int j = 0; j < NJ; ++j)
                    acc[i][j] = __builtin_amdgcn_mfma_f32_16x16x32_bf16(af[i], bfr[j], acc[i][j], 0, 0, 0);
        }
        __syncthreads();
    }
    const int r0 = m0 + wm + (lane >> 4) * 4;
#pragma unroll
    for (int i = 0; i < MI; ++i) {
#pragma unroll
        for (int j = 0; j < NJ; ++j) {
            int n = n0 + wn + j * 16 + fr;
            float bv = bias[n];
#pragma unroll
            for (int r = 0; r < 4; ++r) {
                int m = r0 + i * 16 + r;
                size_t idx = (size_t)m * N + n;
                float v = acc[i][j][r] + bv;
                if (ACT) v = fmaxf(v, 0.f);
                if (WBF) Cb[idx] = f2bf(v);
                else     Cf[idx] = v;
            }
        }
    }
}

// ---------------- tri-branch single-product GEMM (BK=64, TN=64): out-proj r/t + up2 ------
template <int TM, int TN>
__global__ __launch_bounds__(256) void gemm_out_tri(
    const unsigned short* __restrict__ A0, const unsigned short* __restrict__ W0,
    const float* __restrict__ b0, float* __restrict__ C0,
    const unsigned short* __restrict__ A1, const unsigned short* __restrict__ W1,
    const float* __restrict__ b1, float* __restrict__ C1,
    const unsigned short* __restrict__ A2, const unsigned short* __restrict__ W2,
    const float* __restrict__ b2, float* __restrict__ C2, int N, int K)
{
    constexpr int MI = TM / 32, NJ = TN / 32;
    constexpr int ARW = TM / 4, BRW = TN / 4;
    __shared__ unsigned short As[2][TM * 32];
    __shared__ unsigned short Bs[2][TN * 32];
    const int tid = threadIdx.x;
    const int wave = tid >> 6, lane = tid & 63;
    int bx = blockIdx.x, by = blockIdx.y, bz = blockIdx.z;
    xcd_swizzle(bx, by, bz);
    const int m0 = by * TM, n0 = bx * TN;
    const unsigned short* A = (bz == 0) ? A0 : (bz == 1) ? A1 : A2;
    const unsigned short* W = (bz == 0) ? W0 : (bz == 1) ? W1 : W2;
    const float* bias       = (bz == 0) ? b0 : (bz == 1) ? b1 : b2;
    float* Cf               = (bz == 0) ? C0 : (bz == 1) ? C1 : C2;
    const int sr = lane >> 2, sc = (lane & 3) * 8;
    const unsigned short* aS = A + (size_t)(m0 + wave * ARW + sr) * K + sc;
    const unsigned short* wS = W + (size_t)(n0 + wave * BRW + sr) * K + sc;
    const int wm = (wave >> 1) * (TM / 2), wn = (wave & 1) * (TN / 2);
    const int fr = lane & 15, fko = (lane >> 4) * 8;

    floatx4 acc[MI][NJ];
#pragma unroll
    for (int i = 0; i < MI; ++i)
#pragma unroll
        for (int j = 0; j < NJ; ++j) acc[i][j] = (floatx4){0.f, 0.f, 0.f, 0.f};

    for (int k0 = 0; k0 < K; k0 += 64) {
#pragma unroll
        for (int h = 0; h < 2; ++h) {
#pragma unroll
            for (int c = 0; c < ARW / 16; ++c)
                gload16(aS + (size_t)(16 * c) * K + k0 + 32 * h, &As[h][(wave * ARW + 16 * c) * 32]);
#pragma unroll
            for (int c = 0; c < BRW / 16; ++c)
                gload16(wS + (size_t)(16 * c) * K + k0 + 32 * h, &Bs[h][(wave * BRW + 16 * c) * 32]);
        }
        __syncthreads();
#pragma unroll
        for (int h = 0; h < 2; ++h) {
            short8 af[MI], bfr[NJ];
#pragma unroll
            for (int i = 0; i < MI; ++i) af[i] = *(const short8*)&As[h][(wm + i * 16 + fr) * 32 + fko];
#pragma unroll
            for (int j = 0; j < NJ; ++j) bfr[j] = *(const short8*)&Bs[h][(wn + j * 16 + fr) * 32 + fko];
#pragma unroll
            for (int i = 0; i < MI; ++i)
#pragma unroll
                for (int j = 0; j < NJ; ++j)
                    acc[i][j] = __builtin_amdgcn_mfma_f32_16x16x32_bf16(af[i], bfr[j], acc[i][j], 0, 0, 0);
        }
        __syncthreads();
    }
    const int r0 = m0 + wm + (lane >> 4) * 4;
#pragma unroll
    for (int i = 0; i < MI; ++i) {
#pragma unroll
        for (int j = 0; j < NJ; ++j) {
            int n = n0 + wn + j * 16 + fr;
            float bv = bias[n];
#pragma unroll
            for (int r = 0; r < 4; ++r) {
                int m = r0 + i * 16 + r;
                Cf[(size_t)m * N + n] = acc[i][j][r] + bv;
            }
        }
    }
}

// ---------------- fused hi/lo 3-product MFMA GEMM (BK=64, single-buffer) ----------------
template <int TM, int TN, int ACT, int WCOPY, int WHILO>
__global__ __launch_bounds__(256) void gemm_mfma3(
    const unsigned short* __restrict__ Ah, const unsigned short* __restrict__ Al,
    const unsigned short* __restrict__ Wh, const unsigned short* __restrict__ Wl,
    const float* __restrict__ bias, float* __restrict__ Cf, float* __restrict__ Ccopy,
    unsigned short* __restrict__ Hh, unsigned short* __restrict__ Hl, int N, int K)
{
    constexpr int MI = TM / 32, NJ = TN / 32;
    constexpr int ARW = TM / 4, BRW = TN / 4;
    __shared__ unsigned short Ash[2][TM * 32];
    __shared__ unsigned short Asl[2][TM * 32];
    __shared__ unsigned short Bsh[2][TN * 32];
    __shared__ unsigned short Bsl[2][TN * 32];
    const int tid = threadIdx.x;
    const int wave = tid >> 6, lane = tid & 63;
    int bx = blockIdx.x, by = blockIdx.y, bz = blockIdx.z;
    xcd_swizzle(bx, by, bz);
    const int m0 = by * TM, n0 = bx * TN;
    const int sr = lane >> 2, sc = (lane & 3) * 8;
    const size_t aoff = (size_t)(m0 + wave * ARW + sr) * K + sc;
    const size_t woff = (size_t)(n0 + wave * BRW + sr) * K + sc;
    const int wm = (wave >> 1) * (TM / 2), wn = (wave & 1) * (TN / 2);
    const int fr = lane & 15, fko = (lane >> 4) * 8;

    floatx4 acc[MI][NJ];
#pragma unroll
    for (int i = 0; i < MI; ++i)
#pragma unroll
        for (int j = 0; j < NJ; ++j) acc[i][j] = (floatx4){0.f, 0.f, 0.f, 0.f};

    for (int k0 = 0; k0 < K; k0 += 64) {
#pragma unroll
        for (int h = 0; h < 2; ++h) {
#pragma unroll
            for (int c = 0; c < ARW / 16; ++c) {
                gload16(Ah + aoff + (size_t)(16 * c) * K + k0 + 32 * h, &Ash[h][(wave * ARW + 16 * c) * 32]);
                gload16(Al + aoff + (size_t)(16 * c) * K + k0 + 32 * h, &Asl[h][(wave * ARW + 16 * c) * 32]);
            }
#pragma unroll
            for (int c = 0; c < BRW / 16; ++c) {
                gload16(Wh + woff + (size_t)(16 * c) * K + k0 + 32 * h, &Bsh[h][(wave * BRW + 16 * c) * 32]);
                gload16(Wl + woff + (size_t)(16 * c) * K + k0 + 32 * h, &Bsl[h][(wave * BRW + 16 * c) * 32]);
            }
        }
        __syncthreads();
#pragma unroll
        for (int h = 0; h < 2; ++h) {
            short8 ah[MI], al[MI], bh[NJ], bl[NJ];
#pragma unroll
            for (int i = 0; i < MI; ++i) {
                ah[i] = *(const short8*)&Ash[h][(wm + i * 16 + fr) * 32 + fko];
                al[i] = *(const short8*)&Asl[h][(wm + i * 16 + fr) * 32 + fko];
            }
#pragma unroll
            for (int j = 0; j < NJ; ++j) {
                bh[j] = *(const short8*)&Bsh[h][(wn + j * 16 + fr) * 32 + fko];
                bl[j] = *(const short8*)&Bsl[h][(wn + j * 16 + fr) * 32 + fko];
            }
#pragma unroll
            for (int i = 0; i < MI; ++i)
#pragma unroll
                for (int j = 0; j < NJ; ++j) {
                    acc[i][j] = __builtin_amdgcn_mfma_f32_16x16x32_bf16(al[i], bh[j], acc[i][j], 0, 0, 0);
                    acc[i][j] = __builtin_amdgcn_mfma_f32_16x16x32_bf16(ah[i], bl[j], acc[i][j], 0, 0, 0);
                    acc[i][j] = __builtin_amdgcn_mfma_f32_16x16x32_bf16(ah[i], bh[j], acc[i][j], 0, 0, 0);
                }
        }
        __syncthreads();
    }
    const int r0 = m0 + wm + (lane >> 4) * 4;
#pragma unroll
    for (int i = 0; i < MI; ++i) {
#pragma unroll
        for (int j = 0; j < NJ; ++j) {
            int n = n0 + wn + j * 16 + fr;
            float bv = bias[n];
#pragma unroll
            for (int r = 0; r < 4; ++r) {
                int m = r0 + i * 16 + r;
                size_t idx = (size_t)m * N + n;
                float v = acc[i][j][r] + bv;
                if (ACT) v = fmaxf(v, 0.f);
                Cf[idx] = v;
                if (WCOPY) Ccopy[idx] = v;
                if (WHILO) {
                    unsigned short h = f2bf(v);
                    Hh[idx] = h;
                    Hl[idx] = f2bf(v - bf2f(h));
                }
            }
        }
    }
}

// ---------------- merged qkv+up1 GEMM (BK=64): z=0 r-qkv 3-product (f32, N=1536),
//                  z=1 t-qkv single (bf16, N=1536), z=2 up1 single (bf16, N=512, bx<4) ----
template <int TM, int TN>
__global__ __launch_bounds__(256) void gemm_qkv_tri(
    const unsigned short* __restrict__ Ah0, const unsigned short* __restrict__ Al0,
    const unsigned short* __restrict__ Wh0, const unsigned short* __restrict__ Wl0,
    const float* __restrict__ b0, float* __restrict__ C0,
    const unsigned short* __restrict__ A1, const unsigned short* __restrict__ W1,
    const float* __restrict__ b1, unsigned short* __restrict__ C1,
    const unsigned short* __restrict__ A2, const unsigned short* __restrict__ W2,
    const float* __restrict__ b2, unsigned short* __restrict__ C2,
    int N, int K)
{
    constexpr int MI = TM / 32, NJ = TN / 32;
    constexpr int ARW = TM / 4, BRW = TN / 4;
    __shared__ unsigned short Ash[2][TM * 32];
    __shared__ unsigned short Asl[2][TM * 32];
    __shared__ unsigned short Bsh[2][TN * 32];
    __shared__ unsigned short Bsl[2][TN * 32];
    const int tid = threadIdx.x;
    const int wave = tid >> 6, lane = tid & 63;
    int bx = blockIdx.x, by = blockIdx.y, bz = blockIdx.z;
    xcd_swizzle(bx, by, bz);
    if (bz == 2 && bx >= 512 / TN) return;   // up1: N=512 only
    const int m0 = by * TM, n0 = bx * TN;
    const int nOut = (bz == 2) ? 512 : N;
    const int sr = lane >> 2, sc = (lane & 3) * 8;
    const size_t aoff = (size_t)(m0 + wave * ARW + sr) * K + sc;
    const size_t woff = (size_t)(n0 + wave * BRW + sr) * K + sc;
    const int wm = (wave >> 1) * (TM / 2), wn = (wave & 1) * (TN / 2);
    const int fr = lane & 15, fko = (lane >> 4) * 8;

    floatx4 acc[MI][NJ];
#pragma unroll
    for (int i = 0; i < MI; ++i)
#pragma unroll
        for (int j = 0; j < NJ; ++j) acc[i][j] = (floatx4){0.f, 0.f, 0.f, 0.f};

    const int r0 = m0 + wm + (lane >> 4) * 4;

    if (bz == 0) {
        // ---- r-branch: 3-product hi/lo ----
        for (int k0 = 0; k0 < K; k0 += 64) {
#pragma unroll
            for (int h = 0; h < 2; ++h) {
#pragma unroll
                for (int c = 0; c < ARW / 16; ++c) {
                    gload16(Ah0 + aoff + (size_t)(16 * c) * K + k0 + 32 * h, &Ash[h][(wave * ARW + 16 * c) * 32]);
                    gload16(Al0 + aoff + (size_t)(16 * c) * K + k0 + 32 * h, &Asl[h][(wave * ARW + 16 * c) * 32]);
                }
#pragma unroll
                for (int c = 0; c < BRW / 16; ++c) {
                    gload16(Wh0 + woff + (size_t)(16 * c) * K + k0 + 32 * h, &Bsh[h][(wave * BRW + 16 * c) * 32]);
                    gload16(Wl0 + woff + (size_t)(16 * c) * K + k0 + 32 * h, &Bsl[h][(wave * BRW + 16 * c) * 32]);
                }
            }
            __syncthreads();
#pragma unroll
            for (int h = 0; h < 2; ++h) {
                short8 ah[MI], al[MI], bh[NJ], bl[NJ];
#pragma unroll
                for (int i = 0; i < MI; ++i) {
                    ah[i] = *(const short8*)&Ash[h][(wm + i * 16 + fr) * 32 + fko];
                    al[i] = *(const short8*)&Asl[h][(wm + i * 16 + fr) * 32 + fko];
                }
#pragma unroll
                for (int j = 0; j < NJ; ++j) {
                    bh[j] = *(const short8*)&Bsh[h][(wn + j * 16 + fr) * 32 + fko];
                    bl[j] = *(const short8*)&Bsl[h][(wn + j * 16 + fr) * 32 + fko];
                }
#pragma unroll
                for (int i = 0; i < MI; ++i)
#pragma unroll
                    for (int j = 0; j < NJ; ++j) {
                        acc[i][j] = __builtin_amdgcn_mfma_f32_16x16x32_bf16(al[i], bh[j], acc[i][j], 0, 0, 0);
                        acc[i][j] = __builtin_amdgcn_mfma_f32_16x16x32_bf16(ah[i], bl[j], acc[i][j], 0, 0, 0);
                        acc[i][j] = __builtin_amdgcn_mfma_f32_16x16x32_bf16(ah[i], bh[j], acc[i][j], 0, 0, 0);
                    }
            }
            __syncthreads();
        }
#pragma unroll
        for (int i = 0; i < MI; ++i)
#pragma unroll
            for (int j = 0; j < NJ; ++j) {
                int n = n0 + wn + j * 16 + fr;
                float bv = b0[n];
#pragma unroll
                for (int r = 0; r < 4; ++r) {
                    int m = r0 + i * 16 + r;
                    C0[(size_t)m * N + n] = acc[i][j][r] + bv;
                }
            }
    } else {
        // ---- single-product: z=1 t-qkv (N), z=2 up1 (512) ----
        const unsigned short* A = (bz == 1) ? A1 : A2;
        const unsigned short* W = (bz == 1) ? W1 : W2;
        const float* bias = (bz == 1) ? b1 : b2;
        unsigned short* Cb = (bz == 1) ? C1 : C2;
        for (int k0 = 0; k0 < K; k0 += 64) {
#pragma unroll
            for (int h = 0; h < 2; ++h) {
#pragma unroll
                for (int c = 0; c < ARW / 16; ++c)
                    gload16(A + aoff + (size_t)(16 * c) * K + k0 + 32 * h, &Ash[h][(wave * ARW + 16 * c) * 32]);
#pragma unroll
                for (int c = 0; c < BRW / 16; ++c)
                    gload16(W + woff + (size_t)(16 * c) * K + k0 + 32 * h, &Bsh[h][(wave * BRW + 16 * c) * 32]);
            }
            __syncthreads();
#pragma unroll
            for (int h = 0; h < 2; ++h) {
                short8 af[MI], bfr[NJ];
#pragma unroll
                for (int i = 0; i < MI; ++i) af[i] = *(const short8*)&Ash[h][(wm + i * 16 + fr) * 32 + fko];
#pragma unroll
                for (int j = 0; j < NJ; ++j) bfr[j] = *(const short8*)&Bsh[h][(wn + j * 16 + fr) * 32 + fko];
#pragma unroll
                for (int i = 0; i < MI; ++i)
#pragma unroll
                    for (int j = 0; j < NJ; ++j)
                        acc[i][j] = __builtin_amdgcn_mfma_f32_16x16x32_bf16(af[i], bfr[j], acc[i][j], 0, 0, 0);
            }
            __syncthreads();
        }
#pragma unroll
        for (int i = 0; i < MI; ++i)
#pragma unroll
            for (int j = 0; j < NJ; ++j) {
                int n = n0 + wn + j * 16 + fr;
                float bv = bias[n];
#pragma unroll
                for (int r = 0; r < 4; ++r) {
                    int m = r0 + i * 16 + r;
                    Cb[(size_t)m * nOut + n] = f2bf(acc[i][j][r] + bv);
                }
            }
    }
}

// ---------------- TEL attention, DUAL: blocks [0,1024) = r (f32 qkv), [1024,2048) = t ----
__global__ __launch_bounds__(256) void attn_dual_kernel(const float* __restrict__ qkvF,
                                                        const unsigned short* __restrict__ qkvB,
                                                        unsigned short* __restrict__ outR,
                                                        unsigned short* __restrict__ outT)
{
    const int isT = blockIdx.x >> 10;
    const int bid = blockIdx.x & 1023;
    const int b = bid >> 3;
    const int h = bid & 7;
    __shared__ float qs[32][65], ks[32][65], vs[32][65];
    __shared__ float ps[32][33];
    const int tid = threadIdx.x;
    if (isT) {
        for (int i = tid; i < 2048; i += 256) {
            int s = i >> 6, d = i & 63;
            size_t base = ((size_t)(b * 32 + s)) * 1536 + h * 64 + d;
            qs[s][d] = bf2f(qkvB[base]);
            ks[s][d] = bf2f(qkvB[base + 512]);
            vs[s][d] = bf2f(qkvB[base + 1024]);
        }
    } else {
        for (int i = tid; i < 2048; i += 256) {
            int s = i >> 6, d = i & 63;
            size_t base = ((size_t)(b * 32 + s)) * 1536 + h * 64 + d;
            qs[s][d] = qkvF[base];
            ks[s][d] = qkvF[base + 512];
            vs[s][d] = qkvF[base + 1024];
        }
    }
    __syncthreads();
    for (int i = tid; i < 1024; i += 256) {
        int si = i >> 5, sj = i & 31;
        float acc = 0.f;
#pragma unroll 8
        for (int d = 0; d < 64; ++d) acc += qs[si][d] * ks[sj][d];
        ps[si][sj] = acc * 0.125f;
    }
    __syncthreads();
    if (tid < 32) {
        float mx = -1e30f;
        for (int j = 0; j < 32; ++j) mx = fmaxf(mx, ps[tid][j]);
        float sum = 0.f;
        for (int j = 0; j < 32; ++j) { float e = __expf(ps[tid][j] - mx); ps[tid][j] = e; sum += e; }
        float inv = 1.f / sum;
        for (int j = 0; j < 32; ++j) ps[tid][j] *= inv;
    }
    __syncthreads();
    unsigned short* ob = isT ? outT : outR;
    for (int i = tid; i < 2048; i += 256) {
        int s = i >> 6, d = i & 63;
        float acc = 0.f;
#pragma unroll 8
        for (int k = 0; k < 32; ++k) acc += ps[s][k] * vs[k][d];
        ob[((size_t)(b * 32 + s)) * 512 + h * 64 + d] = f2bf(acc);
    }
}

// ---------------- complex self-attention: LDS-resident, grid (128 batch, 2 half) ----------
__global__ __launch_bounds__(512) void cattn2_kernel(const float* __restrict__ LL,
                                                     unsigned short* __restrict__ outHi,
                                                     unsigned short* __restrict__ outLo)
{
    extern __shared__ float Xs[];
    __shared__ float Pr[16][33], Pi[16][33];
    const int b = blockIdx.x, half = blockIdx.y;
    const int tid = threadIdx.x;
    const float* base = LL + (size_t)b * 16384;
    for (int i = tid; i < 16384; i += 512) {
        int c = i >> 9, e = i & 511;
        Xs[e * 32 + ((c ^ e) & 31)] = base[i];
    }
    __syncthreads();
    {
        const int li = tid >> 5;                 // 0..15
        const int ci = half * 16 + li;
        const int ck = tid & 31;
        float ar = 0.f, ai = 0.f;
#pragma unroll 4
        for (int er = 0; er < 256; ++er) {
            const int sw = er & 31;
            float yr = Xs[er * 32 + ((ck ^ sw) & 31)];
            float yi = Xs[(er + 256) * 32 + ((ck ^ sw) & 31)];
            float xr = Xs[er * 32 + ((ci ^ sw) & 31)];
            float xi = Xs[(er + 256) * 32 + ((ci ^ sw) & 31)];
            ar += xr * yr - xi * yi;
            ai += xr * yi + xi * yr;
        }
        Pr[li][ck] = ar * 0.0625f;
        Pi[li][ck] = ai * 0.0625f;
    }
    __syncthreads();
    if (tid < 32) {
        int r = tid & 15;
        float (*P)[33] = (tid < 16) ? Pr : Pi;
        float mx = -1e30f;
        for (int j = 0; j < 32; ++j) mx = fmaxf(mx, P[r][j]);
        float s = 0.f;
        for (int j = 0; j < 32; ++j) { float e = __expf(P[r][j] - mx); P[r][j] = e; s += e; }
        float inv = 1.f / s;
        for (int j = 0; j < 32; ++j) P[r][j] *= inv;
    }
    __syncthreads();
    const int er = tid & 255;
    const int th = tid >> 8;                     // 0 or 1: t in [th*8, th*8+8)
    const int sw = er & 31;
    float accr[8], acci[8];
#pragma unroll
    for (int t = 0; t < 8; ++t) { accr[t] = 0.f; acci[t] = 0.f; }
    for (int k = 0; k < 32; ++k) {
        float yr = Xs[er * 32 + ((k ^ sw) & 31)];
        float yi = Xs[(er + 256) * 32 + ((k ^ sw) & 31)];
#pragma unroll
        for (int t = 0; t < 8; ++t) {
            float pr = Pr[th * 8 + t][k], pi = Pi[th * 8 + t][k];
            accr[t] += pr * yr - pi * yi;
            acci[t] += pr * yi + pi * yr;
        }
    }
#pragma unroll
    for (int t = 0; t < 8; ++t) {
        int c = half * 16 + th * 8 + t;
        float vr = Xs[er * 32 + ((c ^ sw) & 31)] + accr[t];
        float vi = Xs[(er + 256) * 32 + ((c ^ sw) & 31)] + acci[t];
        size_t ir = (size_t)b * 16384 + (size_t)c * 512 + er;
        unsigned short hr = f2bf(vr), hi2 = f2bf(vi);
        outHi[ir] = hr;        outLo[ir] = f2bf(vr - bf2f(hr));
        outHi[ir + 256] = hi2; outLo[ir + 256] = f2bf(vi - bf2f(hi2));
    }
}

// ---------------- DUAL add+LN (512), f32 resid, out bf16 hi/lo; rows>=4096 = branch 1 ----
__global__ __launch_bounds__(256) void add_ln_d1(
    const float* __restrict__ r0, const float* __restrict__ y0,
    const float* __restrict__ w0, const float* __restrict__ b0,
    unsigned short* __restrict__ h0, unsigned short* __restrict__ l0,
    const float* __restrict__ r1, const float* __restrict__ y1,
    const float* __restrict__ w1, const float* __restrict__ b1,
    unsigned short* __restrict__ h1, unsigned short* __restrict__ l1)
{
    const int row = blockIdx.x;
    const int br = row >> 12;
    const int rl = row & 4095;
    const float* resid = br ? r1 : r0;
    const float* y     = br ? y1 : y0;
    const float* w     = br ? w1 : w0;
    const float* bb    = br ? b1 : b0;
    unsigned short* oh = br ? h1 : h0;
    unsigned short* ol = br ? l1 : l0;
    const int tid = threadIdx.x;
    const size_t base = (size_t)rl * 512;
    float v0 = resid[base + tid] + y[base + tid];
    float v1 = resid[base + 256 + tid] + y[base + 256 + tid];
    float s = v0 + v1, q = v0 * v0 + v1 * v1;
    for (int off = 32; off; off >>= 1) { s += __shfl_down(s, off); q += __shfl_down(q, off); }
    __shared__ float sw[4], qw[4], ms, is;
    int wid = tid >> 6, lane = tid & 63;
    if (lane == 0) { sw[wid] = s; qw[wid] = q; }
    __syncthreads();
    if (tid == 0) {
        float S = sw[0] + sw[1] + sw[2] + sw[3];
        float Q = qw[0] + qw[1] + qw[2] + qw[3];
        float m = S * (1.f / 512.f);
        ms = m;
        is = rsqrtf(Q * (1.f / 512.f) - m * m + 1e-5f);
    }
    __syncthreads();
    float m = ms, inv = is;
    float o0 = (v0 - m) * inv * w[tid] + bb[tid];
    float o1 = (v1 - m) * inv * w[256 + tid] + bb[256 + tid];
    unsigned short e0 = f2bf(o0), e1 = f2bf(o1);
    oh[base + tid] = e0;       ol[base + tid] = f2bf(o0 - bf2f(e0));
    oh[base + 256 + tid] = e1; ol[base + 256 + tid] = f2bf(o1 - bf2f(e1));
}

// ---------------- DUAL add+LN (512), bf16 hi/lo resid, out f32 --------------------------
__global__ __launch_bounds__(256) void add_ln_d2(
    const unsigned short* __restrict__ rh0, const unsigned short* __restrict__ rl0,
    const float* __restrict__ y0, const float* __restrict__ w0, const float* __restrict__ b0,
    float* __restrict__ o0p,
    const unsigned short* __restrict__ rh1, const unsigned short* __restrict__ rl1,
    const float* __restrict__ y1, const float* __restrict__ w1, const float* __restrict__ b1,
    float* __restrict__ o1p)
{
    const int row = blockIdx.x;
    const int br = row >> 12;
    const int rl = row & 4095;
    const unsigned short* rh = br ? rh1 : rh0;
    const unsigned short* rlo = br ? rl1 : rl0;
    const float* y  = br ? y1 : y0;
    const float* w  = br ? w1 : w0;
    const float* bb = br ? b1 : b0;
    float* op = br ? o1p : o0p;
    const int tid = threadIdx.x;
    const size_t base = (size_t)rl * 512;
    float v0 = bf2f(rh[base + tid]) + bf2f(rlo[base + tid]) + y[base + tid];
    float v1 = bf2f(rh[base + 256 + tid]) + bf2f(rlo[base + 256 + tid]) + y[base + 256 + tid];
    float s = v0 + v1, q = v0 * v0 + v1 * v1;
    for (int off = 32; off; off >>= 1) { s += __shfl_down(s, off); q += __shfl_down(q, off); }
    __shared__ float sw[4], qw[4], ms, is;
    int wid = tid >> 6, lane = tid & 63;
    if (lane == 0) { sw[wid] = s; qw[wid] = q; }
    __syncthreads();
    if (tid == 0) {
        float S = sw[0] + sw[1] + sw[2] + sw[3];
        float Q = qw[0] + qw[1] + qw[2] + qw[3];
        float m = S * (1.f / 512.f);
        ms = m;
        is = rsqrtf(Q * (1.f / 512.f) - m * m + 1e-5f);
    }
    __syncthreads();
    float m = ms, inv = is;
    op[base + tid]       = (v0 - m) * inv * w[tid] + bb[tid];
    op[base + 256 + tid] = (v1 - m) * inv * w[256 + tid] + bb[256 + tid];
}

// ---------------- fused relu+batchLN x2: rf = LN(relu(x2R)) kept in LDS,
//                  res = LN(relu(x2T)) + rf. One block per batch, 1024 threads. ----------
__global__ __launch_bounds__(1024) void relu_bln_fused(
    const float* __restrict__ xR, const float* __restrict__ w2, const float* __restrict__ b2,
    const float* __restrict__ xT, const float* __restrict__ w1, const float* __restrict__ b1,
    float* __restrict__ out)
{
    __shared__ float rfs[16384];
    __shared__ float sw_[16], qw_[16], ms_, is_;
    const int bb = blockIdx.x, tid = threadIdx.x;
    const int wid = tid >> 6, lane = tid & 63;
    const float* xr = xR + (size_t)bb * 16384;
    float s = 0.f, q = 0.f;
    for (int i = tid; i < 16384; i += 1024) { float v = fmaxf(xr[i], 0.f); s += v; q += v * v; }
    for (int off = 32; off; off >>= 1) { s += __shfl_down(s, off); q += __shfl_down(q, off); }
    if (lane == 0) { sw_[wid] = s; qw_[wid] = q; }
    __syncthreads();
    if (tid == 0) {
        float S = 0.f, Q = 0.f;
        for (int i = 0; i < 16; ++i) { S += sw_[i]; Q += qw_[i]; }
        float m = S * (1.f / 16384.f);
        ms_ = m;
        is_ = rsqrtf(Q * (1.f / 16384.f) - m * m + 1e-5f);
    }
    __syncthreads();
    float m = ms_, inv = is_;
    for (int i = tid; i < 16384; i += 1024) {
        float v = fmaxf(xr[i], 0.f);
        rfs[i] = (v - m) * inv * w2[i] + b2[i];
    }
    const float* xt = xT + (size_t)bb * 16384;
    s = 0.f; q = 0.f;
    for (int i = tid; i < 16384; i += 1024) { float v = fmaxf(xt[i], 0.f); s += v; q += v * v; }
    for (int off = 32; off; off >>= 1) { s += __shfl_down(s, off); q += __shfl_down(q, off); }
    if (lane == 0) { sw_[wid] = s; qw_[wid] = q; }
    __syncthreads();
    if (tid == 0) {
        float S = 0.f, Q = 0.f;
        for (int i = 0; i < 16; ++i) { S += sw_[i]; Q += qw_[i]; }
        float m2 = S * (1.f / 16384.f);
        ms_ = m2;
        is_ = rsqrtf(Q * (1.f / 16384.f) - m2 * m2 + 1e-5f);
    }
    __syncthreads();
    m = ms_; inv = is_;
    float* op = out + (size_t)bb * 16384;
    for (int i = tid; i < 16384; i += 1024) {
        float v = fmaxf(xt[i], 0.f);
        op[i] = (v - m) * inv * w1[i] + b1[i] + rfs[i];
    }
}

extern "C" void kernel_launch(void* const* d_in, const int* in_sizes, int n_in,
                              void* d_out, int out_size, void* d_ws, size_t ws_size,
                              hipStream_t stream)
{
    (void)in_sizes; (void)n_in; (void)out_size; (void)ws_size;
    const float* x        = (const float*)d_in[0];
    const float* t_in_w   = (const float*)d_in[1];
    const float* t_in_b   = (const float*)d_in[2];
    const float* t_out_w  = (const float*)d_in[3];
    const float* t_out_b  = (const float*)d_in[4];
    const float* t_ln1_w  = (const float*)d_in[5];
    const float* t_ln1_b  = (const float*)d_in[6];
    const float* t_lin1_w = (const float*)d_in[7];
    const float* t_lin1_b = (const float*)d_in[8];
    const float* t_lin2_w = (const float*)d_in[9];
    const float* t_lin2_b = (const float*)d_in[10];
    const float* t_ln2_w  = (const float*)d_in[11];
    const float* t_ln2_b  = (const float*)d_in[12];
    const float* r_in_w   = (const float*)d_in[13];
    const float* r_in_b   = (const float*)d_in[14];
    const float* r_out_w  = (const float*)d_in[15];
    const float* r_out_b  = (const float*)d_in[16];
    const float* r_ln1_w  = (const float*)d_in[17];
    const float* r_ln1_b  = (const float*)d_in[18];
    const float* r_lin1_w = (const float*)d_in[19];
    const float* r_lin1_b = (const float*)d_in[20];
    const float* r_lin2_w = (const float*)d_in[21];
    const float* r_lin2_b = (const float*)d_in[22];
    const float* r_ln2_w  = (const float*)d_in[23];
    const float* r_ln2_b  = (const float*)d_in[24];
    const float* lc_w     = (const float*)d_in[25];
    const float* lc_b     = (const float*)d_in[26];
    const float* up1_w    = (const float*)d_in[27];
    const float* up1_b    = (const float*)d_in[28];
    const float* up2_w    = (const float*)d_in[29];
    const float* up2_b    = (const float*)d_in[30];
    const float* n1_w     = (const float*)d_in[31];
    const float* n1_b     = (const float*)d_in[32];
    const float* n2_w     = (const float*)d_in[33];
    const float* n2_b     = (const float*)d_in[34];
    const float* l1_re    = (const float*)d_in[35];
    const float* l1_im    = (const float*)d_in[36];
    const float* lb1_re   = (const float*)d_in[39];
    const float* lb1_im   = (const float*)d_in[40];

    float* outp = (float*)d_out;

    // ---- workspace map (float offsets; total 21,774,336 f = 87.1 MB) ----
    float* WS   = (float*)d_ws;
    float* LL   = WS;                                        // 2M f (also fa f32, later y_r)
    float* FA   = WS;
    float* yR   = WS;
    float* QR   = WS + 2097152;                              // 6.29M f
    float* tabC = QR;                                        // 131072
    float* tabS = QR + 131072;
    unsigned short* WaHu = (unsigned short*)(QR + 786432);
    unsigned short* WaLu = (unsigned short*)(QR + 917504);
    unsigned short* WmHu = (unsigned short*)(QR + 1048576);
    unsigned short* WmLu = (unsigned short*)(QR + 1179648);
    float* qkvR = QR;                                        // 6.29M f: [2097152, 8388608)
    unsigned short* x1rH = (unsigned short*)(WS + 2097152);
    unsigned short* x1rL = (unsigned short*)(WS + 3145728);
    unsigned short* x1tH = (unsigned short*)(WS + 4194304);
    unsigned short* x1tL = (unsigned short*)(WS + 5242880);
    float* yT   = WS + 6291456;                              // 2M f (written by lin2, after qkvR dead)
    unsigned short* qkvT = (unsigned short*)(WS + 8388608);  // 6.29M ushort: [8388608, 11534336)
    unsigned short* f1R  = (unsigned short*)(WS + 8388608);  // 8.39M ushort
    float* x2R  = WS + 8388608;                              // 2M f
    float* x2T  = WS + 10485760;                             // 2M f
    unsigned short* xHi = (unsigned short*)(WS + 11534336);
    unsigned short* xLo = (unsigned short*)(WS + 12582912);
    unsigned short* aoR = (unsigned short*)(WS + 11534336);
    unsigned short* aoT = (unsigned short*)(WS + 12582912);
    unsigned short* f1T = (unsigned short*)(WS + 12582912);  // 8.39M ushort
    unsigned short* LLH = (unsigned short*)(WS + 13631488);
    unsigned short* LLL = (unsigned short*)(WS + 14680064);
    float* oR   = WS + 13631488;                             // 2M f
    float* oT   = WS + 15728640;                             // 2M f
    unsigned short* faHi = (unsigned short*)(WS + 15728640);
    unsigned short* faLo = (unsigned short*)(WS + 16777216);
    unsigned short* rinLoU = (unsigned short*)(WS + 17825792);  // 786432 ushort
    float* LB   = WS + 18219008;                             // 512 f
    unsigned short* WB = (unsigned short*)(WS + 18366464);

    // u1b (up1 bf16 out, 1M ushort) parks in the OUTPUT res slot outp[0..1048576 f):
    // res is written only by the final relu_bln_fused; nothing else touches it.
    unsigned short* u1b = (unsigned short*)outp;

    unsigned short* w_tin  = WB + 0;        // 1536x512
    unsigned short* w_tout = WB + 786432;   // 512x512
    unsigned short* w_tl1  = WB + 1048576;  // 2048x512
    unsigned short* w_tl2  = WB + 2097152;  // 512x2048
    unsigned short* w_rin  = WB + 3145728;  // 1536x512
    unsigned short* w_rout = WB + 3932160;  // 512x512
    unsigned short* w_rl1  = WB + 4194304;  // 2048x512
    unsigned short* w_rl2  = WB + 5242880;  // 512x2048
    unsigned short* w_up1  = WB + 6291456;  // 512x512
    unsigned short* w_up2  = WB + 6553600;  // 512x512

    dim3 blk(256);

    // ---- prep (3 dispatches) ----
    tab_kernel<<<dim3(512), blk, 0, stream>>>(tabC, tabS);
    wawm_kernel<<<dim3(512, 2, 2), blk, 0, stream>>>(l1_re, l1_im, lc_w, tabC, tabS,
                                                     WaHu, WaLu, WmHu, WmLu);
    uber_prep_kernel<<<dim3(34818), blk, 0, stream>>>(t_in_w, t_out_w, t_lin1_w, t_lin2_w,
                                                      r_in_w, r_out_w, r_lin1_w, r_lin2_w,
                                                      up1_w, up2_w, WB, rinLoU,
                                                      x, xHi, xLo, outp + NOUT,
                                                      lb1_re, lb1_im, LB);

    // ---- freq branch ----
    gemm_mfma3<64,64,1,0,0><<<dim3(8, 64), blk, 0, stream>>>(xHi, xLo, WaHu, WaLu, LB,
                                                             LL, nullptr, nullptr, nullptr, 512, 512);
    cattn2_kernel<<<dim3(128, 2), dim3(512), 65536, stream>>>(LL, LLH, LLL);         // LL hi/lo
    gemm_mfma3<64,64,0,1,1><<<dim3(8, 64), blk, 0, stream>>>(LLH, LLL, WmHu, WmLu, lc_b,
                                                             FA, outp + 2 * NOUT, faHi, faLo, 512, 512);

    // ---- qkv both TELs + up1 (merged, z=0/1/2) ----
    gemm_qkv_tri<64,128><<<dim3(12, 64, 3), blk, 0, stream>>>(faHi, faLo, w_rin, rinLoU, r_in_b, qkvR,
                                                              xHi, w_tin, t_in_b, qkvT,
                                                              faHi, w_up1, up1_b, u1b, 1536, 512);

    // ---- dual TEL pipeline + up2 ----
    attn_dual_kernel<<<dim3(2048), blk, 0, stream>>>(qkvR, qkvT, aoR, aoT);
    gemm_out_tri<64,64><<<dim3(8, 64, 3), blk, 0, stream>>>(aoR, w_rout, r_out_b, oR,
                                                            aoT, w_tout, t_out_b, oT,
                                                            u1b, w_up2, up2_b, outp + 3 * NOUT, 512, 512);
    add_ln_d1<<<dim3(8192), blk, 0, stream>>>(FA, oR, r_ln1_w, r_ln1_b, x1rH, x1rL,
                                              x,  oT, t_ln1_w, t_ln1_b, x1tH, x1tL);
    gemm_dual<64,128,1,1><<<dim3(16, 64, 2), blk, 0, stream>>>(x1rH, x1tH, w_rl1, w_tl1,
                                                               r_lin1_b, t_lin1_b, nullptr, nullptr,
                                                               f1R, f1T, 2048, 512);
    gemm_dual<64,64,0,0><<<dim3(8, 64, 2), blk, 0, stream>>>(f1R, f1T, w_rl2, w_tl2,
                                                             r_lin2_b, t_lin2_b, yR, yT,
                                                             nullptr, nullptr, 512, 2048);
    add_ln_d2<<<dim3(8192), blk, 0, stream>>>(x1rH, x1rL, yR, r_ln2_w, r_ln2_b, x2R,
                                              x1tH, x1tL, yT, t_ln2_w, t_ln2_b, x2T);
    relu_bln_fused<<<dim3(128), dim3(1024), 0, stream>>>(x2R, n2_w, n2_b, x2T, n1_w, n1_b, outp);
}

// Round 13
// 458.823 us; speedup vs baseline: 1.0533x; 1.0486x over previous
//
#include <hip/hip_runtime.h>
#include <math.h>

// NoiScaleModule: B=128, C=32(seq), S=512(d_model), EMB=256, NHEAD=8, DFF=2048
// All tensors FLOAT32. Outputs concat flat: res[2M], down_x[2M], fa[2M], up[2M]
//
// R15: schedule fusion. 520->470 (best known-good).
// R17/R18: up1+up2 folds — alias bugs. R19: fixed (u1b -> outp res slot) but
//      qkv_tri=81us vs qkv_dual 56+up1 13: folding a SMALL gemm into a LARGE
//      latency-bound dispatch stretches it (481, net loss).
// R20: keep only the good fold: qkv_dual (R15 form, 56us) + standalone up1 +
//      out_tri{out_r,out_t,up2} (three identical-shape GEMMs, verified R19).
//      15 dispatches; u1b parks in outp[0..1M) (res slot, dead until last kernel).

#define NROW 4096
#define NOUT 2097152

typedef __attribute__((ext_vector_type(8))) short short8;
typedef __attribute__((ext_vector_type(4))) float floatx4;

__device__ __forceinline__ unsigned short f2bf(float f) {
    union { float f; unsigned u; } v; v.f = f;
    return (unsigned short)((v.u + 0x7fffu + ((v.u >> 16) & 1u)) >> 16);
}
__device__ __forceinline__ float bf2f(unsigned short h) {
    union { unsigned u; float f; } v; v.u = ((unsigned)h) << 16;
    return v.f;
}

__device__ __forceinline__ void gload16(const unsigned short* g, unsigned short* l) {
    __builtin_amdgcn_global_load_lds((const __attribute__((address_space(1))) void*)g,
                                     (__attribute__((address_space(3))) void*)l, 16, 0, 0);
}

// XCD-chunked swizzle (T1): requires nwg % 8 == 0.
__device__ __forceinline__ void xcd_swizzle(int& bx, int& by, int& bz) {
    const int gx = gridDim.x, gy = gridDim.y;
    const int nwg = gx * gy * gridDim.z;
    int b = (bz * gy + by) * gx + bx;
    const int chunk = nwg >> 3;
    const int lb = (b & 7) * chunk + (b >> 3);
    bx = lb % gx;
    const int rem = lb / gx;
    by = rem % gy;
    bz = rem / gy;
}

// ---------------- prep: cos/sin tables tab[n][k], n<512, k<256 ----------------
__global__ __launch_bounds__(256) void tab_kernel(float* __restrict__ tabC, float* __restrict__ tabS)
{
    int n = blockIdx.x, k = threadIdx.x;
    int m = (n * k) & 511;
    float th = (float)m * 0.01227184630308513f;  // 2*pi/512
    float s, c; sincosf(th, &s, &c);
    tabC[n * 256 + k] = c;
    tabS[n * 256 + k] = s;
}

// Wa (z=0) and Wm (z=1) in one dispatch; both emit bf16 hi/lo directly.
__global__ __launch_bounds__(256) void wawm_kernel(const float* __restrict__ l1_re, const float* __restrict__ l1_im,
                                                   const float* __restrict__ lc_w,
                                                   const float* __restrict__ tabC, const float* __restrict__ tabS,
                                                   unsigned short* __restrict__ WaH, unsigned short* __restrict__ WaL,
                                                   unsigned short* __restrict__ WmH, unsigned short* __restrict__ WmL)
{
    __shared__ float lw[512];
    const float inv = 0.04419417382415922f;  // 1/sqrt(512)
    if (blockIdx.z == 0) {
        int n  = blockIdx.x;
        int ep = blockIdx.y * 256 + threadIdx.x;
        float acc = 0.f;
        if (ep < 256) {
            for (int k = 0; k < 128; ++k) {
                float c = tabC[n * 256 + k], s = tabS[n * 256 + k];
                acc += c * l1_re[k * 256 + ep] + s * l1_im[k * 256 + ep];
            }
        } else {
            int e = ep - 256;
            for (int k = 0; k < 128; ++k) {
                float c = tabC[n * 256 + k], s = tabS[n * 256 + k];
                acc += c * l1_im[k * 256 + e] - s * l1_re[k * 256 + e];
            }
        }
        float v = acc * inv;
        size_t idx = (size_t)ep * 512 + n;
        unsigned short h = f2bf(v);
        WaH[idx] = h;
        WaL[idx] = f2bf(v - bf2f(h));
    } else {
        int s  = blockIdx.x;
        int kk = blockIdx.y * 256 + threadIdx.x;
        for (int i = threadIdx.x; i < 512; i += 256) lw[i] = lc_w[s * 512 + i];
        __syncthreads();
        float acc = 0.f;
        if (kk < 256) {
            int k = kk;
            for (int n = 0; n < 512; ++n) acc += tabC[n * 256 + k] * lw[n];
            acc *= (k == 0) ? inv : 2.f * inv;
        } else {
            int k = kk - 256;
            if (k == 0) acc = 0.f;
            else {
                for (int n = 0; n < 512; ++n) acc += tabS[n * 256 + k] * lw[n];
                acc *= -2.f * inv;
            }
        }
        size_t idx = (size_t)s * 512 + kk;
        unsigned short h = f2bf(acc);
        WmH[idx] = h;
        WmL[idx] = f2bf(acc - bf2f(h));
    }
}

// ---------------- uber elementwise prep: wcvt(+rinLo) | xsplit | lbpack ----------------
__global__ __launch_bounds__(256) void uber_prep_kernel(
    const float* s0, const float* s1, const float* s2, const float* s3, const float* s4,
    const float* s5, const float* s6, const float* s7, const float* s8, const float* s9,
    unsigned short* __restrict__ o, unsigned short* __restrict__ rinLo,
    const float* __restrict__ x, unsigned short* __restrict__ xhi,
    unsigned short* __restrict__ xlo, float* __restrict__ xcp,
    const float* __restrict__ lbre, const float* __restrict__ lbim, float* __restrict__ lbout)
{
    const int bid = blockIdx.x, tid = threadIdx.x;
    if (bid < 26624) {
        int i = bid * 256 + tid;  // exactly covers 6815744
        const float* s; int off;
        if (i < 3145728) {
            if (i < 1048576) { if (i < 786432) { s = s0; off = 0; } else { s = s1; off = 786432; } }
            else             { if (i < 2097152) { s = s2; off = 1048576; } else { s = s3; off = 2097152; } }
        } else {
            if (i < 5242880) {
                if (i < 3932160) { s = s4; off = 3145728; }
                else if (i < 4194304) { s = s5; off = 3932160; }
                else { s = s6; off = 4194304; }
            } else {
                if (i < 6291456) { s = s7; off = 5242880; }
                else if (i < 6553600) { s = s8; off = 6291456; }
                else { s = s9; off = 6553600; }
            }
        }
        float v = s[i - off];
        unsigned short h = f2bf(v);
        o[i] = h;
        if (i >= 3145728 && i < 3932160) rinLo[i - 3145728] = f2bf(v - bf2f(h));
    } else if (bid < 34816) {
        int i = (bid - 26624) * 256 + tid;  // exactly covers 2097152
        float v = x[i];
        unsigned short h = f2bf(v);
        xhi[i] = h;
        xlo[i] = f2bf(v - bf2f(h));
        xcp[i] = v;
    } else {
        int i = (bid - 34816) * 256 + tid;
        if (i < 512) lbout[i] = (i < 256) ? lbre[i] : lbim[i - 256];
    }
}

// ---------------- MFMA GEMM (BK=64, single LDS buffer): for up1 ----------------
template <int TM, int TN, int ACT, int WF, int WBF>
__global__ __launch_bounds__(256) void gemm_mfma(
    const unsigned short* __restrict__ A, const unsigned short* __restrict__ W,
    const float* __restrict__ bias, float* __restrict__ Cf,
    unsigned short* __restrict__ Cb, int N, int K)
{
    constexpr int MI = TM / 32, NJ = TN / 32;
    constexpr int ARW = TM / 4, BRW = TN / 4;
    __shared__ unsigned short As[2][TM * 32];
    __shared__ unsigned short Bs[2][TN * 32];
    const int tid = threadIdx.x;
    const int wave = tid >> 6, lane = tid & 63;
    int bx = blockIdx.x, by = blockIdx.y, bz = blockIdx.z;
    xcd_swizzle(bx, by, bz);
    const int m0 = by * TM, n0 = bx * TN;
    const int sr = lane >> 2, sc = (lane & 3) * 8;
    const unsigned short* aS = A + (size_t)(m0 + wave * ARW + sr) * K + sc;
    const unsigned short* wS = W + (size_t)(n0 + wave * BRW + sr) * K + sc;
    const int wm = (wave >> 1) * (TM / 2), wn = (wave & 1) * (TN / 2);
    const int fr = lane & 15, fko = (lane >> 4) * 8;

    floatx4 acc[MI][NJ];
#pragma unroll
    for (int i = 0; i < MI; ++i)
#pragma unroll
        for (int j = 0; j < NJ; ++j) acc[i][j] = (floatx4){0.f, 0.f, 0.f, 0.f};

    for (int k0 = 0; k0 < K; k0 += 64) {
#pragma unroll
        for (int h = 0; h < 2; ++h) {
#pragma unroll
            for (int c = 0; c < ARW / 16; ++c)
                gload16(aS + (size_t)(16 * c) * K + k0 + 32 * h, &As[h][(wave * ARW + 16 * c) * 32]);
#pragma unroll
            for (int c = 0; c < BRW / 16; ++c)
                gload16(wS + (size_t)(16 * c) * K + k0 + 32 * h, &Bs[h][(wave * BRW + 16 * c) * 32]);
        }
        __syncthreads();
#pragma unroll
        for (int h = 0; h < 2; ++h) {
            short8 af[MI], bfr[NJ];
#pragma unroll
            for (int i = 0; i < MI; ++i) af[i] = *(const short8*)&As[h][(wm + i * 16 + fr) * 32 + fko];
#pragma unroll
            for (int j = 0; j < NJ; ++j) bfr[j] = *(const short8*)&Bs[h][(wn + j * 16 + fr) * 32 + fko];
#pragma unroll
            for (int i = 0; i < MI; ++i)
#pragma unroll
                for (int j = 0; j < NJ; ++j)
                    acc[i][j] = __builtin_amdgcn_mfma_f32_16x16x32_bf16(af[i], bfr[j], acc[i][j], 0, 0, 0);
        }
        __syncthreads();
    }
    const int r0 = m0 + wm + (lane >> 4) * 4;
#pragma unroll
    for (int i = 0; i < MI; ++i) {
#pragma unroll
        for (int j = 0; j < NJ; ++j) {
            int n = n0 + wn + j * 16 + fr;
            float bv = bias[n];
#pragma unroll
            for (int r = 0; r < 4; ++r) {
                int m = r0 + i * 16 + r;
                size_t idx = (size_t)m * N + n;
                float v = acc[i][j][r] + bv;
                if (ACT) v = fmaxf(v, 0.f);
                if (WF) Cf[idx] = v;
                if (WBF) Cb[idx] = f2bf(v);
            }
        }
    }
}

// ---------------- dual-branch GEMM (BK=64): z=0/1 select. For lin1/lin2. ----------------
template <int TM, int TN, int ACT, int WBF>
__global__ __launch_bounds__(256) void gemm_dual(
    const unsigned short* __restrict__ A0, const unsigned short* __restrict__ A1,
    const unsigned short* __restrict__ W0, const unsigned short* __restrict__ W1,
    const float* __restrict__ b0, const float* __restrict__ b1,
    float* __restrict__ C0, float* __restrict__ C1,
    unsigned short* __restrict__ D0, unsigned short* __restrict__ D1, int N, int K)
{
    constexpr int MI = TM / 32, NJ = TN / 32;
    constexpr int ARW = TM / 4, BRW = TN / 4;
    __shared__ unsigned short As[2][TM * 32];
    __shared__ unsigned short Bs[2][TN * 32];
    const int tid = threadIdx.x;
    const int wave = tid >> 6, lane = tid & 63;
    int bx = blockIdx.x, by = blockIdx.y, bz = blockIdx.z;
    xcd_swizzle(bx, by, bz);
    const int m0 = by * TM, n0 = bx * TN;
    const int z = bz;
    const unsigned short* A = z ? A1 : A0;
    const unsigned short* W = z ? W1 : W0;
    const float* bias = z ? b1 : b0;
    float* Cf = z ? C1 : C0;
    unsigned short* Cb = z ? D1 : D0;
    const int sr = lane >> 2, sc = (lane & 3) * 8;
    const unsigned short* aS = A + (size_t)(m0 + wave * ARW + sr) * K + sc;
    const unsigned short* wS = W + (size_t)(n0 + wave * BRW + sr) * K + sc;
    const int wm = (wave >> 1) * (TM / 2), wn = (wave & 1) * (TN / 2);
    const int fr = lane & 15, fko = (lane >> 4) * 8;

    floatx4 acc[MI][NJ];
#pragma unroll
    for (int i = 0; i < MI; ++i)
#pragma unroll
        for (int j = 0; j < NJ; ++j) acc[i][j] = (floatx4){0.f, 0.f, 0.f, 0.f};

    for (int k0 = 0; k0 < K; k0 += 64) {
#pragma unroll
        for (int h = 0; h < 2; ++h) {
#pragma unroll
            for (int c = 0; c < ARW / 16; ++c)
                gload16(aS + (size_t)(16 * c) * K + k0 + 32 * h, &As[h][(wave * ARW + 16 * c) * 32]);
#pragma unroll
            for (int c = 0; c < BRW / 16; ++c)
                gload16(wS + (size_t)(16 * c) * K + k0 + 32 * h, &Bs[h][(wave * BRW + 16 * c) * 32]);
        }
        __syncthreads();
#pragma unroll
        for (int h = 0; h < 2; ++h) {
            short8 af[MI], bfr[NJ];
#pragma unroll
            for (int i = 0; i < MI; ++i) af[i] = *(const short8*)&As[h][(wm + i * 16 + fr) * 32 + fko];
#pragma unroll
            for (int j = 0; j < NJ; ++j) bfr[j] = *(const short8*)&Bs[h][(wn + j * 16 + fr) * 32 + fko];
#pragma unroll
            for (int i = 0; i < MI; ++i)
#pragma unroll
                for (int j = 0; j < NJ; ++j)
                    acc[i][j] = __builtin_amdgcn_mfma_f32_16x16x32_bf16(af[i], bfr[j], acc[i][j], 0, 0, 0);
        }
        __syncthreads();
    }
    const int r0 = m0 + wm + (lane >> 4) * 4;
#pragma unroll
    for (int i = 0; i < MI; ++i) {
#pragma unroll
        for (int j = 0; j < NJ; ++j) {
            int n = n0 + wn + j * 16 + fr;
            float bv = bias[n];
#pragma unroll
            for (int r = 0; r < 4; ++r) {
                int m = r0 + i * 16 + r;
                size_t idx = (size_t)m * N + n;
                float v = acc[i][j][r] + bv;
                if (ACT) v = fmaxf(v, 0.f);
                if (WBF) Cb[idx] = f2bf(v);
                else     Cf[idx] = v;
            }
        }
    }
}

// ---------------- tri-branch single-product GEMM (BK=64, TN=64): out-proj r/t + up2 ------
template <int TM, int TN>
__global__ __launch_bounds__(256) void gemm_out_tri(
    const unsigned short* __restrict__ A0, const unsigned short* __restrict__ W0,
    const float* __restrict__ b0, float* __restrict__ C0,
    const unsigned short* __restrict__ A1, const unsigned short* __restrict__ W1,
    const float* __restrict__ b1, float* __restrict__ C1,
    const unsigned short* __restrict__ A2, const unsigned short* __restrict__ W2,
    const float* __restrict__ b2, float* __restrict__ C2, int N, int K)
{
    constexpr int MI = TM / 32, NJ = TN / 32;
    constexpr int ARW = TM / 4, BRW = TN / 4;
    __shared__ unsigned short As[2][TM * 32];
    __shared__ unsigned short Bs[2][TN * 32];
    const int tid = threadIdx.x;
    const int wave = tid >> 6, lane = tid & 63;
    int bx = blockIdx.x, by = blockIdx.y, bz = blockIdx.z;
    xcd_swizzle(bx, by, bz);
    const int m0 = by * TM, n0 = bx * TN;
    const unsigned short* A = (bz == 0) ? A0 : (bz == 1) ? A1 : A2;
    const unsigned short* W = (bz == 0) ? W0 : (bz == 1) ? W1 : W2;
    const float* bias       = (bz == 0) ? b0 : (bz == 1) ? b1 : b2;
    float* Cf               = (bz == 0) ? C0 : (bz == 1) ? C1 : C2;
    const int sr = lane >> 2, sc = (lane & 3) * 8;
    const unsigned short* aS = A + (size_t)(m0 + wave * ARW + sr) * K + sc;
    const unsigned short* wS = W + (size_t)(n0 + wave * BRW + sr) * K + sc;
    const int wm = (wave >> 1) * (TM / 2), wn = (wave & 1) * (TN / 2);
    const int fr = lane & 15, fko = (lane >> 4) * 8;

    floatx4 acc[MI][NJ];
#pragma unroll
    for (int i = 0; i < MI; ++i)
#pragma unroll
        for (int j = 0; j < NJ; ++j) acc[i][j] = (floatx4){0.f, 0.f, 0.f, 0.f};

    for (int k0 = 0; k0 < K; k0 += 64) {
#pragma unroll
        for (int h = 0; h < 2; ++h) {
#pragma unroll
            for (int c = 0; c < ARW / 16; ++c)
                gload16(aS + (size_t)(16 * c) * K + k0 + 32 * h, &As[h][(wave * ARW + 16 * c) * 32]);
#pragma unroll
            for (int c = 0; c < BRW / 16; ++c)
                gload16(wS + (size_t)(16 * c) * K + k0 + 32 * h, &Bs[h][(wave * BRW + 16 * c) * 32]);
        }
        __syncthreads();
#pragma unroll
        for (int h = 0; h < 2; ++h) {
            short8 af[MI], bfr[NJ];
#pragma unroll
            for (int i = 0; i < MI; ++i) af[i] = *(const short8*)&As[h][(wm + i * 16 + fr) * 32 + fko];
#pragma unroll
            for (int j = 0; j < NJ; ++j) bfr[j] = *(const short8*)&Bs[h][(wn + j * 16 + fr) * 32 + fko];
#pragma unroll
            for (int i = 0; i < MI; ++i)
#pragma unroll
                for (int j = 0; j < NJ; ++j)
                    acc[i][j] = __builtin_amdgcn_mfma_f32_16x16x32_bf16(af[i], bfr[j], acc[i][j], 0, 0, 0);
        }
        __syncthreads();
    }
    const int r0 = m0 + wm + (lane >> 4) * 4;
#pragma unroll
    for (int i = 0; i < MI; ++i) {
#pragma unroll
        for (int j = 0; j < NJ; ++j) {
            int n = n0 + wn + j * 16 + fr;
            float bv = bias[n];
#pragma unroll
            for (int r = 0; r < 4; ++r) {
                int m = r0 + i * 16 + r;
                Cf[(size_t)m * N + n] = acc[i][j][r] + bv;
            }
        }
    }
}

// ---------------- fused hi/lo 3-product MFMA GEMM (BK=64, single-buffer) ----------------
template <int TM, int TN, int ACT, int WCOPY, int WHILO>
__global__ __launch_bounds__(256) void gemm_mfma3(
    const unsigned short* __restrict__ Ah, const unsigned short* __restrict__ Al,
    const unsigned short* __restrict__ Wh, const unsigned short* __restrict__ Wl,
    const float* __restrict__ bias, float* __restrict__ Cf, float* __restrict__ Ccopy,
    unsigned short* __restrict__ Hh, unsigned short* __restrict__ Hl, int N, int K)
{
    constexpr int MI = TM / 32, NJ = TN / 32;
    constexpr int ARW = TM / 4, BRW = TN / 4;
    __shared__ unsigned short Ash[2][TM * 32];
    __shared__ unsigned short Asl[2][TM * 32];
    __shared__ unsigned short Bsh[2][TN * 32];
    __shared__ unsigned short Bsl[2][TN * 32];
    const int tid = threadIdx.x;
    const int wave = tid >> 6, lane = tid & 63;
    int bx = blockIdx.x, by = blockIdx.y, bz = blockIdx.z;
    xcd_swizzle(bx, by, bz);
    const int m0 = by * TM, n0 = bx * TN;
    const int sr = lane >> 2, sc = (lane & 3) * 8;
    const size_t aoff = (size_t)(m0 + wave * ARW + sr) * K + sc;
    const size_t woff = (size_t)(n0 + wave * BRW + sr) * K + sc;
    const int wm = (wave >> 1) * (TM / 2), wn = (wave & 1) * (TN / 2);
    const int fr = lane & 15, fko = (lane >> 4) * 8;

    floatx4 acc[MI][NJ];
#pragma unroll
    for (int i = 0; i < MI; ++i)
#pragma unroll
        for (int j = 0; j < NJ; ++j) acc[i][j] = (floatx4){0.f, 0.f, 0.f, 0.f};

    for (int k0 = 0; k0 < K; k0 += 64) {
#pragma unroll
        for (int h = 0; h < 2; ++h) {
#pragma unroll
            for (int c = 0; c < ARW / 16; ++c) {
                gload16(Ah + aoff + (size_t)(16 * c) * K + k0 + 32 * h, &Ash[h][(wave * ARW + 16 * c) * 32]);
                gload16(Al + aoff + (size_t)(16 * c) * K + k0 + 32 * h, &Asl[h][(wave * ARW + 16 * c) * 32]);
            }
#pragma unroll
            for (int c = 0; c < BRW / 16; ++c) {
                gload16(Wh + woff + (size_t)(16 * c) * K + k0 + 32 * h, &Bsh[h][(wave * BRW + 16 * c) * 32]);
                gload16(Wl + woff + (size_t)(16 * c) * K + k0 + 32 * h, &Bsl[h][(wave * BRW + 16 * c) * 32]);
            }
        }
        __syncthreads();
#pragma unroll
        for (int h = 0; h < 2; ++h) {
            short8 ah[MI], al[MI], bh[NJ], bl[NJ];
#pragma unroll
            for (int i = 0; i < MI; ++i) {
                ah[i] = *(const short8*)&Ash[h][(wm + i * 16 + fr) * 32 + fko];
                al[i] = *(const short8*)&Asl[h][(wm + i * 16 + fr) * 32 + fko];
            }
#pragma unroll
            for (int j = 0; j < NJ; ++j) {
                bh[j] = *(const short8*)&Bsh[h][(wn + j * 16 + fr) * 32 + fko];
                bl[j] = *(const short8*)&Bsl[h][(wn + j * 16 + fr) * 32 + fko];
            }
#pragma unroll
            for (int i = 0; i < MI; ++i)
#pragma unroll
                for (int j = 0; j < NJ; ++j) {
                    acc[i][j] = __builtin_amdgcn_mfma_f32_16x16x32_bf16(al[i], bh[j], acc[i][j], 0, 0, 0);
                    acc[i][j] = __builtin_amdgcn_mfma_f32_16x16x32_bf16(ah[i], bl[j], acc[i][j], 0, 0, 0);
                    acc[i][j] = __builtin_amdgcn_mfma_f32_16x16x32_bf16(ah[i], bh[j], acc[i][j], 0, 0, 0);
                }
        }
        __syncthreads();
    }
    const int r0 = m0 + wm + (lane >> 4) * 4;
#pragma unroll
    for (int i = 0; i < MI; ++i) {
#pragma unroll
        for (int j = 0; j < NJ; ++j) {
            int n = n0 + wn + j * 16 + fr;
            float bv = bias[n];
#pragma unroll
            for (int r = 0; r < 4; ++r) {
                int m = r0 + i * 16 + r;
                size_t idx = (size_t)m * N + n;
                float v = acc[i][j][r] + bv;
                if (ACT) v = fmaxf(v, 0.f);
                Cf[idx] = v;
                if (WCOPY) Ccopy[idx] = v;
                if (WHILO) {
                    unsigned short h = f2bf(v);
                    Hh[idx] = h;
                    Hl[idx] = f2bf(v - bf2f(h));
                }
            }
        }
    }
}

// ---------------- merged qkv GEMM (BK=64): z=0 r-qkv 3-product (f32),
//                  z=1 t-qkv single (bf16). R15 proven form. ----------------------------
template <int TM, int TN>
__global__ __launch_bounds__(256) void gemm_qkv_dual(
    const unsigned short* __restrict__ Ah0, const unsigned short* __restrict__ Al0,
    const unsigned short* __restrict__ Wh0, const unsigned short* __restrict__ Wl0,
    const float* __restrict__ b0, float* __restrict__ C0,
    const unsigned short* __restrict__ A1, const unsigned short* __restrict__ W1,
    const float* __restrict__ b1, unsigned short* __restrict__ C1,
    int N, int K)
{
    constexpr int MI = TM / 32, NJ = TN / 32;
    constexpr int ARW = TM / 4, BRW = TN / 4;
    __shared__ unsigned short Ash[2][TM * 32];
    __shared__ unsigned short Asl[2][TM * 32];
    __shared__ unsigned short Bsh[2][TN * 32];
    __shared__ unsigned short Bsl[2][TN * 32];
    const int tid = threadIdx.x;
    const int wave = tid >> 6, lane = tid & 63;
    int bx = blockIdx.x, by = blockIdx.y, bz = blockIdx.z;
    xcd_swizzle(bx, by, bz);
    const int m0 = by * TM, n0 = bx * TN;
    const int sr = lane >> 2, sc = (lane & 3) * 8;
    const size_t aoff = (size_t)(m0 + wave * ARW + sr) * K + sc;
    const size_t woff = (size_t)(n0 + wave * BRW + sr) * K + sc;
    const int wm = (wave >> 1) * (TM / 2), wn = (wave & 1) * (TN / 2);
    const int fr = lane & 15, fko = (lane >> 4) * 8;

    floatx4 acc[MI][NJ];
#pragma unroll
    for (int i = 0; i < MI; ++i)
#pragma unroll
        for (int j = 0; j < NJ; ++j) acc[i][j] = (floatx4){0.f, 0.f, 0.f, 0.f};

    const int r0 = m0 + wm + (lane >> 4) * 4;

    if (bz == 0) {
        for (int k0 = 0; k0 < K; k0 += 64) {
#pragma unroll
            for (int h = 0; h < 2; ++h) {
#pragma unroll
                for (int c = 0; c < ARW / 16; ++c) {
                    gload16(Ah0 + aoff + (size_t)(16 * c) * K + k0 + 32 * h, &Ash[h][(wave * ARW + 16 * c) * 32]);
                    gload16(Al0 + aoff + (size_t)(16 * c) * K + k0 + 32 * h, &Asl[h][(wave * ARW + 16 * c) * 32]);
                }
#pragma unroll
                for (int c = 0; c < BRW / 16; ++c) {
                    gload16(Wh0 + woff + (size_t)(16 * c) * K + k0 + 32 * h, &Bsh[h][(wave * BRW + 16 * c) * 32]);
                    gload16(Wl0 + woff + (size_t)(16 * c) * K + k0 + 32 * h, &Bsl[h][(wave * BRW + 16 * c) * 32]);
                }
            }
            __syncthreads();
#pragma unroll
            for (int h = 0; h < 2; ++h) {
                short8 ah[MI], al[MI], bh[NJ], bl[NJ];
#pragma unroll
                for (int i = 0; i < MI; ++i) {
                    ah[i] = *(const short8*)&Ash[h][(wm + i * 16 + fr) * 32 + fko];
                    al[i] = *(const short8*)&Asl[h][(wm + i * 16 + fr) * 32 + fko];
                }
#pragma unroll
                for (int j = 0; j < NJ; ++j) {
                    bh[j] = *(const short8*)&Bsh[h][(wn + j * 16 + fr) * 32 + fko];
                    bl[j] = *(const short8*)&Bsl[h][(wn + j * 16 + fr) * 32 + fko];
                }
#pragma unroll
                for (int i = 0; i < MI; ++i)
#pragma unroll
                    for (int j = 0; j < NJ; ++j) {
                        acc[i][j] = __builtin_amdgcn_mfma_f32_16x16x32_bf16(al[i], bh[j], acc[i][j], 0, 0, 0);
                        acc[i][j] = __builtin_amdgcn_mfma_f32_16x16x32_bf16(ah[i], bl[j], acc[i][j], 0, 0, 0);
                        acc[i][j] = __builtin_amdgcn_mfma_f32_16x16x32_bf16(ah[i], bh[j], acc[i][j], 0, 0, 0);
                    }
            }
            __syncthreads();
        }
#pragma unroll
        for (int i = 0; i < MI; ++i)
#pragma unroll
            for (int j = 0; j < NJ; ++j) {
                int n = n0 + wn + j * 16 + fr;
                float bv = b0[n];
#pragma unroll
                for (int r = 0; r < 4; ++r) {
                    int m = r0 + i * 16 + r;
                    C0[(size_t)m * N + n] = acc[i][j][r] + bv;
                }
            }
    } else {
        for (int k0 = 0; k0 < K; k0 += 64) {
#pragma unroll
            for (int h = 0; h < 2; ++h) {
#pragma unroll
                for (int c = 0; c < ARW / 16; ++c)
                    gload16(A1 + aoff + (size_t)(16 * c) * K + k0 + 32 * h, &Ash[h][(wave * ARW + 16 * c) * 32]);
#pragma unroll
                for (int c = 0; c < BRW / 16; ++c)
                    gload16(W1 + woff + (size_t)(16 * c) * K + k0 + 32 * h, &Bsh[h][(wave * BRW + 16 * c) * 32]);
            }
            __syncthreads();
#pragma unroll
            for (int h = 0; h < 2; ++h) {
                short8 af[MI], bfr[NJ];
#pragma unroll
                for (int i = 0; i < MI; ++i) af[i] = *(const short8*)&Ash[h][(wm + i * 16 + fr) * 32 + fko];
#pragma unroll
                for (int j = 0; j < NJ; ++j) bfr[j] = *(const short8*)&Bsh[h][(wn + j * 16 + fr) * 32 + fko];
#pragma unroll
                for (int i = 0; i < MI; ++i)
#pragma unroll
                    for (int j = 0; j < NJ; ++j)
                        acc[i][j] = __builtin_amdgcn_mfma_f32_16x16x32_bf16(af[i], bfr[j], acc[i][j], 0, 0, 0);
            }
            __syncthreads();
        }
#pragma unroll
        for (int i = 0; i < MI; ++i)
#pragma unroll
            for (int j = 0; j < NJ; ++j) {
                int n = n0 + wn + j * 16 + fr;
                float bv = b1[n];
#pragma unroll
                for (int r = 0; r < 4; ++r) {
                    int m = r0 + i * 16 + r;
                    C1[(size_t)m * N + n] = f2bf(acc[i][j][r] + bv);
                }
            }
    }
}

// ---------------- TEL attention, DUAL: blocks [0,1024) = r (f32 qkv), [1024,2048) = t ----
__global__ __launch_bounds__(256) void attn_dual_kernel(const float* __restrict__ qkvF,
                                                        const unsigned short* __restrict__ qkvB,
                                                        unsigned short* __restrict__ outR,
                                                        unsigned short* __restrict__ outT)
{
    const int isT = blockIdx.x >> 10;
    const int bid = blockIdx.x & 1023;
    const int b = bid >> 3;
    const int h = bid & 7;
    __shared__ float qs[32][65], ks[32][65], vs[32][65];
    __shared__ float ps[32][33];
    const int tid = threadIdx.x;
    if (isT) {
        for (int i = tid; i < 2048; i += 256) {
            int s = i >> 6, d = i & 63;
            size_t base = ((size_t)(b * 32 + s)) * 1536 + h * 64 + d;
            qs[s][d] = bf2f(qkvB[base]);
            ks[s][d] = bf2f(qkvB[base + 512]);
            vs[s][d] = bf2f(qkvB[base + 1024]);
        }
    } else {
        for (int i = tid; i < 2048; i += 256) {
            int s = i >> 6, d = i & 63;
            size_t base = ((size_t)(b * 32 + s)) * 1536 + h * 64 + d;
            qs[s][d] = qkvF[base];
            ks[s][d] = qkvF[base + 512];
            vs[s][d] = qkvF[base + 1024];
        }
    }
    __syncthreads();
    for (int i = tid; i < 1024; i += 256) {
        int si = i >> 5, sj = i & 31;
        float acc = 0.f;
#pragma unroll 8
        for (int d = 0; d < 64; ++d) acc += qs[si][d] * ks[sj][d];
        ps[si][sj] = acc * 0.125f;
    }
    __syncthreads();
    if (tid < 32) {
        float mx = -1e30f;
        for (int j = 0; j < 32; ++j) mx = fmaxf(mx, ps[tid][j]);
        float sum = 0.f;
        for (int j = 0; j < 32; ++j) { float e = __expf(ps[tid][j] - mx); ps[tid][j] = e; sum += e; }
        float inv = 1.f / sum;
        for (int j = 0; j < 32; ++j) ps[tid][j] *= inv;
    }
    __syncthreads();
    unsigned short* ob = isT ? outT : outR;
    for (int i = tid; i < 2048; i += 256) {
        int s = i >> 6, d = i & 63;
        float acc = 0.f;
#pragma unroll 8
        for (int k = 0; k < 32; ++k) acc += ps[s][k] * vs[k][d];
        ob[((size_t)(b * 32 + s)) * 512 + h * 64 + d] = f2bf(acc);
    }
}

// ---------------- complex self-attention: LDS-resident, grid (128 batch, 2 half) ----------
__global__ __launch_bounds__(512) void cattn2_kernel(const float* __restrict__ LL,
                                                     unsigned short* __restrict__ outHi,
                                                     unsigned short* __restrict__ outLo)
{
    extern __shared__ float Xs[];
    __shared__ float Pr[16][33], Pi[16][33];
    const int b = blockIdx.x, half = blockIdx.y;
    const int tid = threadIdx.x;
    const float* base = LL + (size_t)b * 16384;
    for (int i = tid; i < 16384; i += 512) {
        int c = i >> 9, e = i & 511;
        Xs[e * 32 + ((c ^ e) & 31)] = base[i];
    }
    __syncthreads();
    {
        const int li = tid >> 5;                 // 0..15
        const int ci = half * 16 + li;
        const int ck = tid & 31;
        float ar = 0.f, ai = 0.f;
#pragma unroll 4
        for (int er = 0; er < 256; ++er) {
            const int sw = er & 31;
            float yr = Xs[er * 32 + ((ck ^ sw) & 31)];
            float yi = Xs[(er + 256) * 32 + ((ck ^ sw) & 31)];
            float xr = Xs[er * 32 + ((ci ^ sw) & 31)];
            float xi = Xs[(er + 256) * 32 + ((ci ^ sw) & 31)];
            ar += xr * yr - xi * yi;
            ai += xr * yi + xi * yr;
        }
        Pr[li][ck] = ar * 0.0625f;
        Pi[li][ck] = ai * 0.0625f;
    }
    __syncthreads();
    if (tid < 32) {
        int r = tid & 15;
        float (*P)[33] = (tid < 16) ? Pr : Pi;
        float mx = -1e30f;
        for (int j = 0; j < 32; ++j) mx = fmaxf(mx, P[r][j]);
        float s = 0.f;
        for (int j = 0; j < 32; ++j) { float e = __expf(P[r][j] - mx); P[r][j] = e; s += e; }
        float inv = 1.f / s;
        for (int j = 0; j < 32; ++j) P[r][j] *= inv;
    }
    __syncthreads();
    const int er = tid & 255;
    const int th = tid >> 8;                     // 0 or 1: t in [th*8, th*8+8)
    const int sw = er & 31;
    float accr[8], acci[8];
#pragma unroll
    for (int t = 0; t < 8; ++t) { accr[t] = 0.f; acci[t] = 0.f; }
    for (int k = 0; k < 32; ++k) {
        float yr = Xs[er * 32 + ((k ^ sw) & 31)];
        float yi = Xs[(er + 256) * 32 + ((k ^ sw) & 31)];
#pragma unroll
        for (int t = 0; t < 8; ++t) {
            float pr = Pr[th * 8 + t][k], pi = Pi[th * 8 + t][k];
            accr[t] += pr * yr - pi * yi;
            acci[t] += pr * yi + pi * yr;
        }
    }
#pragma unroll
    for (int t = 0; t < 8; ++t) {
        int c = half * 16 + th * 8 + t;
        float vr = Xs[er * 32 + ((c ^ sw) & 31)] + accr[t];
        float vi = Xs[(er + 256) * 32 + ((c ^ sw) & 31)] + acci[t];
        size_t ir = (size_t)b * 16384 + (size_t)c * 512 + er;
        unsigned short hr = f2bf(vr), hi2 = f2bf(vi);
        outHi[ir] = hr;        outLo[ir] = f2bf(vr - bf2f(hr));
        outHi[ir + 256] = hi2; outLo[ir + 256] = f2bf(vi - bf2f(hi2));
    }
}

// ---------------- DUAL add+LN (512), f32 resid, out bf16 hi/lo; rows>=4096 = branch 1 ----
__global__ __launch_bounds__(256) void add_ln_d1(
    const float* __restrict__ r0, const float* __restrict__ y0,
    const float* __restrict__ w0, const float* __restrict__ b0,
    unsigned short* __restrict__ h0, unsigned short* __restrict__ l0,
    const float* __restrict__ r1, const float* __restrict__ y1,
    const float* __restrict__ w1, const float* __restrict__ b1,
    unsigned short* __restrict__ h1, unsigned short* __restrict__ l1)
{
    const int row = blockIdx.x;
    const int br = row >> 12;
    const int rl = row & 4095;
    const float* resid = br ? r1 : r0;
    const float* y     = br ? y1 : y0;
    const float* w     = br ? w1 : w0;
    const float* bb    = br ? b1 : b0;
    unsigned short* oh = br ? h1 : h0;
    unsigned short* ol = br ? l1 : l0;
    const int tid = threadIdx.x;
    const size_t base = (size_t)rl * 512;
    float v0 = resid[base + tid] + y[base + tid];
    float v1 = resid[base + 256 + tid] + y[base + 256 + tid];
    float s = v0 + v1, q = v0 * v0 + v1 * v1;
    for (int off = 32; off; off >>= 1) { s += __shfl_down(s, off); q += __shfl_down(q, off); }
    __shared__ float sw[4], qw[4], ms, is;
    int wid = tid >> 6, lane = tid & 63;
    if (lane == 0) { sw[wid] = s; qw[wid] = q; }
    __syncthreads();
    if (tid == 0) {
        float S = sw[0] + sw[1] + sw[2] + sw[3];
        float Q = qw[0] + qw[1] + qw[2] + qw[3];
        float m = S * (1.f / 512.f);
        ms = m;
        is = rsqrtf(Q * (1.f / 512.f) - m * m + 1e-5f);
    }
    __syncthreads();
    float m = ms, inv = is;
    float o0 = (v0 - m) * inv * w[tid] + bb[tid];
    float o1 = (v1 - m) * inv * w[256 + tid] + bb[256 + tid];
    unsigned short e0 = f2bf(o0), e1 = f2bf(o1);
    oh[base + tid] = e0;       ol[base + tid] = f2bf(o0 - bf2f(e0));
    oh[base + 256 + tid] = e1; ol[base + 256 + tid] = f2bf(o1 - bf2f(e1));
}

// ---------------- DUAL add+LN (512), bf16 hi/lo resid, out f32 --------------------------
__global__ __launch_bounds__(256) void add_ln_d2(
    const unsigned short* __restrict__ rh0, const unsigned short* __restrict__ rl0,
    const float* __restrict__ y0, const float* __restrict__ w0, const float* __restrict__ b0,
    float* __restrict__ o0p,
    const unsigned short* __restrict__ rh1, const unsigned short* __restrict__ rl1,
    const float* __restrict__ y1, const float* __restrict__ w1, const float* __restrict__ b1,
    float* __restrict__ o1p)
{
    const int row = blockIdx.x;
    const int br = row >> 12;
    const int rl = row & 4095;
    const unsigned short* rh = br ? rh1 : rh0;
    const unsigned short* rlo = br ? rl1 : rl0;
    const float* y  = br ? y1 : y0;
    const float* w  = br ? w1 : w0;
    const float* bb = br ? b1 : b0;
    float* op = br ? o1p : o0p;
    const int tid = threadIdx.x;
    const size_t base = (size_t)rl * 512;
    float v0 = bf2f(rh[base + tid]) + bf2f(rlo[base + tid]) + y[base + tid];
    float v1 = bf2f(rh[base + 256 + tid]) + bf2f(rlo[base + 256 + tid]) + y[base + 256 + tid];
    float s = v0 + v1, q = v0 * v0 + v1 * v1;
    for (int off = 32; off; off >>= 1) { s += __shfl_down(s, off); q += __shfl_down(q, off); }
    __shared__ float sw[4], qw[4], ms, is;
    int wid = tid >> 6, lane = tid & 63;
    if (lane == 0) { sw[wid] = s; qw[wid] = q; }
    __syncthreads();
    if (tid == 0) {
        float S = sw[0] + sw[1] + sw[2] + sw[3];
        float Q = qw[0] + qw[1] + qw[2] + qw[3];
        float m = S * (1.f / 512.f);
        ms = m;
        is = rsqrtf(Q * (1.f / 512.f) - m * m + 1e-5f);
    }
    __syncthreads();
    float m = ms, inv = is;
    op[base + tid]       = (v0 - m) * inv * w[tid] + bb[tid];
    op[base + 256 + tid] = (v1 - m) * inv * w[256 + tid] + bb[256 + tid];
}

// ---------------- fused relu+batchLN x2: rf = LN(relu(x2R)) kept in LDS,
//                  res = LN(relu(x2T)) + rf. One block per batch, 1024 threads. ----------
__global__ __launch_bounds__(1024) void relu_bln_fused(
    const float* __restrict__ xR, const float* __restrict__ w2, const float* __restrict__ b2,
    const float* __restrict__ xT, const float* __restrict__ w1, const float* __restrict__ b1,
    float* __restrict__ out)
{
    __shared__ float rfs[16384];
    __shared__ float sw_[16], qw_[16], ms_, is_;
    const int bb = blockIdx.x, tid = threadIdx.x;
    const int wid = tid >> 6, lane = tid & 63;
    const float* xr = xR + (size_t)bb * 16384;
    float s = 0.f, q = 0.f;
    for (int i = tid; i < 16384; i += 1024) { float v = fmaxf(xr[i], 0.f); s += v; q += v * v; }
    for (int off = 32; off; off >>= 1) { s += __shfl_down(s, off); q += __shfl_down(q, off); }
    if (lane == 0) { sw_[wid] = s; qw_[wid] = q; }
    __syncthreads();
    if (tid == 0) {
        float S = 0.f, Q = 0.f;
        for (int i = 0; i < 16; ++i) { S += sw_[i]; Q += qw_[i]; }
        float m = S * (1.f / 16384.f);
        ms_ = m;
        is_ = rsqrtf(Q * (1.f / 16384.f) - m * m + 1e-5f);
    }
    __syncthreads();
    float m = ms_, inv = is_;
    for (int i = tid; i < 16384; i += 1024) {
        float v = fmaxf(xr[i], 0.f);
        rfs[i] = (v - m) * inv * w2[i] + b2[i];
    }
    const float* xt = xT + (size_t)bb * 16384;
    s = 0.f; q = 0.f;
    for (int i = tid; i < 16384; i += 1024) { float v = fmaxf(xt[i], 0.f); s += v; q += v * v; }
    for (int off = 32; off; off >>= 1) { s += __shfl_down(s, off); q += __shfl_down(q, off); }
    if (lane == 0) { sw_[wid] = s; qw_[wid] = q; }
    __syncthreads();
    if (tid == 0) {
        float S = 0.f, Q = 0.f;
        for (int i = 0; i < 16; ++i) { S += sw_[i]; Q += qw_[i]; }
        float m2 = S * (1.f / 16384.f);
        ms_ = m2;
        is_ = rsqrtf(Q * (1.f / 16384.f) - m2 * m2 + 1e-5f);
    }
    __syncthreads();
    m = ms_; inv = is_;
    float* op = out + (size_t)bb * 16384;
    for (int i = tid; i < 16384; i += 1024) {
        float v = fmaxf(xt[i], 0.f);
        op[i] = (v - m) * inv * w1[i] + b1[i] + rfs[i];
    }
}

extern "C" void kernel_launch(void* const* d_in, const int* in_sizes, int n_in,
                              void* d_out, int out_size, void* d_ws, size_t ws_size,
                              hipStream_t stream)
{
    (void)in_sizes; (void)n_in; (void)out_size; (void)ws_size;
    const float* x        = (const float*)d_in[0];
    const float* t_in_w   = (const float*)d_in[1];
    const float* t_in_b   = (const float*)d_in[2];
    const float* t_out_w  = (const float*)d_in[3];
    const float* t_out_b  = (const float*)d_in[4];
    const float* t_ln1_w  = (const float*)d_in[5];
    const float* t_ln1_b  = (const float*)d_in[6];
    const float* t_lin1_w = (const float*)d_in[7];
    const float* t_lin1_b = (const float*)d_in[8];
    const float* t_lin2_w = (const float*)d_in[9];
    const float* t_lin2_b = (const float*)d_in[10];
    const float* t_ln2_w  = (const float*)d_in[11];
    const float* t_ln2_b  = (const float*)d_in[12];
    const float* r_in_w   = (const float*)d_in[13];
    const float* r_in_b   = (const float*)d_in[14];
    const float* r_out_w  = (const float*)d_in[15];
    const float* r_out_b  = (const float*)d_in[16];
    const float* r_ln1_w  = (const float*)d_in[17];
    const float* r_ln1_b  = (const float*)d_in[18];
    const float* r_lin1_w = (const float*)d_in[19];
    const float* r_lin1_b = (const float*)d_in[20];
    const float* r_lin2_w = (const float*)d_in[21];
    const float* r_lin2_b = (const float*)d_in[22];
    const float* r_ln2_w  = (const float*)d_in[23];
    const float* r_ln2_b  = (const float*)d_in[24];
    const float* lc_w     = (const float*)d_in[25];
    const float* lc_b     = (const float*)d_in[26];
    const float* up1_w    = (const float*)d_in[27];
    const float* up1_b    = (const float*)d_in[28];
    const float* up2_w    = (const float*)d_in[29];
    const float* up2_b    = (const float*)d_in[30];
    const float* n1_w     = (const float*)d_in[31];
    const float* n1_b     = (const float*)d_in[32];
    const float* n2_w     = (const float*)d_in[33];
    const float* n2_b     = (const float*)d_in[34];
    const float* l1_re    = (const float*)d_in[35];
    const float* l1_im    = (const float*)d_in[36];
    const float* lb1_re   = (const float*)d_in[39];
    const float* lb1_im   = (const float*)d_in[40];

    float* outp = (float*)d_out;

    // ---- workspace map (float offsets; total 21,774,336 f = 87.1 MB) ----
    float* WS   = (float*)d_ws;
    float* LL   = WS;                                        // 2M f (also fa f32, later y_r)
    float* FA   = WS;
    float* yR   = WS;
    float* QR   = WS + 2097152;                              // 6.29M f
    float* tabC = QR;                                        // 131072
    float* tabS = QR + 131072;
    unsigned short* WaHu = (unsigned short*)(QR + 786432);
    unsigned short* WaLu = (unsigned short*)(QR + 917504);
    unsigned short* WmHu = (unsigned short*)(QR + 1048576);
    unsigned short* WmLu = (unsigned short*)(QR + 1179648);
    float* qkvR = QR;                                        // 6.29M f: [2097152, 8388608)
    unsigned short* x1rH = (unsigned short*)(WS + 2097152);
    unsigned short* x1rL = (unsigned short*)(WS + 3145728);
    unsigned short* x1tH = (unsigned short*)(WS + 4194304);
    unsigned short* x1tL = (unsigned short*)(WS + 5242880);
    float* yT   = WS + 6291456;                              // 2M f
    unsigned short* qkvT = (unsigned short*)(WS + 8388608);  // 6.29M ushort
    unsigned short* f1R  = (unsigned short*)(WS + 8388608);  // 8.39M ushort
    float* x2R  = WS + 8388608;                              // 2M f
    float* x2T  = WS + 10485760;                             // 2M f
    unsigned short* xHi = (unsigned short*)(WS + 11534336);
    unsigned short* xLo = (unsigned short*)(WS + 12582912);
    unsigned short* aoR = (unsigned short*)(WS + 11534336);
    unsigned short* aoT = (unsigned short*)(WS + 12582912);
    unsigned short* f1T = (unsigned short*)(WS + 12582912);  // 8.39M ushort
    unsigned short* LLH = (unsigned short*)(WS + 13631488);
    unsigned short* LLL = (unsigned short*)(WS + 14680064);
    float* oR   = WS + 13631488;                             // 2M f
    float* oT   = WS + 15728640;                             // 2M f
    unsigned short* faHi = (unsigned short*)(WS + 15728640);
    unsigned short* faLo = (unsigned short*)(WS + 16777216);
    unsigned short* rinLoU = (unsigned short*)(WS + 17825792);  // 786432 ushort
    float* LB   = WS + 18219008;                             // 512 f
    unsigned short* WB = (unsigned short*)(WS + 18366464);

    // u1b (up1 bf16 out, 1M ushort) parks in the OUTPUT res slot outp[0..1048576 f):
    // res is written only by the final relu_bln_fused (verified passing in R19).
    unsigned short* u1b = (unsigned short*)outp;

    unsigned short* w_tin  = WB + 0;        // 1536x512
    unsigned short* w_tout = WB + 786432;   // 512x512
    unsigned short* w_tl1  = WB + 1048576;  // 2048x512
    unsigned short* w_tl2  = WB + 2097152;  // 512x2048
    unsigned short* w_rin  = WB + 3145728;  // 1536x512
    unsigned short* w_rout = WB + 3932160;  // 512x512
    unsigned short* w_rl1  = WB + 4194304;  // 2048x512
    unsigned short* w_rl2  = WB + 5242880;  // 512x2048
    unsigned short* w_up1  = WB + 6291456;  // 512x512
    unsigned short* w_up2  = WB + 6553600;  // 512x512

    dim3 blk(256);

    // ---- prep (3 dispatches) ----
    tab_kernel<<<dim3(512), blk, 0, stream>>>(tabC, tabS);
    wawm_kernel<<<dim3(512, 2, 2), blk, 0, stream>>>(l1_re, l1_im, lc_w, tabC, tabS,
                                                     WaHu, WaLu, WmHu, WmLu);
    uber_prep_kernel<<<dim3(34818), blk, 0, stream>>>(t_in_w, t_out_w, t_lin1_w, t_lin2_w,
                                                      r_in_w, r_out_w, r_lin1_w, r_lin2_w,
                                                      up1_w, up2_w, WB, rinLoU,
                                                      x, xHi, xLo, outp + NOUT,
                                                      lb1_re, lb1_im, LB);

    // ---- freq branch ----
    gemm_mfma3<64,64,1,0,0><<<dim3(8, 64), blk, 0, stream>>>(xHi, xLo, WaHu, WaLu, LB,
                                                             LL, nullptr, nullptr, nullptr, 512, 512);
    cattn2_kernel<<<dim3(128, 2), dim3(512), 65536, stream>>>(LL, LLH, LLL);         // LL hi/lo
    gemm_mfma3<64,64,0,1,1><<<dim3(8, 64), blk, 0, stream>>>(LLH, LLL, WmHu, WmLu, lc_b,
                                                             FA, outp + 2 * NOUT, faHi, faLo, 512, 512);

    // ---- qkv both TELs (R15 proven dual form) ----
    gemm_qkv_dual<64,128><<<dim3(12, 64, 2), blk, 0, stream>>>(faHi, faLo, w_rin, rinLoU, r_in_b, qkvR,
                                                               xHi, w_tin, t_in_b, qkvT, 1536, 512);

    // ---- up1 standalone (u1b -> outp res slot) ----
    gemm_mfma<64,64,0,0,1><<<dim3(8, 64), blk, 0, stream>>>(faHi, w_up1, up1_b, nullptr, u1b, 512, 512);

    // ---- dual TEL pipeline + up2 folded into out_tri ----
    attn_dual_kernel<<<dim3(2048), blk, 0, stream>>>(qkvR, qkvT, aoR, aoT);
    gemm_out_tri<64,64><<<dim3(8, 64, 3), blk, 0, stream>>>(aoR, w_rout, r_out_b, oR,
                                                            aoT, w_tout, t_out_b, oT,
                                                            u1b, w_up2, up2_b, outp + 3 * NOUT, 512, 512);
    add_ln_d1<<<dim3(8192), blk, 0, stream>>>(FA, oR, r_ln1_w, r_ln1_b, x1rH, x1rL,
                                              x,  oT, t_ln1_w, t_ln1_b, x1tH, x1tL);
    gemm_dual<64,128,1,1><<<dim3(16, 64, 2), blk, 0, stream>>>(x1rH, x1tH, w_rl1, w_tl1,
                                                               r_lin1_b, t_lin1_b, nullptr, nullptr,
                                                               f1R, f1T, 2048, 512);
    gemm_dual<64,64,0,0><<<dim3(8, 64, 2), blk, 0, stream>>>(f1R, f1T, w_rl2, w_tl2,
                                                             r_lin2_b, t_lin2_b, yR, yT,
                                                             nullptr, nullptr, 512, 2048);
    add_ln_d2<<<dim3(8192), blk, 0, stream>>>(x1rH, x1rL, yR, r_ln2_w, r_ln2_b, x2R,
                                              x1tH, x1tL, yT, t_ln2_w, t_ln2_b, x2T);
    relu_bln_fused<<<dim3(128), dim3(1024), 0, stream>>>(x2R, n2_w, n2_b, x2T, n1_w, n1_b, outp);
}

// Round 14
// 458.268 us; speedup vs baseline: 1.0545x; 1.0012x over previous
//
#include <hip/hip_runtime.h>
#include <math.h>

// NoiScaleModule: B=128, C=32(seq), S=512(d_model), EMB=256, NHEAD=8, DFF=2048
// All tensors FLOAT32. Outputs concat flat: res[2M], down_x[2M], fa[2M], up[2M]
//
// R15: schedule fusion. 520->470. R20: qkv_dual + standalone up1 + out_tri
//      (up2 folded; u1b parks in outp res slot). 470->458.8 (best).
// R21: two same-size-co-runner folds: (1) tab_kernel -> uber_prep tail
//      (independent; tabC/tabS region disjoint from uber outputs);
//      (2) up1 + attn_dual merged (z=0/1 attn r/t, z=2 up1 512-of-1024 blocks,
//      whole-block early exit; 29.2KB LDS union; manual 512-chunk swizzle).
//      15 -> 13 dispatches.

#define NROW 4096
#define NOUT 2097152

typedef __attribute__((ext_vector_type(8))) short short8;
typedef __attribute__((ext_vector_type(4))) float floatx4;

__device__ __forceinline__ unsigned short f2bf(float f) {
    union { float f; unsigned u; } v; v.f = f;
    return (unsigned short)((v.u + 0x7fffu + ((v.u >> 16) & 1u)) >> 16);
}
__device__ __forceinline__ float bf2f(unsigned short h) {
    union { unsigned u; float f; } v; v.u = ((unsigned)h) << 16;
    return v.f;
}

__device__ __forceinline__ void gload16(const unsigned short* g, unsigned short* l) {
    __builtin_amdgcn_global_load_lds((const __attribute__((address_space(1))) void*)g,
                                     (__attribute__((address_space(3))) void*)l, 16, 0, 0);
}

// XCD-chunked swizzle (T1): requires nwg % 8 == 0.
__device__ __forceinline__ void xcd_swizzle(int& bx, int& by, int& bz) {
    const int gx = gridDim.x, gy = gridDim.y;
    const int nwg = gx * gy * gridDim.z;
    int b = (bz * gy + by) * gx + bx;
    const int chunk = nwg >> 3;
    const int lb = (b & 7) * chunk + (b >> 3);
    bx = lb % gx;
    const int rem = lb / gx;
    by = rem % gy;
    bz = rem / gy;
}

// Wa (z=0) and Wm (z=1) in one dispatch; both emit bf16 hi/lo directly.
__global__ __launch_bounds__(256) void wawm_kernel(const float* __restrict__ l1_re, const float* __restrict__ l1_im,
                                                   const float* __restrict__ lc_w,
                                                   const float* __restrict__ tabC, const float* __restrict__ tabS,
                                                   unsigned short* __restrict__ WaH, unsigned short* __restrict__ WaL,
                                                   unsigned short* __restrict__ WmH, unsigned short* __restrict__ WmL)
{
    __shared__ float lw[512];
    const float inv = 0.04419417382415922f;  // 1/sqrt(512)
    if (blockIdx.z == 0) {
        int n  = blockIdx.x;
        int ep = blockIdx.y * 256 + threadIdx.x;
        float acc = 0.f;
        if (ep < 256) {
            for (int k = 0; k < 128; ++k) {
                float c = tabC[n * 256 + k], s = tabS[n * 256 + k];
                acc += c * l1_re[k * 256 + ep] + s * l1_im[k * 256 + ep];
            }
        } else {
            int e = ep - 256;
            for (int k = 0; k < 128; ++k) {
                float c = tabC[n * 256 + k], s = tabS[n * 256 + k];
                acc += c * l1_im[k * 256 + e] - s * l1_re[k * 256 + e];
            }
        }
        float v = acc * inv;
        size_t idx = (size_t)ep * 512 + n;
        unsigned short h = f2bf(v);
        WaH[idx] = h;
        WaL[idx] = f2bf(v - bf2f(h));
    } else {
        int s  = blockIdx.x;
        int kk = blockIdx.y * 256 + threadIdx.x;
        for (int i = threadIdx.x; i < 512; i += 256) lw[i] = lc_w[s * 512 + i];
        __syncthreads();
        float acc = 0.f;
        if (kk < 256) {
            int k = kk;
            for (int n = 0; n < 512; ++n) acc += tabC[n * 256 + k] * lw[n];
            acc *= (k == 0) ? inv : 2.f * inv;
        } else {
            int k = kk - 256;
            if (k == 0) acc = 0.f;
            else {
                for (int n = 0; n < 512; ++n) acc += tabS[n * 256 + k] * lw[n];
                acc *= -2.f * inv;
            }
        }
        size_t idx = (size_t)s * 512 + kk;
        unsigned short h = f2bf(acc);
        WmH[idx] = h;
        WmL[idx] = f2bf(acc - bf2f(h));
    }
}

// ---------------- uber elementwise prep: wcvt(+rinLo) | xsplit | lbpack | tab ------------
// blocks [0,26624): weight cvt; [26624,34816): xsplit; [34816,34818): lbpack;
// [34818,35330): cos/sin table (folded tab_kernel, independent of the rest).
__global__ __launch_bounds__(256) void uber_prep_kernel(
    const float* s0, const float* s1, const float* s2, const float* s3, const float* s4,
    const float* s5, const float* s6, const float* s7, const float* s8, const float* s9,
    unsigned short* __restrict__ o, unsigned short* __restrict__ rinLo,
    const float* __restrict__ x, unsigned short* __restrict__ xhi,
    unsigned short* __restrict__ xlo, float* __restrict__ xcp,
    const float* __restrict__ lbre, const float* __restrict__ lbim, float* __restrict__ lbout,
    float* __restrict__ tabC, float* __restrict__ tabS)
{
    const int bid = blockIdx.x, tid = threadIdx.x;
    if (bid < 26624) {
        int i = bid * 256 + tid;  // exactly covers 6815744
        const float* s; int off;
        if (i < 3145728) {
            if (i < 1048576) { if (i < 786432) { s = s0; off = 0; } else { s = s1; off = 786432; } }
            else             { if (i < 2097152) { s = s2; off = 1048576; } else { s = s3; off = 2097152; } }
        } else {
            if (i < 5242880) {
                if (i < 3932160) { s = s4; off = 3145728; }
                else if (i < 4194304) { s = s5; off = 3932160; }
                else { s = s6; off = 4194304; }
            } else {
                if (i < 6291456) { s = s7; off = 5242880; }
                else if (i < 6553600) { s = s8; off = 6291456; }
                else { s = s9; off = 6553600; }
            }
        }
        float v = s[i - off];
        unsigned short h = f2bf(v);
        o[i] = h;
        if (i >= 3145728 && i < 3932160) rinLo[i - 3145728] = f2bf(v - bf2f(h));
    } else if (bid < 34816) {
        int i = (bid - 26624) * 256 + tid;  // exactly covers 2097152
        float v = x[i];
        unsigned short h = f2bf(v);
        xhi[i] = h;
        xlo[i] = f2bf(v - bf2f(h));
        xcp[i] = v;
    } else if (bid < 34818) {
        int i = (bid - 34816) * 256 + tid;
        if (i < 512) lbout[i] = (i < 256) ? lbre[i] : lbim[i - 256];
    } else {
        int n = bid - 34818;                 // 0..511
        int k = tid;                         // 0..255
        int m = (n * k) & 511;
        float th = (float)m * 0.01227184630308513f;  // 2*pi/512
        float sv, cv; sincosf(th, &sv, &cv);
        tabC[n * 256 + k] = cv;
        tabS[n * 256 + k] = sv;
    }
}

// ---------------- dual-branch GEMM (BK=64): z=0/1 select. For lin1/lin2. ----------------
template <int TM, int TN, int ACT, int WBF>
__global__ __launch_bounds__(256) void gemm_dual(
    const unsigned short* __restrict__ A0, const unsigned short* __restrict__ A1,
    const unsigned short* __restrict__ W0, const unsigned short* __restrict__ W1,
    const float* __restrict__ b0, const float* __restrict__ b1,
    float* __restrict__ C0, float* __restrict__ C1,
    unsigned short* __restrict__ D0, unsigned short* __restrict__ D1, int N, int K)
{
    constexpr int MI = TM / 32, NJ = TN / 32;
    constexpr int ARW = TM / 4, BRW = TN / 4;
    __shared__ unsigned short As[2][TM * 32];
    __shared__ unsigned short Bs[2][TN * 32];
    const int tid = threadIdx.x;
    const int wave = tid >> 6, lane = tid & 63;
    int bx = blockIdx.x, by = blockIdx.y, bz = blockIdx.z;
    xcd_swizzle(bx, by, bz);
    const int m0 = by * TM, n0 = bx * TN;
    const int z = bz;
    const unsigned short* A = z ? A1 : A0;
    const unsigned short* W = z ? W1 : W0;
    const float* bias = z ? b1 : b0;
    float* Cf = z ? C1 : C0;
    unsigned short* Cb = z ? D1 : D0;
    const int sr = lane >> 2, sc = (lane & 3) * 8;
    const unsigned short* aS = A + (size_t)(m0 + wave * ARW + sr) * K + sc;
    const unsigned short* wS = W + (size_t)(n0 + wave * BRW + sr) * K + sc;
    const int wm = (wave >> 1) * (TM / 2), wn = (wave & 1) * (TN / 2);
    const int fr = lane & 15, fko = (lane >> 4) * 8;

    floatx4 acc[MI][NJ];
#pragma unroll
    for (int i = 0; i < MI; ++i)
#pragma unroll
        for (int j = 0; j < NJ; ++j) acc[i][j] = (floatx4){0.f, 0.f, 0.f, 0.f};

    for (int k0 = 0; k0 < K; k0 += 64) {
#pragma unroll
        for (int h = 0; h < 2; ++h) {
#pragma unroll
            for (int c = 0; c < ARW / 16; ++c)
                gload16(aS + (size_t)(16 * c) * K + k0 + 32 * h, &As[h][(wave * ARW + 16 * c) * 32]);
#pragma unroll
            for (int c = 0; c < BRW / 16; ++c)
                gload16(wS + (size_t)(16 * c) * K + k0 + 32 * h, &Bs[h][(wave * BRW + 16 * c) * 32]);
        }
        __syncthreads();
#pragma unroll
        for (int h = 0; h < 2; ++h) {
            short8 af[MI], bfr[NJ];
#pragma unroll
            for (int i = 0; i < MI; ++i) af[i] = *(const short8*)&As[h][(wm + i * 16 + fr) * 32 + fko];
#pragma unroll
            for (int j = 0; j < NJ; ++j) bfr[j] = *(const short8*)&Bs[h][(wn + j * 16 + fr) * 32 + fko];
#pragma unroll
            for (int i = 0; i < MI; ++i)
#pragma unroll
                for (int j = 0; j < NJ; ++j)
                    acc[i][j] = __builtin_amdgcn_mfma_f32_16x16x32_bf16(af[i], bfr[j], acc[i][j], 0, 0, 0);
        }
        __syncthreads();
    }
    const int r0 = m0 + wm + (lane >> 4) * 4;
#pragma unroll
    for (int i = 0; i < MI; ++i) {
#pragma unroll
        for (int j = 0; j < NJ; ++j) {
            int n = n0 + wn + j * 16 + fr;
            float bv = bias[n];
#pragma unroll
            for (int r = 0; r < 4; ++r) {
                int m = r0 + i * 16 + r;
                size_t idx = (size_t)m * N + n;
                float v = acc[i][j][r] + bv;
                if (ACT) v = fmaxf(v, 0.f);
                if (WBF) Cb[idx] = f2bf(v);
                else     Cf[idx] = v;
            }
        }
    }
}

// ---------------- tri-branch single-product GEMM (BK=64, TN=64): out-proj r/t + up2 ------
template <int TM, int TN>
__global__ __launch_bounds__(256) void gemm_out_tri(
    const unsigned short* __restrict__ A0, const unsigned short* __restrict__ W0,
    const float* __restrict__ b0, float* __restrict__ C0,
    const unsigned short* __restrict__ A1, const unsigned short* __restrict__ W1,
    const float* __restrict__ b1, float* __restrict__ C1,
    const unsigned short* __restrict__ A2, const unsigned short* __restrict__ W2,
    const float* __restrict__ b2, float* __restrict__ C2, int N, int K)
{
    constexpr int MI = TM / 32, NJ = TN / 32;
    constexpr int ARW = TM / 4, BRW = TN / 4;
    __shared__ unsigned short As[2][TM * 32];
    __shared__ unsigned short Bs[2][TN * 32];
    const int tid = threadIdx.x;
    const int wave = tid >> 6, lane = tid & 63;
    int bx = blockIdx.x, by = blockIdx.y, bz = blockIdx.z;
    xcd_swizzle(bx, by, bz);
    const int m0 = by * TM, n0 = bx * TN;
    const unsigned short* A = (bz == 0) ? A0 : (bz == 1) ? A1 : A2;
    const unsigned short* W = (bz == 0) ? W0 : (bz == 1) ? W1 : W2;
    const float* bias       = (bz == 0) ? b0 : (bz == 1) ? b1 : b2;
    float* Cf               = (bz == 0) ? C0 : (bz == 1) ? C1 : C2;
    const int sr = lane >> 2, sc = (lane & 3) * 8;
    const unsigned short* aS = A + (size_t)(m0 + wave * ARW + sr) * K + sc;
    const unsigned short* wS = W + (size_t)(n0 + wave * BRW + sr) * K + sc;
    const int wm = (wave >> 1) * (TM / 2), wn = (wave & 1) * (TN / 2);
    const int fr = lane & 15, fko = (lane >> 4) * 8;

    floatx4 acc[MI][NJ];
#pragma unroll
    for (int i = 0; i < MI; ++i)
#pragma unroll
        for (int j = 0; j < NJ; ++j) acc[i][j] = (floatx4){0.f, 0.f, 0.f, 0.f};

    for (int k0 = 0; k0 < K; k0 += 64) {
#pragma unroll
        for (int h = 0; h < 2; ++h) {
#pragma unroll
            for (int c = 0; c < ARW / 16; ++c)
                gload16(aS + (size_t)(16 * c) * K + k0 + 32 * h, &As[h][(wave * ARW + 16 * c) * 32]);
#pragma unroll
            for (int c = 0; c < BRW / 16; ++c)
                gload16(wS + (size_t)(16 * c) * K + k0 + 32 * h, &Bs[h][(wave * BRW + 16 * c) * 32]);
        }
        __syncthreads();
#pragma unroll
        for (int h = 0; h < 2; ++h) {
            short8 af[MI], bfr[NJ];
#pragma unroll
            for (int i = 0; i < MI; ++i) af[i] = *(const short8*)&As[h][(wm + i * 16 + fr) * 32 + fko];
#pragma unroll
            for (int j = 0; j < NJ; ++j) bfr[j] = *(const short8*)&Bs[h][(wn + j * 16 + fr) * 32 + fko];
#pragma unroll
            for (int i = 0; i < MI; ++i)
#pragma unroll
                for (int j = 0; j < NJ; ++j)
                    acc[i][j] = __builtin_amdgcn_mfma_f32_16x16x32_bf16(af[i], bfr[j], acc[i][j], 0, 0, 0);
        }
        __syncthreads();
    }
    const int r0 = m0 + wm + (lane >> 4) * 4;
#pragma unroll
    for (int i = 0; i < MI; ++i) {
#pragma unroll
        for (int j = 0; j < NJ; ++j) {
            int n = n0 + wn + j * 16 + fr;
            float bv = bias[n];
#pragma unroll
            for (int r = 0; r < 4; ++r) {
                int m = r0 + i * 16 + r;
                Cf[(size_t)m * N + n] = acc[i][j][r] + bv;
            }
        }
    }
}

// ---------------- fused hi/lo 3-product MFMA GEMM (BK=64, single-buffer) ----------------
template <int TM, int TN, int ACT, int WCOPY, int WHILO>
__global__ __launch_bounds__(256) void gemm_mfma3(
    const unsigned short* __restrict__ Ah, const unsigned short* __restrict__ Al,
    const unsigned short* __restrict__ Wh, const unsigned short* __restrict__ Wl,
    const float* __restrict__ bias, float* __restrict__ Cf, float* __restrict__ Ccopy,
    unsigned short* __restrict__ Hh, unsigned short* __restrict__ Hl, int N, int K)
{
    constexpr int MI = TM / 32, NJ = TN / 32;
    constexpr int ARW = TM / 4, BRW = TN / 4;
    __shared__ unsigned short Ash[2][TM * 32];
    __shared__ unsigned short Asl[2][TM * 32];
    __shared__ unsigned short Bsh[2][TN * 32];
    __shared__ unsigned short Bsl[2][TN * 32];
    const int tid = threadIdx.x;
    const int wave = tid >> 6, lane = tid & 63;
    int bx = blockIdx.x, by = blockIdx.y, bz = blockIdx.z;
    xcd_swizzle(bx, by, bz);
    const int m0 = by * TM, n0 = bx * TN;
    const int sr = lane >> 2, sc = (lane & 3) * 8;
    const size_t aoff = (size_t)(m0 + wave * ARW + sr) * K + sc;
    const size_t woff = (size_t)(n0 + wave * BRW + sr) * K + sc;
    const int wm = (wave >> 1) * (TM / 2), wn = (wave & 1) * (TN / 2);
    const int fr = lane & 15, fko = (lane >> 4) * 8;

    floatx4 acc[MI][NJ];
#pragma unroll
    for (int i = 0; i < MI; ++i)
#pragma unroll
        for (int j = 0; j < NJ; ++j) acc[i][j] = (floatx4){0.f, 0.f, 0.f, 0.f};

    for (int k0 = 0; k0 < K; k0 += 64) {
#pragma unroll
        for (int h = 0; h < 2; ++h) {
#pragma unroll
            for (int c = 0; c < ARW / 16; ++c) {
                gload16(Ah + aoff + (size_t)(16 * c) * K + k0 + 32 * h, &Ash[h][(wave * ARW + 16 * c) * 32]);
                gload16(Al + aoff + (size_t)(16 * c) * K + k0 + 32 * h, &Asl[h][(wave * ARW + 16 * c) * 32]);
            }
#pragma unroll
            for (int c = 0; c < BRW / 16; ++c) {
                gload16(Wh + woff + (size_t)(16 * c) * K + k0 + 32 * h, &Bsh[h][(wave * BRW + 16 * c) * 32]);
                gload16(Wl + woff + (size_t)(16 * c) * K + k0 + 32 * h, &Bsl[h][(wave * BRW + 16 * c) * 32]);
            }
        }
        __syncthreads();
#pragma unroll
        for (int h = 0; h < 2; ++h) {
            short8 ah[MI], al[MI], bh[NJ], bl[NJ];
#pragma unroll
            for (int i = 0; i < MI; ++i) {
                ah[i] = *(const short8*)&Ash[h][(wm + i * 16 + fr) * 32 + fko];
                al[i] = *(const short8*)&Asl[h][(wm + i * 16 + fr) * 32 + fko];
            }
#pragma unroll
            for (int j = 0; j < NJ; ++j) {
                bh[j] = *(const short8*)&Bsh[h][(wn + j * 16 + fr) * 32 + fko];
                bl[j] = *(const short8*)&Bsl[h][(wn + j * 16 + fr) * 32 + fko];
            }
#pragma unroll
            for (int i = 0; i < MI; ++i)
#pragma unroll
                for (int j = 0; j < NJ; ++j) {
                    acc[i][j] = __builtin_amdgcn_mfma_f32_16x16x32_bf16(al[i], bh[j], acc[i][j], 0, 0, 0);
                    acc[i][j] = __builtin_amdgcn_mfma_f32_16x16x32_bf16(ah[i], bl[j], acc[i][j], 0, 0, 0);
                    acc[i][j] = __builtin_amdgcn_mfma_f32_16x16x32_bf16(ah[i], bh[j], acc[i][j], 0, 0, 0);
                }
        }
        __syncthreads();
    }
    const int r0 = m0 + wm + (lane >> 4) * 4;
#pragma unroll
    for (int i = 0; i < MI; ++i) {
#pragma unroll
        for (int j = 0; j < NJ; ++j) {
            int n = n0 + wn + j * 16 + fr;
            float bv = bias[n];
#pragma unroll
            for (int r = 0; r < 4; ++r) {
                int m = r0 + i * 16 + r;
                size_t idx = (size_t)m * N + n;
                float v = acc[i][j][r] + bv;
                if (ACT) v = fmaxf(v, 0.f);
                Cf[idx] = v;
                if (WCOPY) Ccopy[idx] = v;
                if (WHILO) {
                    unsigned short h = f2bf(v);
                    Hh[idx] = h;
                    Hl[idx] = f2bf(v - bf2f(h));
                }
            }
        }
    }
}

// ---------------- merged qkv GEMM (BK=64): z=0 r-qkv 3-product (f32),
//                  z=1 t-qkv single (bf16). R15 proven form. ----------------------------
template <int TM, int TN>
__global__ __launch_bounds__(256) void gemm_qkv_dual(
    const unsigned short* __restrict__ Ah0, const unsigned short* __restrict__ Al0,
    const unsigned short* __restrict__ Wh0, const unsigned short* __restrict__ Wl0,
    const float* __restrict__ b0, float* __restrict__ C0,
    const unsigned short* __restrict__ A1, const unsigned short* __restrict__ W1,
    const float* __restrict__ b1, unsigned short* __restrict__ C1,
    int N, int K)
{
    constexpr int MI = TM / 32, NJ = TN / 32;
    constexpr int ARW = TM / 4, BRW = TN / 4;
    __shared__ unsigned short Ash[2][TM * 32];
    __shared__ unsigned short Asl[2][TM * 32];
    __shared__ unsigned short Bsh[2][TN * 32];
    __shared__ unsigned short Bsl[2][TN * 32];
    const int tid = threadIdx.x;
    const int wave = tid >> 6, lane = tid & 63;
    int bx = blockIdx.x, by = blockIdx.y, bz = blockIdx.z;
    xcd_swizzle(bx, by, bz);
    const int m0 = by * TM, n0 = bx * TN;
    const int sr = lane >> 2, sc = (lane & 3) * 8;
    const size_t aoff = (size_t)(m0 + wave * ARW + sr) * K + sc;
    const size_t woff = (size_t)(n0 + wave * BRW + sr) * K + sc;
    const int wm = (wave >> 1) * (TM / 2), wn = (wave & 1) * (TN / 2);
    const int fr = lane & 15, fko = (lane >> 4) * 8;

    floatx4 acc[MI][NJ];
#pragma unroll
    for (int i = 0; i < MI; ++i)
#pragma unroll
        for (int j = 0; j < NJ; ++j) acc[i][j] = (floatx4){0.f, 0.f, 0.f, 0.f};

    const int r0 = m0 + wm + (lane >> 4) * 4;

    if (bz == 0) {
        for (int k0 = 0; k0 < K; k0 += 64) {
#pragma unroll
            for (int h = 0; h < 2; ++h) {
#pragma unroll
                for (int c = 0; c < ARW / 16; ++c) {
                    gload16(Ah0 + aoff + (size_t)(16 * c) * K + k0 + 32 * h, &Ash[h][(wave * ARW + 16 * c) * 32]);
                    gload16(Al0 + aoff + (size_t)(16 * c) * K + k0 + 32 * h, &Asl[h][(wave * ARW + 16 * c) * 32]);
                }
#pragma unroll
                for (int c = 0; c < BRW / 16; ++c) {
                    gload16(Wh0 + woff + (size_t)(16 * c) * K + k0 + 32 * h, &Bsh[h][(wave * BRW + 16 * c) * 32]);
                    gload16(Wl0 + woff + (size_t)(16 * c) * K + k0 + 32 * h, &Bsl[h][(wave * BRW + 16 * c) * 32]);
                }
            }
            __syncthreads();
#pragma unroll
            for (int h = 0; h < 2; ++h) {
                short8 ah[MI], al[MI], bh[NJ], bl[NJ];
#pragma unroll
                for (int i = 0; i < MI; ++i) {
                    ah[i] = *(const short8*)&Ash[h][(wm + i * 16 + fr) * 32 + fko];
                    al[i] = *(const short8*)&Asl[h][(wm + i * 16 + fr) * 32 + fko];
                }
#pragma unroll
                for (int j = 0; j < NJ; ++j) {
                    bh[j] = *(const short8*)&Bsh[h][(wn + j * 16 + fr) * 32 + fko];
                    bl[j] = *(const short8*)&Bsl[h][(wn + j * 16 + fr) * 32 + fko];
                }
#pragma unroll
                for (int i = 0; i < MI; ++i)
#pragma unroll
                    for (int j = 0; j < NJ; ++j) {
                        acc[i][j] = __builtin_amdgcn_mfma_f32_16x16x32_bf16(al[i], bh[j], acc[i][j], 0, 0, 0);
                        acc[i][j] = __builtin_amdgcn_mfma_f32_16x16x32_bf16(ah[i], bl[j], acc[i][j], 0, 0, 0);
                        acc[i][j] = __builtin_amdgcn_mfma_f32_16x16x32_bf16(ah[i], bh[j], acc[i][j], 0, 0, 0);
                    }
            }
            __syncthreads();
        }
#pragma unroll
        for (int i = 0; i < MI; ++i)
#pragma unroll
            for (int j = 0; j < NJ; ++j) {
                int n = n0 + wn + j * 16 + fr;
                float bv = b0[n];
#pragma unroll
                for (int r = 0; r < 4; ++r) {
                    int m = r0 + i * 16 + r;
                    C0[(size_t)m * N + n] = acc[i][j][r] + bv;
                }
            }
    } else {
        for (int k0 = 0; k0 < K; k0 += 64) {
#pragma unroll
            for (int h = 0; h < 2; ++h) {
#pragma unroll
                for (int c = 0; c < ARW / 16; ++c)
                    gload16(A1 + aoff + (size_t)(16 * c) * K + k0 + 32 * h, &Ash[h][(wave * ARW + 16 * c) * 32]);
#pragma unroll
                for (int c = 0; c < BRW / 16; ++c)
                    gload16(W1 + woff + (size_t)(16 * c) * K + k0 + 32 * h, &Bsh[h][(wave * BRW + 16 * c) * 32]);
            }
            __syncthreads();
#pragma unroll
            for (int h = 0; h < 2; ++h) {
                short8 af[MI], bfr[NJ];
#pragma unroll
                for (int i = 0; i < MI; ++i) af[i] = *(const short8*)&Ash[h][(wm + i * 16 + fr) * 32 + fko];
#pragma unroll
                for (int j = 0; j < NJ; ++j) bfr[j] = *(const short8*)&Bsh[h][(wn + j * 16 + fr) * 32 + fko];
#pragma unroll
                for (int i = 0; i < MI; ++i)
#pragma unroll
                    for (int j = 0; j < NJ; ++j)
                        acc[i][j] = __builtin_amdgcn_mfma_f32_16x16x32_bf16(af[i], bfr[j], acc[i][j], 0, 0, 0);
            }
            __syncthreads();
        }
#pragma unroll
        for (int i = 0; i < MI; ++i)
#pragma unroll
            for (int j = 0; j < NJ; ++j) {
                int n = n0 + wn + j * 16 + fr;
                float bv = b1[n];
#pragma unroll
                for (int r = 0; r < 4; ++r) {
                    int m = r0 + i * 16 + r;
                    C1[(size_t)m * N + n] = f2bf(acc[i][j][r] + bv);
                }
            }
    }
}

// ---------------- merged attention + up1: z=0 attn-r (f32 qkv), z=1 attn-t (bf16 qkv),
//                  z=2 up1 GEMM (512 of 1024 blocks; whole-block early exit). ------------
__global__ __launch_bounds__(256) void attn_up1_kernel(
    const float* __restrict__ qkvF, const unsigned short* __restrict__ qkvB,
    unsigned short* __restrict__ outR, unsigned short* __restrict__ outT,
    const unsigned short* __restrict__ A2, const unsigned short* __restrict__ W2,
    const float* __restrict__ b2, unsigned short* __restrict__ C2)
{
    __shared__ __align__(16) char smem[29184];
    const int tid = threadIdx.x;
    if (blockIdx.z < 2) {
        // ---- attention branch (29184 B LDS) ----
        float (*qs)[65] = (float(*)[65])smem;
        float (*ks)[65] = (float(*)[65])(smem + 8320);
        float (*vs)[65] = (float(*)[65])(smem + 16640);
        float (*ps)[33] = (float(*)[33])(smem + 24960);
        const int isT = blockIdx.z;
        const int b = blockIdx.x >> 3;
        const int h = blockIdx.x & 7;
        if (isT) {
            for (int i = tid; i < 2048; i += 256) {
                int s = i >> 6, d = i & 63;
                size_t base = ((size_t)(b * 32 + s)) * 1536 + h * 64 + d;
                qs[s][d] = bf2f(qkvB[base]);
                ks[s][d] = bf2f(qkvB[base + 512]);
                vs[s][d] = bf2f(qkvB[base + 1024]);
            }
        } else {
            for (int i = tid; i < 2048; i += 256) {
                int s = i >> 6, d = i & 63;
                size_t base = ((size_t)(b * 32 + s)) * 1536 + h * 64 + d;
                qs[s][d] = qkvF[base];
                ks[s][d] = qkvF[base + 512];
                vs[s][d] = qkvF[base + 1024];
            }
        }
        __syncthreads();
        for (int i = tid; i < 1024; i += 256) {
            int si = i >> 5, sj = i & 31;
            float acc = 0.f;
#pragma unroll 8
            for (int d = 0; d < 64; ++d) acc += qs[si][d] * ks[sj][d];
            ps[si][sj] = acc * 0.125f;
        }
        __syncthreads();
        if (tid < 32) {
            float mx = -1e30f;
            for (int j = 0; j < 32; ++j) mx = fmaxf(mx, ps[tid][j]);
            float sum = 0.f;
            for (int j = 0; j < 32; ++j) { float e = __expf(ps[tid][j] - mx); ps[tid][j] = e; sum += e; }
            float inv = 1.f / sum;
            for (int j = 0; j < 32; ++j) ps[tid][j] *= inv;
        }
        __syncthreads();
        unsigned short* ob = isT ? outT : outR;
        for (int i = tid; i < 2048; i += 256) {
            int s = i >> 6, d = i & 63;
            float acc = 0.f;
#pragma unroll 8
            for (int k = 0; k < 32; ++k) acc += ps[s][k] * vs[k][d];
            ob[((size_t)(b * 32 + s)) * 512 + h * 64 + d] = f2bf(acc);
        }
    } else {
        // ---- up1 GEMM branch: 64x64 tile, BK=64, N=K=512, 512 blocks ----
        const int b = blockIdx.x;
        if (b >= 512) return;                      // whole block exits pre-barrier
        const int lb = (b & 7) * 64 + (b >> 3);    // manual 512-chunk swizzle
        const int bxg = lb & 7, byg = lb >> 3;
        unsigned short (*As)[2048] = (unsigned short(*)[2048])smem;          // 2*4096B
        unsigned short (*Bs)[2048] = (unsigned short(*)[2048])(smem + 8192); // 2*4096B
        const int wave = tid >> 6, lane = tid & 63;
        const int m0 = byg * 64, n0 = bxg * 64;
        const int sr = lane >> 2, sc = (lane & 3) * 8;
        const unsigned short* aS = A2 + (size_t)(m0 + wave * 16 + sr) * 512 + sc;
        const unsigned short* wS = W2 + (size_t)(n0 + wave * 16 + sr) * 512 + sc;
        const int wm = (wave >> 1) * 32, wn = (wave & 1) * 32;
        const int fr = lane & 15, fko = (lane >> 4) * 8;
        floatx4 acc[2][2];
#pragma unroll
        for (int i = 0; i < 2; ++i)
#pragma unroll
            for (int j = 0; j < 2; ++j) acc[i][j] = (floatx4){0.f, 0.f, 0.f, 0.f};
        for (int k0 = 0; k0 < 512; k0 += 64) {
#pragma unroll
            for (int h = 0; h < 2; ++h) {
                gload16(aS + k0 + 32 * h, &As[h][(wave * 16) * 32]);
                gload16(wS + k0 + 32 * h, &Bs[h][(wave * 16) * 32]);
            }
            __syncthreads();
#pragma unroll
            for (int h = 0; h < 2; ++h) {
                short8 af[2], bfr[2];
#pragma unroll
                for (int i = 0; i < 2; ++i) af[i] = *(const short8*)&As[h][(wm + i * 16 + fr) * 32 + fko];
#pragma unroll
                for (int j = 0; j < 2; ++j) bfr[j] = *(const short8*)&Bs[h][(wn + j * 16 + fr) * 32 + fko];
#pragma unroll
                for (int i = 0; i < 2; ++i)
#pragma unroll
                    for (int j = 0; j < 2; ++j)
                        acc[i][j] = __builtin_amdgcn_mfma_f32_16x16x32_bf16(af[i], bfr[j], acc[i][j], 0, 0, 0);
            }
            __syncthreads();
        }
        const int r0 = m0 + wm + (lane >> 4) * 4;
#pragma unroll
        for (int i = 0; i < 2; ++i)
#pragma unroll
            for (int j = 0; j < 2; ++j) {
                int n = n0 + wn + j * 16 + fr;
                float bv = b2[n];
#pragma unroll
                for (int r = 0; r < 4; ++r) {
                    int m = r0 + i * 16 + r;
                    C2[(size_t)m * 512 + n] = f2bf(acc[i][j][r] + bv);
                }
            }
    }
}

// ---------------- complex self-attention: LDS-resident, grid (128 batch, 2 half) ----------
__global__ __launch_bounds__(512) void cattn2_kernel(const float* __restrict__ LL,
                                                     unsigned short* __restrict__ outHi,
                                                     unsigned short* __restrict__ outLo)
{
    extern __shared__ float Xs[];
    __shared__ float Pr[16][33], Pi[16][33];
    const int b = blockIdx.x, half = blockIdx.y;
    const int tid = threadIdx.x;
    const float* base = LL + (size_t)b * 16384;
    for (int i = tid; i < 16384; i += 512) {
        int c = i >> 9, e = i & 511;
        Xs[e * 32 + ((c ^ e) & 31)] = base[i];
    }
    __syncthreads();
    {
        const int li = tid >> 5;                 // 0..15
        const int ci = half * 16 + li;
        const int ck = tid & 31;
        float ar = 0.f, ai = 0.f;
#pragma unroll 4
        for (int er = 0; er < 256; ++er) {
            const int sw = er & 31;
            float yr = Xs[er * 32 + ((ck ^ sw) & 31)];
            float yi = Xs[(er + 256) * 32 + ((ck ^ sw) & 31)];
            float xr = Xs[er * 32 + ((ci ^ sw) & 31)];
            float xi = Xs[(er + 256) * 32 + ((ci ^ sw) & 31)];
            ar += xr * yr - xi * yi;
            ai += xr * yi + xi * yr;
        }
        Pr[li][ck] = ar * 0.0625f;
        Pi[li][ck] = ai * 0.0625f;
    }
    __syncthreads();
    if (tid < 32) {
        int r = tid & 15;
        float (*P)[33] = (tid < 16) ? Pr : Pi;
        float mx = -1e30f;
        for (int j = 0; j < 32; ++j) mx = fmaxf(mx, P[r][j]);
        float s = 0.f;
        for (int j = 0; j < 32; ++j) { float e = __expf(P[r][j] - mx); P[r][j] = e; s += e; }
        float inv = 1.f / s;
        for (int j = 0; j < 32; ++j) P[r][j] *= inv;
    }
    __syncthreads();
    const int er = tid & 255;
    const int th = tid >> 8;                     // 0 or 1: t in [th*8, th*8+8)
    const int sw = er & 31;
    float accr[8], acci[8];
#pragma unroll
    for (int t = 0; t < 8; ++t) { accr[t] = 0.f; acci[t] = 0.f; }
    for (int k = 0; k < 32; ++k) {
        float yr = Xs[er * 32 + ((k ^ sw) & 31)];
        float yi = Xs[(er + 256) * 32 + ((k ^ sw) & 31)];
#pragma unroll
        for (int t = 0; t < 8; ++t) {
            float pr = Pr[th * 8 + t][k], pi = Pi[th * 8 + t][k];
            accr[t] += pr * yr - pi * yi;
            acci[t] += pr * yi + pi * yr;
        }
    }
#pragma unroll
    for (int t = 0; t < 8; ++t) {
        int c = half * 16 + th * 8 + t;
        float vr = Xs[er * 32 + ((c ^ sw) & 31)] + accr[t];
        float vi = Xs[(er + 256) * 32 + ((c ^ sw) & 31)] + acci[t];
        size_t ir = (size_t)b * 16384 + (size_t)c * 512 + er;
        unsigned short hr = f2bf(vr), hi2 = f2bf(vi);
        outHi[ir] = hr;        outLo[ir] = f2bf(vr - bf2f(hr));
        outHi[ir + 256] = hi2; outLo[ir + 256] = f2bf(vi - bf2f(hi2));
    }
}

// ---------------- DUAL add+LN (512), f32 resid, out bf16 hi/lo; rows>=4096 = branch 1 ----
__global__ __launch_bounds__(256) void add_ln_d1(
    const float* __restrict__ r0, const float* __restrict__ y0,
    const float* __restrict__ w0, const float* __restrict__ b0,
    unsigned short* __restrict__ h0, unsigned short* __restrict__ l0,
    const float* __restrict__ r1, const float* __restrict__ y1,
    const float* __restrict__ w1, const float* __restrict__ b1,
    unsigned short* __restrict__ h1, unsigned short* __restrict__ l1)
{
    const int row = blockIdx.x;
    const int br = row >> 12;
    const int rl = row & 4095;
    const float* resid = br ? r1 : r0;
    const float* y     = br ? y1 : y0;
    const float* w     = br ? w1 : w0;
    const float* bb    = br ? b1 : b0;
    unsigned short* oh = br ? h1 : h0;
    unsigned short* ol = br ? l1 : l0;
    const int tid = threadIdx.x;
    const size_t base = (size_t)rl * 512;
    float v0 = resid[base + tid] + y[base + tid];
    float v1 = resid[base + 256 + tid] + y[base + 256 + tid];
    float s = v0 + v1, q = v0 * v0 + v1 * v1;
    for (int off = 32; off; off >>= 1) { s += __shfl_down(s, off); q += __shfl_down(q, off); }
    __shared__ float sw[4], qw[4], ms, is;
    int wid = tid >> 6, lane = tid & 63;
    if (lane == 0) { sw[wid] = s; qw[wid] = q; }
    __syncthreads();
    if (tid == 0) {
        float S = sw[0] + sw[1] + sw[2] + sw[3];
        float Q = qw[0] + qw[1] + qw[2] + qw[3];
        float m = S * (1.f / 512.f);
        ms = m;
        is = rsqrtf(Q * (1.f / 512.f) - m * m + 1e-5f);
    }
    __syncthreads();
    float m = ms, inv = is;
    float o0 = (v0 - m) * inv * w[tid] + bb[tid];
    float o1 = (v1 - m) * inv * w[256 + tid] + bb[256 + tid];
    unsigned short e0 = f2bf(o0), e1 = f2bf(o1);
    oh[base + tid] = e0;       ol[base + tid] = f2bf(o0 - bf2f(e0));
    oh[base + 256 + tid] = e1; ol[base + 256 + tid] = f2bf(o1 - bf2f(e1));
}

// ---------------- DUAL add+LN (512), bf16 hi/lo resid, out f32 --------------------------
__global__ __launch_bounds__(256) void add_ln_d2(
    const unsigned short* __restrict__ rh0, const unsigned short* __restrict__ rl0,
    const float* __restrict__ y0, const float* __restrict__ w0, const float* __restrict__ b0,
    float* __restrict__ o0p,
    const unsigned short* __restrict__ rh1, const unsigned short* __restrict__ rl1,
    const float* __restrict__ y1, const float* __restrict__ w1, const float* __restrict__ b1,
    float* __restrict__ o1p)
{
    const int row = blockIdx.x;
    const int br = row >> 12;
    const int rl = row & 4095;
    const unsigned short* rh = br ? rh1 : rh0;
    const unsigned short* rlo = br ? rl1 : rl0;
    const float* y  = br ? y1 : y0;
    const float* w  = br ? w1 : w0;
    const float* bb = br ? b1 : b0;
    float* op = br ? o1p : o0p;
    const int tid = threadIdx.x;
    const size_t base = (size_t)rl * 512;
    float v0 = bf2f(rh[base + tid]) + bf2f(rlo[base + tid]) + y[base + tid];
    float v1 = bf2f(rh[base + 256 + tid]) + bf2f(rlo[base + 256 + tid]) + y[base + 256 + tid];
    float s = v0 + v1, q = v0 * v0 + v1 * v1;
    for (int off = 32; off; off >>= 1) { s += __shfl_down(s, off); q += __shfl_down(q, off); }
    __shared__ float sw[4], qw[4], ms, is;
    int wid = tid >> 6, lane = tid & 63;
    if (lane == 0) { sw[wid] = s; qw[wid] = q; }
    __syncthreads();
    if (tid == 0) {
        float S = sw[0] + sw[1] + sw[2] + sw[3];
        float Q = qw[0] + qw[1] + qw[2] + qw[3];
        float m = S * (1.f / 512.f);
        ms = m;
        is = rsqrtf(Q * (1.f / 512.f) - m * m + 1e-5f);
    }
    __syncthreads();
    float m = ms, inv = is;
    op[base + tid]       = (v0 - m) * inv * w[tid] + bb[tid];
    op[base + 256 + tid] = (v1 - m) * inv * w[256 + tid] + bb[256 + tid];
}

// ---------------- fused relu+batchLN x2: rf = LN(relu(x2R)) kept in LDS,
//                  res = LN(relu(x2T)) + rf. One block per batch, 1024 threads. ----------
__global__ __launch_bounds__(1024) void relu_bln_fused(
    const float* __restrict__ xR, const float* __restrict__ w2, const float* __restrict__ b2,
    const float* __restrict__ xT, const float* __restrict__ w1, const float* __restrict__ b1,
    float* __restrict__ out)
{
    __shared__ float rfs[16384];
    __shared__ float sw_[16], qw_[16], ms_, is_;
    const int bb = blockIdx.x, tid = threadIdx.x;
    const int wid = tid >> 6, lane = tid & 63;
    const float* xr = xR + (size_t)bb * 16384;
    float s = 0.f, q = 0.f;
    for (int i = tid; i < 16384; i += 1024) { float v = fmaxf(xr[i], 0.f); s += v; q += v * v; }
    for (int off = 32; off; off >>= 1) { s += __shfl_down(s, off); q += __shfl_down(q, off); }
    if (lane == 0) { sw_[wid] = s; qw_[wid] = q; }
    __syncthreads();
    if (tid == 0) {
        float S = 0.f, Q = 0.f;
        for (int i = 0; i < 16; ++i) { S += sw_[i]; Q += qw_[i]; }
        float m = S * (1.f / 16384.f);
        ms_ = m;
        is_ = rsqrtf(Q * (1.f / 16384.f) - m * m + 1e-5f);
    }
    __syncthreads();
    float m = ms_, inv = is_;
    for (int i = tid; i < 16384; i += 1024) {
        float v = fmaxf(xr[i], 0.f);
        rfs[i] = (v - m) * inv * w2[i] + b2[i];
    }
    const float* xt = xT + (size_t)bb * 16384;
    s = 0.f; q = 0.f;
    for (int i = tid; i < 16384; i += 1024) { float v = fmaxf(xt[i], 0.f); s += v; q += v * v; }
    for (int off = 32; off; off >>= 1) { s += __shfl_down(s, off); q += __shfl_down(q, off); }
    if (lane == 0) { sw_[wid] = s; qw_[wid] = q; }
    __syncthreads();
    if (tid == 0) {
        float S = 0.f, Q = 0.f;
        for (int i = 0; i < 16; ++i) { S += sw_[i]; Q += qw_[i]; }
        float m2 = S * (1.f / 16384.f);
        ms_ = m2;
        is_ = rsqrtf(Q * (1.f / 16384.f) - m2 * m2 + 1e-5f);
    }
    __syncthreads();
    m = ms_; inv = is_;
    float* op = out + (size_t)bb * 16384;
    for (int i = tid; i < 16384; i += 1024) {
        float v = fmaxf(xt[i], 0.f);
        op[i] = (v - m) * inv * w1[i] + b1[i] + rfs[i];
    }
}

extern "C" void kernel_launch(void* const* d_in, const int* in_sizes, int n_in,
                              void* d_out, int out_size, void* d_ws, size_t ws_size,
                              hipStream_t stream)
{
    (void)in_sizes; (void)n_in; (void)out_size; (void)ws_size;
    const float* x        = (const float*)d_in[0];
    const float* t_in_w   = (const float*)d_in[1];
    const float* t_in_b   = (const float*)d_in[2];
    const float* t_out_w  = (const float*)d_in[3];
    const float* t_out_b  = (const float*)d_in[4];
    const float* t_ln1_w  = (const float*)d_in[5];
    const float* t_ln1_b  = (const float*)d_in[6];
    const float* t_lin1_w = (const float*)d_in[7];
    const float* t_lin1_b = (const float*)d_in[8];
    const float* t_lin2_w = (const float*)d_in[9];
    const float* t_lin2_b = (const float*)d_in[10];
    const float* t_ln2_w  = (const float*)d_in[11];
    const float* t_ln2_b  = (const float*)d_in[12];
    const float* r_in_w   = (const float*)d_in[13];
    const float* r_in_b   = (const float*)d_in[14];
    const float* r_out_w  = (const float*)d_in[15];
    const float* r_out_b  = (const float*)d_in[16];
    const float* r_ln1_w  = (const float*)d_in[17];
    const float* r_ln1_b  = (const float*)d_in[18];
    const float* r_lin1_w = (const float*)d_in[19];
    const float* r_lin1_b = (const float*)d_in[20];
    const float* r_lin2_w = (const float*)d_in[21];
    const float* r_lin2_b = (const float*)d_in[22];
    const float* r_ln2_w  = (const float*)d_in[23];
    const float* r_ln2_b  = (const float*)d_in[24];
    const float* lc_w     = (const float*)d_in[25];
    const float* lc_b     = (const float*)d_in[26];
    const float* up1_w    = (const float*)d_in[27];
    const float* up1_b    = (const float*)d_in[28];
    const float* up2_w    = (const float*)d_in[29];
    const float* up2_b    = (const float*)d_in[30];
    const float* n1_w     = (const float*)d_in[31];
    const float* n1_b     = (const float*)d_in[32];
    const float* n2_w     = (const float*)d_in[33];
    const float* n2_b     = (const float*)d_in[34];
    const float* l1_re    = (const float*)d_in[35];
    const float* l1_im    = (const float*)d_in[36];
    const float* lb1_re   = (const float*)d_in[39];
    const float* lb1_im   = (const float*)d_in[40];

    float* outp = (float*)d_out;

    // ---- workspace map (float offsets; total 21,774,336 f = 87.1 MB) ----
    float* WS   = (float*)d_ws;
    float* LL   = WS;                                        // 2M f (also fa f32, later y_r)
    float* FA   = WS;
    float* yR   = WS;
    float* QR   = WS + 2097152;                              // 6.29M f
    float* tabC = QR;                                        // 131072
    float* tabS = QR + 131072;
    unsigned short* WaHu = (unsigned short*)(QR + 786432);
    unsigned short* WaLu = (unsigned short*)(QR + 917504);
    unsigned short* WmHu = (unsigned short*)(QR + 1048576);
    unsigned short* WmLu = (unsigned short*)(QR + 1179648);
    float* qkvR = QR;                                        // 6.29M f: [2097152, 8388608)
    unsigned short* x1rH = (unsigned short*)(WS + 2097152);
    unsigned short* x1rL = (unsigned short*)(WS + 3145728);
    unsigned short* x1tH = (unsigned short*)(WS + 4194304);
    unsigned short* x1tL = (unsigned short*)(WS + 5242880);
    float* yT   = WS + 6291456;                              // 2M f
    unsigned short* qkvT = (unsigned short*)(WS + 8388608);  // 6.29M ushort
    unsigned short* f1R  = (unsigned short*)(WS + 8388608);  // 8.39M ushort
    float* x2R  = WS + 8388608;                              // 2M f
    float* x2T  = WS + 10485760;                             // 2M f
    unsigned short* xHi = (unsigned short*)(WS + 11534336);
    unsigned short* xLo = (unsigned short*)(WS + 12582912);
    unsigned short* aoR = (unsigned short*)(WS + 11534336);
    unsigned short* aoT = (unsigned short*)(WS + 12582912);
    unsigned short* f1T = (unsigned short*)(WS + 12582912);  // 8.39M ushort
    unsigned short* LLH = (unsigned short*)(WS + 13631488);
    unsigned short* LLL = (unsigned short*)(WS + 14680064);
    float* oR   = WS + 13631488;                             // 2M f
    float* oT   = WS + 15728640;                             // 2M f
    unsigned short* faHi = (unsigned short*)(WS + 15728640);
    unsigned short* faLo = (unsigned short*)(WS + 16777216);
    unsigned short* rinLoU = (unsigned short*)(WS + 17825792);  // 786432 ushort
    float* LB   = WS + 18219008;                             // 512 f
    unsigned short* WB = (unsigned short*)(WS + 18366464);

    // u1b (up1 bf16 out, 1M ushort) parks in the OUTPUT res slot outp[0..1048576 f):
    // res is written only by the final relu_bln_fused (verified passing in R19/R20).
    unsigned short* u1b = (unsigned short*)outp;

    unsigned short* w_tin  = WB + 0;        // 1536x512
    unsigned short* w_tout = WB + 786432;   // 512x512
    unsigned short* w_tl1  = WB + 1048576;  // 2048x512
    unsigned short* w_tl2  = WB + 2097152;  // 512x2048
    unsigned short* w_rin  = WB + 3145728;  // 1536x512
    unsigned short* w_rout = WB + 3932160;  // 512x512
    unsigned short* w_rl1  = WB + 4194304;  // 2048x512
    unsigned short* w_rl2  = WB + 5242880;  // 512x2048
    unsigned short* w_up1  = WB + 6291456;  // 512x512
    unsigned short* w_up2  = WB + 6553600;  // 512x512

    dim3 blk(256);

    // ---- prep (2 dispatches: uber(+tab), wawm) ----
    uber_prep_kernel<<<dim3(35330), blk, 0, stream>>>(t_in_w, t_out_w, t_lin1_w, t_lin2_w,
                                                      r_in_w, r_out_w, r_lin1_w, r_lin2_w,
                                                      up1_w, up2_w, WB, rinLoU,
                                                      x, xHi, xLo, outp + NOUT,
                                                      lb1_re, lb1_im, LB, tabC, tabS);
    wawm_kernel<<<dim3(512, 2, 2), blk, 0, stream>>>(l1_re, l1_im, lc_w, tabC, tabS,
                                                     WaHu, WaLu, WmHu, WmLu);

    // ---- freq branch ----
    gemm_mfma3<64,64,1,0,0><<<dim3(8, 64), blk, 0, stream>>>(xHi, xLo, WaHu, WaLu, LB,
                                                             LL, nullptr, nullptr, nullptr, 512, 512);
    cattn2_kernel<<<dim3(128, 2), dim3(512), 65536, stream>>>(LL, LLH, LLL);         // LL hi/lo
    gemm_mfma3<64,64,0,1,1><<<dim3(8, 64), blk, 0, stream>>>(LLH, LLL, WmHu, WmLu, lc_b,
                                                             FA, outp + 2 * NOUT, faHi, faLo, 512, 512);

    // ---- qkv both TELs (R15 proven dual form) ----
    gemm_qkv_dual<64,128><<<dim3(12, 64, 2), blk, 0, stream>>>(faHi, faLo, w_rin, rinLoU, r_in_b, qkvR,
                                                               xHi, w_tin, t_in_b, qkvT, 1536, 512);

    // ---- attention (r+t) + up1, merged ----
    attn_up1_kernel<<<dim3(1024, 1, 3), blk, 0, stream>>>(qkvR, qkvT, aoR, aoT,
                                                          faHi, w_up1, up1_b, u1b);

    // ---- out-proj r/t + up2 (tri) ----
    gemm_out_tri<64,64><<<dim3(8, 64, 3), blk, 0, stream>>>(aoR, w_rout, r_out_b, oR,
                                                            aoT, w_tout, t_out_b, oT,
                                                            u1b, w_up2, up2_b, outp + 3 * NOUT, 512, 512);
    add_ln_d1<<<dim3(8192), blk, 0, stream>>>(FA, oR, r_ln1_w, r_ln1_b, x1rH, x1rL,
                                              x,  oT, t_ln1_w, t_ln1_b, x1tH, x1tL);
    gemm_dual<64,128,1,1><<<dim3(16, 64, 2), blk, 0, stream>>>(x1rH, x1tH, w_rl1, w_tl1,
                                                               r_lin1_b, t_lin1_b, nullptr, nullptr,
                                                               f1R, f1T, 2048, 512);
    gemm_dual<64,64,0,0><<<dim3(8, 64, 2), blk, 0, stream>>>(f1R, f1T, w_rl2, w_tl2,
                                                             r_lin2_b, t_lin2_b, yR, yT,
                                                             nullptr, nullptr, 512, 2048);
    add_ln_d2<<<dim3(8192), blk, 0, stream>>>(x1rH, x1rL, yR, r_ln2_w, r_ln2_b, x2R,
                                              x1tH, x1tL, yT, t_ln2_w, t_ln2_b, x2T);
    relu_bln_fused<<<dim3(128), dim3(1024), 0, stream>>>(x2R, n2_w, n2_b, x2T, n1_w, n1_b, outp);
}

// Round 15
// 431.365 us; speedup vs baseline: 1.1203x; 1.0624x over previous
//
#include <hip/hip_runtime.h>
#include <math.h>

// NoiScaleModule: B=128, C=32(seq), S=512(d_model), EMB=256, NHEAD=8, DFF=2048
// All tensors FLOAT32. Outputs concat flat: res[2M], down_x[2M], fa[2M], up[2M]
//
// R20: qkv_dual + out_tri(up2). 470->458.8. R21: tab/up1 folds — NEUTRAL (458.3);
//      dispatch-boundary axis exhausted.
// R22: r-qkv 3-product -> single-product bf16. Audit: every other GEMM in the
//      r-TEL chain (out-proj, lin1, lin2) already consumes plain bf16, and the
//      t-branch qkv is bf16 with bf16 OUTPUT; r-qkv keeps f32 output so it is
//      strictly MORE precise than the passing t path. Freq branch (fa/up direct
//      outputs) keeps hi/lo. qkv LDS 48KB->24KB, z=0 MFMA work /3.

#define NROW 4096
#define NOUT 2097152

typedef __attribute__((ext_vector_type(8))) short short8;
typedef __attribute__((ext_vector_type(4))) float floatx4;

__device__ __forceinline__ unsigned short f2bf(float f) {
    union { float f; unsigned u; } v; v.f = f;
    return (unsigned short)((v.u + 0x7fffu + ((v.u >> 16) & 1u)) >> 16);
}
__device__ __forceinline__ float bf2f(unsigned short h) {
    union { unsigned u; float f; } v; v.u = ((unsigned)h) << 16;
    return v.f;
}

__device__ __forceinline__ void gload16(const unsigned short* g, unsigned short* l) {
    __builtin_amdgcn_global_load_lds((const __attribute__((address_space(1))) void*)g,
                                     (__attribute__((address_space(3))) void*)l, 16, 0, 0);
}

// XCD-chunked swizzle (T1): requires nwg % 8 == 0.
__device__ __forceinline__ void xcd_swizzle(int& bx, int& by, int& bz) {
    const int gx = gridDim.x, gy = gridDim.y;
    const int nwg = gx * gy * gridDim.z;
    int b = (bz * gy + by) * gx + bx;
    const int chunk = nwg >> 3;
    const int lb = (b & 7) * chunk + (b >> 3);
    bx = lb % gx;
    const int rem = lb / gx;
    by = rem % gy;
    bz = rem / gy;
}

// Wa (z=0) and Wm (z=1) in one dispatch; both emit bf16 hi/lo directly.
__global__ __launch_bounds__(256) void wawm_kernel(const float* __restrict__ l1_re, const float* __restrict__ l1_im,
                                                   const float* __restrict__ lc_w,
                                                   const float* __restrict__ tabC, const float* __restrict__ tabS,
                                                   unsigned short* __restrict__ WaH, unsigned short* __restrict__ WaL,
                                                   unsigned short* __restrict__ WmH, unsigned short* __restrict__ WmL)
{
    __shared__ float lw[512];
    const float inv = 0.04419417382415922f;  // 1/sqrt(512)
    if (blockIdx.z == 0) {
        int n  = blockIdx.x;
        int ep = blockIdx.y * 256 + threadIdx.x;
        float acc = 0.f;
        if (ep < 256) {
            for (int k = 0; k < 128; ++k) {
                float c = tabC[n * 256 + k], s = tabS[n * 256 + k];
                acc += c * l1_re[k * 256 + ep] + s * l1_im[k * 256 + ep];
            }
        } else {
            int e = ep - 256;
            for (int k = 0; k < 128; ++k) {
                float c = tabC[n * 256 + k], s = tabS[n * 256 + k];
                acc += c * l1_im[k * 256 + e] - s * l1_re[k * 256 + e];
            }
        }
        float v = acc * inv;
        size_t idx = (size_t)ep * 512 + n;
        unsigned short h = f2bf(v);
        WaH[idx] = h;
        WaL[idx] = f2bf(v - bf2f(h));
    } else {
        int s  = blockIdx.x;
        int kk = blockIdx.y * 256 + threadIdx.x;
        for (int i = threadIdx.x; i < 512; i += 256) lw[i] = lc_w[s * 512 + i];
        __syncthreads();
        float acc = 0.f;
        if (kk < 256) {
            int k = kk;
            for (int n = 0; n < 512; ++n) acc += tabC[n * 256 + k] * lw[n];
            acc *= (k == 0) ? inv : 2.f * inv;
        } else {
            int k = kk - 256;
            if (k == 0) acc = 0.f;
            else {
                for (int n = 0; n < 512; ++n) acc += tabS[n * 256 + k] * lw[n];
                acc *= -2.f * inv;
            }
        }
        size_t idx = (size_t)s * 512 + kk;
        unsigned short h = f2bf(acc);
        WmH[idx] = h;
        WmL[idx] = f2bf(acc - bf2f(h));
    }
}

// ---------------- uber elementwise prep: wcvt(+rinLo) | xsplit | lbpack | tab ------------
__global__ __launch_bounds__(256) void uber_prep_kernel(
    const float* s0, const float* s1, const float* s2, const float* s3, const float* s4,
    const float* s5, const float* s6, const float* s7, const float* s8, const float* s9,
    unsigned short* __restrict__ o, unsigned short* __restrict__ rinLo,
    const float* __restrict__ x, unsigned short* __restrict__ xhi,
    unsigned short* __restrict__ xlo, float* __restrict__ xcp,
    const float* __restrict__ lbre, const float* __restrict__ lbim, float* __restrict__ lbout,
    float* __restrict__ tabC, float* __restrict__ tabS)
{
    const int bid = blockIdx.x, tid = threadIdx.x;
    if (bid < 26624) {
        int i = bid * 256 + tid;  // exactly covers 6815744
        const float* s; int off;
        if (i < 3145728) {
            if (i < 1048576) { if (i < 786432) { s = s0; off = 0; } else { s = s1; off = 786432; } }
            else             { if (i < 2097152) { s = s2; off = 1048576; } else { s = s3; off = 2097152; } }
        } else {
            if (i < 5242880) {
                if (i < 3932160) { s = s4; off = 3145728; }
                else if (i < 4194304) { s = s5; off = 3932160; }
                else { s = s6; off = 4194304; }
            } else {
                if (i < 6291456) { s = s7; off = 5242880; }
                else if (i < 6553600) { s = s8; off = 6291456; }
                else { s = s9; off = 6553600; }
            }
        }
        float v = s[i - off];
        unsigned short h = f2bf(v);
        o[i] = h;
        if (i >= 3145728 && i < 3932160) rinLo[i - 3145728] = f2bf(v - bf2f(h));
    } else if (bid < 34816) {
        int i = (bid - 26624) * 256 + tid;  // exactly covers 2097152
        float v = x[i];
        unsigned short h = f2bf(v);
        xhi[i] = h;
        xlo[i] = f2bf(v - bf2f(h));
        xcp[i] = v;
    } else if (bid < 34818) {
        int i = (bid - 34816) * 256 + tid;
        if (i < 512) lbout[i] = (i < 256) ? lbre[i] : lbim[i - 256];
    } else {
        int n = bid - 34818;                 // 0..511
        int k = tid;                         // 0..255
        int m = (n * k) & 511;
        float th = (float)m * 0.01227184630308513f;  // 2*pi/512
        float sv, cv; sincosf(th, &sv, &cv);
        tabC[n * 256 + k] = cv;
        tabS[n * 256 + k] = sv;
    }
}

// ---------------- dual-branch GEMM (BK=64): z=0/1 select. For lin1/lin2. ----------------
template <int TM, int TN, int ACT, int WBF>
__global__ __launch_bounds__(256) void gemm_dual(
    const unsigned short* __restrict__ A0, const unsigned short* __restrict__ A1,
    const unsigned short* __restrict__ W0, const unsigned short* __restrict__ W1,
    const float* __restrict__ b0, const float* __restrict__ b1,
    float* __restrict__ C0, float* __restrict__ C1,
    unsigned short* __restrict__ D0, unsigned short* __restrict__ D1, int N, int K)
{
    constexpr int MI = TM / 32, NJ = TN / 32;
    constexpr int ARW = TM / 4, BRW = TN / 4;
    __shared__ unsigned short As[2][TM * 32];
    __shared__ unsigned short Bs[2][TN * 32];
    const int tid = threadIdx.x;
    const int wave = tid >> 6, lane = tid & 63;
    int bx = blockIdx.x, by = blockIdx.y, bz = blockIdx.z;
    xcd_swizzle(bx, by, bz);
    const int m0 = by * TM, n0 = bx * TN;
    const int z = bz;
    const unsigned short* A = z ? A1 : A0;
    const unsigned short* W = z ? W1 : W0;
    const float* bias = z ? b1 : b0;
    float* Cf = z ? C1 : C0;
    unsigned short* Cb = z ? D1 : D0;
    const int sr = lane >> 2, sc = (lane & 3) * 8;
    const unsigned short* aS = A + (size_t)(m0 + wave * ARW + sr) * K + sc;
    const unsigned short* wS = W + (size_t)(n0 + wave * BRW + sr) * K + sc;
    const int wm = (wave >> 1) * (TM / 2), wn = (wave & 1) * (TN / 2);
    const int fr = lane & 15, fko = (lane >> 4) * 8;

    floatx4 acc[MI][NJ];
#pragma unroll
    for (int i = 0; i < MI; ++i)
#pragma unroll
        for (int j = 0; j < NJ; ++j) acc[i][j] = (floatx4){0.f, 0.f, 0.f, 0.f};

    for (int k0 = 0; k0 < K; k0 += 64) {
#pragma unroll
        for (int h = 0; h < 2; ++h) {
#pragma unroll
            for (int c = 0; c < ARW / 16; ++c)
                gload16(aS + (size_t)(16 * c) * K + k0 + 32 * h, &As[h][(wave * ARW + 16 * c) * 32]);
#pragma unroll
            for (int c = 0; c < BRW / 16; ++c)
                gload16(wS + (size_t)(16 * c) * K + k0 + 32 * h, &Bs[h][(wave * BRW + 16 * c) * 32]);
        }
        __syncthreads();
#pragma unroll
        for (int h = 0; h < 2; ++h) {
            short8 af[MI], bfr[NJ];
#pragma unroll
            for (int i = 0; i < MI; ++i) af[i] = *(const short8*)&As[h][(wm + i * 16 + fr) * 32 + fko];
#pragma unroll
            for (int j = 0; j < NJ; ++j) bfr[j] = *(const short8*)&Bs[h][(wn + j * 16 + fr) * 32 + fko];
#pragma unroll
            for (int i = 0; i < MI; ++i)
#pragma unroll
                for (int j = 0; j < NJ; ++j)
                    acc[i][j] = __builtin_amdgcn_mfma_f32_16x16x32_bf16(af[i], bfr[j], acc[i][j], 0, 0, 0);
        }
        __syncthreads();
    }
    const int r0 = m0 + wm + (lane >> 4) * 4;
#pragma unroll
    for (int i = 0; i < MI; ++i) {
#pragma unroll
        for (int j = 0; j < NJ; ++j) {
            int n = n0 + wn + j * 16 + fr;
            float bv = bias[n];
#pragma unroll
            for (int r = 0; r < 4; ++r) {
                int m = r0 + i * 16 + r;
                size_t idx = (size_t)m * N + n;
                float v = acc[i][j][r] + bv;
                if (ACT) v = fmaxf(v, 0.f);
                if (WBF) Cb[idx] = f2bf(v);
                else     Cf[idx] = v;
            }
        }
    }
}

// ---------------- tri-branch single-product GEMM (BK=64, TN=64): out-proj r/t + up2 ------
template <int TM, int TN>
__global__ __launch_bounds__(256) void gemm_out_tri(
    const unsigned short* __restrict__ A0, const unsigned short* __restrict__ W0,
    const float* __restrict__ b0, float* __restrict__ C0,
    const unsigned short* __restrict__ A1, const unsigned short* __restrict__ W1,
    const float* __restrict__ b1, float* __restrict__ C1,
    const unsigned short* __restrict__ A2, const unsigned short* __restrict__ W2,
    const float* __restrict__ b2, float* __restrict__ C2, int N, int K)
{
    constexpr int MI = TM / 32, NJ = TN / 32;
    constexpr int ARW = TM / 4, BRW = TN / 4;
    __shared__ unsigned short As[2][TM * 32];
    __shared__ unsigned short Bs[2][TN * 32];
    const int tid = threadIdx.x;
    const int wave = tid >> 6, lane = tid & 63;
    int bx = blockIdx.x, by = blockIdx.y, bz = blockIdx.z;
    xcd_swizzle(bx, by, bz);
    const int m0 = by * TM, n0 = bx * TN;
    const unsigned short* A = (bz == 0) ? A0 : (bz == 1) ? A1 : A2;
    const unsigned short* W = (bz == 0) ? W0 : (bz == 1) ? W1 : W2;
    const float* bias       = (bz == 0) ? b0 : (bz == 1) ? b1 : b2;
    float* Cf               = (bz == 0) ? C0 : (bz == 1) ? C1 : C2;
    const int sr = lane >> 2, sc = (lane & 3) * 8;
    const unsigned short* aS = A + (size_t)(m0 + wave * ARW + sr) * K + sc;
    const unsigned short* wS = W + (size_t)(n0 + wave * BRW + sr) * K + sc;
    const int wm = (wave >> 1) * (TM / 2), wn = (wave & 1) * (TN / 2);
    const int fr = lane & 15, fko = (lane >> 4) * 8;

    floatx4 acc[MI][NJ];
#pragma unroll
    for (int i = 0; i < MI; ++i)
#pragma unroll
        for (int j = 0; j < NJ; ++j) acc[i][j] = (floatx4){0.f, 0.f, 0.f, 0.f};

    for (int k0 = 0; k0 < K; k0 += 64) {
#pragma unroll
        for (int h = 0; h < 2; ++h) {
#pragma unroll
            for (int c = 0; c < ARW / 16; ++c)
                gload16(aS + (size_t)(16 * c) * K + k0 + 32 * h, &As[h][(wave * ARW + 16 * c) * 32]);
#pragma unroll
            for (int c = 0; c < BRW / 16; ++c)
                gload16(wS + (size_t)(16 * c) * K + k0 + 32 * h, &Bs[h][(wave * BRW + 16 * c) * 32]);
        }
        __syncthreads();
#pragma unroll
        for (int h = 0; h < 2; ++h) {
            short8 af[MI], bfr[NJ];
#pragma unroll
            for (int i = 0; i < MI; ++i) af[i] = *(const short8*)&As[h][(wm + i * 16 + fr) * 32 + fko];
#pragma unroll
            for (int j = 0; j < NJ; ++j) bfr[j] = *(const short8*)&Bs[h][(wn + j * 16 + fr) * 32 + fko];
#pragma unroll
            for (int i = 0; i < MI; ++i)
#pragma unroll
                for (int j = 0; j < NJ; ++j)
                    acc[i][j] = __builtin_amdgcn_mfma_f32_16x16x32_bf16(af[i], bfr[j], acc[i][j], 0, 0, 0);
        }
        __syncthreads();
    }
    const int r0 = m0 + wm + (lane >> 4) * 4;
#pragma unroll
    for (int i = 0; i < MI; ++i) {
#pragma unroll
        for (int j = 0; j < NJ; ++j) {
            int n = n0 + wn + j * 16 + fr;
            float bv = bias[n];
#pragma unroll
            for (int r = 0; r < 4; ++r) {
                int m = r0 + i * 16 + r;
                Cf[(size_t)m * N + n] = acc[i][j][r] + bv;
            }
        }
    }
}

// ---------------- fused hi/lo 3-product MFMA GEMM (BK=64, single-buffer) ----------------
template <int TM, int TN, int ACT, int WCOPY, int WHILO>
__global__ __launch_bounds__(256) void gemm_mfma3(
    const unsigned short* __restrict__ Ah, const unsigned short* __restrict__ Al,
    const unsigned short* __restrict__ Wh, const unsigned short* __restrict__ Wl,
    const float* __restrict__ bias, float* __restrict__ Cf, float* __restrict__ Ccopy,
    unsigned short* __restrict__ Hh, unsigned short* __restrict__ Hl, int N, int K)
{
    constexpr int MI = TM / 32, NJ = TN / 32;
    constexpr int ARW = TM / 4, BRW = TN / 4;
    __shared__ unsigned short Ash[2][TM * 32];
    __shared__ unsigned short Asl[2][TM * 32];
    __shared__ unsigned short Bsh[2][TN * 32];
    __shared__ unsigned short Bsl[2][TN * 32];
    const int tid = threadIdx.x;
    const int wave = tid >> 6, lane = tid & 63;
    int bx = blockIdx.x, by = blockIdx.y, bz = blockIdx.z;
    xcd_swizzle(bx, by, bz);
    const int m0 = by * TM, n0 = bx * TN;
    const int sr = lane >> 2, sc = (lane & 3) * 8;
    const size_t aoff = (size_t)(m0 + wave * ARW + sr) * K + sc;
    const size_t woff = (size_t)(n0 + wave * BRW + sr) * K + sc;
    const int wm = (wave >> 1) * (TM / 2), wn = (wave & 1) * (TN / 2);
    const int fr = lane & 15, fko = (lane >> 4) * 8;

    floatx4 acc[MI][NJ];
#pragma unroll
    for (int i = 0; i < MI; ++i)
#pragma unroll
        for (int j = 0; j < NJ; ++j) acc[i][j] = (floatx4){0.f, 0.f, 0.f, 0.f};

    for (int k0 = 0; k0 < K; k0 += 64) {
#pragma unroll
        for (int h = 0; h < 2; ++h) {
#pragma unroll
            for (int c = 0; c < ARW / 16; ++c) {
                gload16(Ah + aoff + (size_t)(16 * c) * K + k0 + 32 * h, &Ash[h][(wave * ARW + 16 * c) * 32]);
                gload16(Al + aoff + (size_t)(16 * c) * K + k0 + 32 * h, &Asl[h][(wave * ARW + 16 * c) * 32]);
            }
#pragma unroll
            for (int c = 0; c < BRW / 16; ++c) {
                gload16(Wh + woff + (size_t)(16 * c) * K + k0 + 32 * h, &Bsh[h][(wave * BRW + 16 * c) * 32]);
                gload16(Wl + woff + (size_t)(16 * c) * K + k0 + 32 * h, &Bsl[h][(wave * BRW + 16 * c) * 32]);
            }
        }
        __syncthreads();
#pragma unroll
        for (int h = 0; h < 2; ++h) {
            short8 ah[MI], al[MI], bh[NJ], bl[NJ];
#pragma unroll
            for (int i = 0; i < MI; ++i) {
                ah[i] = *(const short8*)&Ash[h][(wm + i * 16 + fr) * 32 + fko];
                al[i] = *(const short8*)&Asl[h][(wm + i * 16 + fr) * 32 + fko];
            }
#pragma unroll
            for (int j = 0; j < NJ; ++j) {
                bh[j] = *(const short8*)&Bsh[h][(wn + j * 16 + fr) * 32 + fko];
                bl[j] = *(const short8*)&Bsl[h][(wn + j * 16 + fr) * 32 + fko];
            }
#pragma unroll
            for (int i = 0; i < MI; ++i)
#pragma unroll
                for (int j = 0; j < NJ; ++j) {
                    acc[i][j] = __builtin_amdgcn_mfma_f32_16x16x32_bf16(al[i], bh[j], acc[i][j], 0, 0, 0);
                    acc[i][j] = __builtin_amdgcn_mfma_f32_16x16x32_bf16(ah[i], bl[j], acc[i][j], 0, 0, 0);
                    acc[i][j] = __builtin_amdgcn_mfma_f32_16x16x32_bf16(ah[i], bh[j], acc[i][j], 0, 0, 0);
                }
        }
        __syncthreads();
    }
    const int r0 = m0 + wm + (lane >> 4) * 4;
#pragma unroll
    for (int i = 0; i < MI; ++i) {
#pragma unroll
        for (int j = 0; j < NJ; ++j) {
            int n = n0 + wn + j * 16 + fr;
            float bv = bias[n];
#pragma unroll
            for (int r = 0; r < 4; ++r) {
                int m = r0 + i * 16 + r;
                size_t idx = (size_t)m * N + n;
                float v = acc[i][j][r] + bv;
                if (ACT) v = fmaxf(v, 0.f);
                Cf[idx] = v;
                if (WCOPY) Ccopy[idx] = v;
                if (WHILO) {
                    unsigned short h = f2bf(v);
                    Hh[idx] = h;
                    Hl[idx] = f2bf(v - bf2f(h));
                }
            }
        }
    }
}

// ---------------- merged qkv GEMM (BK=64, single-product both branches):
//                  z=0 r-qkv faHi x w_rin -> f32; z=1 t-qkv xHi x w_tin -> bf16. ----------
template <int TM, int TN>
__global__ __launch_bounds__(256) void gemm_qkv_dual(
    const unsigned short* __restrict__ A0, const unsigned short* __restrict__ W0,
    const float* __restrict__ b0, float* __restrict__ C0,
    const unsigned short* __restrict__ A1, const unsigned short* __restrict__ W1,
    const float* __restrict__ b1, unsigned short* __restrict__ C1,
    int N, int K)
{
    constexpr int MI = TM / 32, NJ = TN / 32;
    constexpr int ARW = TM / 4, BRW = TN / 4;
    __shared__ unsigned short As[2][TM * 32];
    __shared__ unsigned short Bs[2][TN * 32];
    const int tid = threadIdx.x;
    const int wave = tid >> 6, lane = tid & 63;
    int bx = blockIdx.x, by = blockIdx.y, bz = blockIdx.z;
    xcd_swizzle(bx, by, bz);
    const int m0 = by * TM, n0 = bx * TN;
    const unsigned short* A = bz ? A1 : A0;
    const unsigned short* W = bz ? W1 : W0;
    const float* bias = bz ? b1 : b0;
    const int sr = lane >> 2, sc = (lane & 3) * 8;
    const unsigned short* aS = A + (size_t)(m0 + wave * ARW + sr) * K + sc;
    const unsigned short* wS = W + (size_t)(n0 + wave * BRW + sr) * K + sc;
    const int wm = (wave >> 1) * (TM / 2), wn = (wave & 1) * (TN / 2);
    const int fr = lane & 15, fko = (lane >> 4) * 8;

    floatx4 acc[MI][NJ];
#pragma unroll
    for (int i = 0; i < MI; ++i)
#pragma unroll
        for (int j = 0; j < NJ; ++j) acc[i][j] = (floatx4){0.f, 0.f, 0.f, 0.f};

    for (int k0 = 0; k0 < K; k0 += 64) {
#pragma unroll
        for (int h = 0; h < 2; ++h) {
#pragma unroll
            for (int c = 0; c < ARW / 16; ++c)
                gload16(aS + (size_t)(16 * c) * K + k0 + 32 * h, &As[h][(wave * ARW + 16 * c) * 32]);
#pragma unroll
            for (int c = 0; c < BRW / 16; ++c)
                gload16(wS + (size_t)(16 * c) * K + k0 + 32 * h, &Bs[h][(wave * BRW + 16 * c) * 32]);
        }
        __syncthreads();
#pragma unroll
        for (int h = 0; h < 2; ++h) {
            short8 af[MI], bfr[NJ];
#pragma unroll
            for (int i = 0; i < MI; ++i) af[i] = *(const short8*)&As[h][(wm + i * 16 + fr) * 32 + fko];
#pragma unroll
            for (int j = 0; j < NJ; ++j) bfr[j] = *(const short8*)&Bs[h][(wn + j * 16 + fr) * 32 + fko];
#pragma unroll
            for (int i = 0; i < MI; ++i)
#pragma unroll
                for (int j = 0; j < NJ; ++j)
                    acc[i][j] = __builtin_amdgcn_mfma_f32_16x16x32_bf16(af[i], bfr[j], acc[i][j], 0, 0, 0);
        }
        __syncthreads();
    }
    const int r0 = m0 + wm + (lane >> 4) * 4;
#pragma unroll
    for (int i = 0; i < MI; ++i) {
#pragma unroll
        for (int j = 0; j < NJ; ++j) {
            int n = n0 + wn + j * 16 + fr;
            float bv = bias[n];
#pragma unroll
            for (int r = 0; r < 4; ++r) {
                int m = r0 + i * 16 + r;
                size_t idx = (size_t)m * N + n;
                float v = acc[i][j][r] + bv;
                if (bz == 0) C0[idx] = v;
                else         C1[idx] = f2bf(v);
            }
        }
    }
}

// ---------------- merged attention + up1: z=0 attn-r (f32 qkv), z=1 attn-t (bf16 qkv),
//                  z=2 up1 GEMM (512 of 1024 blocks; whole-block early exit). ------------
__global__ __launch_bounds__(256) void attn_up1_kernel(
    const float* __restrict__ qkvF, const unsigned short* __restrict__ qkvB,
    unsigned short* __restrict__ outR, unsigned short* __restrict__ outT,
    const unsigned short* __restrict__ A2, const unsigned short* __restrict__ W2,
    const float* __restrict__ b2, unsigned short* __restrict__ C2)
{
    __shared__ __align__(16) char smem[29184];
    const int tid = threadIdx.x;
    if (blockIdx.z < 2) {
        // ---- attention branch (29184 B LDS) ----
        float (*qs)[65] = (float(*)[65])smem;
        float (*ks)[65] = (float(*)[65])(smem + 8320);
        float (*vs)[65] = (float(*)[65])(smem + 16640);
        float (*ps)[33] = (float(*)[33])(smem + 24960);
        const int isT = blockIdx.z;
        const int b = blockIdx.x >> 3;
        const int h = blockIdx.x & 7;
        if (isT) {
            for (int i = tid; i < 2048; i += 256) {
                int s = i >> 6, d = i & 63;
                size_t base = ((size_t)(b * 32 + s)) * 1536 + h * 64 + d;
                qs[s][d] = bf2f(qkvB[base]);
                ks[s][d] = bf2f(qkvB[base + 512]);
                vs[s][d] = bf2f(qkvB[base + 1024]);
            }
        } else {
            for (int i = tid; i < 2048; i += 256) {
                int s = i >> 6, d = i & 63;
                size_t base = ((size_t)(b * 32 + s)) * 1536 + h * 64 + d;
                qs[s][d] = qkvF[base];
                ks[s][d] = qkvF[base + 512];
                vs[s][d] = qkvF[base + 1024];
            }
        }
        __syncthreads();
        for (int i = tid; i < 1024; i += 256) {
            int si = i >> 5, sj = i & 31;
            float acc = 0.f;
#pragma unroll 8
            for (int d = 0; d < 64; ++d) acc += qs[si][d] * ks[sj][d];
            ps[si][sj] = acc * 0.125f;
        }
        __syncthreads();
        if (tid < 32) {
            float mx = -1e30f;
            for (int j = 0; j < 32; ++j) mx = fmaxf(mx, ps[tid][j]);
            float sum = 0.f;
            for (int j = 0; j < 32; ++j) { float e = __expf(ps[tid][j] - mx); ps[tid][j] = e; sum += e; }
            float inv = 1.f / sum;
            for (int j = 0; j < 32; ++j) ps[tid][j] *= inv;
        }
        __syncthreads();
        unsigned short* ob = isT ? outT : outR;
        for (int i = tid; i < 2048; i += 256) {
            int s = i >> 6, d = i & 63;
            float acc = 0.f;
#pragma unroll 8
            for (int k = 0; k < 32; ++k) acc += ps[s][k] * vs[k][d];
            ob[((size_t)(b * 32 + s)) * 512 + h * 64 + d] = f2bf(acc);
        }
    } else {
        // ---- up1 GEMM branch: 64x64 tile, BK=64, N=K=512, 512 blocks ----
        const int b = blockIdx.x;
        if (b >= 512) return;                      // whole block exits pre-barrier
        const int lb = (b & 7) * 64 + (b >> 3);    // manual 512-chunk swizzle
        const int bxg = lb & 7, byg = lb >> 3;
        unsigned short (*As)[2048] = (unsigned short(*)[2048])smem;          // 2*4096B
        unsigned short (*Bs)[2048] = (unsigned short(*)[2048])(smem + 8192); // 2*4096B
        const int wave = tid >> 6, lane = tid & 63;
        const int m0 = byg * 64, n0 = bxg * 64;
        const int sr = lane >> 2, sc = (lane & 3) * 8;
        const unsigned short* aS = A2 + (size_t)(m0 + wave * 16 + sr) * 512 + sc;
        const unsigned short* wS = W2 + (size_t)(n0 + wave * 16 + sr) * 512 + sc;
        const int wm = (wave >> 1) * 32, wn = (wave & 1) * 32;
        const int fr = lane & 15, fko = (lane >> 4) * 8;
        floatx4 acc[2][2];
#pragma unroll
        for (int i = 0; i < 2; ++i)
#pragma unroll
            for (int j = 0; j < 2; ++j) acc[i][j] = (floatx4){0.f, 0.f, 0.f, 0.f};
        for (int k0 = 0; k0 < 512; k0 += 64) {
#pragma unroll
            for (int h = 0; h < 2; ++h) {
                gload16(aS + k0 + 32 * h, &As[h][(wave * 16) * 32]);
                gload16(wS + k0 + 32 * h, &Bs[h][(wave * 16) * 32]);
            }
            __syncthreads();
#pragma unroll
            for (int h = 0; h < 2; ++h) {
                short8 af[2], bfr[2];
#pragma unroll
                for (int i = 0; i < 2; ++i) af[i] = *(const short8*)&As[h][(wm + i * 16 + fr) * 32 + fko];
#pragma unroll
                for (int j = 0; j < 2; ++j) bfr[j] = *(const short8*)&Bs[h][(wn + j * 16 + fr) * 32 + fko];
#pragma unroll
                for (int i = 0; i < 2; ++i)
#pragma unroll
                    for (int j = 0; j < 2; ++j)
                        acc[i][j] = __builtin_amdgcn_mfma_f32_16x16x32_bf16(af[i], bfr[j], acc[i][j], 0, 0, 0);
            }
            __syncthreads();
        }
        const int r0 = m0 + wm + (lane >> 4) * 4;
#pragma unroll
        for (int i = 0; i < 2; ++i)
#pragma unroll
            for (int j = 0; j < 2; ++j) {
                int n = n0 + wn + j * 16 + fr;
                float bv = b2[n];
#pragma unroll
                for (int r = 0; r < 4; ++r) {
                    int m = r0 + i * 16 + r;
                    C2[(size_t)m * 512 + n] = f2bf(acc[i][j][r] + bv);
                }
            }
    }
}

// ---------------- complex self-attention: LDS-resident, grid (128 batch, 2 half) ----------
__global__ __launch_bounds__(512) void cattn2_kernel(const float* __restrict__ LL,
                                                     unsigned short* __restrict__ outHi,
                                                     unsigned short* __restrict__ outLo)
{
    extern __shared__ float Xs[];
    __shared__ float Pr[16][33], Pi[16][33];
    const int b = blockIdx.x, half = blockIdx.y;
    const int tid = threadIdx.x;
    const float* base = LL + (size_t)b * 16384;
    for (int i = tid; i < 16384; i += 512) {
        int c = i >> 9, e = i & 511;
        Xs[e * 32 + ((c ^ e) & 31)] = base[i];
    }
    __syncthreads();
    {
        const int li = tid >> 5;                 // 0..15
        const int ci = half * 16 + li;
        const int ck = tid & 31;
        float ar = 0.f, ai = 0.f;
#pragma unroll 4
        for (int er = 0; er < 256; ++er) {
            const int sw = er & 31;
            float yr = Xs[er * 32 + ((ck ^ sw) & 31)];
            float yi = Xs[(er + 256) * 32 + ((ck ^ sw) & 31)];
            float xr = Xs[er * 32 + ((ci ^ sw) & 31)];
            float xi = Xs[(er + 256) * 32 + ((ci ^ sw) & 31)];
            ar += xr * yr - xi * yi;
            ai += xr * yi + xi * yr;
        }
        Pr[li][ck] = ar * 0.0625f;
        Pi[li][ck] = ai * 0.0625f;
    }
    __syncthreads();
    if (tid < 32) {
        int r = tid & 15;
        float (*P)[33] = (tid < 16) ? Pr : Pi;
        float mx = -1e30f;
        for (int j = 0; j < 32; ++j) mx = fmaxf(mx, P[r][j]);
        float s = 0.f;
        for (int j = 0; j < 32; ++j) { float e = __expf(P[r][j] - mx); P[r][j] = e; s += e; }
        float inv = 1.f / s;
        for (int j = 0; j < 32; ++j) P[r][j] *= inv;
    }
    __syncthreads();
    const int er = tid & 255;
    const int th = tid >> 8;                     // 0 or 1: t in [th*8, th*8+8)
    const int sw = er & 31;
    float accr[8], acci[8];
#pragma unroll
    for (int t = 0; t < 8; ++t) { accr[t] = 0.f; acci[t] = 0.f; }
    for (int k = 0; k < 32; ++k) {
        float yr = Xs[er * 32 + ((k ^ sw) & 31)];
        float yi = Xs[(er + 256) * 32 + ((k ^ sw) & 31)];
#pragma unroll
        for (int t = 0; t < 8; ++t) {
            float pr = Pr[th * 8 + t][k], pi = Pi[th * 8 + t][k];
            accr[t] += pr * yr - pi * yi;
            acci[t] += pr * yi + pi * yr;
        }
    }
#pragma unroll
    for (int t = 0; t < 8; ++t) {
        int c = half * 16 + th * 8 + t;
        float vr = Xs[er * 32 + ((c ^ sw) & 31)] + accr[t];
        float vi = Xs[(er + 256) * 32 + ((c ^ sw) & 31)] + acci[t];
        size_t ir = (size_t)b * 16384 + (size_t)c * 512 + er;
        unsigned short hr = f2bf(vr), hi2 = f2bf(vi);
        outHi[ir] = hr;        outLo[ir] = f2bf(vr - bf2f(hr));
        outHi[ir + 256] = hi2; outLo[ir + 256] = f2bf(vi - bf2f(hi2));
    }
}

// ---------------- DUAL add+LN (512), f32 resid, out bf16 hi/lo; rows>=4096 = branch 1 ----
__global__ __launch_bounds__(256) void add_ln_d1(
    const float* __restrict__ r0, const float* __restrict__ y0,
    const float* __restrict__ w0, const float* __restrict__ b0,
    unsigned short* __restrict__ h0, unsigned short* __restrict__ l0,
    const float* __restrict__ r1, const float* __restrict__ y1,
    const float* __restrict__ w1, const float* __restrict__ b1,
    unsigned short* __restrict__ h1, unsigned short* __restrict__ l1)
{
    const int row = blockIdx.x;
    const int br = row >> 12;
    const int rl = row & 4095;
    const float* resid = br ? r1 : r0;
    const float* y     = br ? y1 : y0;
    const float* w     = br ? w1 : w0;
    const float* bb    = br ? b1 : b0;
    unsigned short* oh = br ? h1 : h0;
    unsigned short* ol = br ? l1 : l0;
    const int tid = threadIdx.x;
    const size_t base = (size_t)rl * 512;
    float v0 = resid[base + tid] + y[base + tid];
    float v1 = resid[base + 256 + tid] + y[base + 256 + tid];
    float s = v0 + v1, q = v0 * v0 + v1 * v1;
    for (int off = 32; off; off >>= 1) { s += __shfl_down(s, off); q += __shfl_down(q, off); }
    __shared__ float sw[4], qw[4], ms, is;
    int wid = tid >> 6, lane = tid & 63;
    if (lane == 0) { sw[wid] = s; qw[wid] = q; }
    __syncthreads();
    if (tid == 0) {
        float S = sw[0] + sw[1] + sw[2] + sw[3];
        float Q = qw[0] + qw[1] + qw[2] + qw[3];
        float m = S * (1.f / 512.f);
        ms = m;
        is = rsqrtf(Q * (1.f / 512.f) - m * m + 1e-5f);
    }
    __syncthreads();
    float m = ms, inv = is;
    float o0 = (v0 - m) * inv * w[tid] + bb[tid];
    float o1 = (v1 - m) * inv * w[256 + tid] + bb[256 + tid];
    unsigned short e0 = f2bf(o0), e1 = f2bf(o1);
    oh[base + tid] = e0;       ol[base + tid] = f2bf(o0 - bf2f(e0));
    oh[base + 256 + tid] = e1; ol[base + 256 + tid] = f2bf(o1 - bf2f(e1));
}

// ---------------- DUAL add+LN (512), bf16 hi/lo resid, out f32 --------------------------
__global__ __launch_bounds__(256) void add_ln_d2(
    const unsigned short* __restrict__ rh0, const unsigned short* __restrict__ rl0,
    const float* __restrict__ y0, const float* __restrict__ w0, const float* __restrict__ b0,
    float* __restrict__ o0p,
    const unsigned short* __restrict__ rh1, const unsigned short* __restrict__ rl1,
    const float* __restrict__ y1, const float* __restrict__ w1, const float* __restrict__ b1,
    float* __restrict__ o1p)
{
    const int row = blockIdx.x;
    const int br = row >> 12;
    const int rl = row & 4095;
    const unsigned short* rh = br ? rh1 : rh0;
    const unsigned short* rlo = br ? rl1 : rl0;
    const float* y  = br ? y1 : y0;
    const float* w  = br ? w1 : w0;
    const float* bb = br ? b1 : b0;
    float* op = br ? o1p : o0p;
    const int tid = threadIdx.x;
    const size_t base = (size_t)rl * 512;
    float v0 = bf2f(rh[base + tid]) + bf2f(rlo[base + tid]) + y[base + tid];
    float v1 = bf2f(rh[base + 256 + tid]) + bf2f(rlo[base + 256 + tid]) + y[base + 256 + tid];
    float s = v0 + v1, q = v0 * v0 + v1 * v1;
    for (int off = 32; off; off >>= 1) { s += __shfl_down(s, off); q += __shfl_down(q, off); }
    __shared__ float sw[4], qw[4], ms, is;
    int wid = tid >> 6, lane = tid & 63;
    if (lane == 0) { sw[wid] = s; qw[wid] = q; }
    __syncthreads();
    if (tid == 0) {
        float S = sw[0] + sw[1] + sw[2] + sw[3];
        float Q = qw[0] + qw[1] + qw[2] + qw[3];
        float m = S * (1.f / 512.f);
        ms = m;
        is = rsqrtf(Q * (1.f / 512.f) - m * m + 1e-5f);
    }
    __syncthreads();
    float m = ms, inv = is;
    op[base + tid]       = (v0 - m) * inv * w[tid] + bb[tid];
    op[base + 256 + tid] = (v1 - m) * inv * w[256 + tid] + bb[256 + tid];
}

// ---------------- fused relu+batchLN x2: rf = LN(relu(x2R)) kept in LDS,
//                  res = LN(relu(x2T)) + rf. One block per batch, 1024 threads. ----------
__global__ __launch_bounds__(1024) void relu_bln_fused(
    const float* __restrict__ xR, const float* __restrict__ w2, const float* __restrict__ b2,
    const float* __restrict__ xT, const float* __restrict__ w1, const float* __restrict__ b1,
    float* __restrict__ out)
{
    __shared__ float rfs[16384];
    __shared__ float sw_[16], qw_[16], ms_, is_;
    const int bb = blockIdx.x, tid = threadIdx.x;
    const int wid = tid >> 6, lane = tid & 63;
    const float* xr = xR + (size_t)bb * 16384;
    float s = 0.f, q = 0.f;
    for (int i = tid; i < 16384; i += 1024) { float v = fmaxf(xr[i], 0.f); s += v; q += v * v; }
    for (int off = 32; off; off >>= 1) { s += __shfl_down(s, off); q += __shfl_down(q, off); }
    if (lane == 0) { sw_[wid] = s; qw_[wid] = q; }
    __syncthreads();
    if (tid == 0) {
        float S = 0.f, Q = 0.f;
        for (int i = 0; i < 16; ++i) { S += sw_[i]; Q += qw_[i]; }
        float m = S * (1.f / 16384.f);
        ms_ = m;
        is_ = rsqrtf(Q * (1.f / 16384.f) - m * m + 1e-5f);
    }
    __syncthreads();
    float m = ms_, inv = is_;
    for (int i = tid; i < 16384; i += 1024) {
        float v = fmaxf(xr[i], 0.f);
        rfs[i] = (v - m) * inv * w2[i] + b2[i];
    }
    const float* xt = xT + (size_t)bb * 16384;
    s = 0.f; q = 0.f;
    for (int i = tid; i < 16384; i += 1024) { float v = fmaxf(xt[i], 0.f); s += v; q += v * v; }
    for (int off = 32; off; off >>= 1) { s += __shfl_down(s, off); q += __shfl_down(q, off); }
    if (lane == 0) { sw_[wid] = s; qw_[wid] = q; }
    __syncthreads();
    if (tid == 0) {
        float S = 0.f, Q = 0.f;
        for (int i = 0; i < 16; ++i) { S += sw_[i]; Q += qw_[i]; }
        float m2 = S * (1.f / 16384.f);
        ms_ = m2;
        is_ = rsqrtf(Q * (1.f / 16384.f) - m2 * m2 + 1e-5f);
    }
    __syncthreads();
    m = ms_; inv = is_;
    float* op = out + (size_t)bb * 16384;
    for (int i = tid; i < 16384; i += 1024) {
        float v = fmaxf(xt[i], 0.f);
        op[i] = (v - m) * inv * w1[i] + b1[i] + rfs[i];
    }
}

extern "C" void kernel_launch(void* const* d_in, const int* in_sizes, int n_in,
                              void* d_out, int out_size, void* d_ws, size_t ws_size,
                              hipStream_t stream)
{
    (void)in_sizes; (void)n_in; (void)out_size; (void)ws_size;
    const float* x        = (const float*)d_in[0];
    const float* t_in_w   = (const float*)d_in[1];
    const float* t_in_b   = (const float*)d_in[2];
    const float* t_out_w  = (const float*)d_in[3];
    const float* t_out_b  = (const float*)d_in[4];
    const float* t_ln1_w  = (const float*)d_in[5];
    const float* t_ln1_b  = (const float*)d_in[6];
    const float* t_lin1_w = (const float*)d_in[7];
    const float* t_lin1_b = (const float*)d_in[8];
    const float* t_lin2_w = (const float*)d_in[9];
    const float* t_lin2_b = (const float*)d_in[10];
    const float* t_ln2_w  = (const float*)d_in[11];
    const float* t_ln2_b  = (const float*)d_in[12];
    const float* r_in_w   = (const float*)d_in[13];
    const float* r_in_b   = (const float*)d_in[14];
    const float* r_out_w  = (const float*)d_in[15];
    const float* r_out_b  = (const float*)d_in[16];
    const float* r_ln1_w  = (const float*)d_in[17];
    const float* r_ln1_b  = (const float*)d_in[18];
    const float* r_lin1_w = (const float*)d_in[19];
    const float* r_lin1_b = (const float*)d_in[20];
    const float* r_lin2_w = (const float*)d_in[21];
    const float* r_lin2_b = (const float*)d_in[22];
    const float* r_ln2_w  = (const float*)d_in[23];
    const float* r_ln2_b  = (const float*)d_in[24];
    const float* lc_w     = (const float*)d_in[25];
    const float* lc_b     = (const float*)d_in[26];
    const float* up1_w    = (const float*)d_in[27];
    const float* up1_b    = (const float*)d_in[28];
    const float* up2_w    = (const float*)d_in[29];
    const float* up2_b    = (const float*)d_in[30];
    const float* n1_w     = (const float*)d_in[31];
    const float* n1_b     = (const float*)d_in[32];
    const float* n2_w     = (const float*)d_in[33];
    const float* n2_b     = (const float*)d_in[34];
    const float* l1_re    = (const float*)d_in[35];
    const float* l1_im    = (const float*)d_in[36];
    const float* lb1_re   = (const float*)d_in[39];
    const float* lb1_im   = (const float*)d_in[40];

    float* outp = (float*)d_out;

    // ---- workspace map (float offsets; total 21,774,336 f = 87.1 MB) ----
    float* WS   = (float*)d_ws;
    float* LL   = WS;                                        // 2M f (also fa f32, later y_r)
    float* FA   = WS;
    float* yR   = WS;
    float* QR   = WS + 2097152;                              // 6.29M f
    float* tabC = QR;                                        // 131072
    float* tabS = QR + 131072;
    unsigned short* WaHu = (unsigned short*)(QR + 786432);
    unsigned short* WaLu = (unsigned short*)(QR + 917504);
    unsigned short* WmHu = (unsigned short*)(QR + 1048576);
    unsigned short* WmLu = (unsigned short*)(QR + 1179648);
    float* qkvR = QR;                                        // 6.29M f: [2097152, 8388608)
    unsigned short* x1rH = (unsigned short*)(WS + 2097152);
    unsigned short* x1rL = (unsigned short*)(WS + 3145728);
    unsigned short* x1tH = (unsigned short*)(WS + 4194304);
    unsigned short* x1tL = (unsigned short*)(WS + 5242880);
    float* yT   = WS + 6291456;                              // 2M f
    unsigned short* qkvT = (unsigned short*)(WS + 8388608);  // 6.29M ushort
    unsigned short* f1R  = (unsigned short*)(WS + 8388608);  // 8.39M ushort
    float* x2R  = WS + 8388608;                              // 2M f
    float* x2T  = WS + 10485760;                             // 2M f
    unsigned short* xHi = (unsigned short*)(WS + 11534336);
    unsigned short* xLo = (unsigned short*)(WS + 12582912);
    unsigned short* aoR = (unsigned short*)(WS + 11534336);
    unsigned short* aoT = (unsigned short*)(WS + 12582912);
    unsigned short* f1T = (unsigned short*)(WS + 12582912);  // 8.39M ushort
    unsigned short* LLH = (unsigned short*)(WS + 13631488);
    unsigned short* LLL = (unsigned short*)(WS + 14680064);
    float* oR   = WS + 13631488;                             // 2M f
    float* oT   = WS + 15728640;                             // 2M f
    unsigned short* faHi = (unsigned short*)(WS + 15728640);
    unsigned short* faLo = (unsigned short*)(WS + 16777216);
    unsigned short* rinLoU = (unsigned short*)(WS + 17825792);  // 786432 ushort
    float* LB   = WS + 18219008;                             // 512 f
    unsigned short* WB = (unsigned short*)(WS + 18366464);

    // u1b (up1 bf16 out, 1M ushort) parks in the OUTPUT res slot outp[0..1048576 f):
    // res is written only by the final relu_bln_fused (verified passing in R19-R21).
    unsigned short* u1b = (unsigned short*)outp;

    unsigned short* w_tin  = WB + 0;        // 1536x512
    unsigned short* w_tout = WB + 786432;   // 512x512
    unsigned short* w_tl1  = WB + 1048576;  // 2048x512
    unsigned short* w_tl2  = WB + 2097152;  // 512x2048
    unsigned short* w_rin  = WB + 3145728;  // 1536x512
    unsigned short* w_rout = WB + 3932160;  // 512x512
    unsigned short* w_rl1  = WB + 4194304;  // 2048x512
    unsigned short* w_rl2  = WB + 5242880;  // 512x2048
    unsigned short* w_up1  = WB + 6291456;  // 512x512
    unsigned short* w_up2  = WB + 6553600;  // 512x512

    dim3 blk(256);

    // ---- prep (2 dispatches: uber(+tab), wawm) ----
    uber_prep_kernel<<<dim3(35330), blk, 0, stream>>>(t_in_w, t_out_w, t_lin1_w, t_lin2_w,
                                                      r_in_w, r_out_w, r_lin1_w, r_lin2_w,
                                                      up1_w, up2_w, WB, rinLoU,
                                                      x, xHi, xLo, outp + NOUT,
                                                      lb1_re, lb1_im, LB, tabC, tabS);
    wawm_kernel<<<dim3(512, 2, 2), blk, 0, stream>>>(l1_re, l1_im, lc_w, tabC, tabS,
                                                     WaHu, WaLu, WmHu, WmLu);

    // ---- freq branch (keeps hi/lo: fa and up are direct outputs) ----
    gemm_mfma3<64,64,1,0,0><<<dim3(8, 64), blk, 0, stream>>>(xHi, xLo, WaHu, WaLu, LB,
                                                             LL, nullptr, nullptr, nullptr, 512, 512);
    cattn2_kernel<<<dim3(128, 2), dim3(512), 65536, stream>>>(LL, LLH, LLL);         // LL hi/lo
    gemm_mfma3<64,64,0,1,1><<<dim3(8, 64), blk, 0, stream>>>(LLH, LLL, WmHu, WmLu, lc_b,
                                                             FA, outp + 2 * NOUT, faHi, faLo, 512, 512);

    // ---- qkv both TELs (single-product bf16 both branches; R22) ----
    gemm_qkv_dual<64,128><<<dim3(12, 64, 2), blk, 0, stream>>>(faHi, w_rin, r_in_b, qkvR,
                                                               xHi, w_tin, t_in_b, qkvT, 1536, 512);

    // ---- attention (r+t) + up1, merged ----
    attn_up1_kernel<<<dim3(1024, 1, 3), blk, 0, stream>>>(qkvR, qkvT, aoR, aoT,
                                                          faHi, w_up1, up1_b, u1b);

    // ---- out-proj r/t + up2 (tri) ----
    gemm_out_tri<64,64><<<dim3(8, 64, 3), blk, 0, stream>>>(aoR, w_rout, r_out_b, oR,
                                                            aoT, w_tout, t_out_b, oT,
                                                            u1b, w_up2, up2_b, outp + 3 * NOUT, 512, 512);
    add_ln_d1<<<dim3(8192), blk, 0, stream>>>(FA, oR, r_ln1_w, r_ln1_b, x1rH, x1rL,
                                              x,  oT, t_ln1_w, t_ln1_b, x1tH, x1tL);
    gemm_dual<64,128,1,1><<<dim3(16, 64, 2), blk, 0, stream>>>(x1rH, x1tH, w_rl1, w_tl1,
                                                               r_lin1_b, t_lin1_b, nullptr, nullptr,
                                                               f1R, f1T, 2048, 512);
    gemm_dual<64,64,0,0><<<dim3(8, 64, 2), blk, 0, stream>>>(f1R, f1T, w_rl2, w_tl2,
                                                             r_lin2_b, t_lin2_b, yR, yT,
                                                             nullptr, nullptr, 512, 2048);
    add_ln_d2<<<dim3(8192), blk, 0, stream>>>(x1rH, x1rL, yR, r_ln2_w, r_ln2_b, x2R,
                                              x1tH, x1tL, yT, t_ln2_w, t_ln2_b, x2T);
    relu_bln_fused<<<dim3(128), dim3(1024), 0, stream>>>(x2R, n2_w, n2_b, x2T, n1_w, n1_b, outp);
}

// Round 16
// 424.868 us; speedup vs baseline: 1.1374x; 1.0153x over previous
//
#include <hip/hip_runtime.h>
#include <math.h>

// NoiScaleModule: B=128, C=32(seq), S=512(d_model), EMB=256, NHEAD=8, DFF=2048
// All tensors FLOAT32. Outputs concat flat: res[2M], down_x[2M], fa[2M], up[2M]
//
// R20: 458.8. R22: r-qkv single-product bf16 (chain-consistent precision),
//      qkv LDS 48->24KB. 458->431.4 (best). Top kernel now attn_up1 (43.8us,
//      VALUBusy 27%, 12x above f32 compute floor): 2 LDS reads/FMA, serial
//      32-thread softmax.
// R23: attention register-blocking: QK shares sj per thread (hoist ks[sj][d],
//      4 rows/load); PV shares d (hoist vs[k][d], 8 rows/load); softmax
//      wave-parallel (32 rows x 8 lanes, shfl_xor reduce). LDS traffic ~/1.7,
//      all 256 lanes active. Same accumulation order per output.

#define NROW 4096
#define NOUT 2097152

typedef __attribute__((ext_vector_type(8))) short short8;
typedef __attribute__((ext_vector_type(4))) float floatx4;

__device__ __forceinline__ unsigned short f2bf(float f) {
    union { float f; unsigned u; } v; v.f = f;
    return (unsigned short)((v.u + 0x7fffu + ((v.u >> 16) & 1u)) >> 16);
}
__device__ __forceinline__ float bf2f(unsigned short h) {
    union { unsigned u; float f; } v; v.u = ((unsigned)h) << 16;
    return v.f;
}

__device__ __forceinline__ void gload16(const unsigned short* g, unsigned short* l) {
    __builtin_amdgcn_global_load_lds((const __attribute__((address_space(1))) void*)g,
                                     (__attribute__((address_space(3))) void*)l, 16, 0, 0);
}

// XCD-chunked swizzle (T1): requires nwg % 8 == 0.
__device__ __forceinline__ void xcd_swizzle(int& bx, int& by, int& bz) {
    const int gx = gridDim.x, gy = gridDim.y;
    const int nwg = gx * gy * gridDim.z;
    int b = (bz * gy + by) * gx + bx;
    const int chunk = nwg >> 3;
    const int lb = (b & 7) * chunk + (b >> 3);
    bx = lb % gx;
    const int rem = lb / gx;
    by = rem % gy;
    bz = rem / gy;
}

// Wa (z=0) and Wm (z=1) in one dispatch; both emit bf16 hi/lo directly.
__global__ __launch_bounds__(256) void wawm_kernel(const float* __restrict__ l1_re, const float* __restrict__ l1_im,
                                                   const float* __restrict__ lc_w,
                                                   const float* __restrict__ tabC, const float* __restrict__ tabS,
                                                   unsigned short* __restrict__ WaH, unsigned short* __restrict__ WaL,
                                                   unsigned short* __restrict__ WmH, unsigned short* __restrict__ WmL)
{
    __shared__ float lw[512];
    const float inv = 0.04419417382415922f;  // 1/sqrt(512)
    if (blockIdx.z == 0) {
        int n  = blockIdx.x;
        int ep = blockIdx.y * 256 + threadIdx.x;
        float acc = 0.f;
        if (ep < 256) {
            for (int k = 0; k < 128; ++k) {
                float c = tabC[n * 256 + k], s = tabS[n * 256 + k];
                acc += c * l1_re[k * 256 + ep] + s * l1_im[k * 256 + ep];
            }
        } else {
            int e = ep - 256;
            for (int k = 0; k < 128; ++k) {
                float c = tabC[n * 256 + k], s = tabS[n * 256 + k];
                acc += c * l1_im[k * 256 + e] - s * l1_re[k * 256 + e];
            }
        }
        float v = acc * inv;
        size_t idx = (size_t)ep * 512 + n;
        unsigned short h = f2bf(v);
        WaH[idx] = h;
        WaL[idx] = f2bf(v - bf2f(h));
    } else {
        int s  = blockIdx.x;
        int kk = blockIdx.y * 256 + threadIdx.x;
        for (int i = threadIdx.x; i < 512; i += 256) lw[i] = lc_w[s * 512 + i];
        __syncthreads();
        float acc = 0.f;
        if (kk < 256) {
            int k = kk;
            for (int n = 0; n < 512; ++n) acc += tabC[n * 256 + k] * lw[n];
            acc *= (k == 0) ? inv : 2.f * inv;
        } else {
            int k = kk - 256;
            if (k == 0) acc = 0.f;
            else {
                for (int n = 0; n < 512; ++n) acc += tabS[n * 256 + k] * lw[n];
                acc *= -2.f * inv;
            }
        }
        size_t idx = (size_t)s * 512 + kk;
        unsigned short h = f2bf(acc);
        WmH[idx] = h;
        WmL[idx] = f2bf(acc - bf2f(h));
    }
}

// ---------------- uber elementwise prep: wcvt(+rinLo) | xsplit | lbpack | tab ------------
__global__ __launch_bounds__(256) void uber_prep_kernel(
    const float* s0, const float* s1, const float* s2, const float* s3, const float* s4,
    const float* s5, const float* s6, const float* s7, const float* s8, const float* s9,
    unsigned short* __restrict__ o, unsigned short* __restrict__ rinLo,
    const float* __restrict__ x, unsigned short* __restrict__ xhi,
    unsigned short* __restrict__ xlo, float* __restrict__ xcp,
    const float* __restrict__ lbre, const float* __restrict__ lbim, float* __restrict__ lbout,
    float* __restrict__ tabC, float* __restrict__ tabS)
{
    const int bid = blockIdx.x, tid = threadIdx.x;
    if (bid < 26624) {
        int i = bid * 256 + tid;  // exactly covers 6815744
        const float* s; int off;
        if (i < 3145728) {
            if (i < 1048576) { if (i < 786432) { s = s0; off = 0; } else { s = s1; off = 786432; } }
            else             { if (i < 2097152) { s = s2; off = 1048576; } else { s = s3; off = 2097152; } }
        } else {
            if (i < 5242880) {
                if (i < 3932160) { s = s4; off = 3145728; }
                else if (i < 4194304) { s = s5; off = 3932160; }
                else { s = s6; off = 4194304; }
            } else {
                if (i < 6291456) { s = s7; off = 5242880; }
                else if (i < 6553600) { s = s8; off = 6291456; }
                else { s = s9; off = 6553600; }
            }
        }
        float v = s[i - off];
        unsigned short h = f2bf(v);
        o[i] = h;
        if (i >= 3145728 && i < 3932160) rinLo[i - 3145728] = f2bf(v - bf2f(h));
    } else if (bid < 34816) {
        int i = (bid - 26624) * 256 + tid;  // exactly covers 2097152
        float v = x[i];
        unsigned short h = f2bf(v);
        xhi[i] = h;
        xlo[i] = f2bf(v - bf2f(h));
        xcp[i] = v;
    } else if (bid < 34818) {
        int i = (bid - 34816) * 256 + tid;
        if (i < 512) lbout[i] = (i < 256) ? lbre[i] : lbim[i - 256];
    } else {
        int n = bid - 34818;                 // 0..511
        int k = tid;                         // 0..255
        int m = (n * k) & 511;
        float th = (float)m * 0.01227184630308513f;  // 2*pi/512
        float sv, cv; sincosf(th, &sv, &cv);
        tabC[n * 256 + k] = cv;
        tabS[n * 256 + k] = sv;
    }
}

// ---------------- dual-branch GEMM (BK=64): z=0/1 select. For lin1/lin2. ----------------
template <int TM, int TN, int ACT, int WBF>
__global__ __launch_bounds__(256) void gemm_dual(
    const unsigned short* __restrict__ A0, const unsigned short* __restrict__ A1,
    const unsigned short* __restrict__ W0, const unsigned short* __restrict__ W1,
    const float* __restrict__ b0, const float* __restrict__ b1,
    float* __restrict__ C0, float* __restrict__ C1,
    unsigned short* __restrict__ D0, unsigned short* __restrict__ D1, int N, int K)
{
    constexpr int MI = TM / 32, NJ = TN / 32;
    constexpr int ARW = TM / 4, BRW = TN / 4;
    __shared__ unsigned short As[2][TM * 32];
    __shared__ unsigned short Bs[2][TN * 32];
    const int tid = threadIdx.x;
    const int wave = tid >> 6, lane = tid & 63;
    int bx = blockIdx.x, by = blockIdx.y, bz = blockIdx.z;
    xcd_swizzle(bx, by, bz);
    const int m0 = by * TM, n0 = bx * TN;
    const int z = bz;
    const unsigned short* A = z ? A1 : A0;
    const unsigned short* W = z ? W1 : W0;
    const float* bias = z ? b1 : b0;
    float* Cf = z ? C1 : C0;
    unsigned short* Cb = z ? D1 : D0;
    const int sr = lane >> 2, sc = (lane & 3) * 8;
    const unsigned short* aS = A + (size_t)(m0 + wave * ARW + sr) * K + sc;
    const unsigned short* wS = W + (size_t)(n0 + wave * BRW + sr) * K + sc;
    const int wm = (wave >> 1) * (TM / 2), wn = (wave & 1) * (TN / 2);
    const int fr = lane & 15, fko = (lane >> 4) * 8;

    floatx4 acc[MI][NJ];
#pragma unroll
    for (int i = 0; i < MI; ++i)
#pragma unroll
        for (int j = 0; j < NJ; ++j) acc[i][j] = (floatx4){0.f, 0.f, 0.f, 0.f};

    for (int k0 = 0; k0 < K; k0 += 64) {
#pragma unroll
        for (int h = 0; h < 2; ++h) {
#pragma unroll
            for (int c = 0; c < ARW / 16; ++c)
                gload16(aS + (size_t)(16 * c) * K + k0 + 32 * h, &As[h][(wave * ARW + 16 * c) * 32]);
#pragma unroll
            for (int c = 0; c < BRW / 16; ++c)
                gload16(wS + (size_t)(16 * c) * K + k0 + 32 * h, &Bs[h][(wave * BRW + 16 * c) * 32]);
        }
        __syncthreads();
#pragma unroll
        for (int h = 0; h < 2; ++h) {
            short8 af[MI], bfr[NJ];
#pragma unroll
            for (int i = 0; i < MI; ++i) af[i] = *(const short8*)&As[h][(wm + i * 16 + fr) * 32 + fko];
#pragma unroll
            for (int j = 0; j < NJ; ++j) bfr[j] = *(const short8*)&Bs[h][(wn + j * 16 + fr) * 32 + fko];
#pragma unroll
            for (int i = 0; i < MI; ++i)
#pragma unroll
                for (int j = 0; j < NJ; ++j)
                    acc[i][j] = __builtin_amdgcn_mfma_f32_16x16x32_bf16(af[i], bfr[j], acc[i][j], 0, 0, 0);
        }
        __syncthreads();
    }
    const int r0 = m0 + wm + (lane >> 4) * 4;
#pragma unroll
    for (int i = 0; i < MI; ++i) {
#pragma unroll
        for (int j = 0; j < NJ; ++j) {
            int n = n0 + wn + j * 16 + fr;
            float bv = bias[n];
#pragma unroll
            for (int r = 0; r < 4; ++r) {
                int m = r0 + i * 16 + r;
                size_t idx = (size_t)m * N + n;
                float v = acc[i][j][r] + bv;
                if (ACT) v = fmaxf(v, 0.f);
                if (WBF) Cb[idx] = f2bf(v);
                else     Cf[idx] = v;
            }
        }
    }
}

// ---------------- tri-branch single-product GEMM (BK=64, TN=64): out-proj r/t + up2 ------
template <int TM, int TN>
__global__ __launch_bounds__(256) void gemm_out_tri(
    const unsigned short* __restrict__ A0, const unsigned short* __restrict__ W0,
    const float* __restrict__ b0, float* __restrict__ C0,
    const unsigned short* __restrict__ A1, const unsigned short* __restrict__ W1,
    const float* __restrict__ b1, float* __restrict__ C1,
    const unsigned short* __restrict__ A2, const unsigned short* __restrict__ W2,
    const float* __restrict__ b2, float* __restrict__ C2, int N, int K)
{
    constexpr int MI = TM / 32, NJ = TN / 32;
    constexpr int ARW = TM / 4, BRW = TN / 4;
    __shared__ unsigned short As[2][TM * 32];
    __shared__ unsigned short Bs[2][TN * 32];
    const int tid = threadIdx.x;
    const int wave = tid >> 6, lane = tid & 63;
    int bx = blockIdx.x, by = blockIdx.y, bz = blockIdx.z;
    xcd_swizzle(bx, by, bz);
    const int m0 = by * TM, n0 = bx * TN;
    const unsigned short* A = (bz == 0) ? A0 : (bz == 1) ? A1 : A2;
    const unsigned short* W = (bz == 0) ? W0 : (bz == 1) ? W1 : W2;
    const float* bias       = (bz == 0) ? b0 : (bz == 1) ? b1 : b2;
    float* Cf               = (bz == 0) ? C0 : (bz == 1) ? C1 : C2;
    const int sr = lane >> 2, sc = (lane & 3) * 8;
    const unsigned short* aS = A + (size_t)(m0 + wave * ARW + sr) * K + sc;
    const unsigned short* wS = W + (size_t)(n0 + wave * BRW + sr) * K + sc;
    const int wm = (wave >> 1) * (TM / 2), wn = (wave & 1) * (TN / 2);
    const int fr = lane & 15, fko = (lane >> 4) * 8;

    floatx4 acc[MI][NJ];
#pragma unroll
    for (int i = 0; i < MI; ++i)
#pragma unroll
        for (int j = 0; j < NJ; ++j) acc[i][j] = (floatx4){0.f, 0.f, 0.f, 0.f};

    for (int k0 = 0; k0 < K; k0 += 64) {
#pragma unroll
        for (int h = 0; h < 2; ++h) {
#pragma unroll
            for (int c = 0; c < ARW / 16; ++c)
                gload16(aS + (size_t)(16 * c) * K + k0 + 32 * h, &As[h][(wave * ARW + 16 * c) * 32]);
#pragma unroll
            for (int c = 0; c < BRW / 16; ++c)
                gload16(wS + (size_t)(16 * c) * K + k0 + 32 * h, &Bs[h][(wave * BRW + 16 * c) * 32]);
        }
        __syncthreads();
#pragma unroll
        for (int h = 0; h < 2; ++h) {
            short8 af[MI], bfr[NJ];
#pragma unroll
            for (int i = 0; i < MI; ++i) af[i] = *(const short8*)&As[h][(wm + i * 16 + fr) * 32 + fko];
#pragma unroll
            for (int j = 0; j < NJ; ++j) bfr[j] = *(const short8*)&Bs[h][(wn + j * 16 + fr) * 32 + fko];
#pragma unroll
            for (int i = 0; i < MI; ++i)
#pragma unroll
                for (int j = 0; j < NJ; ++j)
                    acc[i][j] = __builtin_amdgcn_mfma_f32_16x16x32_bf16(af[i], bfr[j], acc[i][j], 0, 0, 0);
        }
        __syncthreads();
    }
    const int r0 = m0 + wm + (lane >> 4) * 4;
#pragma unroll
    for (int i = 0; i < MI; ++i) {
#pragma unroll
        for (int j = 0; j < NJ; ++j) {
            int n = n0 + wn + j * 16 + fr;
            float bv = bias[n];
#pragma unroll
            for (int r = 0; r < 4; ++r) {
                int m = r0 + i * 16 + r;
                Cf[(size_t)m * N + n] = acc[i][j][r] + bv;
            }
        }
    }
}

// ---------------- fused hi/lo 3-product MFMA GEMM (BK=64, single-buffer) ----------------
template <int TM, int TN, int ACT, int WCOPY, int WHILO>
__global__ __launch_bounds__(256) void gemm_mfma3(
    const unsigned short* __restrict__ Ah, const unsigned short* __restrict__ Al,
    const unsigned short* __restrict__ Wh, const unsigned short* __restrict__ Wl,
    const float* __restrict__ bias, float* __restrict__ Cf, float* __restrict__ Ccopy,
    unsigned short* __restrict__ Hh, unsigned short* __restrict__ Hl, int N, int K)
{
    constexpr int MI = TM / 32, NJ = TN / 32;
    constexpr int ARW = TM / 4, BRW = TN / 4;
    __shared__ unsigned short Ash[2][TM * 32];
    __shared__ unsigned short Asl[2][TM * 32];
    __shared__ unsigned short Bsh[2][TN * 32];
    __shared__ unsigned short Bsl[2][TN * 32];
    const int tid = threadIdx.x;
    const int wave = tid >> 6, lane = tid & 63;
    int bx = blockIdx.x, by = blockIdx.y, bz = blockIdx.z;
    xcd_swizzle(bx, by, bz);
    const int m0 = by * TM, n0 = bx * TN;
    const int sr = lane >> 2, sc = (lane & 3) * 8;
    const size_t aoff = (size_t)(m0 + wave * ARW + sr) * K + sc;
    const size_t woff = (size_t)(n0 + wave * BRW + sr) * K + sc;
    const int wm = (wave >> 1) * (TM / 2), wn = (wave & 1) * (TN / 2);
    const int fr = lane & 15, fko = (lane >> 4) * 8;

    floatx4 acc[MI][NJ];
#pragma unroll
    for (int i = 0; i < MI; ++i)
#pragma unroll
        for (int j = 0; j < NJ; ++j) acc[i][j] = (floatx4){0.f, 0.f, 0.f, 0.f};

    for (int k0 = 0; k0 < K; k0 += 64) {
#pragma unroll
        for (int h = 0; h < 2; ++h) {
#pragma unroll
            for (int c = 0; c < ARW / 16; ++c) {
                gload16(Ah + aoff + (size_t)(16 * c) * K + k0 + 32 * h, &Ash[h][(wave * ARW + 16 * c) * 32]);
                gload16(Al + aoff + (size_t)(16 * c) * K + k0 + 32 * h, &Asl[h][(wave * ARW + 16 * c) * 32]);
            }
#pragma unroll
            for (int c = 0; c < BRW / 16; ++c) {
                gload16(Wh + woff + (size_t)(16 * c) * K + k0 + 32 * h, &Bsh[h][(wave * BRW + 16 * c) * 32]);
                gload16(Wl + woff + (size_t)(16 * c) * K + k0 + 32 * h, &Bsl[h][(wave * BRW + 16 * c) * 32]);
            }
        }
        __syncthreads();
#pragma unroll
        for (int h = 0; h < 2; ++h) {
            short8 ah[MI], al[MI], bh[NJ], bl[NJ];
#pragma unroll
            for (int i = 0; i < MI; ++i) {
                ah[i] = *(const short8*)&Ash[h][(wm + i * 16 + fr) * 32 + fko];
                al[i] = *(const short8*)&Asl[h][(wm + i * 16 + fr) * 32 + fko];
            }
#pragma unroll
            for (int j = 0; j < NJ; ++j) {
                bh[j] = *(const short8*)&Bsh[h][(wn + j * 16 + fr) * 32 + fko];
                bl[j] = *(const short8*)&Bsl[h][(wn + j * 16 + fr) * 32 + fko];
            }
#pragma unroll
            for (int i = 0; i < MI; ++i)
#pragma unroll
                for (int j = 0; j < NJ; ++j) {
                    acc[i][j] = __builtin_amdgcn_mfma_f32_16x16x32_bf16(al[i], bh[j], acc[i][j], 0, 0, 0);
                    acc[i][j] = __builtin_amdgcn_mfma_f32_16x16x32_bf16(ah[i], bl[j], acc[i][j], 0, 0, 0);
                    acc[i][j] = __builtin_amdgcn_mfma_f32_16x16x32_bf16(ah[i], bh[j], acc[i][j], 0, 0, 0);
                }
        }
        __syncthreads();
    }
    const int r0 = m0 + wm + (lane >> 4) * 4;
#pragma unroll
    for (int i = 0; i < MI; ++i) {
#pragma unroll
        for (int j = 0; j < NJ; ++j) {
            int n = n0 + wn + j * 16 + fr;
            float bv = bias[n];
#pragma unroll
            for (int r = 0; r < 4; ++r) {
                int m = r0 + i * 16 + r;
                size_t idx = (size_t)m * N + n;
                float v = acc[i][j][r] + bv;
                if (ACT) v = fmaxf(v, 0.f);
                Cf[idx] = v;
                if (WCOPY) Ccopy[idx] = v;
                if (WHILO) {
                    unsigned short h = f2bf(v);
                    Hh[idx] = h;
                    Hl[idx] = f2bf(v - bf2f(h));
                }
            }
        }
    }
}

// ---------------- merged qkv GEMM (BK=64, single-product both branches):
//                  z=0 r-qkv faHi x w_rin -> f32; z=1 t-qkv xHi x w_tin -> bf16. ----------
template <int TM, int TN>
__global__ __launch_bounds__(256) void gemm_qkv_dual(
    const unsigned short* __restrict__ A0, const unsigned short* __restrict__ W0,
    const float* __restrict__ b0, float* __restrict__ C0,
    const unsigned short* __restrict__ A1, const unsigned short* __restrict__ W1,
    const float* __restrict__ b1, unsigned short* __restrict__ C1,
    int N, int K)
{
    constexpr int MI = TM / 32, NJ = TN / 32;
    constexpr int ARW = TM / 4, BRW = TN / 4;
    __shared__ unsigned short As[2][TM * 32];
    __shared__ unsigned short Bs[2][TN * 32];
    const int tid = threadIdx.x;
    const int wave = tid >> 6, lane = tid & 63;
    int bx = blockIdx.x, by = blockIdx.y, bz = blockIdx.z;
    xcd_swizzle(bx, by, bz);
    const int m0 = by * TM, n0 = bx * TN;
    const unsigned short* A = bz ? A1 : A0;
    const unsigned short* W = bz ? W1 : W0;
    const float* bias = bz ? b1 : b0;
    const int sr = lane >> 2, sc = (lane & 3) * 8;
    const unsigned short* aS = A + (size_t)(m0 + wave * ARW + sr) * K + sc;
    const unsigned short* wS = W + (size_t)(n0 + wave * BRW + sr) * K + sc;
    const int wm = (wave >> 1) * (TM / 2), wn = (wave & 1) * (TN / 2);
    const int fr = lane & 15, fko = (lane >> 4) * 8;

    floatx4 acc[MI][NJ];
#pragma unroll
    for (int i = 0; i < MI; ++i)
#pragma unroll
        for (int j = 0; j < NJ; ++j) acc[i][j] = (floatx4){0.f, 0.f, 0.f, 0.f};

    for (int k0 = 0; k0 < K; k0 += 64) {
#pragma unroll
        for (int h = 0; h < 2; ++h) {
#pragma unroll
            for (int c = 0; c < ARW / 16; ++c)
                gload16(aS + (size_t)(16 * c) * K + k0 + 32 * h, &As[h][(wave * ARW + 16 * c) * 32]);
#pragma unroll
            for (int c = 0; c < BRW / 16; ++c)
                gload16(wS + (size_t)(16 * c) * K + k0 + 32 * h, &Bs[h][(wave * BRW + 16 * c) * 32]);
        }
        __syncthreads();
#pragma unroll
        for (int h = 0; h < 2; ++h) {
            short8 af[MI], bfr[NJ];
#pragma unroll
            for (int i = 0; i < MI; ++i) af[i] = *(const short8*)&As[h][(wm + i * 16 + fr) * 32 + fko];
#pragma unroll
            for (int j = 0; j < NJ; ++j) bfr[j] = *(const short8*)&Bs[h][(wn + j * 16 + fr) * 32 + fko];
#pragma unroll
            for (int i = 0; i < MI; ++i)
#pragma unroll
                for (int j = 0; j < NJ; ++j)
                    acc[i][j] = __builtin_amdgcn_mfma_f32_16x16x32_bf16(af[i], bfr[j], acc[i][j], 0, 0, 0);
        }
        __syncthreads();
    }
    const int r0 = m0 + wm + (lane >> 4) * 4;
#pragma unroll
    for (int i = 0; i < MI; ++i) {
#pragma unroll
        for (int j = 0; j < NJ; ++j) {
            int n = n0 + wn + j * 16 + fr;
            float bv = bias[n];
#pragma unroll
            for (int r = 0; r < 4; ++r) {
                int m = r0 + i * 16 + r;
                size_t idx = (size_t)m * N + n;
                float v = acc[i][j][r] + bv;
                if (bz == 0) C0[idx] = v;
                else         C1[idx] = f2bf(v);
            }
        }
    }
}

// ---------------- merged attention + up1: z=0 attn-r (f32 qkv), z=1 attn-t (bf16 qkv),
//                  z=2 up1 GEMM (512 of 1024 blocks; whole-block early exit).
// R23: register-blocked QK/PV + wave-parallel softmax. ------------------------------------
__global__ __launch_bounds__(256) void attn_up1_kernel(
    const float* __restrict__ qkvF, const unsigned short* __restrict__ qkvB,
    unsigned short* __restrict__ outR, unsigned short* __restrict__ outT,
    const unsigned short* __restrict__ A2, const unsigned short* __restrict__ W2,
    const float* __restrict__ b2, unsigned short* __restrict__ C2)
{
    __shared__ __align__(16) char smem[29184];
    const int tid = threadIdx.x;
    if (blockIdx.z < 2) {
        // ---- attention branch (29184 B LDS) ----
        float (*qs)[65] = (float(*)[65])smem;
        float (*ks)[65] = (float(*)[65])(smem + 8320);
        float (*vs)[65] = (float(*)[65])(smem + 16640);
        float (*ps)[33] = (float(*)[33])(smem + 24960);
        const int isT = blockIdx.z;
        const int b = blockIdx.x >> 3;
        const int h = blockIdx.x & 7;
        if (isT) {
            for (int i = tid; i < 2048; i += 256) {
                int s = i >> 6, d = i & 63;
                size_t base = ((size_t)(b * 32 + s)) * 1536 + h * 64 + d;
                qs[s][d] = bf2f(qkvB[base]);
                ks[s][d] = bf2f(qkvB[base + 512]);
                vs[s][d] = bf2f(qkvB[base + 1024]);
            }
        } else {
            for (int i = tid; i < 2048; i += 256) {
                int s = i >> 6, d = i & 63;
                size_t base = ((size_t)(b * 32 + s)) * 1536 + h * 64 + d;
                qs[s][d] = qkvF[base];
                ks[s][d] = qkvF[base + 512];
                vs[s][d] = qkvF[base + 1024];
            }
        }
        __syncthreads();
        // ---- QK: thread owns col sj, rows si0+8p (shared ks load, 4 chains) ----
        {
            const int sj = tid & 31;
            const int si0 = tid >> 5;          // 0..7
            float acc0 = 0.f, acc1 = 0.f, acc2 = 0.f, acc3 = 0.f;
#pragma unroll 8
            for (int d = 0; d < 64; ++d) {
                float kd = ks[sj][d];
                acc0 += qs[si0][d] * kd;
                acc1 += qs[si0 + 8][d] * kd;
                acc2 += qs[si0 + 16][d] * kd;
                acc3 += qs[si0 + 24][d] * kd;
            }
            ps[si0][sj]      = acc0 * 0.125f;
            ps[si0 + 8][sj]  = acc1 * 0.125f;
            ps[si0 + 16][sj] = acc2 * 0.125f;
            ps[si0 + 24][sj] = acc3 * 0.125f;
        }
        __syncthreads();
        // ---- softmax: 32 rows x 8 lanes, shfl_xor reduce within 8-lane groups ----
        {
            const int r = tid >> 3, sub = tid & 7;
            float mx = -1e30f;
#pragma unroll
            for (int j = 0; j < 4; ++j) mx = fmaxf(mx, ps[r][sub + 8 * j]);
#pragma unroll
            for (int o = 4; o; o >>= 1) mx = fmaxf(mx, __shfl_xor(mx, o));
            float sum = 0.f;
            float e[4];
#pragma unroll
            for (int j = 0; j < 4; ++j) { e[j] = __expf(ps[r][sub + 8 * j] - mx); sum += e[j]; }
#pragma unroll
            for (int o = 4; o; o >>= 1) sum += __shfl_xor(sum, o);
            float inv = 1.f / sum;
#pragma unroll
            for (int j = 0; j < 4; ++j) ps[r][sub + 8 * j] = e[j] * inv;
        }
        __syncthreads();
        // ---- PV: thread owns col d, rows s0+4p (shared vs load, 8 chains) ----
        unsigned short* ob = isT ? outT : outR;
        {
            const int d = tid & 63;
            const int s0 = tid >> 6;           // 0..3
            float acc[8];
#pragma unroll
            for (int p = 0; p < 8; ++p) acc[p] = 0.f;
#pragma unroll 4
            for (int k = 0; k < 32; ++k) {
                float vk = vs[k][d];
#pragma unroll
                for (int p = 0; p < 8; ++p)
                    acc[p] += ps[s0 + 4 * p][k] * vk;
            }
#pragma unroll
            for (int p = 0; p < 8; ++p) {
                int s = s0 + 4 * p;
                ob[((size_t)(b * 32 + s)) * 512 + h * 64 + d] = f2bf(acc[p]);
            }
        }
    } else {
        // ---- up1 GEMM branch: 64x64 tile, BK=64, N=K=512, 512 blocks ----
        const int b = blockIdx.x;
        if (b >= 512) return;                      // whole block exits pre-barrier
        const int lb = (b & 7) * 64 + (b >> 3);    // manual 512-chunk swizzle
        const int bxg = lb & 7, byg = lb >> 3;
        unsigned short (*As)[2048] = (unsigned short(*)[2048])smem;          // 2*4096B
        unsigned short (*Bs)[2048] = (unsigned short(*)[2048])(smem + 8192); // 2*4096B
        const int wave = tid >> 6, lane = tid & 63;
        const int m0 = byg * 64, n0 = bxg * 64;
        const int sr = lane >> 2, sc = (lane & 3) * 8;
        const unsigned short* aS = A2 + (size_t)(m0 + wave * 16 + sr) * 512 + sc;
        const unsigned short* wS = W2 + (size_t)(n0 + wave * 16 + sr) * 512 + sc;
        const int wm = (wave >> 1) * 32, wn = (wave & 1) * 32;
        const int fr = lane & 15, fko = (lane >> 4) * 8;
        floatx4 acc[2][2];
#pragma unroll
        for (int i = 0; i < 2; ++i)
#pragma unroll
            for (int j = 0; j < 2; ++j) acc[i][j] = (floatx4){0.f, 0.f, 0.f, 0.f};
        for (int k0 = 0; k0 < 512; k0 += 64) {
#pragma unroll
            for (int h = 0; h < 2; ++h) {
                gload16(aS + k0 + 32 * h, &As[h][(wave * 16) * 32]);
                gload16(wS + k0 + 32 * h, &Bs[h][(wave * 16) * 32]);
            }
            __syncthreads();
#pragma unroll
            for (int h = 0; h < 2; ++h) {
                short8 af[2], bfr[2];
#pragma unroll
                for (int i = 0; i < 2; ++i) af[i] = *(const short8*)&As[h][(wm + i * 16 + fr) * 32 + fko];
#pragma unroll
                for (int j = 0; j < 2; ++j) bfr[j] = *(const short8*)&Bs[h][(wn + j * 16 + fr) * 32 + fko];
#pragma unroll
                for (int i = 0; i < 2; ++i)
#pragma unroll
                    for (int j = 0; j < 2; ++j)
                        acc[i][j] = __builtin_amdgcn_mfma_f32_16x16x32_bf16(af[i], bfr[j], acc[i][j], 0, 0, 0);
            }
            __syncthreads();
        }
        const int r0 = m0 + wm + (lane >> 4) * 4;
#pragma unroll
        for (int i = 0; i < 2; ++i)
#pragma unroll
            for (int j = 0; j < 2; ++j) {
                int n = n0 + wn + j * 16 + fr;
                float bv = b2[n];
#pragma unroll
                for (int r = 0; r < 4; ++r) {
                    int m = r0 + i * 16 + r;
                    C2[(size_t)m * 512 + n] = f2bf(acc[i][j][r] + bv);
                }
            }
    }
}

// ---------------- complex self-attention: LDS-resident, grid (128 batch, 2 half) ----------
__global__ __launch_bounds__(512) void cattn2_kernel(const float* __restrict__ LL,
                                                     unsigned short* __restrict__ outHi,
                                                     unsigned short* __restrict__ outLo)
{
    extern __shared__ float Xs[];
    __shared__ float Pr[16][33], Pi[16][33];
    const int b = blockIdx.x, half = blockIdx.y;
    const int tid = threadIdx.x;
    const float* base = LL + (size_t)b * 16384;
    for (int i = tid; i < 16384; i += 512) {
        int c = i >> 9, e = i & 511;
        Xs[e * 32 + ((c ^ e) & 31)] = base[i];
    }
    __syncthreads();
    {
        const int li = tid >> 5;                 // 0..15
        const int ci = half * 16 + li;
        const int ck = tid & 31;
        float ar = 0.f, ai = 0.f;
#pragma unroll 4
        for (int er = 0; er < 256; ++er) {
            const int sw = er & 31;
            float yr = Xs[er * 32 + ((ck ^ sw) & 31)];
            float yi = Xs[(er + 256) * 32 + ((ck ^ sw) & 31)];
            float xr = Xs[er * 32 + ((ci ^ sw) & 31)];
            float xi = Xs[(er + 256) * 32 + ((ci ^ sw) & 31)];
            ar += xr * yr - xi * yi;
            ai += xr * yi + xi * yr;
        }
        Pr[li][ck] = ar * 0.0625f;
        Pi[li][ck] = ai * 0.0625f;
    }
    __syncthreads();
    if (tid < 32) {
        int r = tid & 15;
        float (*P)[33] = (tid < 16) ? Pr : Pi;
        float mx = -1e30f;
        for (int j = 0; j < 32; ++j) mx = fmaxf(mx, P[r][j]);
        float s = 0.f;
        for (int j = 0; j < 32; ++j) { float e = __expf(P[r][j] - mx); P[r][j] = e; s += e; }
        float inv = 1.f / s;
        for (int j = 0; j < 32; ++j) P[r][j] *= inv;
    }
    __syncthreads();
    const int er = tid & 255;
    const int th = tid >> 8;                     // 0 or 1: t in [th*8, th*8+8)
    const int sw = er & 31;
    float accr[8], acci[8];
#pragma unroll
    for (int t = 0; t < 8; ++t) { accr[t] = 0.f; acci[t] = 0.f; }
    for (int k = 0; k < 32; ++k) {
        float yr = Xs[er * 32 + ((k ^ sw) & 31)];
        float yi = Xs[(er + 256) * 32 + ((k ^ sw) & 31)];
#pragma unroll
        for (int t = 0; t < 8; ++t) {
            float pr = Pr[th * 8 + t][k], pi = Pi[th * 8 + t][k];
            accr[t] += pr * yr - pi * yi;
            acci[t] += pr * yi + pi * yr;
        }
    }
#pragma unroll
    for (int t = 0; t < 8; ++t) {
        int c = half * 16 + th * 8 + t;
        float vr = Xs[er * 32 + ((c ^ sw) & 31)] + accr[t];
        float vi = Xs[(er + 256) * 32 + ((c ^ sw) & 31)] + acci[t];
        size_t ir = (size_t)b * 16384 + (size_t)c * 512 + er;
        unsigned short hr = f2bf(vr), hi2 = f2bf(vi);
        outHi[ir] = hr;        outLo[ir] = f2bf(vr - bf2f(hr));
        outHi[ir + 256] = hi2; outLo[ir + 256] = f2bf(vi - bf2f(hi2));
    }
}

// ---------------- DUAL add+LN (512), f32 resid, out bf16 hi/lo; rows>=4096 = branch 1 ----
__global__ __launch_bounds__(256) void add_ln_d1(
    const float* __restrict__ r0, const float* __restrict__ y0,
    const float* __restrict__ w0, const float* __restrict__ b0,
    unsigned short* __restrict__ h0, unsigned short* __restrict__ l0,
    const float* __restrict__ r1, const float* __restrict__ y1,
    const float* __restrict__ w1, const float* __restrict__ b1,
    unsigned short* __restrict__ h1, unsigned short* __restrict__ l1)
{
    const int row = blockIdx.x;
    const int br = row >> 12;
    const int rl = row & 4095;
    const float* resid = br ? r1 : r0;
    const float* y     = br ? y1 : y0;
    const float* w     = br ? w1 : w0;
    const float* bb    = br ? b1 : b0;
    unsigned short* oh = br ? h1 : h0;
    unsigned short* ol = br ? l1 : l0;
    const int tid = threadIdx.x;
    const size_t base = (size_t)rl * 512;
    float v0 = resid[base + tid] + y[base + tid];
    float v1 = resid[base + 256 + tid] + y[base + 256 + tid];
    float s = v0 + v1, q = v0 * v0 + v1 * v1;
    for (int off = 32; off; off >>= 1) { s += __shfl_down(s, off); q += __shfl_down(q, off); }
    __shared__ float sw[4], qw[4], ms, is;
    int wid = tid >> 6, lane = tid & 63;
    if (lane == 0) { sw[wid] = s; qw[wid] = q; }
    __syncthreads();
    if (tid == 0) {
        float S = sw[0] + sw[1] + sw[2] + sw[3];
        float Q = qw[0] + qw[1] + qw[2] + qw[3];
        float m = S * (1.f / 512.f);
        ms = m;
        is = rsqrtf(Q * (1.f / 512.f) - m * m + 1e-5f);
    }
    __syncthreads();
    float m = ms, inv = is;
    float o0 = (v0 - m) * inv * w[tid] + bb[tid];
    float o1 = (v1 - m) * inv * w[256 + tid] + bb[256 + tid];
    unsigned short e0 = f2bf(o0), e1 = f2bf(o1);
    oh[base + tid] = e0;       ol[base + tid] = f2bf(o0 - bf2f(e0));
    oh[base + 256 + tid] = e1; ol[base + 256 + tid] = f2bf(o1 - bf2f(e1));
}

// ---------------- DUAL add+LN (512), bf16 hi/lo resid, out f32 --------------------------
__global__ __launch_bounds__(256) void add_ln_d2(
    const unsigned short* __restrict__ rh0, const unsigned short* __restrict__ rl0,
    const float* __restrict__ y0, const float* __restrict__ w0, const float* __restrict__ b0,
    float* __restrict__ o0p,
    const unsigned short* __restrict__ rh1, const unsigned short* __restrict__ rl1,
    const float* __restrict__ y1, const float* __restrict__ w1, const float* __restrict__ b1,
    float* __restrict__ o1p)
{
    const int row = blockIdx.x;
    const int br = row >> 12;
    const int rl = row & 4095;
    const unsigned short* rh = br ? rh1 : rh0;
    const unsigned short* rlo = br ? rl1 : rl0;
    const float* y  = br ? y1 : y0;
    const float* w  = br ? w1 : w0;
    const float* bb = br ? b1 : b0;
    float* op = br ? o1p : o0p;
    const int tid = threadIdx.x;
    const size_t base = (size_t)rl * 512;
    float v0 = bf2f(rh[base + tid]) + bf2f(rlo[base + tid]) + y[base + tid];
    float v1 = bf2f(rh[base + 256 + tid]) + bf2f(rlo[base + 256 + tid]) + y[base + 256 + tid];
    float s = v0 + v1, q = v0 * v0 + v1 * v1;
    for (int off = 32; off; off >>= 1) { s += __shfl_down(s, off); q += __shfl_down(q, off); }
    __shared__ float sw[4], qw[4], ms, is;
    int wid = tid >> 6, lane = tid & 63;
    if (lane == 0) { sw[wid] = s; qw[wid] = q; }
    __syncthreads();
    if (tid == 0) {
        float S = sw[0] + sw[1] + sw[2] + sw[3];
        float Q = qw[0] + qw[1] + qw[2] + qw[3];
        float m = S * (1.f / 512.f);
        ms = m;
        is = rsqrtf(Q * (1.f / 512.f) - m * m + 1e-5f);
    }
    __syncthreads();
    float m = ms, inv = is;
    op[base + tid]       = (v0 - m) * inv * w[tid] + bb[tid];
    op[base + 256 + tid] = (v1 - m) * inv * w[256 + tid] + bb[256 + tid];
}

// ---------------- fused relu+batchLN x2: rf = LN(relu(x2R)) kept in LDS,
//                  res = LN(relu(x2T)) + rf. One block per batch, 1024 threads. ----------
__global__ __launch_bounds__(1024) void relu_bln_fused(
    const float* __restrict__ xR, const float* __restrict__ w2, const float* __restrict__ b2,
    const float* __restrict__ xT, const float* __restrict__ w1, const float* __restrict__ b1,
    float* __restrict__ out)
{
    __shared__ float rfs[16384];
    __shared__ float sw_[16], qw_[16], ms_, is_;
    const int bb = blockIdx.x, tid = threadIdx.x;
    const int wid = tid >> 6, lane = tid & 63;
    const float* xr = xR + (size_t)bb * 16384;
    float s = 0.f, q = 0.f;
    for (int i = tid; i < 16384; i += 1024) { float v = fmaxf(xr[i], 0.f); s += v; q += v * v; }
    for (int off = 32; off; off >>= 1) { s += __shfl_down(s, off); q += __shfl_down(q, off); }
    if (lane == 0) { sw_[wid] = s; qw_[wid] = q; }
    __syncthreads();
    if (tid == 0) {
        float S = 0.f, Q = 0.f;
        for (int i = 0; i < 16; ++i) { S += sw_[i]; Q += qw_[i]; }
        float m = S * (1.f / 16384.f);
        ms_ = m;
        is_ = rsqrtf(Q * (1.f / 16384.f) - m * m + 1e-5f);
    }
    __syncthreads();
    float m = ms_, inv = is_;
    for (int i = tid; i < 16384; i += 1024) {
        float v = fmaxf(xr[i], 0.f);
        rfs[i] = (v - m) * inv * w2[i] + b2[i];
    }
    const float* xt = xT + (size_t)bb * 16384;
    s = 0.f; q = 0.f;
    for (int i = tid; i < 16384; i += 1024) { float v = fmaxf(xt[i], 0.f); s += v; q += v * v; }
    for (int off = 32; off; off >>= 1) { s += __shfl_down(s, off); q += __shfl_down(q, off); }
    if (lane == 0) { sw_[wid] = s; qw_[wid] = q; }
    __syncthreads();
    if (tid == 0) {
        float S = 0.f, Q = 0.f;
        for (int i = 0; i < 16; ++i) { S += sw_[i]; Q += qw_[i]; }
        float m2 = S * (1.f / 16384.f);
        ms_ = m2;
        is_ = rsqrtf(Q * (1.f / 16384.f) - m2 * m2 + 1e-5f);
    }
    __syncthreads();
    m = ms_; inv = is_;
    float* op = out + (size_t)bb * 16384;
    for (int i = tid; i < 16384; i += 1024) {
        float v = fmaxf(xt[i], 0.f);
        op[i] = (v - m) * inv * w1[i] + b1[i] + rfs[i];
    }
}

extern "C" void kernel_launch(void* const* d_in, const int* in_sizes, int n_in,
                              void* d_out, int out_size, void* d_ws, size_t ws_size,
                              hipStream_t stream)
{
    (void)in_sizes; (void)n_in; (void)out_size; (void)ws_size;
    const float* x        = (const float*)d_in[0];
    const float* t_in_w   = (const float*)d_in[1];
    const float* t_in_b   = (const float*)d_in[2];
    const float* t_out_w  = (const float*)d_in[3];
    const float* t_out_b  = (const float*)d_in[4];
    const float* t_ln1_w  = (const float*)d_in[5];
    const float* t_ln1_b  = (const float*)d_in[6];
    const float* t_lin1_w = (const float*)d_in[7];
    const float* t_lin1_b = (const float*)d_in[8];
    const float* t_lin2_w = (const float*)d_in[9];
    const float* t_lin2_b = (const float*)d_in[10];
    const float* t_ln2_w  = (const float*)d_in[11];
    const float* t_ln2_b  = (const float*)d_in[12];
    const float* r_in_w   = (const float*)d_in[13];
    const float* r_in_b   = (const float*)d_in[14];
    const float* r_out_w  = (const float*)d_in[15];
    const float* r_out_b  = (const float*)d_in[16];
    const float* r_ln1_w  = (const float*)d_in[17];
    const float* r_ln1_b  = (const float*)d_in[18];
    const float* r_lin1_w = (const float*)d_in[19];
    const float* r_lin1_b = (const float*)d_in[20];
    const float* r_lin2_w = (const float*)d_in[21];
    const float* r_lin2_b = (const float*)d_in[22];
    const float* r_ln2_w  = (const float*)d_in[23];
    const float* r_ln2_b  = (const float*)d_in[24];
    const float* lc_w     = (const float*)d_in[25];
    const float* lc_b     = (const float*)d_in[26];
    const float* up1_w    = (const float*)d_in[27];
    const float* up1_b    = (const float*)d_in[28];
    const float* up2_w    = (const float*)d_in[29];
    const float* up2_b    = (const float*)d_in[30];
    const float* n1_w     = (const float*)d_in[31];
    const float* n1_b     = (const float*)d_in[32];
    const float* n2_w     = (const float*)d_in[33];
    const float* n2_b     = (const float*)d_in[34];
    const float* l1_re    = (const float*)d_in[35];
    const float* l1_im    = (const float*)d_in[36];
    const float* lb1_re   = (const float*)d_in[39];
    const float* lb1_im   = (const float*)d_in[40];

    float* outp = (float*)d_out;

    // ---- workspace map (float offsets; total 21,774,336 f = 87.1 MB) ----
    float* WS   = (float*)d_ws;
    float* LL   = WS;                                        // 2M f (also fa f32, later y_r)
    float* FA   = WS;
    float* yR   = WS;
    float* QR   = WS + 2097152;                              // 6.29M f
    float* tabC = QR;                                        // 131072
    float* tabS = QR + 131072;
    unsigned short* WaHu = (unsigned short*)(QR + 786432);
    unsigned short* WaLu = (unsigned short*)(QR + 917504);
    unsigned short* WmHu = (unsigned short*)(QR + 1048576);
    unsigned short* WmLu = (unsigned short*)(QR + 1179648);
    float* qkvR = QR;                                        // 6.29M f: [2097152, 8388608)
    unsigned short* x1rH = (unsigned short*)(WS + 2097152);
    unsigned short* x1rL = (unsigned short*)(WS + 3145728);
    unsigned short* x1tH = (unsigned short*)(WS + 4194304);
    unsigned short* x1tL = (unsigned short*)(WS + 5242880);
    float* yT   = WS + 6291456;                              // 2M f
    unsigned short* qkvT = (unsigned short*)(WS + 8388608);  // 6.29M ushort
    unsigned short* f1R  = (unsigned short*)(WS + 8388608);  // 8.39M ushort
    float* x2R  = WS + 8388608;                              // 2M f
    float* x2T  = WS + 10485760;                             // 2M f
    unsigned short* xHi = (unsigned short*)(WS + 11534336);
    unsigned short* xLo = (unsigned short*)(WS + 12582912);
    unsigned short* aoR = (unsigned short*)(WS + 11534336);
    unsigned short* aoT = (unsigned short*)(WS + 12582912);
    unsigned short* f1T = (unsigned short*)(WS + 12582912);  // 8.39M ushort
    unsigned short* LLH = (unsigned short*)(WS + 13631488);
    unsigned short* LLL = (unsigned short*)(WS + 14680064);
    float* oR   = WS + 13631488;                             // 2M f
    float* oT   = WS + 15728640;                             // 2M f
    unsigned short* faHi = (unsigned short*)(WS + 15728640);
    unsigned short* faLo = (unsigned short*)(WS + 16777216);
    unsigned short* rinLoU = (unsigned short*)(WS + 17825792);  // 786432 ushort
    float* LB   = WS + 18219008;                             // 512 f
    unsigned short* WB = (unsigned short*)(WS + 18366464);

    // u1b (up1 bf16 out, 1M ushort) parks in the OUTPUT res slot outp[0..1048576 f):
    // res is written only by the final relu_bln_fused (verified passing in R19-R22).
    unsigned short* u1b = (unsigned short*)outp;

    unsigned short* w_tin  = WB + 0;        // 1536x512
    unsigned short* w_tout = WB + 786432;   // 512x512
    unsigned short* w_tl1  = WB + 1048576;  // 2048x512
    unsigned short* w_tl2  = WB + 2097152;  // 512x2048
    unsigned short* w_rin  = WB + 3145728;  // 1536x512
    unsigned short* w_rout = WB + 3932160;  // 512x512
    unsigned short* w_rl1  = WB + 4194304;  // 2048x512
    unsigned short* w_rl2  = WB + 5242880;  // 512x2048
    unsigned short* w_up1  = WB + 6291456;  // 512x512
    unsigned short* w_up2  = WB + 6553600;  // 512x512

    dim3 blk(256);

    // ---- prep (2 dispatches: uber(+tab), wawm) ----
    uber_prep_kernel<<<dim3(35330), blk, 0, stream>>>(t_in_w, t_out_w, t_lin1_w, t_lin2_w,
                                                      r_in_w, r_out_w, r_lin1_w, r_lin2_w,
                                                      up1_w, up2_w, WB, rinLoU,
                                                      x, xHi, xLo, outp + NOUT,
                                                      lb1_re, lb1_im, LB, tabC, tabS);
    wawm_kernel<<<dim3(512, 2, 2), blk, 0, stream>>>(l1_re, l1_im, lc_w, tabC, tabS,
                                                     WaHu, WaLu, WmHu, WmLu);

    // ---- freq branch (keeps hi/lo: fa and up are direct outputs) ----
    gemm_mfma3<64,64,1,0,0><<<dim3(8, 64), blk, 0, stream>>>(xHi, xLo, WaHu, WaLu, LB,
                                                             LL, nullptr, nullptr, nullptr, 512, 512);
    cattn2_kernel<<<dim3(128, 2), dim3(512), 65536, stream>>>(LL, LLH, LLL);         // LL hi/lo
    gemm_mfma3<64,64,0,1,1><<<dim3(8, 64), blk, 0, stream>>>(LLH, LLL, WmHu, WmLu, lc_b,
                                                             FA, outp + 2 * NOUT, faHi, faLo, 512, 512);

    // ---- qkv both TELs (single-product bf16 both branches; R22) ----
    gemm_qkv_dual<64,128><<<dim3(12, 64, 2), blk, 0, stream>>>(faHi, w_rin, r_in_b, qkvR,
                                                               xHi, w_tin, t_in_b, qkvT, 1536, 512);

    // ---- attention (r+t) + up1, merged (R23 register-blocked) ----
    attn_up1_kernel<<<dim3(1024, 1, 3), blk, 0, stream>>>(qkvR, qkvT, aoR, aoT,
                                                          faHi, w_up1, up1_b, u1b);

    // ---- out-proj r/t + up2 (tri) ----
    gemm_out_tri<64,64><<<dim3(8, 64, 3), blk, 0, stream>>>(aoR, w_rout, r_out_b, oR,
                                                            aoT, w_tout, t_out_b, oT,
                                                            u1b, w_up2, up2_b, outp + 3 * NOUT, 512, 512);
    add_ln_d1<<<dim3(8192), blk, 0, stream>>>(FA, oR, r_ln1_w, r_ln1_b, x1rH, x1rL,
                                              x,  oT, t_ln1_w, t_ln1_b, x1tH, x1tL);
    gemm_dual<64,128,1,1><<<dim3(16, 64, 2), blk, 0, stream>>>(x1rH, x1tH, w_rl1, w_tl1,
                                                               r_lin1_b, t_lin1_b, nullptr, nullptr,
                                                               f1R, f1T, 2048, 512);
    gemm_dual<64,64,0,0><<<dim3(8, 64, 2), blk, 0, stream>>>(f1R, f1T, w_rl2, w_tl2,
                                                             r_lin2_b, t_lin2_b, yR, yT,
                                                             nullptr, nullptr, 512, 2048);
    add_ln_d2<<<dim3(8192), blk, 0, stream>>>(x1rH, x1rL, yR, r_ln2_w, r_ln2_b, x2R,
                                              x1tH, x1tL, yT, t_ln2_w, t_ln2_b, x2T);
    relu_bln_fused<<<dim3(128), dim3(1024), 0, stream>>>(x2R, n2_w, n2_b, x2T, n1_w, n1_b, outp);
}

// Round 17
// 421.402 us; speedup vs baseline: 1.1468x; 1.0082x over previous
//
#include <hip/hip_runtime.h>
#include <math.h>

// NoiScaleModule: B=128, C=32(seq), S=512(d_model), EMB=256, NHEAD=8, DFF=2048
// All tensors FLOAT32. Outputs concat flat: res[2M], down_x[2M], fa[2M], up[2M]
//
// R22: r-qkv single-product. 458->431. R23: attention register-blocking +
//      wave-parallel softmax. 431->424.9 (best). All kernels now < 42us noise floor.
// R24: lin1 only -> 128x128 tile (grid (16,32,2)=1024 blocks=4/CU, resident;
//      R12's failure mode was <=1 block/CU; R14 ran this exact lin1 config in a
//      passing bundle). FLOPs/staged-byte 32->64. lin2 stays 64x128 (128-class
//      would be 2/CU, the R14 regressor).

#define NROW 4096
#define NOUT 2097152

typedef __attribute__((ext_vector_type(8))) short short8;
typedef __attribute__((ext_vector_type(4))) float floatx4;

__device__ __forceinline__ unsigned short f2bf(float f) {
    union { float f; unsigned u; } v; v.f = f;
    return (unsigned short)((v.u + 0x7fffu + ((v.u >> 16) & 1u)) >> 16);
}
__device__ __forceinline__ float bf2f(unsigned short h) {
    union { unsigned u; float f; } v; v.u = ((unsigned)h) << 16;
    return v.f;
}

__device__ __forceinline__ void gload16(const unsigned short* g, unsigned short* l) {
    __builtin_amdgcn_global_load_lds((const __attribute__((address_space(1))) void*)g,
                                     (__attribute__((address_space(3))) void*)l, 16, 0, 0);
}

// XCD-chunked swizzle (T1): requires nwg % 8 == 0.
__device__ __forceinline__ void xcd_swizzle(int& bx, int& by, int& bz) {
    const int gx = gridDim.x, gy = gridDim.y;
    const int nwg = gx * gy * gridDim.z;
    int b = (bz * gy + by) * gx + bx;
    const int chunk = nwg >> 3;
    const int lb = (b & 7) * chunk + (b >> 3);
    bx = lb % gx;
    const int rem = lb / gx;
    by = rem % gy;
    bz = rem / gy;
}

// Wa (z=0) and Wm (z=1) in one dispatch; both emit bf16 hi/lo directly.
__global__ __launch_bounds__(256) void wawm_kernel(const float* __restrict__ l1_re, const float* __restrict__ l1_im,
                                                   const float* __restrict__ lc_w,
                                                   const float* __restrict__ tabC, const float* __restrict__ tabS,
                                                   unsigned short* __restrict__ WaH, unsigned short* __restrict__ WaL,
                                                   unsigned short* __restrict__ WmH, unsigned short* __restrict__ WmL)
{
    __shared__ float lw[512];
    const float inv = 0.04419417382415922f;  // 1/sqrt(512)
    if (blockIdx.z == 0) {
        int n  = blockIdx.x;
        int ep = blockIdx.y * 256 + threadIdx.x;
        float acc = 0.f;
        if (ep < 256) {
            for (int k = 0; k < 128; ++k) {
                float c = tabC[n * 256 + k], s = tabS[n * 256 + k];
                acc += c * l1_re[k * 256 + ep] + s * l1_im[k * 256 + ep];
            }
        } else {
            int e = ep - 256;
            for (int k = 0; k < 128; ++k) {
                float c = tabC[n * 256 + k], s = tabS[n * 256 + k];
                acc += c * l1_im[k * 256 + e] - s * l1_re[k * 256 + e];
            }
        }
        float v = acc * inv;
        size_t idx = (size_t)ep * 512 + n;
        unsigned short h = f2bf(v);
        WaH[idx] = h;
        WaL[idx] = f2bf(v - bf2f(h));
    } else {
        int s  = blockIdx.x;
        int kk = blockIdx.y * 256 + threadIdx.x;
        for (int i = threadIdx.x; i < 512; i += 256) lw[i] = lc_w[s * 512 + i];
        __syncthreads();
        float acc = 0.f;
        if (kk < 256) {
            int k = kk;
            for (int n = 0; n < 512; ++n) acc += tabC[n * 256 + k] * lw[n];
            acc *= (k == 0) ? inv : 2.f * inv;
        } else {
            int k = kk - 256;
            if (k == 0) acc = 0.f;
            else {
                for (int n = 0; n < 512; ++n) acc += tabS[n * 256 + k] * lw[n];
                acc *= -2.f * inv;
            }
        }
        size_t idx = (size_t)s * 512 + kk;
        unsigned short h = f2bf(acc);
        WmH[idx] = h;
        WmL[idx] = f2bf(acc - bf2f(h));
    }
}

// ---------------- uber elementwise prep: wcvt(+rinLo) | xsplit | lbpack | tab ------------
__global__ __launch_bounds__(256) void uber_prep_kernel(
    const float* s0, const float* s1, const float* s2, const float* s3, const float* s4,
    const float* s5, const float* s6, const float* s7, const float* s8, const float* s9,
    unsigned short* __restrict__ o, unsigned short* __restrict__ rinLo,
    const float* __restrict__ x, unsigned short* __restrict__ xhi,
    unsigned short* __restrict__ xlo, float* __restrict__ xcp,
    const float* __restrict__ lbre, const float* __restrict__ lbim, float* __restrict__ lbout,
    float* __restrict__ tabC, float* __restrict__ tabS)
{
    const int bid = blockIdx.x, tid = threadIdx.x;
    if (bid < 26624) {
        int i = bid * 256 + tid;  // exactly covers 6815744
        const float* s; int off;
        if (i < 3145728) {
            if (i < 1048576) { if (i < 786432) { s = s0; off = 0; } else { s = s1; off = 786432; } }
            else             { if (i < 2097152) { s = s2; off = 1048576; } else { s = s3; off = 2097152; } }
        } else {
            if (i < 5242880) {
                if (i < 3932160) { s = s4; off = 3145728; }
                else if (i < 4194304) { s = s5; off = 3932160; }
                else { s = s6; off = 4194304; }
            } else {
                if (i < 6291456) { s = s7; off = 5242880; }
                else if (i < 6553600) { s = s8; off = 6291456; }
                else { s = s9; off = 6553600; }
            }
        }
        float v = s[i - off];
        unsigned short h = f2bf(v);
        o[i] = h;
        if (i >= 3145728 && i < 3932160) rinLo[i - 3145728] = f2bf(v - bf2f(h));
    } else if (bid < 34816) {
        int i = (bid - 26624) * 256 + tid;  // exactly covers 2097152
        float v = x[i];
        unsigned short h = f2bf(v);
        xhi[i] = h;
        xlo[i] = f2bf(v - bf2f(h));
        xcp[i] = v;
    } else if (bid < 34818) {
        int i = (bid - 34816) * 256 + tid;
        if (i < 512) lbout[i] = (i < 256) ? lbre[i] : lbim[i - 256];
    } else {
        int n = bid - 34818;                 // 0..511
        int k = tid;                         // 0..255
        int m = (n * k) & 511;
        float th = (float)m * 0.01227184630308513f;  // 2*pi/512
        float sv, cv; sincosf(th, &sv, &cv);
        tabC[n * 256 + k] = cv;
        tabS[n * 256 + k] = sv;
    }
}

// ---------------- dual-branch GEMM (BK=64): z=0/1 select. For lin1/lin2. ----------------
template <int TM, int TN, int ACT, int WBF>
__global__ __launch_bounds__(256) void gemm_dual(
    const unsigned short* __restrict__ A0, const unsigned short* __restrict__ A1,
    const unsigned short* __restrict__ W0, const unsigned short* __restrict__ W1,
    const float* __restrict__ b0, const float* __restrict__ b1,
    float* __restrict__ C0, float* __restrict__ C1,
    unsigned short* __restrict__ D0, unsigned short* __restrict__ D1, int N, int K)
{
    constexpr int MI = TM / 32, NJ = TN / 32;
    constexpr int ARW = TM / 4, BRW = TN / 4;
    __shared__ unsigned short As[2][TM * 32];
    __shared__ unsigned short Bs[2][TN * 32];
    const int tid = threadIdx.x;
    const int wave = tid >> 6, lane = tid & 63;
    int bx = blockIdx.x, by = blockIdx.y, bz = blockIdx.z;
    xcd_swizzle(bx, by, bz);
    const int m0 = by * TM, n0 = bx * TN;
    const int z = bz;
    const unsigned short* A = z ? A1 : A0;
    const unsigned short* W = z ? W1 : W0;
    const float* bias = z ? b1 : b0;
    float* Cf = z ? C1 : C0;
    unsigned short* Cb = z ? D1 : D0;
    const int sr = lane >> 2, sc = (lane & 3) * 8;
    const unsigned short* aS = A + (size_t)(m0 + wave * ARW + sr) * K + sc;
    const unsigned short* wS = W + (size_t)(n0 + wave * BRW + sr) * K + sc;
    const int wm = (wave >> 1) * (TM / 2), wn = (wave & 1) * (TN / 2);
    const int fr = lane & 15, fko = (lane >> 4) * 8;

    floatx4 acc[MI][NJ];
#pragma unroll
    for (int i = 0; i < MI; ++i)
#pragma unroll
        for (int j = 0; j < NJ; ++j) acc[i][j] = (floatx4){0.f, 0.f, 0.f, 0.f};

    for (int k0 = 0; k0 < K; k0 += 64) {
#pragma unroll
        for (int h = 0; h < 2; ++h) {
#pragma unroll
            for (int c = 0; c < ARW / 16; ++c)
                gload16(aS + (size_t)(16 * c) * K + k0 + 32 * h, &As[h][(wave * ARW + 16 * c) * 32]);
#pragma unroll
            for (int c = 0; c < BRW / 16; ++c)
                gload16(wS + (size_t)(16 * c) * K + k0 + 32 * h, &Bs[h][(wave * BRW + 16 * c) * 32]);
        }
        __syncthreads();
#pragma unroll
        for (int h = 0; h < 2; ++h) {
            short8 af[MI], bfr[NJ];
#pragma unroll
            for (int i = 0; i < MI; ++i) af[i] = *(const short8*)&As[h][(wm + i * 16 + fr) * 32 + fko];
#pragma unroll
            for (int j = 0; j < NJ; ++j) bfr[j] = *(const short8*)&Bs[h][(wn + j * 16 + fr) * 32 + fko];
#pragma unroll
            for (int i = 0; i < MI; ++i)
#pragma unroll
                for (int j = 0; j < NJ; ++j)
                    acc[i][j] = __builtin_amdgcn_mfma_f32_16x16x32_bf16(af[i], bfr[j], acc[i][j], 0, 0, 0);
        }
        __syncthreads();
    }
    const int r0 = m0 + wm + (lane >> 4) * 4;
#pragma unroll
    for (int i = 0; i < MI; ++i) {
#pragma unroll
        for (int j = 0; j < NJ; ++j) {
            int n = n0 + wn + j * 16 + fr;
            float bv = bias[n];
#pragma unroll
            for (int r = 0; r < 4; ++r) {
                int m = r0 + i * 16 + r;
                size_t idx = (size_t)m * N + n;
                float v = acc[i][j][r] + bv;
                if (ACT) v = fmaxf(v, 0.f);
                if (WBF) Cb[idx] = f2bf(v);
                else     Cf[idx] = v;
            }
        }
    }
}

// ---------------- tri-branch single-product GEMM (BK=64, TN=64): out-proj r/t + up2 ------
template <int TM, int TN>
__global__ __launch_bounds__(256) void gemm_out_tri(
    const unsigned short* __restrict__ A0, const unsigned short* __restrict__ W0,
    const float* __restrict__ b0, float* __restrict__ C0,
    const unsigned short* __restrict__ A1, const unsigned short* __restrict__ W1,
    const float* __restrict__ b1, float* __restrict__ C1,
    const unsigned short* __restrict__ A2, const unsigned short* __restrict__ W2,
    const float* __restrict__ b2, float* __restrict__ C2, int N, int K)
{
    constexpr int MI = TM / 32, NJ = TN / 32;
    constexpr int ARW = TM / 4, BRW = TN / 4;
    __shared__ unsigned short As[2][TM * 32];
    __shared__ unsigned short Bs[2][TN * 32];
    const int tid = threadIdx.x;
    const int wave = tid >> 6, lane = tid & 63;
    int bx = blockIdx.x, by = blockIdx.y, bz = blockIdx.z;
    xcd_swizzle(bx, by, bz);
    const int m0 = by * TM, n0 = bx * TN;
    const unsigned short* A = (bz == 0) ? A0 : (bz == 1) ? A1 : A2;
    const unsigned short* W = (bz == 0) ? W0 : (bz == 1) ? W1 : W2;
    const float* bias       = (bz == 0) ? b0 : (bz == 1) ? b1 : b2;
    float* Cf               = (bz == 0) ? C0 : (bz == 1) ? C1 : C2;
    const int sr = lane >> 2, sc = (lane & 3) * 8;
    const unsigned short* aS = A + (size_t)(m0 + wave * ARW + sr) * K + sc;
    const unsigned short* wS = W + (size_t)(n0 + wave * BRW + sr) * K + sc;
    const int wm = (wave >> 1) * (TM / 2), wn = (wave & 1) * (TN / 2);
    const int fr = lane & 15, fko = (lane >> 4) * 8;

    floatx4 acc[MI][NJ];
#pragma unroll
    for (int i = 0; i < MI; ++i)
#pragma unroll
        for (int j = 0; j < NJ; ++j) acc[i][j] = (floatx4){0.f, 0.f, 0.f, 0.f};

    for (int k0 = 0; k0 < K; k0 += 64) {
#pragma unroll
        for (int h = 0; h < 2; ++h) {
#pragma unroll
            for (int c = 0; c < ARW / 16; ++c)
                gload16(aS + (size_t)(16 * c) * K + k0 + 32 * h, &As[h][(wave * ARW + 16 * c) * 32]);
#pragma unroll
            for (int c = 0; c < BRW / 16; ++c)
                gload16(wS + (size_t)(16 * c) * K + k0 + 32 * h, &Bs[h][(wave * BRW + 16 * c) * 32]);
        }
        __syncthreads();
#pragma unroll
        for (int h = 0; h < 2; ++h) {
            short8 af[MI], bfr[NJ];
#pragma unroll
            for (int i = 0; i < MI; ++i) af[i] = *(const short8*)&As[h][(wm + i * 16 + fr) * 32 + fko];
#pragma unroll
            for (int j = 0; j < NJ; ++j) bfr[j] = *(const short8*)&Bs[h][(wn + j * 16 + fr) * 32 + fko];
#pragma unroll
            for (int i = 0; i < MI; ++i)
#pragma unroll
                for (int j = 0; j < NJ; ++j)
                    acc[i][j] = __builtin_amdgcn_mfma_f32_16x16x32_bf16(af[i], bfr[j], acc[i][j], 0, 0, 0);
        }
        __syncthreads();
    }
    const int r0 = m0 + wm + (lane >> 4) * 4;
#pragma unroll
    for (int i = 0; i < MI; ++i) {
#pragma unroll
        for (int j = 0; j < NJ; ++j) {
            int n = n0 + wn + j * 16 + fr;
            float bv = bias[n];
#pragma unroll
            for (int r = 0; r < 4; ++r) {
                int m = r0 + i * 16 + r;
                Cf[(size_t)m * N + n] = acc[i][j][r] + bv;
            }
        }
    }
}

// ---------------- fused hi/lo 3-product MFMA GEMM (BK=64, single-buffer) ----------------
template <int TM, int TN, int ACT, int WCOPY, int WHILO>
__global__ __launch_bounds__(256) void gemm_mfma3(
    const unsigned short* __restrict__ Ah, const unsigned short* __restrict__ Al,
    const unsigned short* __restrict__ Wh, const unsigned short* __restrict__ Wl,
    const float* __restrict__ bias, float* __restrict__ Cf, float* __restrict__ Ccopy,
    unsigned short* __restrict__ Hh, unsigned short* __restrict__ Hl, int N, int K)
{
    constexpr int MI = TM / 32, NJ = TN / 32;
    constexpr int ARW = TM / 4, BRW = TN / 4;
    __shared__ unsigned short Ash[2][TM * 32];
    __shared__ unsigned short Asl[2][TM * 32];
    __shared__ unsigned short Bsh[2][TN * 32];
    __shared__ unsigned short Bsl[2][TN * 32];
    const int tid = threadIdx.x;
    const int wave = tid >> 6, lane = tid & 63;
    int bx = blockIdx.x, by = blockIdx.y, bz = blockIdx.z;
    xcd_swizzle(bx, by, bz);
    const int m0 = by * TM, n0 = bx * TN;
    const int sr = lane >> 2, sc = (lane & 3) * 8;
    const size_t aoff = (size_t)(m0 + wave * ARW + sr) * K + sc;
    const size_t woff = (size_t)(n0 + wave * BRW + sr) * K + sc;
    const int wm = (wave >> 1) * (TM / 2), wn = (wave & 1) * (TN / 2);
    const int fr = lane & 15, fko = (lane >> 4) * 8;

    floatx4 acc[MI][NJ];
#pragma unroll
    for (int i = 0; i < MI; ++i)
#pragma unroll
        for (int j = 0; j < NJ; ++j) acc[i][j] = (floatx4){0.f, 0.f, 0.f, 0.f};

    for (int k0 = 0; k0 < K; k0 += 64) {
#pragma unroll
        for (int h = 0; h < 2; ++h) {
#pragma unroll
            for (int c = 0; c < ARW / 16; ++c) {
                gload16(Ah + aoff + (size_t)(16 * c) * K + k0 + 32 * h, &Ash[h][(wave * ARW + 16 * c) * 32]);
                gload16(Al + aoff + (size_t)(16 * c) * K + k0 + 32 * h, &Asl[h][(wave * ARW + 16 * c) * 32]);
            }
#pragma unroll
            for (int c = 0; c < BRW / 16; ++c) {
                gload16(Wh + woff + (size_t)(16 * c) * K + k0 + 32 * h, &Bsh[h][(wave * BRW + 16 * c) * 32]);
                gload16(Wl + woff + (size_t)(16 * c) * K + k0 + 32 * h, &Bsl[h][(wave * BRW + 16 * c) * 32]);
            }
        }
        __syncthreads();
#pragma unroll
        for (int h = 0; h < 2; ++h) {
            short8 ah[MI], al[MI], bh[NJ], bl[NJ];
#pragma unroll
            for (int i = 0; i < MI; ++i) {
                ah[i] = *(const short8*)&Ash[h][(wm + i * 16 + fr) * 32 + fko];
                al[i] = *(const short8*)&Asl[h][(wm + i * 16 + fr) * 32 + fko];
            }
#pragma unroll
            for (int j = 0; j < NJ; ++j) {
                bh[j] = *(const short8*)&Bsh[h][(wn + j * 16 + fr) * 32 + fko];
                bl[j] = *(const short8*)&Bsl[h][(wn + j * 16 + fr) * 32 + fko];
            }
#pragma unroll
            for (int i = 0; i < MI; ++i)
#pragma unroll
                for (int j = 0; j < NJ; ++j) {
                    acc[i][j] = __builtin_amdgcn_mfma_f32_16x16x32_bf16(al[i], bh[j], acc[i][j], 0, 0, 0);
                    acc[i][j] = __builtin_amdgcn_mfma_f32_16x16x32_bf16(ah[i], bl[j], acc[i][j], 0, 0, 0);
                    acc[i][j] = __builtin_amdgcn_mfma_f32_16x16x32_bf16(ah[i], bh[j], acc[i][j], 0, 0, 0);
                }
        }
        __syncthreads();
    }
    const int r0 = m0 + wm + (lane >> 4) * 4;
#pragma unroll
    for (int i = 0; i < MI; ++i) {
#pragma unroll
        for (int j = 0; j < NJ; ++j) {
            int n = n0 + wn + j * 16 + fr;
            float bv = bias[n];
#pragma unroll
            for (int r = 0; r < 4; ++r) {
                int m = r0 + i * 16 + r;
                size_t idx = (size_t)m * N + n;
                float v = acc[i][j][r] + bv;
                if (ACT) v = fmaxf(v, 0.f);
                Cf[idx] = v;
                if (WCOPY) Ccopy[idx] = v;
                if (WHILO) {
                    unsigned short h = f2bf(v);
                    Hh[idx] = h;
                    Hl[idx] = f2bf(v - bf2f(h));
                }
            }
        }
    }
}

// ---------------- merged qkv GEMM (BK=64, single-product both branches):
//                  z=0 r-qkv faHi x w_rin -> f32; z=1 t-qkv xHi x w_tin -> bf16. ----------
template <int TM, int TN>
__global__ __launch_bounds__(256) void gemm_qkv_dual(
    const unsigned short* __restrict__ A0, const unsigned short* __restrict__ W0,
    const float* __restrict__ b0, float* __restrict__ C0,
    const unsigned short* __restrict__ A1, const unsigned short* __restrict__ W1,
    const float* __restrict__ b1, unsigned short* __restrict__ C1,
    int N, int K)
{
    constexpr int MI = TM / 32, NJ = TN / 32;
    constexpr int ARW = TM / 4, BRW = TN / 4;
    __shared__ unsigned short As[2][TM * 32];
    __shared__ unsigned short Bs[2][TN * 32];
    const int tid = threadIdx.x;
    const int wave = tid >> 6, lane = tid & 63;
    int bx = blockIdx.x, by = blockIdx.y, bz = blockIdx.z;
    xcd_swizzle(bx, by, bz);
    const int m0 = by * TM, n0 = bx * TN;
    const unsigned short* A = bz ? A1 : A0;
    const unsigned short* W = bz ? W1 : W0;
    const float* bias = bz ? b1 : b0;
    const int sr = lane >> 2, sc = (lane & 3) * 8;
    const unsigned short* aS = A + (size_t)(m0 + wave * ARW + sr) * K + sc;
    const unsigned short* wS = W + (size_t)(n0 + wave * BRW + sr) * K + sc;
    const int wm = (wave >> 1) * (TM / 2), wn = (wave & 1) * (TN / 2);
    const int fr = lane & 15, fko = (lane >> 4) * 8;

    floatx4 acc[MI][NJ];
#pragma unroll
    for (int i = 0; i < MI; ++i)
#pragma unroll
        for (int j = 0; j < NJ; ++j) acc[i][j] = (floatx4){0.f, 0.f, 0.f, 0.f};

    for (int k0 = 0; k0 < K; k0 += 64) {
#pragma unroll
        for (int h = 0; h < 2; ++h) {
#pragma unroll
            for (int c = 0; c < ARW / 16; ++c)
                gload16(aS + (size_t)(16 * c) * K + k0 + 32 * h, &As[h][(wave * ARW + 16 * c) * 32]);
#pragma unroll
            for (int c = 0; c < BRW / 16; ++c)
                gload16(wS + (size_t)(16 * c) * K + k0 + 32 * h, &Bs[h][(wave * BRW + 16 * c) * 32]);
        }
        __syncthreads();
#pragma unroll
        for (int h = 0; h < 2; ++h) {
            short8 af[MI], bfr[NJ];
#pragma unroll
            for (int i = 0; i < MI; ++i) af[i] = *(const short8*)&As[h][(wm + i * 16 + fr) * 32 + fko];
#pragma unroll
            for (int j = 0; j < NJ; ++j) bfr[j] = *(const short8*)&Bs[h][(wn + j * 16 + fr) * 32 + fko];
#pragma unroll
            for (int i = 0; i < MI; ++i)
#pragma unroll
                for (int j = 0; j < NJ; ++j)
                    acc[i][j] = __builtin_amdgcn_mfma_f32_16x16x32_bf16(af[i], bfr[j], acc[i][j], 0, 0, 0);
        }
        __syncthreads();
    }
    const int r0 = m0 + wm + (lane >> 4) * 4;
#pragma unroll
    for (int i = 0; i < MI; ++i) {
#pragma unroll
        for (int j = 0; j < NJ; ++j) {
            int n = n0 + wn + j * 16 + fr;
            float bv = bias[n];
#pragma unroll
            for (int r = 0; r < 4; ++r) {
                int m = r0 + i * 16 + r;
                size_t idx = (size_t)m * N + n;
                float v = acc[i][j][r] + bv;
                if (bz == 0) C0[idx] = v;
                else         C1[idx] = f2bf(v);
            }
        }
    }
}

// ---------------- merged attention + up1: z=0 attn-r (f32 qkv), z=1 attn-t (bf16 qkv),
//                  z=2 up1 GEMM (512 of 1024 blocks; whole-block early exit).
// R23: register-blocked QK/PV + wave-parallel softmax. ------------------------------------
__global__ __launch_bounds__(256) void attn_up1_kernel(
    const float* __restrict__ qkvF, const unsigned short* __restrict__ qkvB,
    unsigned short* __restrict__ outR, unsigned short* __restrict__ outT,
    const unsigned short* __restrict__ A2, const unsigned short* __restrict__ W2,
    const float* __restrict__ b2, unsigned short* __restrict__ C2)
{
    __shared__ __align__(16) char smem[29184];
    const int tid = threadIdx.x;
    if (blockIdx.z < 2) {
        // ---- attention branch (29184 B LDS) ----
        float (*qs)[65] = (float(*)[65])smem;
        float (*ks)[65] = (float(*)[65])(smem + 8320);
        float (*vs)[65] = (float(*)[65])(smem + 16640);
        float (*ps)[33] = (float(*)[33])(smem + 24960);
        const int isT = blockIdx.z;
        const int b = blockIdx.x >> 3;
        const int h = blockIdx.x & 7;
        if (isT) {
            for (int i = tid; i < 2048; i += 256) {
                int s = i >> 6, d = i & 63;
                size_t base = ((size_t)(b * 32 + s)) * 1536 + h * 64 + d;
                qs[s][d] = bf2f(qkvB[base]);
                ks[s][d] = bf2f(qkvB[base + 512]);
                vs[s][d] = bf2f(qkvB[base + 1024]);
            }
        } else {
            for (int i = tid; i < 2048; i += 256) {
                int s = i >> 6, d = i & 63;
                size_t base = ((size_t)(b * 32 + s)) * 1536 + h * 64 + d;
                qs[s][d] = qkvF[base];
                ks[s][d] = qkvF[base + 512];
                vs[s][d] = qkvF[base + 1024];
            }
        }
        __syncthreads();
        // ---- QK: thread owns col sj, rows si0+8p (shared ks load, 4 chains) ----
        {
            const int sj = tid & 31;
            const int si0 = tid >> 5;          // 0..7
            float acc0 = 0.f, acc1 = 0.f, acc2 = 0.f, acc3 = 0.f;
#pragma unroll 8
            for (int d = 0; d < 64; ++d) {
                float kd = ks[sj][d];
                acc0 += qs[si0][d] * kd;
                acc1 += qs[si0 + 8][d] * kd;
                acc2 += qs[si0 + 16][d] * kd;
                acc3 += qs[si0 + 24][d] * kd;
            }
            ps[si0][sj]      = acc0 * 0.125f;
            ps[si0 + 8][sj]  = acc1 * 0.125f;
            ps[si0 + 16][sj] = acc2 * 0.125f;
            ps[si0 + 24][sj] = acc3 * 0.125f;
        }
        __syncthreads();
        // ---- softmax: 32 rows x 8 lanes, shfl_xor reduce within 8-lane groups ----
        {
            const int r = tid >> 3, sub = tid & 7;
            float mx = -1e30f;
#pragma unroll
            for (int j = 0; j < 4; ++j) mx = fmaxf(mx, ps[r][sub + 8 * j]);
#pragma unroll
            for (int o = 4; o; o >>= 1) mx = fmaxf(mx, __shfl_xor(mx, o));
            float sum = 0.f;
            float e[4];
#pragma unroll
            for (int j = 0; j < 4; ++j) { e[j] = __expf(ps[r][sub + 8 * j] - mx); sum += e[j]; }
#pragma unroll
            for (int o = 4; o; o >>= 1) sum += __shfl_xor(sum, o);
            float inv = 1.f / sum;
#pragma unroll
            for (int j = 0; j < 4; ++j) ps[r][sub + 8 * j] = e[j] * inv;
        }
        __syncthreads();
        // ---- PV: thread owns col d, rows s0+4p (shared vs load, 8 chains) ----
        unsigned short* ob = isT ? outT : outR;
        {
            const int d = tid & 63;
            const int s0 = tid >> 6;           // 0..3
            float acc[8];
#pragma unroll
            for (int p = 0; p < 8; ++p) acc[p] = 0.f;
#pragma unroll 4
            for (int k = 0; k < 32; ++k) {
                float vk = vs[k][d];
#pragma unroll
                for (int p = 0; p < 8; ++p)
                    acc[p] += ps[s0 + 4 * p][k] * vk;
            }
#pragma unroll
            for (int p = 0; p < 8; ++p) {
                int s = s0 + 4 * p;
                ob[((size_t)(b * 32 + s)) * 512 + h * 64 + d] = f2bf(acc[p]);
            }
        }
    } else {
        // ---- up1 GEMM branch: 64x64 tile, BK=64, N=K=512, 512 blocks ----
        const int b = blockIdx.x;
        if (b >= 512) return;                      // whole block exits pre-barrier
        const int lb = (b & 7) * 64 + (b >> 3);    // manual 512-chunk swizzle
        const int bxg = lb & 7, byg = lb >> 3;
        unsigned short (*As)[2048] = (unsigned short(*)[2048])smem;          // 2*4096B
        unsigned short (*Bs)[2048] = (unsigned short(*)[2048])(smem + 8192); // 2*4096B
        const int wave = tid >> 6, lane = tid & 63;
        const int m0 = byg * 64, n0 = bxg * 64;
        const int sr = lane >> 2, sc = (lane & 3) * 8;
        const unsigned short* aS = A2 + (size_t)(m0 + wave * 16 + sr) * 512 + sc;
        const unsigned short* wS = W2 + (size_t)(n0 + wave * 16 + sr) * 512 + sc;
        const int wm = (wave >> 1) * 32, wn = (wave & 1) * 32;
        const int fr = lane & 15, fko = (lane >> 4) * 8;
        floatx4 acc[2][2];
#pragma unroll
        for (int i = 0; i < 2; ++i)
#pragma unroll
            for (int j = 0; j < 2; ++j) acc[i][j] = (floatx4){0.f, 0.f, 0.f, 0.f};
        for (int k0 = 0; k0 < 512; k0 += 64) {
#pragma unroll
            for (int h = 0; h < 2; ++h) {
                gload16(aS + k0 + 32 * h, &As[h][(wave * 16) * 32]);
                gload16(wS + k0 + 32 * h, &Bs[h][(wave * 16) * 32]);
            }
            __syncthreads();
#pragma unroll
            for (int h = 0; h < 2; ++h) {
                short8 af[2], bfr[2];
#pragma unroll
                for (int i = 0; i < 2; ++i) af[i] = *(const short8*)&As[h][(wm + i * 16 + fr) * 32 + fko];
#pragma unroll
                for (int j = 0; j < 2; ++j) bfr[j] = *(const short8*)&Bs[h][(wn + j * 16 + fr) * 32 + fko];
#pragma unroll
                for (int i = 0; i < 2; ++i)
#pragma unroll
                    for (int j = 0; j < 2; ++j)
                        acc[i][j] = __builtin_amdgcn_mfma_f32_16x16x32_bf16(af[i], bfr[j], acc[i][j], 0, 0, 0);
            }
            __syncthreads();
        }
        const int r0 = m0 + wm + (lane >> 4) * 4;
#pragma unroll
        for (int i = 0; i < 2; ++i)
#pragma unroll
            for (int j = 0; j < 2; ++j) {
                int n = n0 + wn + j * 16 + fr;
                float bv = b2[n];
#pragma unroll
                for (int r = 0; r < 4; ++r) {
                    int m = r0 + i * 16 + r;
                    C2[(size_t)m * 512 + n] = f2bf(acc[i][j][r] + bv);
                }
            }
    }
}

// ---------------- complex self-attention: LDS-resident, grid (128 batch, 2 half) ----------
__global__ __launch_bounds__(512) void cattn2_kernel(const float* __restrict__ LL,
                                                     unsigned short* __restrict__ outHi,
                                                     unsigned short* __restrict__ outLo)
{
    extern __shared__ float Xs[];
    __shared__ float Pr[16][33], Pi[16][33];
    const int b = blockIdx.x, half = blockIdx.y;
    const int tid = threadIdx.x;
    const float* base = LL + (size_t)b * 16384;
    for (int i = tid; i < 16384; i += 512) {
        int c = i >> 9, e = i & 511;
        Xs[e * 32 + ((c ^ e) & 31)] = base[i];
    }
    __syncthreads();
    {
        const int li = tid >> 5;                 // 0..15
        const int ci = half * 16 + li;
        const int ck = tid & 31;
        float ar = 0.f, ai = 0.f;
#pragma unroll 4
        for (int er = 0; er < 256; ++er) {
            const int sw = er & 31;
            float yr = Xs[er * 32 + ((ck ^ sw) & 31)];
            float yi = Xs[(er + 256) * 32 + ((ck ^ sw) & 31)];
            float xr = Xs[er * 32 + ((ci ^ sw) & 31)];
            float xi = Xs[(er + 256) * 32 + ((ci ^ sw) & 31)];
            ar += xr * yr - xi * yi;
            ai += xr * yi + xi * yr;
        }
        Pr[li][ck] = ar * 0.0625f;
        Pi[li][ck] = ai * 0.0625f;
    }
    __syncthreads();
    if (tid < 32) {
        int r = tid & 15;
        float (*P)[33] = (tid < 16) ? Pr : Pi;
        float mx = -1e30f;
        for (int j = 0; j < 32; ++j) mx = fmaxf(mx, P[r][j]);
        float s = 0.f;
        for (int j = 0; j < 32; ++j) { float e = __expf(P[r][j] - mx); P[r][j] = e; s += e; }
        float inv = 1.f / s;
        for (int j = 0; j < 32; ++j) P[r][j] *= inv;
    }
    __syncthreads();
    const int er = tid & 255;
    const int th = tid >> 8;                     // 0 or 1: t in [th*8, th*8+8)
    const int sw = er & 31;
    float accr[8], acci[8];
#pragma unroll
    for (int t = 0; t < 8; ++t) { accr[t] = 0.f; acci[t] = 0.f; }
    for (int k = 0; k < 32; ++k) {
        float yr = Xs[er * 32 + ((k ^ sw) & 31)];
        float yi = Xs[(er + 256) * 32 + ((k ^ sw) & 31)];
#pragma unroll
        for (int t = 0; t < 8; ++t) {
            float pr = Pr[th * 8 + t][k], pi = Pi[th * 8 + t][k];
            accr[t] += pr * yr - pi * yi;
            acci[t] += pr * yi + pi * yr;
        }
    }
#pragma unroll
    for (int t = 0; t < 8; ++t) {
        int c = half * 16 + th * 8 + t;
        float vr = Xs[er * 32 + ((c ^ sw) & 31)] + accr[t];
        float vi = Xs[(er + 256) * 32 + ((c ^ sw) & 31)] + acci[t];
        size_t ir = (size_t)b * 16384 + (size_t)c * 512 + er;
        unsigned short hr = f2bf(vr), hi2 = f2bf(vi);
        outHi[ir] = hr;        outLo[ir] = f2bf(vr - bf2f(hr));
        outHi[ir + 256] = hi2; outLo[ir + 256] = f2bf(vi - bf2f(hi2));
    }
}

// ---------------- DUAL add+LN (512), f32 resid, out bf16 hi/lo; rows>=4096 = branch 1 ----
__global__ __launch_bounds__(256) void add_ln_d1(
    const float* __restrict__ r0, const float* __restrict__ y0,
    const float* __restrict__ w0, const float* __restrict__ b0,
    unsigned short* __restrict__ h0, unsigned short* __restrict__ l0,
    const float* __restrict__ r1, const float* __restrict__ y1,
    const float* __restrict__ w1, const float* __restrict__ b1,
    unsigned short* __restrict__ h1, unsigned short* __restrict__ l1)
{
    const int row = blockIdx.x;
    const int br = row >> 12;
    const int rl = row & 4095;
    const float* resid = br ? r1 : r0;
    const float* y     = br ? y1 : y0;
    const float* w     = br ? w1 : w0;
    const float* bb    = br ? b1 : b0;
    unsigned short* oh = br ? h1 : h0;
    unsigned short* ol = br ? l1 : l0;
    const int tid = threadIdx.x;
    const size_t base = (size_t)rl * 512;
    float v0 = resid[base + tid] + y[base + tid];
    float v1 = resid[base + 256 + tid] + y[base + 256 + tid];
    float s = v0 + v1, q = v0 * v0 + v1 * v1;
    for (int off = 32; off; off >>= 1) { s += __shfl_down(s, off); q += __shfl_down(q, off); }
    __shared__ float sw[4], qw[4], ms, is;
    int wid = tid >> 6, lane = tid & 63;
    if (lane == 0) { sw[wid] = s; qw[wid] = q; }
    __syncthreads();
    if (tid == 0) {
        float S = sw[0] + sw[1] + sw[2] + sw[3];
        float Q = qw[0] + qw[1] + qw[2] + qw[3];
        float m = S * (1.f / 512.f);
        ms = m;
        is = rsqrtf(Q * (1.f / 512.f) - m * m + 1e-5f);
    }
    __syncthreads();
    float m = ms, inv = is;
    float o0 = (v0 - m) * inv * w[tid] + bb[tid];
    float o1 = (v1 - m) * inv * w[256 + tid] + bb[256 + tid];
    unsigned short e0 = f2bf(o0), e1 = f2bf(o1);
    oh[base + tid] = e0;       ol[base + tid] = f2bf(o0 - bf2f(e0));
    oh[base + 256 + tid] = e1; ol[base + 256 + tid] = f2bf(o1 - bf2f(e1));
}

// ---------------- DUAL add+LN (512), bf16 hi/lo resid, out f32 --------------------------
__global__ __launch_bounds__(256) void add_ln_d2(
    const unsigned short* __restrict__ rh0, const unsigned short* __restrict__ rl0,
    const float* __restrict__ y0, const float* __restrict__ w0, const float* __restrict__ b0,
    float* __restrict__ o0p,
    const unsigned short* __restrict__ rh1, const unsigned short* __restrict__ rl1,
    const float* __restrict__ y1, const float* __restrict__ w1, const float* __restrict__ b1,
    float* __restrict__ o1p)
{
    const int row = blockIdx.x;
    const int br = row >> 12;
    const int rl = row & 4095;
    const unsigned short* rh = br ? rh1 : rh0;
    const unsigned short* rlo = br ? rl1 : rl0;
    const float* y  = br ? y1 : y0;
    const float* w  = br ? w1 : w0;
    const float* bb = br ? b1 : b0;
    float* op = br ? o1p : o0p;
    const int tid = threadIdx.x;
    const size_t base = (size_t)rl * 512;
    float v0 = bf2f(rh[base + tid]) + bf2f(rlo[base + tid]) + y[base + tid];
    float v1 = bf2f(rh[base + 256 + tid]) + bf2f(rlo[base + 256 + tid]) + y[base + 256 + tid];
    float s = v0 + v1, q = v0 * v0 + v1 * v1;
    for (int off = 32; off; off >>= 1) { s += __shfl_down(s, off); q += __shfl_down(q, off); }
    __shared__ float sw[4], qw[4], ms, is;
    int wid = tid >> 6, lane = tid & 63;
    if (lane == 0) { sw[wid] = s; qw[wid] = q; }
    __syncthreads();
    if (tid == 0) {
        float S = sw[0] + sw[1] + sw[2] + sw[3];
        float Q = qw[0] + qw[1] + qw[2] + qw[3];
        float m = S * (1.f / 512.f);
        ms = m;
        is = rsqrtf(Q * (1.f / 512.f) - m * m + 1e-5f);
    }
    __syncthreads();
    float m = ms, inv = is;
    op[base + tid]       = (v0 - m) * inv * w[tid] + bb[tid];
    op[base + 256 + tid] = (v1 - m) * inv * w[256 + tid] + bb[256 + tid];
}

// ---------------- fused relu+batchLN x2: rf = LN(relu(x2R)) kept in LDS,
//                  res = LN(relu(x2T)) + rf. One block per batch, 1024 threads. ----------
__global__ __launch_bounds__(1024) void relu_bln_fused(
    const float* __restrict__ xR, const float* __restrict__ w2, const float* __restrict__ b2,
    const float* __restrict__ xT, const float* __restrict__ w1, const float* __restrict__ b1,
    float* __restrict__ out)
{
    __shared__ float rfs[16384];
    __shared__ float sw_[16], qw_[16], ms_, is_;
    const int bb = blockIdx.x, tid = threadIdx.x;
    const int wid = tid >> 6, lane = tid & 63;
    const float* xr = xR + (size_t)bb * 16384;
    float s = 0.f, q = 0.f;
    for (int i = tid; i < 16384; i += 1024) { float v = fmaxf(xr[i], 0.f); s += v; q += v * v; }
    for (int off = 32; off; off >>= 1) { s += __shfl_down(s, off); q += __shfl_down(q, off); }
    if (lane == 0) { sw_[wid] = s; qw_[wid] = q; }
    __syncthreads();
    if (tid == 0) {
        float S = 0.f, Q = 0.f;
        for (int i = 0; i < 16; ++i) { S += sw_[i]; Q += qw_[i]; }
        float m = S * (1.f / 16384.f);
        ms_ = m;
        is_ = rsqrtf(Q * (1.f / 16384.f) - m * m + 1e-5f);
    }
    __syncthreads();
    float m = ms_, inv = is_;
    for (int i = tid; i < 16384; i += 1024) {
        float v = fmaxf(xr[i], 0.f);
        rfs[i] = (v - m) * inv * w2[i] + b2[i];
    }
    const float* xt = xT + (size_t)bb * 16384;
    s = 0.f; q = 0.f;
    for (int i = tid; i < 16384; i += 1024) { float v = fmaxf(xt[i], 0.f); s += v; q += v * v; }
    for (int off = 32; off; off >>= 1) { s += __shfl_down(s, off); q += __shfl_down(q, off); }
    if (lane == 0) { sw_[wid] = s; qw_[wid] = q; }
    __syncthreads();
    if (tid == 0) {
        float S = 0.f, Q = 0.f;
        for (int i = 0; i < 16; ++i) { S += sw_[i]; Q += qw_[i]; }
        float m2 = S * (1.f / 16384.f);
        ms_ = m2;
        is_ = rsqrtf(Q * (1.f / 16384.f) - m2 * m2 + 1e-5f);
    }
    __syncthreads();
    m = ms_; inv = is_;
    float* op = out + (size_t)bb * 16384;
    for (int i = tid; i < 16384; i += 1024) {
        float v = fmaxf(xt[i], 0.f);
        op[i] = (v - m) * inv * w1[i] + b1[i] + rfs[i];
    }
}

extern "C" void kernel_launch(void* const* d_in, const int* in_sizes, int n_in,
                              void* d_out, int out_size, void* d_ws, size_t ws_size,
                              hipStream_t stream)
{
    (void)in_sizes; (void)n_in; (void)out_size; (void)ws_size;
    const float* x        = (const float*)d_in[0];
    const float* t_in_w   = (const float*)d_in[1];
    const float* t_in_b   = (const float*)d_in[2];
    const float* t_out_w  = (const float*)d_in[3];
    const float* t_out_b  = (const float*)d_in[4];
    const float* t_ln1_w  = (const float*)d_in[5];
    const float* t_ln1_b  = (const float*)d_in[6];
    const float* t_lin1_w = (const float*)d_in[7];
    const float* t_lin1_b = (const float*)d_in[8];
    const float* t_lin2_w = (const float*)d_in[9];
    const float* t_lin2_b = (const float*)d_in[10];
    const float* t_ln2_w  = (const float*)d_in[11];
    const float* t_ln2_b  = (const float*)d_in[12];
    const float* r_in_w   = (const float*)d_in[13];
    const float* r_in_b   = (const float*)d_in[14];
    const float* r_out_w  = (const float*)d_in[15];
    const float* r_out_b  = (const float*)d_in[16];
    const float* r_ln1_w  = (const float*)d_in[17];
    const float* r_ln1_b  = (const float*)d_in[18];
    const float* r_lin1_w = (const float*)d_in[19];
    const float* r_lin1_b = (const float*)d_in[20];
    const float* r_lin2_w = (const float*)d_in[21];
    const float* r_lin2_b = (const float*)d_in[22];
    const float* r_ln2_w  = (const float*)d_in[23];
    const float* r_ln2_b  = (const float*)d_in[24];
    const float* lc_w     = (const float*)d_in[25];
    const float* lc_b     = (const float*)d_in[26];
    const float* up1_w    = (const float*)d_in[27];
    const float* up1_b    = (const float*)d_in[28];
    const float* up2_w    = (const float*)d_in[29];
    const float* up2_b    = (const float*)d_in[30];
    const float* n1_w     = (const float*)d_in[31];
    const float* n1_b     = (const float*)d_in[32];
    const float* n2_w     = (const float*)d_in[33];
    const float* n2_b     = (const float*)d_in[34];
    const float* l1_re    = (const float*)d_in[35];
    const float* l1_im    = (const float*)d_in[36];
    const float* lb1_re   = (const float*)d_in[39];
    const float* lb1_im   = (const float*)d_in[40];

    float* outp = (float*)d_out;

    // ---- workspace map (float offsets; total 21,774,336 f = 87.1 MB) ----
    float* WS   = (float*)d_ws;
    float* LL   = WS;                                        // 2M f (also fa f32, later y_r)
    float* FA   = WS;
    float* yR   = WS;
    float* QR   = WS + 2097152;                              // 6.29M f
    float* tabC = QR;                                        // 131072
    float* tabS = QR + 131072;
    unsigned short* WaHu = (unsigned short*)(QR + 786432);
    unsigned short* WaLu = (unsigned short*)(QR + 917504);
    unsigned short* WmHu = (unsigned short*)(QR + 1048576);
    unsigned short* WmLu = (unsigned short*)(QR + 1179648);
    float* qkvR = QR;                                        // 6.29M f: [2097152, 8388608)
    unsigned short* x1rH = (unsigned short*)(WS + 2097152);
    unsigned short* x1rL = (unsigned short*)(WS + 3145728);
    unsigned short* x1tH = (unsigned short*)(WS + 4194304);
    unsigned short* x1tL = (unsigned short*)(WS + 5242880);
    float* yT   = WS + 6291456;                              // 2M f
    unsigned short* qkvT = (unsigned short*)(WS + 8388608);  // 6.29M ushort
    unsigned short* f1R  = (unsigned short*)(WS + 8388608);  // 8.39M ushort
    float* x2R  = WS + 8388608;                              // 2M f
    float* x2T  = WS + 10485760;                             // 2M f
    unsigned short* xHi = (unsigned short*)(WS + 11534336);
    unsigned short* xLo = (unsigned short*)(WS + 12582912);
    unsigned short* aoR = (unsigned short*)(WS + 11534336);
    unsigned short* aoT = (unsigned short*)(WS + 12582912);
    unsigned short* f1T = (unsigned short*)(WS + 12582912);  // 8.39M ushort
    unsigned short* LLH = (unsigned short*)(WS + 13631488);
    unsigned short* LLL = (unsigned short*)(WS + 14680064);
    float* oR   = WS + 13631488;                             // 2M f
    float* oT   = WS + 15728640;                             // 2M f
    unsigned short* faHi = (unsigned short*)(WS + 15728640);
    unsigned short* faLo = (unsigned short*)(WS + 16777216);
    unsigned short* rinLoU = (unsigned short*)(WS + 17825792);  // 786432 ushort
    float* LB   = WS + 18219008;                             // 512 f
    unsigned short* WB = (unsigned short*)(WS + 18366464);

    // u1b (up1 bf16 out, 1M ushort) parks in the OUTPUT res slot outp[0..1048576 f):
    // res is written only by the final relu_bln_fused (verified passing in R19-R23).
    unsigned short* u1b = (unsigned short*)outp;

    unsigned short* w_tin  = WB + 0;        // 1536x512
    unsigned short* w_tout = WB + 786432;   // 512x512
    unsigned short* w_tl1  = WB + 1048576;  // 2048x512
    unsigned short* w_tl2  = WB + 2097152;  // 512x2048
    unsigned short* w_rin  = WB + 3145728;  // 1536x512
    unsigned short* w_rout = WB + 3932160;  // 512x512
    unsigned short* w_rl1  = WB + 4194304;  // 2048x512
    unsigned short* w_rl2  = WB + 5242880;  // 512x2048
    unsigned short* w_up1  = WB + 6291456;  // 512x512
    unsigned short* w_up2  = WB + 6553600;  // 512x512

    dim3 blk(256);

    // ---- prep (2 dispatches: uber(+tab), wawm) ----
    uber_prep_kernel<<<dim3(35330), blk, 0, stream>>>(t_in_w, t_out_w, t_lin1_w, t_lin2_w,
                                                      r_in_w, r_out_w, r_lin1_w, r_lin2_w,
                                                      up1_w, up2_w, WB, rinLoU,
                                                      x, xHi, xLo, outp + NOUT,
                                                      lb1_re, lb1_im, LB, tabC, tabS);
    wawm_kernel<<<dim3(512, 2, 2), blk, 0, stream>>>(l1_re, l1_im, lc_w, tabC, tabS,
                                                     WaHu, WaLu, WmHu, WmLu);

    // ---- freq branch (keeps hi/lo: fa and up are direct outputs) ----
    gemm_mfma3<64,64,1,0,0><<<dim3(8, 64), blk, 0, stream>>>(xHi, xLo, WaHu, WaLu, LB,
                                                             LL, nullptr, nullptr, nullptr, 512, 512);
    cattn2_kernel<<<dim3(128, 2), dim3(512), 65536, stream>>>(LL, LLH, LLL);         // LL hi/lo
    gemm_mfma3<64,64,0,1,1><<<dim3(8, 64), blk, 0, stream>>>(LLH, LLL, WmHu, WmLu, lc_b,
                                                             FA, outp + 2 * NOUT, faHi, faLo, 512, 512);

    // ---- qkv both TELs (single-product bf16 both branches; R22) ----
    gemm_qkv_dual<64,128><<<dim3(12, 64, 2), blk, 0, stream>>>(faHi, w_rin, r_in_b, qkvR,
                                                               xHi, w_tin, t_in_b, qkvT, 1536, 512);

    // ---- attention (r+t) + up1, merged (R23 register-blocked) ----
    attn_up1_kernel<<<dim3(1024, 1, 3), blk, 0, stream>>>(qkvR, qkvT, aoR, aoT,
                                                          faHi, w_up1, up1_b, u1b);

    // ---- out-proj r/t + up2 (tri) ----
    gemm_out_tri<64,64><<<dim3(8, 64, 3), blk, 0, stream>>>(aoR, w_rout, r_out_b, oR,
                                                            aoT, w_tout, t_out_b, oT,
                                                            u1b, w_up2, up2_b, outp + 3 * NOUT, 512, 512);
    add_ln_d1<<<dim3(8192), blk, 0, stream>>>(FA, oR, r_ln1_w, r_ln1_b, x1rH, x1rL,
                                              x,  oT, t_ln1_w, t_ln1_b, x1tH, x1tL);
    gemm_dual<128,128,1,1><<<dim3(16, 32, 2), blk, 0, stream>>>(x1rH, x1tH, w_rl1, w_tl1,
                                                                r_lin1_b, t_lin1_b, nullptr, nullptr,
                                                                f1R, f1T, 2048, 512);
    gemm_dual<64,128,0,0><<<dim3(4, 64, 2), blk, 0, stream>>>(f1R, f1T, w_rl2, w_tl2,
                                                              r_lin2_b, t_lin2_b, yR, yT,
                                                              nullptr, nullptr, 512, 2048);
    add_ln_d2<<<dim3(8192), blk, 0, stream>>>(x1rH, x1rL, yR, r_ln2_w, r_ln2_b, x2R,
                                              x1tH, x1tL, yT, t_ln2_w, t_ln2_b, x2T);
    relu_bln_fused<<<dim3(128), dim3(1024), 0, stream>>>(x2R, n2_w, n2_b, x2T, n1_w, n1_b, outp);
}

// Round 18
// 420.784 us; speedup vs baseline: 1.1485x; 1.0015x over previous
//
#include <hip/hip_runtime.h>
#include <math.h>

// NoiScaleModule: B=128, C=32(seq), S=512(d_model), EMB=256, NHEAD=8, DFF=2048
// All tensors FLOAT32. Outputs concat flat: res[2M], down_x[2M], fa[2M], up[2M]
//
// R23: attention register-blocking. 431->424.9. R24: lin1 128x128 (4/CU). ->421.4.
// R25: qkv_dual 64x128 -> 128x128 (grid (12,32,2)=768 blocks=3/CU, resident;
//      same body R24 validated at 4/CU on lin1). FLOPs/staged-byte 42.7->64.
//      Single isolated change; all else byte-identical to R24.

#define NROW 4096
#define NOUT 2097152

typedef __attribute__((ext_vector_type(8))) short short8;
typedef __attribute__((ext_vector_type(4))) float floatx4;

__device__ __forceinline__ unsigned short f2bf(float f) {
    union { float f; unsigned u; } v; v.f = f;
    return (unsigned short)((v.u + 0x7fffu + ((v.u >> 16) & 1u)) >> 16);
}
__device__ __forceinline__ float bf2f(unsigned short h) {
    union { unsigned u; float f; } v; v.u = ((unsigned)h) << 16;
    return v.f;
}

__device__ __forceinline__ void gload16(const unsigned short* g, unsigned short* l) {
    __builtin_amdgcn_global_load_lds((const __attribute__((address_space(1))) void*)g,
                                     (__attribute__((address_space(3))) void*)l, 16, 0, 0);
}

// XCD-chunked swizzle (T1): requires nwg % 8 == 0.
__device__ __forceinline__ void xcd_swizzle(int& bx, int& by, int& bz) {
    const int gx = gridDim.x, gy = gridDim.y;
    const int nwg = gx * gy * gridDim.z;
    int b = (bz * gy + by) * gx + bx;
    const int chunk = nwg >> 3;
    const int lb = (b & 7) * chunk + (b >> 3);
    bx = lb % gx;
    const int rem = lb / gx;
    by = rem % gy;
    bz = rem / gy;
}

// Wa (z=0) and Wm (z=1) in one dispatch; both emit bf16 hi/lo directly.
__global__ __launch_bounds__(256) void wawm_kernel(const float* __restrict__ l1_re, const float* __restrict__ l1_im,
                                                   const float* __restrict__ lc_w,
                                                   const float* __restrict__ tabC, const float* __restrict__ tabS,
                                                   unsigned short* __restrict__ WaH, unsigned short* __restrict__ WaL,
                                                   unsigned short* __restrict__ WmH, unsigned short* __restrict__ WmL)
{
    __shared__ float lw[512];
    const float inv = 0.04419417382415922f;  // 1/sqrt(512)
    if (blockIdx.z == 0) {
        int n  = blockIdx.x;
        int ep = blockIdx.y * 256 + threadIdx.x;
        float acc = 0.f;
        if (ep < 256) {
            for (int k = 0; k < 128; ++k) {
                float c = tabC[n * 256 + k], s = tabS[n * 256 + k];
                acc += c * l1_re[k * 256 + ep] + s * l1_im[k * 256 + ep];
            }
        } else {
            int e = ep - 256;
            for (int k = 0; k < 128; ++k) {
                float c = tabC[n * 256 + k], s = tabS[n * 256 + k];
                acc += c * l1_im[k * 256 + e] - s * l1_re[k * 256 + e];
            }
        }
        float v = acc * inv;
        size_t idx = (size_t)ep * 512 + n;
        unsigned short h = f2bf(v);
        WaH[idx] = h;
        WaL[idx] = f2bf(v - bf2f(h));
    } else {
        int s  = blockIdx.x;
        int kk = blockIdx.y * 256 + threadIdx.x;
        for (int i = threadIdx.x; i < 512; i += 256) lw[i] = lc_w[s * 512 + i];
        __syncthreads();
        float acc = 0.f;
        if (kk < 256) {
            int k = kk;
            for (int n = 0; n < 512; ++n) acc += tabC[n * 256 + k] * lw[n];
            acc *= (k == 0) ? inv : 2.f * inv;
        } else {
            int k = kk - 256;
            if (k == 0) acc = 0.f;
            else {
                for (int n = 0; n < 512; ++n) acc += tabS[n * 256 + k] * lw[n];
                acc *= -2.f * inv;
            }
        }
        size_t idx = (size_t)s * 512 + kk;
        unsigned short h = f2bf(acc);
        WmH[idx] = h;
        WmL[idx] = f2bf(acc - bf2f(h));
    }
}

// ---------------- uber elementwise prep: wcvt(+rinLo) | xsplit | lbpack | tab ------------
__global__ __launch_bounds__(256) void uber_prep_kernel(
    const float* s0, const float* s1, const float* s2, const float* s3, const float* s4,
    const float* s5, const float* s6, const float* s7, const float* s8, const float* s9,
    unsigned short* __restrict__ o, unsigned short* __restrict__ rinLo,
    const float* __restrict__ x, unsigned short* __restrict__ xhi,
    unsigned short* __restrict__ xlo, float* __restrict__ xcp,
    const float* __restrict__ lbre, const float* __restrict__ lbim, float* __restrict__ lbout,
    float* __restrict__ tabC, float* __restrict__ tabS)
{
    const int bid = blockIdx.x, tid = threadIdx.x;
    if (bid < 26624) {
        int i = bid * 256 + tid;  // exactly covers 6815744
        const float* s; int off;
        if (i < 3145728) {
            if (i < 1048576) { if (i < 786432) { s = s0; off = 0; } else { s = s1; off = 786432; } }
            else             { if (i < 2097152) { s = s2; off = 1048576; } else { s = s3; off = 2097152; } }
        } else {
            if (i < 5242880) {
                if (i < 3932160) { s = s4; off = 3145728; }
                else if (i < 4194304) { s = s5; off = 3932160; }
                else { s = s6; off = 4194304; }
            } else {
                if (i < 6291456) { s = s7; off = 5242880; }
                else if (i < 6553600) { s = s8; off = 6291456; }
                else { s = s9; off = 6553600; }
            }
        }
        float v = s[i - off];
        unsigned short h = f2bf(v);
        o[i] = h;
        if (i >= 3145728 && i < 3932160) rinLo[i - 3145728] = f2bf(v - bf2f(h));
    } else if (bid < 34816) {
        int i = (bid - 26624) * 256 + tid;  // exactly covers 2097152
        float v = x[i];
        unsigned short h = f2bf(v);
        xhi[i] = h;
        xlo[i] = f2bf(v - bf2f(h));
        xcp[i] = v;
    } else if (bid < 34818) {
        int i = (bid - 34816) * 256 + tid;
        if (i < 512) lbout[i] = (i < 256) ? lbre[i] : lbim[i - 256];
    } else {
        int n = bid - 34818;                 // 0..511
        int k = tid;                         // 0..255
        int m = (n * k) & 511;
        float th = (float)m * 0.01227184630308513f;  // 2*pi/512
        float sv, cv; sincosf(th, &sv, &cv);
        tabC[n * 256 + k] = cv;
        tabS[n * 256 + k] = sv;
    }
}

// ---------------- dual-branch GEMM (BK=64): z=0/1 select. For lin1/lin2. ----------------
template <int TM, int TN, int ACT, int WBF>
__global__ __launch_bounds__(256) void gemm_dual(
    const unsigned short* __restrict__ A0, const unsigned short* __restrict__ A1,
    const unsigned short* __restrict__ W0, const unsigned short* __restrict__ W1,
    const float* __restrict__ b0, const float* __restrict__ b1,
    float* __restrict__ C0, float* __restrict__ C1,
    unsigned short* __restrict__ D0, unsigned short* __restrict__ D1, int N, int K)
{
    constexpr int MI = TM / 32, NJ = TN / 32;
    constexpr int ARW = TM / 4, BRW = TN / 4;
    __shared__ unsigned short As[2][TM * 32];
    __shared__ unsigned short Bs[2][TN * 32];
    const int tid = threadIdx.x;
    const int wave = tid >> 6, lane = tid & 63;
    int bx = blockIdx.x, by = blockIdx.y, bz = blockIdx.z;
    xcd_swizzle(bx, by, bz);
    const int m0 = by * TM, n0 = bx * TN;
    const int z = bz;
    const unsigned short* A = z ? A1 : A0;
    const unsigned short* W = z ? W1 : W0;
    const float* bias = z ? b1 : b0;
    float* Cf = z ? C1 : C0;
    unsigned short* Cb = z ? D1 : D0;
    const int sr = lane >> 2, sc = (lane & 3) * 8;
    const unsigned short* aS = A + (size_t)(m0 + wave * ARW + sr) * K + sc;
    const unsigned short* wS = W + (size_t)(n0 + wave * BRW + sr) * K + sc;
    const int wm = (wave >> 1) * (TM / 2), wn = (wave & 1) * (TN / 2);
    const int fr = lane & 15, fko = (lane >> 4) * 8;

    floatx4 acc[MI][NJ];
#pragma unroll
    for (int i = 0; i < MI; ++i)
#pragma unroll
        for (int j = 0; j < NJ; ++j) acc[i][j] = (floatx4){0.f, 0.f, 0.f, 0.f};

    for (int k0 = 0; k0 < K; k0 += 64) {
#pragma unroll
        for (int h = 0; h < 2; ++h) {
#pragma unroll
            for (int c = 0; c < ARW / 16; ++c)
                gload16(aS + (size_t)(16 * c) * K + k0 + 32 * h, &As[h][(wave * ARW + 16 * c) * 32]);
#pragma unroll
            for (int c = 0; c < BRW / 16; ++c)
                gload16(wS + (size_t)(16 * c) * K + k0 + 32 * h, &Bs[h][(wave * BRW + 16 * c) * 32]);
        }
        __syncthreads();
#pragma unroll
        for (int h = 0; h < 2; ++h) {
            short8 af[MI], bfr[NJ];
#pragma unroll
            for (int i = 0; i < MI; ++i) af[i] = *(const short8*)&As[h][(wm + i * 16 + fr) * 32 + fko];
#pragma unroll
            for (int j = 0; j < NJ; ++j) bfr[j] = *(const short8*)&Bs[h][(wn + j * 16 + fr) * 32 + fko];
#pragma unroll
            for (int i = 0; i < MI; ++i)
#pragma unroll
                for (int j = 0; j < NJ; ++j)
                    acc[i][j] = __builtin_amdgcn_mfma_f32_16x16x32_bf16(af[i], bfr[j], acc[i][j], 0, 0, 0);
        }
        __syncthreads();
    }
    const int r0 = m0 + wm + (lane >> 4) * 4;
#pragma unroll
    for (int i = 0; i < MI; ++i) {
#pragma unroll
        for (int j = 0; j < NJ; ++j) {
            int n = n0 + wn + j * 16 + fr;
            float bv = bias[n];
#pragma unroll
            for (int r = 0; r < 4; ++r) {
                int m = r0 + i * 16 + r;
                size_t idx = (size_t)m * N + n;
                float v = acc[i][j][r] + bv;
                if (ACT) v = fmaxf(v, 0.f);
                if (WBF) Cb[idx] = f2bf(v);
                else     Cf[idx] = v;
            }
        }
    }
}

// ---------------- tri-branch single-product GEMM (BK=64, TN=64): out-proj r/t + up2 ------
template <int TM, int TN>
__global__ __launch_bounds__(256) void gemm_out_tri(
    const unsigned short* __restrict__ A0, const unsigned short* __restrict__ W0,
    const float* __restrict__ b0, float* __restrict__ C0,
    const unsigned short* __restrict__ A1, const unsigned short* __restrict__ W1,
    const float* __restrict__ b1, float* __restrict__ C1,
    const unsigned short* __restrict__ A2, const unsigned short* __restrict__ W2,
    const float* __restrict__ b2, float* __restrict__ C2, int N, int K)
{
    constexpr int MI = TM / 32, NJ = TN / 32;
    constexpr int ARW = TM / 4, BRW = TN / 4;
    __shared__ unsigned short As[2][TM * 32];
    __shared__ unsigned short Bs[2][TN * 32];
    const int tid = threadIdx.x;
    const int wave = tid >> 6, lane = tid & 63;
    int bx = blockIdx.x, by = blockIdx.y, bz = blockIdx.z;
    xcd_swizzle(bx, by, bz);
    const int m0 = by * TM, n0 = bx * TN;
    const unsigned short* A = (bz == 0) ? A0 : (bz == 1) ? A1 : A2;
    const unsigned short* W = (bz == 0) ? W0 : (bz == 1) ? W1 : W2;
    const float* bias       = (bz == 0) ? b0 : (bz == 1) ? b1 : b2;
    float* Cf               = (bz == 0) ? C0 : (bz == 1) ? C1 : C2;
    const int sr = lane >> 2, sc = (lane & 3) * 8;
    const unsigned short* aS = A + (size_t)(m0 + wave * ARW + sr) * K + sc;
    const unsigned short* wS = W + (size_t)(n0 + wave * BRW + sr) * K + sc;
    const int wm = (wave >> 1) * (TM / 2), wn = (wave & 1) * (TN / 2);
    const int fr = lane & 15, fko = (lane >> 4) * 8;

    floatx4 acc[MI][NJ];
#pragma unroll
    for (int i = 0; i < MI; ++i)
#pragma unroll
        for (int j = 0; j < NJ; ++j) acc[i][j] = (floatx4){0.f, 0.f, 0.f, 0.f};

    for (int k0 = 0; k0 < K; k0 += 64) {
#pragma unroll
        for (int h = 0; h < 2; ++h) {
#pragma unroll
            for (int c = 0; c < ARW / 16; ++c)
                gload16(aS + (size_t)(16 * c) * K + k0 + 32 * h, &As[h][(wave * ARW + 16 * c) * 32]);
#pragma unroll
            for (int c = 0; c < BRW / 16; ++c)
                gload16(wS + (size_t)(16 * c) * K + k0 + 32 * h, &Bs[h][(wave * BRW + 16 * c) * 32]);
        }
        __syncthreads();
#pragma unroll
        for (int h = 0; h < 2; ++h) {
            short8 af[MI], bfr[NJ];
#pragma unroll
            for (int i = 0; i < MI; ++i) af[i] = *(const short8*)&As[h][(wm + i * 16 + fr) * 32 + fko];
#pragma unroll
            for (int j = 0; j < NJ; ++j) bfr[j] = *(const short8*)&Bs[h][(wn + j * 16 + fr) * 32 + fko];
#pragma unroll
            for (int i = 0; i < MI; ++i)
#pragma unroll
                for (int j = 0; j < NJ; ++j)
                    acc[i][j] = __builtin_amdgcn_mfma_f32_16x16x32_bf16(af[i], bfr[j], acc[i][j], 0, 0, 0);
        }
        __syncthreads();
    }
    const int r0 = m0 + wm + (lane >> 4) * 4;
#pragma unroll
    for (int i = 0; i < MI; ++i) {
#pragma unroll
        for (int j = 0; j < NJ; ++j) {
            int n = n0 + wn + j * 16 + fr;
            float bv = bias[n];
#pragma unroll
            for (int r = 0; r < 4; ++r) {
                int m = r0 + i * 16 + r;
                Cf[(size_t)m * N + n] = acc[i][j][r] + bv;
            }
        }
    }
}

// ---------------- fused hi/lo 3-product MFMA GEMM (BK=64, single-buffer) ----------------
template <int TM, int TN, int ACT, int WCOPY, int WHILO>
__global__ __launch_bounds__(256) void gemm_mfma3(
    const unsigned short* __restrict__ Ah, const unsigned short* __restrict__ Al,
    const unsigned short* __restrict__ Wh, const unsigned short* __restrict__ Wl,
    const float* __restrict__ bias, float* __restrict__ Cf, float* __restrict__ Ccopy,
    unsigned short* __restrict__ Hh, unsigned short* __restrict__ Hl, int N, int K)
{
    constexpr int MI = TM / 32, NJ = TN / 32;
    constexpr int ARW = TM / 4, BRW = TN / 4;
    __shared__ unsigned short Ash[2][TM * 32];
    __shared__ unsigned short Asl[2][TM * 32];
    __shared__ unsigned short Bsh[2][TN * 32];
    __shared__ unsigned short Bsl[2][TN * 32];
    const int tid = threadIdx.x;
    const int wave = tid >> 6, lane = tid & 63;
    int bx = blockIdx.x, by = blockIdx.y, bz = blockIdx.z;
    xcd_swizzle(bx, by, bz);
    const int m0 = by * TM, n0 = bx * TN;
    const int sr = lane >> 2, sc = (lane & 3) * 8;
    const size_t aoff = (size_t)(m0 + wave * ARW + sr) * K + sc;
    const size_t woff = (size_t)(n0 + wave * BRW + sr) * K + sc;
    const int wm = (wave >> 1) * (TM / 2), wn = (wave & 1) * (TN / 2);
    const int fr = lane & 15, fko = (lane >> 4) * 8;

    floatx4 acc[MI][NJ];
#pragma unroll
    for (int i = 0; i < MI; ++i)
#pragma unroll
        for (int j = 0; j < NJ; ++j) acc[i][j] = (floatx4){0.f, 0.f, 0.f, 0.f};

    for (int k0 = 0; k0 < K; k0 += 64) {
#pragma unroll
        for (int h = 0; h < 2; ++h) {
#pragma unroll
            for (int c = 0; c < ARW / 16; ++c) {
                gload16(Ah + aoff + (size_t)(16 * c) * K + k0 + 32 * h, &Ash[h][(wave * ARW + 16 * c) * 32]);
                gload16(Al + aoff + (size_t)(16 * c) * K + k0 + 32 * h, &Asl[h][(wave * ARW + 16 * c) * 32]);
            }
#pragma unroll
            for (int c = 0; c < BRW / 16; ++c) {
                gload16(Wh + woff + (size_t)(16 * c) * K + k0 + 32 * h, &Bsh[h][(wave * BRW + 16 * c) * 32]);
                gload16(Wl + woff + (size_t)(16 * c) * K + k0 + 32 * h, &Bsl[h][(wave * BRW + 16 * c) * 32]);
            }
        }
        __syncthreads();
#pragma unroll
        for (int h = 0; h < 2; ++h) {
            short8 ah[MI], al[MI], bh[NJ], bl[NJ];
#pragma unroll
            for (int i = 0; i < MI; ++i) {
                ah[i] = *(const short8*)&Ash[h][(wm + i * 16 + fr) * 32 + fko];
                al[i] = *(const short8*)&Asl[h][(wm + i * 16 + fr) * 32 + fko];
            }
#pragma unroll
            for (int j = 0; j < NJ; ++j) {
                bh[j] = *(const short8*)&Bsh[h][(wn + j * 16 + fr) * 32 + fko];
                bl[j] = *(const short8*)&Bsl[h][(wn + j * 16 + fr) * 32 + fko];
            }
#pragma unroll
            for (int i = 0; i < MI; ++i)
#pragma unroll
                for (int j = 0; j < NJ; ++j) {
                    acc[i][j] = __builtin_amdgcn_mfma_f32_16x16x32_bf16(al[i], bh[j], acc[i][j], 0, 0, 0);
                    acc[i][j] = __builtin_amdgcn_mfma_f32_16x16x32_bf16(ah[i], bl[j], acc[i][j], 0, 0, 0);
                    acc[i][j] = __builtin_amdgcn_mfma_f32_16x16x32_bf16(ah[i], bh[j], acc[i][j], 0, 0, 0);
                }
        }
        __syncthreads();
    }
    const int r0 = m0 + wm + (lane >> 4) * 4;
#pragma unroll
    for (int i = 0; i < MI; ++i) {
#pragma unroll
        for (int j = 0; j < NJ; ++j) {
            int n = n0 + wn + j * 16 + fr;
            float bv = bias[n];
#pragma unroll
            for (int r = 0; r < 4; ++r) {
                int m = r0 + i * 16 + r;
                size_t idx = (size_t)m * N + n;
                float v = acc[i][j][r] + bv;
                if (ACT) v = fmaxf(v, 0.f);
                Cf[idx] = v;
                if (WCOPY) Ccopy[idx] = v;
                if (WHILO) {
                    unsigned short h = f2bf(v);
                    Hh[idx] = h;
                    Hl[idx] = f2bf(v - bf2f(h));
                }
            }
        }
    }
}

// ---------------- merged qkv GEMM (BK=64, single-product both branches):
//                  z=0 r-qkv faHi x w_rin -> f32; z=1 t-qkv xHi x w_tin -> bf16. ----------
template <int TM, int TN>
__global__ __launch_bounds__(256) void gemm_qkv_dual(
    const unsigned short* __restrict__ A0, const unsigned short* __restrict__ W0,
    const float* __restrict__ b0, float* __restrict__ C0,
    const unsigned short* __restrict__ A1, const unsigned short* __restrict__ W1,
    const float* __restrict__ b1, unsigned short* __restrict__ C1,
    int N, int K)
{
    constexpr int MI = TM / 32, NJ = TN / 32;
    constexpr int ARW = TM / 4, BRW = TN / 4;
    __shared__ unsigned short As[2][TM * 32];
    __shared__ unsigned short Bs[2][TN * 32];
    const int tid = threadIdx.x;
    const int wave = tid >> 6, lane = tid & 63;
    int bx = blockIdx.x, by = blockIdx.y, bz = blockIdx.z;
    xcd_swizzle(bx, by, bz);
    const int m0 = by * TM, n0 = bx * TN;
    const unsigned short* A = bz ? A1 : A0;
    const unsigned short* W = bz ? W1 : W0;
    const float* bias = bz ? b1 : b0;
    const int sr = lane >> 2, sc = (lane & 3) * 8;
    const unsigned short* aS = A + (size_t)(m0 + wave * ARW + sr) * K + sc;
    const unsigned short* wS = W + (size_t)(n0 + wave * BRW + sr) * K + sc;
    const int wm = (wave >> 1) * (TM / 2), wn = (wave & 1) * (TN / 2);
    const int fr = lane & 15, fko = (lane >> 4) * 8;

    floatx4 acc[MI][NJ];
#pragma unroll
    for (int i = 0; i < MI; ++i)
#pragma unroll
        for (int j = 0; j < NJ; ++j) acc[i][j] = (floatx4){0.f, 0.f, 0.f, 0.f};

    for (int k0 = 0; k0 < K; k0 += 64) {
#pragma unroll
        for (int h = 0; h < 2; ++h) {
#pragma unroll
            for (int c = 0; c < ARW / 16; ++c)
                gload16(aS + (size_t)(16 * c) * K + k0 + 32 * h, &As[h][(wave * ARW + 16 * c) * 32]);
#pragma unroll
            for (int c = 0; c < BRW / 16; ++c)
                gload16(wS + (size_t)(16 * c) * K + k0 + 32 * h, &Bs[h][(wave * BRW + 16 * c) * 32]);
        }
        __syncthreads();
#pragma unroll
        for (int h = 0; h < 2; ++h) {
            short8 af[MI], bfr[NJ];
#pragma unroll
            for (int i = 0; i < MI; ++i) af[i] = *(const short8*)&As[h][(wm + i * 16 + fr) * 32 + fko];
#pragma unroll
            for (int j = 0; j < NJ; ++j) bfr[j] = *(const short8*)&Bs[h][(wn + j * 16 + fr) * 32 + fko];
#pragma unroll
            for (int i = 0; i < MI; ++i)
#pragma unroll
                for (int j = 0; j < NJ; ++j)
                    acc[i][j] = __builtin_amdgcn_mfma_f32_16x16x32_bf16(af[i], bfr[j], acc[i][j], 0, 0, 0);
        }
        __syncthreads();
    }
    const int r0 = m0 + wm + (lane >> 4) * 4;
#pragma unroll
    for (int i = 0; i < MI; ++i) {
#pragma unroll
        for (int j = 0; j < NJ; ++j) {
            int n = n0 + wn + j * 16 + fr;
            float bv = bias[n];
#pragma unroll
            for (int r = 0; r < 4; ++r) {
                int m = r0 + i * 16 + r;
                size_t idx = (size_t)m * N + n;
                float v = acc[i][j][r] + bv;
                if (bz == 0) C0[idx] = v;
                else         C1[idx] = f2bf(v);
            }
        }
    }
}

// ---------------- merged attention + up1: z=0 attn-r (f32 qkv), z=1 attn-t (bf16 qkv),
//                  z=2 up1 GEMM (512 of 1024 blocks; whole-block early exit).
// R23: register-blocked QK/PV + wave-parallel softmax. ------------------------------------
__global__ __launch_bounds__(256) void attn_up1_kernel(
    const float* __restrict__ qkvF, const unsigned short* __restrict__ qkvB,
    unsigned short* __restrict__ outR, unsigned short* __restrict__ outT,
    const unsigned short* __restrict__ A2, const unsigned short* __restrict__ W2,
    const float* __restrict__ b2, unsigned short* __restrict__ C2)
{
    __shared__ __align__(16) char smem[29184];
    const int tid = threadIdx.x;
    if (blockIdx.z < 2) {
        // ---- attention branch (29184 B LDS) ----
        float (*qs)[65] = (float(*)[65])smem;
        float (*ks)[65] = (float(*)[65])(smem + 8320);
        float (*vs)[65] = (float(*)[65])(smem + 16640);
        float (*ps)[33] = (float(*)[33])(smem + 24960);
        const int isT = blockIdx.z;
        const int b = blockIdx.x >> 3;
        const int h = blockIdx.x & 7;
        if (isT) {
            for (int i = tid; i < 2048; i += 256) {
                int s = i >> 6, d = i & 63;
                size_t base = ((size_t)(b * 32 + s)) * 1536 + h * 64 + d;
                qs[s][d] = bf2f(qkvB[base]);
                ks[s][d] = bf2f(qkvB[base + 512]);
                vs[s][d] = bf2f(qkvB[base + 1024]);
            }
        } else {
            for (int i = tid; i < 2048; i += 256) {
                int s = i >> 6, d = i & 63;
                size_t base = ((size_t)(b * 32 + s)) * 1536 + h * 64 + d;
                qs[s][d] = qkvF[base];
                ks[s][d] = qkvF[base + 512];
                vs[s][d] = qkvF[base + 1024];
            }
        }
        __syncthreads();
        // ---- QK: thread owns col sj, rows si0+8p (shared ks load, 4 chains) ----
        {
            const int sj = tid & 31;
            const int si0 = tid >> 5;          // 0..7
            float acc0 = 0.f, acc1 = 0.f, acc2 = 0.f, acc3 = 0.f;
#pragma unroll 8
            for (int d = 0; d < 64; ++d) {
                float kd = ks[sj][d];
                acc0 += qs[si0][d] * kd;
                acc1 += qs[si0 + 8][d] * kd;
                acc2 += qs[si0 + 16][d] * kd;
                acc3 += qs[si0 + 24][d] * kd;
            }
            ps[si0][sj]      = acc0 * 0.125f;
            ps[si0 + 8][sj]  = acc1 * 0.125f;
            ps[si0 + 16][sj] = acc2 * 0.125f;
            ps[si0 + 24][sj] = acc3 * 0.125f;
        }
        __syncthreads();
        // ---- softmax: 32 rows x 8 lanes, shfl_xor reduce within 8-lane groups ----
        {
            const int r = tid >> 3, sub = tid & 7;
            float mx = -1e30f;
#pragma unroll
            for (int j = 0; j < 4; ++j) mx = fmaxf(mx, ps[r][sub + 8 * j]);
#pragma unroll
            for (int o = 4; o; o >>= 1) mx = fmaxf(mx, __shfl_xor(mx, o));
            float sum = 0.f;
            float e[4];
#pragma unroll
            for (int j = 0; j < 4; ++j) { e[j] = __expf(ps[r][sub + 8 * j] - mx); sum += e[j]; }
#pragma unroll
            for (int o = 4; o; o >>= 1) sum += __shfl_xor(sum, o);
            float inv = 1.f / sum;
#pragma unroll
            for (int j = 0; j < 4; ++j) ps[r][sub + 8 * j] = e[j] * inv;
        }
        __syncthreads();
        // ---- PV: thread owns col d, rows s0+4p (shared vs load, 8 chains) ----
        unsigned short* ob = isT ? outT : outR;
        {
            const int d = tid & 63;
            const int s0 = tid >> 6;           // 0..3
            float acc[8];
#pragma unroll
            for (int p = 0; p < 8; ++p) acc[p] = 0.f;
#pragma unroll 4
            for (int k = 0; k < 32; ++k) {
                float vk = vs[k][d];
#pragma unroll
                for (int p = 0; p < 8; ++p)
                    acc[p] += ps[s0 + 4 * p][k] * vk;
            }
#pragma unroll
            for (int p = 0; p < 8; ++p) {
                int s = s0 + 4 * p;
                ob[((size_t)(b * 32 + s)) * 512 + h * 64 + d] = f2bf(acc[p]);
            }
        }
    } else {
        // ---- up1 GEMM branch: 64x64 tile, BK=64, N=K=512, 512 blocks ----
        const int b = blockIdx.x;
        if (b >= 512) return;                      // whole block exits pre-barrier
        const int lb = (b & 7) * 64 + (b >> 3);    // manual 512-chunk swizzle
        const int bxg = lb & 7, byg = lb >> 3;
        unsigned short (*As)[2048] = (unsigned short(*)[2048])smem;          // 2*4096B
        unsigned short (*Bs)[2048] = (unsigned short(*)[2048])(smem + 8192); // 2*4096B
        const int wave = tid >> 6, lane = tid & 63;
        const int m0 = byg * 64, n0 = bxg * 64;
        const int sr = lane >> 2, sc = (lane & 3) * 8;
        const unsigned short* aS = A2 + (size_t)(m0 + wave * 16 + sr) * 512 + sc;
        const unsigned short* wS = W2 + (size_t)(n0 + wave * 16 + sr) * 512 + sc;
        const int wm = (wave >> 1) * 32, wn = (wave & 1) * 32;
        const int fr = lane & 15, fko = (lane >> 4) * 8;
        floatx4 acc[2][2];
#pragma unroll
        for (int i = 0; i < 2; ++i)
#pragma unroll
            for (int j = 0; j < 2; ++j) acc[i][j] = (floatx4){0.f, 0.f, 0.f, 0.f};
        for (int k0 = 0; k0 < 512; k0 += 64) {
#pragma unroll
            for (int h = 0; h < 2; ++h) {
                gload16(aS + k0 + 32 * h, &As[h][(wave * 16) * 32]);
                gload16(wS + k0 + 32 * h, &Bs[h][(wave * 16) * 32]);
            }
            __syncthreads();
#pragma unroll
            for (int h = 0; h < 2; ++h) {
                short8 af[2], bfr[2];
#pragma unroll
                for (int i = 0; i < 2; ++i) af[i] = *(const short8*)&As[h][(wm + i * 16 + fr) * 32 + fko];
#pragma unroll
                for (int j = 0; j < 2; ++j) bfr[j] = *(const short8*)&Bs[h][(wn + j * 16 + fr) * 32 + fko];
#pragma unroll
                for (int i = 0; i < 2; ++i)
#pragma unroll
                    for (int j = 0; j < 2; ++j)
                        acc[i][j] = __builtin_amdgcn_mfma_f32_16x16x32_bf16(af[i], bfr[j], acc[i][j], 0, 0, 0);
            }
            __syncthreads();
        }
        const int r0 = m0 + wm + (lane >> 4) * 4;
#pragma unroll
        for (int i = 0; i < 2; ++i)
#pragma unroll
            for (int j = 0; j < 2; ++j) {
                int n = n0 + wn + j * 16 + fr;
                float bv = b2[n];
#pragma unroll
                for (int r = 0; r < 4; ++r) {
                    int m = r0 + i * 16 + r;
                    C2[(size_t)m * 512 + n] = f2bf(acc[i][j][r] + bv);
                }
            }
    }
}

// ---------------- complex self-attention: LDS-resident, grid (128 batch, 2 half) ----------
__global__ __launch_bounds__(512) void cattn2_kernel(const float* __restrict__ LL,
                                                     unsigned short* __restrict__ outHi,
                                                     unsigned short* __restrict__ outLo)
{
    extern __shared__ float Xs[];
    __shared__ float Pr[16][33], Pi[16][33];
    const int b = blockIdx.x, half = blockIdx.y;
    const int tid = threadIdx.x;
    const float* base = LL + (size_t)b * 16384;
    for (int i = tid; i < 16384; i += 512) {
        int c = i >> 9, e = i & 511;
        Xs[e * 32 + ((c ^ e) & 31)] = base[i];
    }
    __syncthreads();
    {
        const int li = tid >> 5;                 // 0..15
        const int ci = half * 16 + li;
        const int ck = tid & 31;
        float ar = 0.f, ai = 0.f;
#pragma unroll 4
        for (int er = 0; er < 256; ++er) {
            const int sw = er & 31;
            float yr = Xs[er * 32 + ((ck ^ sw) & 31)];
            float yi = Xs[(er + 256) * 32 + ((ck ^ sw) & 31)];
            float xr = Xs[er * 32 + ((ci ^ sw) & 31)];
            float xi = Xs[(er + 256) * 32 + ((ci ^ sw) & 31)];
            ar += xr * yr - xi * yi;
            ai += xr * yi + xi * yr;
        }
        Pr[li][ck] = ar * 0.0625f;
        Pi[li][ck] = ai * 0.0625f;
    }
    __syncthreads();
    if (tid < 32) {
        int r = tid & 15;
        float (*P)[33] = (tid < 16) ? Pr : Pi;
        float mx = -1e30f;
        for (int j = 0; j < 32; ++j) mx = fmaxf(mx, P[r][j]);
        float s = 0.f;
        for (int j = 0; j < 32; ++j) { float e = __expf(P[r][j] - mx); P[r][j] = e; s += e; }
        float inv = 1.f / s;
        for (int j = 0; j < 32; ++j) P[r][j] *= inv;
    }
    __syncthreads();
    const int er = tid & 255;
    const int th = tid >> 8;                     // 0 or 1: t in [th*8, th*8+8)
    const int sw = er & 31;
    float accr[8], acci[8];
#pragma unroll
    for (int t = 0; t < 8; ++t) { accr[t] = 0.f; acci[t] = 0.f; }
    for (int k = 0; k < 32; ++k) {
        float yr = Xs[er * 32 + ((k ^ sw) & 31)];
        float yi = Xs[(er + 256) * 32 + ((k ^ sw) & 31)];
#pragma unroll
        for (int t = 0; t < 8; ++t) {
            float pr = Pr[th * 8 + t][k], pi = Pi[th * 8 + t][k];
            accr[t] += pr * yr - pi * yi;
            acci[t] += pr * yi + pi * yr;
        }
    }
#pragma unroll
    for (int t = 0; t < 8; ++t) {
        int c = half * 16 + th * 8 + t;
        float vr = Xs[er * 32 + ((c ^ sw) & 31)] + accr[t];
        float vi = Xs[(er + 256) * 32 + ((c ^ sw) & 31)] + acci[t];
        size_t ir = (size_t)b * 16384 + (size_t)c * 512 + er;
        unsigned short hr = f2bf(vr), hi2 = f2bf(vi);
        outHi[ir] = hr;        outLo[ir] = f2bf(vr - bf2f(hr));
        outHi[ir + 256] = hi2; outLo[ir + 256] = f2bf(vi - bf2f(hi2));
    }
}

// ---------------- DUAL add+LN (512), f32 resid, out bf16 hi/lo; rows>=4096 = branch 1 ----
__global__ __launch_bounds__(256) void add_ln_d1(
    const float* __restrict__ r0, const float* __restrict__ y0,
    const float* __restrict__ w0, const float* __restrict__ b0,
    unsigned short* __restrict__ h0, unsigned short* __restrict__ l0,
    const float* __restrict__ r1, const float* __restrict__ y1,
    const float* __restrict__ w1, const float* __restrict__ b1,
    unsigned short* __restrict__ h1, unsigned short* __restrict__ l1)
{
    const int row = blockIdx.x;
    const int br = row >> 12;
    const int rl = row & 4095;
    const float* resid = br ? r1 : r0;
    const float* y     = br ? y1 : y0;
    const float* w     = br ? w1 : w0;
    const float* bb    = br ? b1 : b0;
    unsigned short* oh = br ? h1 : h0;
    unsigned short* ol = br ? l1 : l0;
    const int tid = threadIdx.x;
    const size_t base = (size_t)rl * 512;
    float v0 = resid[base + tid] + y[base + tid];
    float v1 = resid[base + 256 + tid] + y[base + 256 + tid];
    float s = v0 + v1, q = v0 * v0 + v1 * v1;
    for (int off = 32; off; off >>= 1) { s += __shfl_down(s, off); q += __shfl_down(q, off); }
    __shared__ float sw[4], qw[4], ms, is;
    int wid = tid >> 6, lane = tid & 63;
    if (lane == 0) { sw[wid] = s; qw[wid] = q; }
    __syncthreads();
    if (tid == 0) {
        float S = sw[0] + sw[1] + sw[2] + sw[3];
        float Q = qw[0] + qw[1] + qw[2] + qw[3];
        float m = S * (1.f / 512.f);
        ms = m;
        is = rsqrtf(Q * (1.f / 512.f) - m * m + 1e-5f);
    }
    __syncthreads();
    float m = ms, inv = is;
    float o0 = (v0 - m) * inv * w[tid] + bb[tid];
    float o1 = (v1 - m) * inv * w[256 + tid] + bb[256 + tid];
    unsigned short e0 = f2bf(o0), e1 = f2bf(o1);
    oh[base + tid] = e0;       ol[base + tid] = f2bf(o0 - bf2f(e0));
    oh[base + 256 + tid] = e1; ol[base + 256 + tid] = f2bf(o1 - bf2f(e1));
}

// ---------------- DUAL add+LN (512), bf16 hi/lo resid, out f32 --------------------------
__global__ __launch_bounds__(256) void add_ln_d2(
    const unsigned short* __restrict__ rh0, const unsigned short* __restrict__ rl0,
    const float* __restrict__ y0, const float* __restrict__ w0, const float* __restrict__ b0,
    float* __restrict__ o0p,
    const unsigned short* __restrict__ rh1, const unsigned short* __restrict__ rl1,
    const float* __restrict__ y1, const float* __restrict__ w1, const float* __restrict__ b1,
    float* __restrict__ o1p)
{
    const int row = blockIdx.x;
    const int br = row >> 12;
    const int rl = row & 4095;
    const unsigned short* rh = br ? rh1 : rh0;
    const unsigned short* rlo = br ? rl1 : rl0;
    const float* y  = br ? y1 : y0;
    const float* w  = br ? w1 : w0;
    const float* bb = br ? b1 : b0;
    float* op = br ? o1p : o0p;
    const int tid = threadIdx.x;
    const size_t base = (size_t)rl * 512;
    float v0 = bf2f(rh[base + tid]) + bf2f(rlo[base + tid]) + y[base + tid];
    float v1 = bf2f(rh[base + 256 + tid]) + bf2f(rlo[base + 256 + tid]) + y[base + 256 + tid];
    float s = v0 + v1, q = v0 * v0 + v1 * v1;
    for (int off = 32; off; off >>= 1) { s += __shfl_down(s, off); q += __shfl_down(q, off); }
    __shared__ float sw[4], qw[4], ms, is;
    int wid = tid >> 6, lane = tid & 63;
    if (lane == 0) { sw[wid] = s; qw[wid] = q; }
    __syncthreads();
    if (tid == 0) {
        float S = sw[0] + sw[1] + sw[2] + sw[3];
        float Q = qw[0] + qw[1] + qw[2] + qw[3];
        float m = S * (1.f / 512.f);
        ms = m;
        is = rsqrtf(Q * (1.f / 512.f) - m * m + 1e-5f);
    }
    __syncthreads();
    float m = ms, inv = is;
    op[base + tid]       = (v0 - m) * inv * w[tid] + bb[tid];
    op[base + 256 + tid] = (v1 - m) * inv * w[256 + tid] + bb[256 + tid];
}

// ---------------- fused relu+batchLN x2: rf = LN(relu(x2R)) kept in LDS,
//                  res = LN(relu(x2T)) + rf. One block per batch, 1024 threads. ----------
__global__ __launch_bounds__(1024) void relu_bln_fused(
    const float* __restrict__ xR, const float* __restrict__ w2, const float* __restrict__ b2,
    const float* __restrict__ xT, const float* __restrict__ w1, const float* __restrict__ b1,
    float* __restrict__ out)
{
    __shared__ float rfs[16384];
    __shared__ float sw_[16], qw_[16], ms_, is_;
    const int bb = blockIdx.x, tid = threadIdx.x;
    const int wid = tid >> 6, lane = tid & 63;
    const float* xr = xR + (size_t)bb * 16384;
    float s = 0.f, q = 0.f;
    for (int i = tid; i < 16384; i += 1024) { float v = fmaxf(xr[i], 0.f); s += v; q += v * v; }
    for (int off = 32; off; off >>= 1) { s += __shfl_down(s, off); q += __shfl_down(q, off); }
    if (lane == 0) { sw_[wid] = s; qw_[wid] = q; }
    __syncthreads();
    if (tid == 0) {
        float S = 0.f, Q = 0.f;
        for (int i = 0; i < 16; ++i) { S += sw_[i]; Q += qw_[i]; }
        float m = S * (1.f / 16384.f);
        ms_ = m;
        is_ = rsqrtf(Q * (1.f / 16384.f) - m * m + 1e-5f);
    }
    __syncthreads();
    float m = ms_, inv = is_;
    for (int i = tid; i < 16384; i += 1024) {
        float v = fmaxf(xr[i], 0.f);
        rfs[i] = (v - m) * inv * w2[i] + b2[i];
    }
    const float* xt = xT + (size_t)bb * 16384;
    s = 0.f; q = 0.f;
    for (int i = tid; i < 16384; i += 1024) { float v = fmaxf(xt[i], 0.f); s += v; q += v * v; }
    for (int off = 32; off; off >>= 1) { s += __shfl_down(s, off); q += __shfl_down(q, off); }
    if (lane == 0) { sw_[wid] = s; qw_[wid] = q; }
    __syncthreads();
    if (tid == 0) {
        float S = 0.f, Q = 0.f;
        for (int i = 0; i < 16; ++i) { S += sw_[i]; Q += qw_[i]; }
        float m2 = S * (1.f / 16384.f);
        ms_ = m2;
        is_ = rsqrtf(Q * (1.f / 16384.f) - m2 * m2 + 1e-5f);
    }
    __syncthreads();
    m = ms_; inv = is_;
    float* op = out + (size_t)bb * 16384;
    for (int i = tid; i < 16384; i += 1024) {
        float v = fmaxf(xt[i], 0.f);
        op[i] = (v - m) * inv * w1[i] + b1[i] + rfs[i];
    }
}

extern "C" void kernel_launch(void* const* d_in, const int* in_sizes, int n_in,
                              void* d_out, int out_size, void* d_ws, size_t ws_size,
                              hipStream_t stream)
{
    (void)in_sizes; (void)n_in; (void)out_size; (void)ws_size;
    const float* x        = (const float*)d_in[0];
    const float* t_in_w   = (const float*)d_in[1];
    const float* t_in_b   = (const float*)d_in[2];
    const float* t_out_w  = (const float*)d_in[3];
    const float* t_out_b  = (const float*)d_in[4];
    const float* t_ln1_w  = (const float*)d_in[5];
    const float* t_ln1_b  = (const float*)d_in[6];
    const float* t_lin1_w = (const float*)d_in[7];
    const float* t_lin1_b = (const float*)d_in[8];
    const float* t_lin2_w = (const float*)d_in[9];
    const float* t_lin2_b = (const float*)d_in[10];
    const float* t_ln2_w  = (const float*)d_in[11];
    const float* t_ln2_b  = (const float*)d_in[12];
    const float* r_in_w   = (const float*)d_in[13];
    const float* r_in_b   = (const float*)d_in[14];
    const float* r_out_w  = (const float*)d_in[15];
    const float* r_out_b  = (const float*)d_in[16];
    const float* r_ln1_w  = (const float*)d_in[17];
    const float* r_ln1_b  = (const float*)d_in[18];
    const float* r_lin1_w = (const float*)d_in[19];
    const float* r_lin1_b = (const float*)d_in[20];
    const float* r_lin2_w = (const float*)d_in[21];
    const float* r_lin2_b = (const float*)d_in[22];
    const float* r_ln2_w  = (const float*)d_in[23];
    const float* r_ln2_b  = (const float*)d_in[24];
    const float* lc_w     = (const float*)d_in[25];
    const float* lc_b     = (const float*)d_in[26];
    const float* up1_w    = (const float*)d_in[27];
    const float* up1_b    = (const float*)d_in[28];
    const float* up2_w    = (const float*)d_in[29];
    const float* up2_b    = (const float*)d_in[30];
    const float* n1_w     = (const float*)d_in[31];
    const float* n1_b     = (const float*)d_in[32];
    const float* n2_w     = (const float*)d_in[33];
    const float* n2_b     = (const float*)d_in[34];
    const float* l1_re    = (const float*)d_in[35];
    const float* l1_im    = (const float*)d_in[36];
    const float* lb1_re   = (const float*)d_in[39];
    const float* lb1_im   = (const float*)d_in[40];

    float* outp = (float*)d_out;

    // ---- workspace map (float offsets; total 21,774,336 f = 87.1 MB) ----
    float* WS   = (float*)d_ws;
    float* LL   = WS;                                        // 2M f (also fa f32, later y_r)
    float* FA   = WS;
    float* yR   = WS;
    float* QR   = WS + 2097152;                              // 6.29M f
    float* tabC = QR;                                        // 131072
    float* tabS = QR + 131072;
    unsigned short* WaHu = (unsigned short*)(QR + 786432);
    unsigned short* WaLu = (unsigned short*)(QR + 917504);
    unsigned short* WmHu = (unsigned short*)(QR + 1048576);
    unsigned short* WmLu = (unsigned short*)(QR + 1179648);
    float* qkvR = QR;                                        // 6.29M f: [2097152, 8388608)
    unsigned short* x1rH = (unsigned short*)(WS + 2097152);
    unsigned short* x1rL = (unsigned short*)(WS + 3145728);
    unsigned short* x1tH = (unsigned short*)(WS + 4194304);
    unsigned short* x1tL = (unsigned short*)(WS + 5242880);
    float* yT   = WS + 6291456;                              // 2M f
    unsigned short* qkvT = (unsigned short*)(WS + 8388608);  // 6.29M ushort
    unsigned short* f1R  = (unsigned short*)(WS + 8388608);  // 8.39M ushort
    float* x2R  = WS + 8388608;                              // 2M f
    float* x2T  = WS + 10485760;                             // 2M f
    unsigned short* xHi = (unsigned short*)(WS + 11534336);
    unsigned short* xLo = (unsigned short*)(WS + 12582912);
    unsigned short* aoR = (unsigned short*)(WS + 11534336);
    unsigned short* aoT = (unsigned short*)(WS + 12582912);
    unsigned short* f1T = (unsigned short*)(WS + 12582912);  // 8.39M ushort
    unsigned short* LLH = (unsigned short*)(WS + 13631488);
    unsigned short* LLL = (unsigned short*)(WS + 14680064);
    float* oR   = WS + 13631488;                             // 2M f
    float* oT   = WS + 15728640;                             // 2M f
    unsigned short* faHi = (unsigned short*)(WS + 15728640);
    unsigned short* faLo = (unsigned short*)(WS + 16777216);
    unsigned short* rinLoU = (unsigned short*)(WS + 17825792);  // 786432 ushort
    float* LB   = WS + 18219008;                             // 512 f
    unsigned short* WB = (unsigned short*)(WS + 18366464);

    // u1b (up1 bf16 out, 1M ushort) parks in the OUTPUT res slot outp[0..1048576 f):
    // res is written only by the final relu_bln_fused (verified passing in R19-R24).
    unsigned short* u1b = (unsigned short*)outp;

    unsigned short* w_tin  = WB + 0;        // 1536x512
    unsigned short* w_tout = WB + 786432;   // 512x512
    unsigned short* w_tl1  = WB + 1048576;  // 2048x512
    unsigned short* w_tl2  = WB + 2097152;  // 512x2048
    unsigned short* w_rin  = WB + 3145728;  // 1536x512
    unsigned short* w_rout = WB + 3932160;  // 512x512
    unsigned short* w_rl1  = WB + 4194304;  // 2048x512
    unsigned short* w_rl2  = WB + 5242880;  // 512x2048
    unsigned short* w_up1  = WB + 6291456;  // 512x512
    unsigned short* w_up2  = WB + 6553600;  // 512x512

    dim3 blk(256);

    // ---- prep (2 dispatches: uber(+tab), wawm) ----
    uber_prep_kernel<<<dim3(35330), blk, 0, stream>>>(t_in_w, t_out_w, t_lin1_w, t_lin2_w,
                                                      r_in_w, r_out_w, r_lin1_w, r_lin2_w,
                                                      up1_w, up2_w, WB, rinLoU,
                                                      x, xHi, xLo, outp + NOUT,
                                                      lb1_re, lb1_im, LB, tabC, tabS);
    wawm_kernel<<<dim3(512, 2, 2), blk, 0, stream>>>(l1_re, l1_im, lc_w, tabC, tabS,
                                                     WaHu, WaLu, WmHu, WmLu);

    // ---- freq branch (keeps hi/lo: fa and up are direct outputs) ----
    gemm_mfma3<64,64,1,0,0><<<dim3(8, 64), blk, 0, stream>>>(xHi, xLo, WaHu, WaLu, LB,
                                                             LL, nullptr, nullptr, nullptr, 512, 512);
    cattn2_kernel<<<dim3(128, 2), dim3(512), 65536, stream>>>(LL, LLH, LLL);         // LL hi/lo
    gemm_mfma3<64,64,0,1,1><<<dim3(8, 64), blk, 0, stream>>>(LLH, LLL, WmHu, WmLu, lc_b,
                                                             FA, outp + 2 * NOUT, faHi, faLo, 512, 512);

    // ---- qkv both TELs (single-product; R25: 128x128 tile, 768 blocks = 3/CU) ----
    gemm_qkv_dual<128,128><<<dim3(12, 32, 2), blk, 0, stream>>>(faHi, w_rin, r_in_b, qkvR,
                                                                xHi, w_tin, t_in_b, qkvT, 1536, 512);

    // ---- attention (r+t) + up1, merged (R23 register-blocked) ----
    attn_up1_kernel<<<dim3(1024, 1, 3), blk, 0, stream>>>(qkvR, qkvT, aoR, aoT,
                                                          faHi, w_up1, up1_b, u1b);

    // ---- out-proj r/t + up2 (tri) ----
    gemm_out_tri<64,64><<<dim3(8, 64, 3), blk, 0, stream>>>(aoR, w_rout, r_out_b, oR,
                                                            aoT, w_tout, t_out_b, oT,
                                                            u1b, w_up2, up2_b, outp + 3 * NOUT, 512, 512);
    add_ln_d1<<<dim3(8192), blk, 0, stream>>>(FA, oR, r_ln1_w, r_ln1_b, x1rH, x1rL,
                                              x,  oT, t_ln1_w, t_ln1_b, x1tH, x1tL);
    gemm_dual<128,128,1,1><<<dim3(16, 32, 2), blk, 0, stream>>>(x1rH, x1tH, w_rl1, w_tl1,
                                                                r_lin1_b, t_lin1_b, nullptr, nullptr,
                                                                f1R, f1T, 2048, 512);
    gemm_dual<64,128,0,0><<<dim3(4, 64, 2), blk, 0, stream>>>(f1R, f1T, w_rl2, w_tl2,
                                                              r_lin2_b, t_lin2_b, yR, yT,
                                                              nullptr, nullptr, 512, 2048);
    add_ln_d2<<<dim3(8192), blk, 0, stream>>>(x1rH, x1rL, yR, r_ln2_w, r_ln2_b, x2R,
                                              x1tH, x1tL, yT, t_ln2_w, t_ln2_b, x2T);
    relu_bln_fused<<<dim3(128), dim3(1024), 0, stream>>>(x2R, n2_w, n2_b, x2T, n1_w, n1_b, outp);
}